// Round 6
// baseline (2378.302 us; speedup 1.0000x reference)
//
#include <hip/hip_runtime.h>
#include <cstddef>

#define NS_ITERS 8
#define MSZ 262144  // 512*512
#define PL  6291456 // 24*MSZ
#define KSLOT 12312 // k-means accumulator slot stride (floats)

typedef unsigned short u16;
typedef __attribute__((ext_vector_type(8))) short bf16x8;
typedef __attribute__((ext_vector_type(4))) float f32x4;
typedef __attribute__((ext_vector_type(4))) short u16x4;

__device__ inline u16 bf16_rne(float x){
  unsigned u = __float_as_uint(x);
  unsigned r = u + 0x7fffu + ((u>>16)&1u);
  return (u16)(r>>16);
}
__device__ inline float bf16f(u16 h){
  return __uint_as_float(((unsigned)h)<<16);
}

// ---------------- workspace offsets (in floats) ----------------
#define OFF_F4C   0ul
#define OFF_F4S   2097152ul
#define OFF_TF    4194304ul
#define OFF_DEC   6291456ul
#define OFF_WSPL  7077888ul
#define OFF_SMALL 10223616ul
#define OFF_ARENA 10354688ul

// SMALL sub-offsets (floats)
#define SM_ASSIGN  12288
#define SM_MU      20480
#define SM_COUNTS  32768
#define SM_SVAL    32800
#define SM_SCALE   32832
#define SM_TVEC    32864
#define SM_STATS_S 39008
#define SM_STATS_D 46688
#define SM_CLOSS   54368
#define SM_TR      54464

// ---------------- kernels ----------------

__global__ __launch_bounds__(256) void zerok(float* p, int n){
  int i = blockIdx.x*256 + threadIdx.x;
  if (i < n) p[i] = 0.f;
}

// direct 3x3 SAME conv (for e1: Cin=3)
template<int COT, int CIT, int POOL, int OUTW, int RZ>
__global__ __launch_bounds__(256,4) void conv3x3(
    const float* __restrict__ in, const float* __restrict__ wgt,
    const float* __restrict__ bias, float* __restrict__ out,
    u16* __restrict__ poh, u16* __restrict__ pol,
    int B, int Cin, int Cout, int H, int W, int relu)
{
  __shared__ float s_in[CIT][34][34];
  __shared__ float s_w[COT][CIT][9];
  const int tid = threadIdx.x;
  const int tx = tid & 15, ty = tid >> 4;
  const int tilesW = W >> 5;
  const int h0 = (blockIdx.x / tilesW) << 5;
  const int w0 = (blockIdx.x % tilesW) << 5;
  const int co0 = blockIdx.y * COT;
  const int b = blockIdx.z;
  float acc[COT][2][2];
  #pragma unroll
  for (int o=0;o<COT;o++){acc[o][0][0]=0.f;acc[o][0][1]=0.f;acc[o][1][0]=0.f;acc[o][1][1]=0.f;}
  const int y0 = ty*2, x0 = tx*2;
  for (int ci0 = 0; ci0 < Cin; ci0 += CIT){
    const int cic = (Cin - ci0 < CIT) ? (Cin - ci0) : CIT;
    const int tot = cic*1156;
    for (int e = tid; e < tot; e += 256){
      int c = e / 1156; int r = e - c*1156;
      int lh = r / 34, lw = r - lh*34;
      int ih = h0 + lh - 1, iw = w0 + lw - 1;
      float v = 0.f;
      if ((unsigned)ih < (unsigned)H && (unsigned)iw < (unsigned)W){
        if constexpr (RZ==2)
          v = in[((size_t)(b*Cin + ci0 + c)*(H>>1) + (ih>>1))*(size_t)(W>>1) + (iw>>1)];
        else
          v = in[((size_t)(b*Cin + ci0 + c)*H + ih)*W + iw];
      }
      s_in[c][lh][lw] = v;
    }
    const int wtot = COT*cic*9;
    for (int e = tid; e < wtot; e += 256){
      int o = e / (cic*9); int r = e - o*(cic*9);
      int c = r / 9, t = r - c*9;
      int co = co0 + o;
      float v = 0.f;
      if (co < Cout) v = wgt[(size_t)(co*Cin + ci0 + c)*9 + t];
      s_w[o][c][t] = v;
    }
    __syncthreads();
    for (int c = 0; c < cic; ++c){
      float p[4][4];
      #pragma unroll
      for (int r=0;r<4;r++)
        #pragma unroll
        for (int s=0;s<4;s++)
          p[r][s] = s_in[c][y0+r][x0+s];
      #pragma unroll
      for (int dh=0; dh<3; dh++)
        #pragma unroll
        for (int dw=0; dw<3; dw++){
          #pragma unroll
          for (int o=0;o<COT;o++){
            float wv = s_w[o][c][dh*3+dw];
            acc[o][0][0] = fmaf(p[dh  ][dw  ], wv, acc[o][0][0]);
            acc[o][0][1] = fmaf(p[dh  ][dw+1], wv, acc[o][0][1]);
            acc[o][1][0] = fmaf(p[dh+1][dw  ], wv, acc[o][1][0]);
            acc[o][1][1] = fmaf(p[dh+1][dw+1], wv, acc[o][1][1]);
          }
        }
    }
    __syncthreads();
  }
  if constexpr (POOL){
    bf16x8 p8h, p8l;
    #pragma unroll
    for (int o=0;o<COT;o++){
      const int co = co0 + o;
      const float bv = bias[co];
      float v00 = fmaxf(acc[o][0][0]+bv, 0.f);
      float v01 = fmaxf(acc[o][0][1]+bv, 0.f);
      float v10 = fmaxf(acc[o][1][0]+bv, 0.f);
      float v11 = fmaxf(acc[o][1][1]+bv, 0.f);
      if constexpr (OUTW){
        *(float2*)&out[((size_t)(b*Cout + co)*H + h0+y0  )*W + w0+x0] = make_float2(v00, v01);
        *(float2*)&out[((size_t)(b*Cout + co)*H + h0+y0+1)*W + w0+x0] = make_float2(v10, v11);
      }
      // same order as pool2k: p[0]+p[1]+p[2W]+p[2W+1]
      float pv = 0.25f*(v00 + v01 + v10 + v11);
      u16 h = bf16_rne(pv);
      p8h[o] = (short)h;
      p8l[o] = (short)bf16_rne(pv - bf16f(h));
    }
    size_t po = ((size_t)(b*(H>>1) + ((h0+y0)>>1))*(W>>1) + ((w0+x0)>>1))*(size_t)Cout + co0;
    *(bf16x8*)&poh[po] = p8h;
    *(bf16x8*)&pol[po] = p8l;
  } else {
    #pragma unroll
    for (int o=0;o<COT;o++){
      int co = co0 + o;
      if (co >= Cout) continue;
      float bv = bias[co];
      float v00 = acc[o][0][0] + bv;
      float v01 = acc[o][0][1] + bv;
      float v10 = acc[o][1][0] + bv;
      float v11 = acc[o][1][1] + bv;
      if (relu){
        v00 = fmaxf(v00, 0.f); v01 = fmaxf(v01, 0.f);
        v10 = fmaxf(v10, 0.f); v11 = fmaxf(v11, 0.f);
      }
      *(float2*)&out[((size_t)(b*Cout + co)*H + h0+y0  )*W + w0+x0] = make_float2(v00, v01);
      *(float2*)&out[((size_t)(b*Cout + co)*H + h0+y0+1)*W + w0+x0] = make_float2(v10, v11);
    }
  }
}

// dedicated d4: Cin=64 -> Cout=3, 256x256 out, nearest-up2 fused (input 128x128 fp32 NCHW).
__global__ __launch_bounds__(256,4) void d4upk(
    const float* __restrict__ in, const float* __restrict__ wgt,
    const float* __restrict__ bias, float* __restrict__ out)
{
  __shared__ float s_in[64][10][10];
  __shared__ float s_w[3][64][9];
  const int tid = threadIdx.x;
  const int b = blockIdx.z;
  const int h0 = (blockIdx.x >> 4) << 4, w0 = (blockIdx.x & 15) << 4;
  const int r0 = (h0 >> 1) - 1, c0 = (w0 >> 1) - 1;
  for (int e = tid; e < 6400; e += 256){
    int c = e / 100, r = e - c*100;
    int lr = r / 10, lc = r - lr*10;
    int gr = r0 + lr, gc = c0 + lc;
    float v = 0.f;
    if ((unsigned)gr < 128u && (unsigned)gc < 128u)
      v = in[((size_t)(b*64 + c)*128 + gr)*128 + gc];
    s_in[c][lr][lc] = v;
  }
  for (int e = tid; e < 1728; e += 256){
    int o = e / 576, r = e - o*576;
    int ci = r / 9, t = r - ci*9;
    s_w[o][ci][t] = wgt[(size_t)(o*64 + ci)*9 + t];
  }
  __syncthreads();
  const int ty = tid >> 4, tx = tid & 15;
  const int oh = h0 + ty, ow = w0 + tx;
  int lr3[3], lc3[3]; bool vr3[3], vc3[3];
  #pragma unroll
  for (int d=0; d<3; d++){
    int ih = oh + d - 1;
    vr3[d] = (unsigned)ih < 256u;
    lr3[d] = (ih >> 1) - r0;
    int iw = ow + d - 1;
    vc3[d] = (unsigned)iw < 256u;
    lc3[d] = (iw >> 1) - c0;
  }
  float a0 = 0.f, a1 = 0.f, a2 = 0.f;
  for (int ci = 0; ci < 64; ++ci){
    #pragma unroll
    for (int dh=0; dh<3; dh++){
      #pragma unroll
      for (int dw=0; dw<3; dw++){
        float v = (vr3[dh] && vc3[dw]) ? s_in[ci][lr3[dh]][lc3[dw]] : 0.f;
        a0 = fmaf(v, s_w[0][ci][dh*3+dw], a0);
        a1 = fmaf(v, s_w[1][ci][dh*3+dw], a1);
        a2 = fmaf(v, s_w[2][ci][dh*3+dw], a2);
      }
    }
  }
  out[((size_t)(b*3 + 0)*256 + oh)*256 + ow] = a0 + bias[0];
  out[((size_t)(b*3 + 1)*256 + oh)*256 + ow] = a1 + bias[1];
  out[((size_t)(b*3 + 2)*256 + oh)*256 + ow] = a2 + bias[2];
}

// pre-split conv weights: dst[(dhw*Cout + co)*Cin + ci]
__global__ __launch_bounds__(256) void wsplitk(const float* __restrict__ wgt,
                                               u16* __restrict__ dh_, u16* __restrict__ dl_,
                                               int Cout, int Cin){
  int idx = blockIdx.x*256 + threadIdx.x;
  int n = 9*Cout*Cin;
  if (idx >= n) return;
  int cc = Cout*Cin;
  int dhw = idx / cc;
  int r = idx - dhw*cc;
  int co = r / Cin, ci = r - co*Cin;
  float v = wgt[((size_t)co*Cin + ci)*9 + dhw];
  u16 h = bf16_rne(v);
  dh_[idx] = h;
  dl_[idx] = bf16_rne(v - bf16f(h));
}

// fp32 NCHW -> split-bf16 NHWC repack (POOL=1: fused avg-pool2, input 2Ho x 2Wo)
// grid: (Ho*Wo/32, C/64, B)
template<int POOL>
__global__ __launch_bounds__(256) void repackk(const float* __restrict__ in,
    u16* __restrict__ oh, u16* __restrict__ ol, int C, int Ho, int Wo)
{
  __shared__ unsigned tr[64][33];
  const int N = Ho*Wo;
  const int n0 = blockIdx.x << 5, c0 = blockIdx.y << 6, b = blockIdx.z;
  const int lnn = threadIdx.x & 31, gc = threadIdx.x >> 5;
  {
    const int n = n0 + lnn;
    const int ho = n / Wo, wo = n - ho*Wo;
    #pragma unroll
    for (int i=0;i<8;i++){
      const int c = (gc<<3) + i;
      float v;
      if constexpr (POOL){
        const float* p = in + ((size_t)(b*C + c0+c)*(Ho*2) + ho*2)*(size_t)(Wo*2) + (size_t)wo*2;
        v = 0.25f*(p[0] + p[1] + p[2*Wo] + p[2*Wo+1]);
      } else {
        v = in[((size_t)(b*C + c0+c))*N + n];
      }
      u16 h = bf16_rne(v);
      tr[c][lnn] = (unsigned)h | ((unsigned)bf16_rne(v - bf16f(h)) << 16);
    }
  }
  __syncthreads();
  const int n2 = threadIdx.x >> 3, oct = threadIdx.x & 7;
  bf16x8 vh, vl;
  #pragma unroll
  for (int j=0;j<8;j++){
    unsigned u = tr[(oct<<3)+j][n2];
    vh[j] = (short)(u & 0xffffu);
    vl[j] = (short)(u >> 16);
  }
  size_t o = ((size_t)b*N + (n0 + n2))*(size_t)C + c0 + (oct<<3);
  *(bf16x8*)&oh[o] = vh;
  *(bf16x8*)&ol[o] = vl;
}

// ---- split-bf16 MFMA direct conv 3x3 SAME; input pre-split NHWC u16 planes ----
// Tile: 64 co x (8x16) px; W staged per (dh,dw) tap. Bit-exact order.
template<int KS, int RESIZE>
__global__ __launch_bounds__(256,4) void convm(
    const u16* __restrict__ xh, const u16* __restrict__ xl,
    const u16* __restrict__ wsh, const u16* __restrict__ wsl,
    const float* __restrict__ bias, float* __restrict__ out,
    int Cin, int Cout, int H, int W, int relu)
{
  const int tilesW = W >> 4;
  const int h0 = (blockIdx.x / tilesW) << 3;
  const int w0 = (blockIdx.x % tilesW) << 4;
  const int co0 = blockIdx.y << 6;
  const int b  = blockIdx.z / KS;
  const int ks = blockIdx.z % KS;
  const int NB = gridDim.z / KS;
  const int tid = threadIdx.x;
  const int wid = tid >> 6, lane = tid & 63;
  const int wm = wid >> 1, wn = wid & 1;
  const int quad = lane >> 4, ln = lane & 15;

  __shared__ __align__(16) u16 sXh[180*40], sXl[180*40];
  __shared__ __align__(16) u16 sWh[64*40],  sWl[64*40];

  f32x4 acc[2][4];
  #pragma unroll
  for (int i=0;i<2;i++)
    #pragma unroll
    for (int j=0;j<4;j++)
      #pragma unroll
      for (int e=0;e<4;e++) acc[i][j][e] = 0.f;

  const int wco = tid >> 2, wcg = (tid & 3) << 3;

  const int ciA = ks*(Cin/KS), ciB = ciA + Cin/KS;
  for (int ci0 = ciA; ci0 < ciB; ci0 += 32){
    // X staging: halo 10x18 px, 4 slots of 8 ci.
    for (int e = tid; e < 720; e += 256){
      const int px = e >> 2, sl = e & 3;
      const int pr = px / 18, pc = px - pr*18;
      const int ih = h0 + pr - 1, iw = w0 + pc - 1;
      bf16x8 vh, vl;
      #pragma unroll
      for (int j=0;j<8;j++){ vh[j] = 0; vl[j] = 0; }
      if ((unsigned)ih < (unsigned)H && (unsigned)iw < (unsigned)W){
        size_t o;
        if constexpr (RESIZE==0)
          o = ((size_t)(b*H + ih)*W + iw)*(size_t)Cin + (size_t)(ci0 + sl*8);
        else
          o = ((size_t)(b*(H>>1) + (ih>>1))*(W>>1) + (iw>>1))*(size_t)Cin + (size_t)(ci0 + sl*8);
        vh = *(const bf16x8*)&xh[o];
        vl = *(const bf16x8*)&xl[o];
      }
      *(bf16x8*)&sXh[px*40 + sl*8] = vh;
      *(bf16x8*)&sXl[px*40 + sl*8] = vl;
    }
    for (int dh = 0; dh < 3; ++dh){
      for (int dw = 0; dw < 3; ++dw){
        {
          const size_t so = ((size_t)((dh*3+dw)*Cout + co0+wco))*Cin + ci0 + wcg;
          *(bf16x8*)&sWh[wco*40 + wcg] = *(const bf16x8*)&wsh[so];
          *(bf16x8*)&sWl[wco*40 + wcg] = *(const bf16x8*)&wsl[so];
        }
        __syncthreads();
        bf16x8 ah[2], al[2], bh[4], bl[4];
        #pragma unroll
        for (int t=0;t<2;t++){
          const int co_l = (wm*2+t)*16 + ln;
          ah[t] = *(const bf16x8*)&sWh[co_l*40 + quad*8];
          al[t] = *(const bf16x8*)&sWl[co_l*40 + quad*8];
        }
        #pragma unroll
        for (int t=0;t<4;t++){
          const int p = (wn*4+t)*16 + ln;
          const int px = ((p>>4) + dh)*18 + (p&15) + dw;
          const int xo = px*40 + quad*8;
          bh[t] = *(const bf16x8*)&sXh[xo];
          bl[t] = *(const bf16x8*)&sXl[xo];
        }
        #pragma unroll
        for (int mi=0;mi<2;mi++)
          #pragma unroll
          for (int ni=0;ni<4;ni++){
            acc[mi][ni] = __builtin_amdgcn_mfma_f32_16x16x32_bf16(ah[mi], bh[ni], acc[mi][ni], 0, 0, 0);
            acc[mi][ni] = __builtin_amdgcn_mfma_f32_16x16x32_bf16(ah[mi], bl[ni], acc[mi][ni], 0, 0, 0);
            acc[mi][ni] = __builtin_amdgcn_mfma_f32_16x16x32_bf16(al[mi], bh[ni], acc[mi][ni], 0, 0, 0);
          }
        __syncthreads();
      }
    }
  }
  #pragma unroll
  for (int mi=0;mi<2;mi++){
    const int co = co0 + (wm*2+mi)*16 + quad*4;
    #pragma unroll
    for (int ni=0;ni<4;ni++){
      const int p = (wn*4+ni)*16 + ln;
      const int oh = h0 + (p>>4), ow = w0 + (p&15);
      #pragma unroll
      for (int rg=0; rg<4; rg++){
        const int cog = co + rg;
        if constexpr (KS==1){
          float v = acc[mi][ni][rg] + bias[cog];
          if (relu) v = fmaxf(v, 0.f);
          out[((size_t)(b*Cout + cog)*H + oh)*W + ow] = v;
        } else {
          out[((size_t)((ks*NB + b)*Cout + cog)*H + oh)*W + ow] = acc[mi][ni][rg];
        }
      }
    }
  }
}

// reduce split-K partials + bias + relu
__global__ __launch_bounds__(256) void sumk(const float* __restrict__ part, const float* __restrict__ bias,
                                            float* __restrict__ out, int Cout, int HW, int KS, int relu, int n){
  int idx = blockIdx.x*256 + threadIdx.x;
  if (idx >= n) return;
  int co = (idx / HW) % Cout;
  float v = bias[co];
  for (int k=0;k<KS;k++) v += part[(size_t)k*n + idx];
  if (relu) v = fmaxf(v, 0.f);
  out[idx] = v;
}

// per-(b,c) spatial mean & std (ddof=0)
__global__ __launch_bounds__(256) void statsk(const float* __restrict__ x, int HW,
                                              float* __restrict__ mo, float* __restrict__ so){
  int bc = blockIdx.x, tid = threadIdx.x;
  const float* p = x + (size_t)bc*HW;
  double s = 0.0, s2 = 0.0;
  for (int i = tid; i < HW; i += 256){ double v = p[i]; s += v; s2 += v*v; }
  __shared__ double sh[256], sh2[256];
  sh[tid] = s; sh2[tid] = s2; __syncthreads();
  for (int k=128;k>0;k>>=1){ if (tid<k){ sh[tid]+=sh[tid+k]; sh2[tid]+=sh2[tid+k]; } __syncthreads(); }
  if (tid == 0){
    double m = sh[0]/HW;
    double var = sh2[0]/HW - m*m;
    if (var < 0.0) var = 0.0;
    mo[bc] = (float)m;
    so[bc] = (float)sqrt(var);
  }
}

// f4 (C-major, per image 512x1024) -> ptsT [8][1024][512]
__global__ __launch_bounds__(256) void transposek(const float* __restrict__ f4c,
                                                  const float* __restrict__ f4s,
                                                  float* __restrict__ ptsT){
  __shared__ float t[32][33];
  int r = blockIdx.z;
  const float* src = (r < 4) ? (f4c + (size_t)r*524288) : (f4s + (size_t)(r-4)*524288);
  int n0 = blockIdx.x*32, c0 = blockIdx.y*32;
  int lx = threadIdx.x & 31, ly = threadIdx.x >> 5;
  for (int j=0;j<32;j+=8)
    t[ly+j][lx] = src[(size_t)(c0+ly+j)*1024 + n0+lx];
  __syncthreads();
  for (int j=0;j<32;j+=8)
    ptsT[((size_t)r*1024 + n0+ly+j)*512 + c0+lx] = t[lx][ly+j];
}

// slot0 init: sums = first 3 points (centroids), counts = 1
__global__ __launch_bounds__(256) void initcent2k(const float* __restrict__ ptsT, float* __restrict__ KACC){
  int i = blockIdx.x*256 + threadIdx.x;
  if (i < 12288){
    int c = i & 511; int k = (i >> 9) % 3; int r = i / 1536;
    KACC[r*1536 + k*512 + c] = ptsT[((size_t)r*1024 + k)*512 + c];
  }
  if (i < 24) KACC[12288 + i] = 1.f;
}

// fused k-means step
__global__ __launch_bounds__(256) void kstepk(const float* __restrict__ ptsT,
    const float* __restrict__ prev, float* __restrict__ next,
    int* __restrict__ a, int nodiv)
{
  const int r = blockIdx.x, sl = blockIdx.y;
  const int tid = threadIdx.x;
  __shared__ float sc[1536];
  __shared__ int sa[32];
  __shared__ float red[3][8][32];
  __shared__ int scnt[3];
  if (tid < 3) scnt[tid] = 0;
  for (int i = tid; i < 1536; i += 256){
    float s = prev[r*1536 + i];
    float cnt = nodiv ? 1.f : (prev[12288 + r*3 + (i>>9)] + 1e-6f);
    sc[i] = s / cnt;
  }
  __syncthreads();
  const float* base = ptsT + (size_t)r*524288;
  const int wid = tid >> 6, lane = tid & 63;
  for (int rep = 0; rep < 8; ++rep){
    int p = wid*8 + rep;
    int n = sl*32 + p;
    const float* pp = base + (size_t)n*512;
    float d0=0.f,d1=0.f,d2=0.f;
    #pragma unroll
    for (int i=0;i<8;i++){
      int c = lane + i*64;
      float v = pp[c];
      float e0 = v - sc[c], e1 = v - sc[512+c], e2 = v - sc[1024+c];
      d0 = fmaf(e0,e0,d0); d1 = fmaf(e1,e1,d1); d2 = fmaf(e2,e2,d2);
    }
    #pragma unroll
    for (int off=32; off>0; off>>=1){
      d0 += __shfl_down(d0, off, 64);
      d1 += __shfl_down(d1, off, 64);
      d2 += __shfl_down(d2, off, 64);
    }
    if (lane == 0){
      int bi = 0; float bd = d0;
      if (d1 < bd){ bd = d1; bi = 1; }
      if (d2 < bd){ bd = d2; bi = 2; }
      sa[p] = bi;
      a[r*1024 + n] = bi;
    }
  }
  __syncthreads();
  if (tid < 32) atomicAdd(&scnt[sa[tid]], 1);
  __syncthreads();
  if (tid < 3) atomicAdd(&next[12288 + r*3 + tid], (float)scnt[tid]);
  const int g = tid >> 5, lc = tid & 31;
  for (int cj = 0; cj < 16; ++cj){
    int c = cj*32 + lc;
    float s0=0.f,s1=0.f,s2=0.f;
    #pragma unroll
    for (int q=0;q<4;q++){
      int nl = g*4 + q;
      float v = base[(size_t)(sl*32+nl)*512 + c];
      int an = sa[nl];
      s0 += (an==0)?v:0.f;
      s1 += (an==1)?v:0.f;
      s2 += (an==2)?v:0.f;
    }
    red[0][g][lc]=s0; red[1][g][lc]=s1; red[2][g][lc]=s2;
    __syncthreads();
    if (g == 0){
      float t0=0.f,t1=0.f,t2=0.f;
      #pragma unroll
      for (int q2=0;q2<8;q2++){ t0+=red[0][q2][lc]; t1+=red[1][q2][lc]; t2+=red[2][q2][lc]; }
      atomicAdd(&next[r*1536 +          c], t0);
      atomicAdd(&next[r*1536 +  512 +   c], t1);
      atomicAdd(&next[r*1536 + 1024 +   c], t2);
    }
    __syncthreads();
  }
}

// final mu/counts from slot 11
__global__ __launch_bounds__(256) void mufink(const float* __restrict__ slot,
                                              float* __restrict__ mu, float* __restrict__ counts){
  int i = blockIdx.x*256 + threadIdx.x;
  if (i >= 12288) return;
  int c = i & 511; int k = (i >> 9) % 3; int r = i / 1536;
  int cs = r >> 2, img = r & 3;
  int i0 = cs*12 + img*3;
  float cnt = slot[12288 + r*3 + k];
  mu[(size_t)(i0+k)*512 + c] = slot[r*1536 + k*512 + c] / (cnt + 1e-6f);
  if (c == 0) counts[i0+k] = cnt;
}

// masked centered split planes
__global__ __launch_bounds__(256) void maskcenterk(const float* __restrict__ f4c, const float* __restrict__ f4s,
        const int* __restrict__ a, const float* __restrict__ mu,
        u16* __restrict__ Ph, u16* __restrict__ Pl){
  size_t i4 = ((size_t)blockIdx.x*256 + threadIdx.x)*4;
  if (i4 >= (size_t)PL*2) return;
  int z = (int)(i4 >> 19);
  int rc = (int)(i4 & 524287);
  int c = rc >> 10, n = rc & 1023;
  int cs = z / 12; int rem = z - cs*12; int img = rem / 3; int k = rem - img*3;
  const float* pts = (cs ? f4s : f4c) + (size_t)img*524288;
  float m = mu[(size_t)z*512 + c];
  const int* an = a + (cs*4 + img)*1024 + n;
  float4 v4 = *(const float4*)&pts[(size_t)c*1024 + n];
  float vv[4] = {v4.x, v4.y, v4.z, v4.w};
  u16x4 oh, ol;
  #pragma unroll
  for (int j=0;j<4;j++){
    float v = (an[j] == k) ? (vv[j] - m) : 0.f;
    u16 h = bf16_rne(v);
    oh[j] = (short)h;
    ol[j] = (short)bf16_rne(v - bf16f(h));
  }
  *(u16x4*)&Ph[i4] = oh;
  *(u16x4*)&Pl[i4] = ol;
}

// covariance via MFMA, trace accumulated. Tile 128M x 64N; grid (8,4,24).
__global__ __launch_bounds__(256,4) void covgemm(const u16* __restrict__ Ph, const u16* __restrict__ Pl,
        const float* __restrict__ counts, float* __restrict__ Ycov, float* __restrict__ trsum){
  const int z = blockIdx.z;
  const u16* Pbh = Ph + (size_t)z*524288;
  const u16* Pbl = Pl + (size_t)z*524288;
  const int m0 = blockIdx.y*128, n0 = blockIdx.x*64;
  const int tid = threadIdx.x;

  __shared__ __align__(16) u16 sAh[128*40], sAl[128*40];
  __shared__ __align__(16) u16 sBh[64*40], sBl[64*40];

  const int ra = tid >> 2, qa = tid & 3;
  const int wid = tid >> 6, lane = tid & 63;
  const int wm = wid >> 1, wn = wid & 1;
  const int quad = lane >> 4, ln = lane & 15;

  f32x4 acc[4][2];
  #pragma unroll
  for (int i=0;i<4;i++)
    #pragma unroll
    for (int j=0;j<2;j++)
      #pragma unroll
      for (int e=0;e<4;e++) acc[i][j][e] = 0.f;

  for (int k0 = 0; k0 < 1024; k0 += 32){
    *(bf16x8*)&sAh[ra*40 + qa*8]      = *(const bf16x8*)&Pbh[(size_t)(m0+ra)*1024    + k0 + qa*8];
    *(bf16x8*)&sAl[ra*40 + qa*8]      = *(const bf16x8*)&Pbl[(size_t)(m0+ra)*1024    + k0 + qa*8];
    *(bf16x8*)&sAh[(ra+64)*40 + qa*8] = *(const bf16x8*)&Pbh[(size_t)(m0+ra+64)*1024 + k0 + qa*8];
    *(bf16x8*)&sAl[(ra+64)*40 + qa*8] = *(const bf16x8*)&Pbl[(size_t)(m0+ra+64)*1024 + k0 + qa*8];
    *(bf16x8*)&sBh[ra*40 + qa*8]      = *(const bf16x8*)&Pbh[(size_t)(n0+ra)*1024    + k0 + qa*8];
    *(bf16x8*)&sBl[ra*40 + qa*8]      = *(const bf16x8*)&Pbl[(size_t)(n0+ra)*1024    + k0 + qa*8];
    __syncthreads();

    bf16x8 ah[4], al[4], bh[2], bl[2];
    #pragma unroll
    for (int t=0;t<4;t++){
      const int moA = ((wm*4+t)*16 + ln)*40 + quad*8;
      ah[t] = *(const bf16x8*)&sAh[moA];
      al[t] = *(const bf16x8*)&sAl[moA];
    }
    #pragma unroll
    for (int t=0;t<2;t++){
      const int moB = ((wn*2+t)*16 + ln)*40 + quad*8;
      bh[t] = *(const bf16x8*)&sBh[moB];
      bl[t] = *(const bf16x8*)&sBl[moB];
    }
    #pragma unroll
    for (int mi=0;mi<4;mi++)
      #pragma unroll
      for (int ni=0;ni<2;ni++){
        acc[mi][ni] = __builtin_amdgcn_mfma_f32_16x16x32_bf16(ah[mi], bh[ni], acc[mi][ni], 0, 0, 0);
        acc[mi][ni] = __builtin_amdgcn_mfma_f32_16x16x32_bf16(ah[mi], bl[ni], acc[mi][ni], 0, 0, 0);
        acc[mi][ni] = __builtin_amdgcn_mfma_f32_16x16x32_bf16(al[mi], bh[ni], acc[mi][ni], 0, 0, 0);
      }
    __syncthreads();
  }
  const float inv = 1.f/(counts[z] + 1e-6f);
  float dsum = 0.f; bool anyd = false;
  #pragma unroll
  for (int mi=0;mi<4;mi++){
    const int mbase = m0 + (wm*4+mi)*16 + quad*4;
    #pragma unroll
    for (int ni=0;ni<2;ni++){
      const int n = n0 + (wn*2+ni)*16 + ln;
      #pragma unroll
      for (int rg=0;rg<4;rg++){
        const int m = mbase + rg;
        float v = acc[mi][ni][rg]*inv + ((m==n)?0.1f:0.f);
        Ycov[(size_t)z*MSZ + (size_t)m*512 + n] = v;
        if (m==n){ dsum += v; anyd = true; }
      }
    }
  }
  if (anyd) atomicAdd(&trsum[z], dsum);
}

// init split planes: Y = Ycov/trace (hi+lo bf16), Z = I
__global__ __launch_bounds__(256) void nsinitk(const float* __restrict__ Ycov, const float* __restrict__ sval,
                                               u16* __restrict__ Yh, u16* __restrict__ Yl,
                                               u16* __restrict__ Zh, u16* __restrict__ Zl){
  size_t idx = (size_t)blockIdx.x*256 + threadIdx.x;
  if (idx >= (size_t)PL) return;
  int z = (int)(idx >> 18);
  int rc = (int)(idx & (MSZ-1));
  int rr = rc >> 9, cc = rc & 511;
  float y = Ycov[idx] / sval[z];
  u16 h = bf16_rne(y);
  Yh[idx] = h;
  Yl[idx] = bf16_rne(y - bf16f(h));
  Zh[idx] = (rr==cc) ? (u16)0x3F80 : (u16)0;
  Zl[idx] = 0;
}

// ---- split-bf16 MFMA batched GEMM 512x512x512; tile 128M x 64N; grid (8,4,z) ----
template<int MODE>
__global__ __launch_bounds__(256,4) void bmms(
    const u16* __restrict__ Ah, const u16* __restrict__ Al,
    const u16* __restrict__ Bh, const u16* __restrict__ Bl,
    u16* __restrict__ Ch, u16* __restrict__ Cl,
    const float* __restrict__ osc,
    int aoff, float* __restrict__ trAcc)
{
  const int z = blockIdx.z;
  const u16* Abh = Ah + (size_t)(z+aoff)*MSZ;
  const u16* Abl = Al + (size_t)(z+aoff)*MSZ;
  const u16* Bbh = Bh + (size_t)z*MSZ;
  const u16* Bbl = Bl + (size_t)z*MSZ;
  const int m0 = blockIdx.y*128, n0 = blockIdx.x*64;
  const int tid = threadIdx.x;

  __shared__ __align__(16) u16 sAh[128*40], sAl[128*40];
  __shared__ __align__(16) u16 sBh[64*40], sBl[64*40];

  const int ra = tid >> 2, qa = tid & 3;
  const int wid = tid >> 6, lane = tid & 63;
  const int wm = wid >> 1, wn = wid & 1;
  const int quad = lane >> 4, ln = lane & 15;

  f32x4 acc[4][2];
  #pragma unroll
  for (int i=0;i<4;i++)
    #pragma unroll
    for (int j=0;j<2;j++)
      #pragma unroll
      for (int e=0;e<4;e++) acc[i][j][e] = 0.f;

  for (int k0 = 0; k0 < 512; k0 += 32){
    *(bf16x8*)&sAh[ra*40 + qa*8]      = *(const bf16x8*)&Abh[(size_t)(m0+ra)*512    + k0 + qa*8];
    *(bf16x8*)&sAl[ra*40 + qa*8]      = *(const bf16x8*)&Abl[(size_t)(m0+ra)*512    + k0 + qa*8];
    *(bf16x8*)&sAh[(ra+64)*40 + qa*8] = *(const bf16x8*)&Abh[(size_t)(m0+ra+64)*512 + k0 + qa*8];
    *(bf16x8*)&sAl[(ra+64)*40 + qa*8] = *(const bf16x8*)&Abl[(size_t)(m0+ra+64)*512 + k0 + qa*8];
    *(bf16x8*)&sBh[ra*40 + qa*8]      = *(const bf16x8*)&Bbh[(size_t)(n0+ra)*512    + k0 + qa*8];
    *(bf16x8*)&sBl[ra*40 + qa*8]      = *(const bf16x8*)&Bbl[(size_t)(n0+ra)*512    + k0 + qa*8];
    __syncthreads();

    bf16x8 ah[4], al[4], bh[2], bl[2];
    #pragma unroll
    for (int t=0;t<4;t++){
      const int moA = ((wm*4+t)*16 + ln)*40 + quad*8;
      ah[t] = *(const bf16x8*)&sAh[moA];
      al[t] = *(const bf16x8*)&sAl[moA];
    }
    #pragma unroll
    for (int t=0;t<2;t++){
      const int moB = ((wn*2+t)*16 + ln)*40 + quad*8;
      bh[t] = *(const bf16x8*)&sBh[moB];
      bl[t] = *(const bf16x8*)&sBl[moB];
    }
    #pragma unroll
    for (int mi=0;mi<4;mi++)
      #pragma unroll
      for (int ni=0;ni<2;ni++){
        acc[mi][ni] = __builtin_amdgcn_mfma_f32_16x16x32_bf16(ah[mi], bh[ni], acc[mi][ni], 0, 0, 0);
        acc[mi][ni] = __builtin_amdgcn_mfma_f32_16x16x32_bf16(ah[mi], bl[ni], acc[mi][ni], 0, 0, 0);
        acc[mi][ni] = __builtin_amdgcn_mfma_f32_16x16x32_bf16(al[mi], bh[ni], acc[mi][ni], 0, 0, 0);
      }
    __syncthreads();
  }

  float alpha = 1.f;
  if constexpr (MODE==2){ alpha = osc[z]; }

  float dsum = 0.f; bool anyd = false;
  #pragma unroll
  for (int mi=0;mi<4;mi++){
    const int mbase = m0 + (wm*4+mi)*16 + quad*4;
    #pragma unroll
    for (int ni=0;ni<2;ni++){
      const int n = n0 + (wn*2+ni)*16 + ln;
      #pragma unroll
      for (int rg=0;rg<4;rg++){
        const int m = mbase + rg;
        const size_t off = (size_t)z*MSZ + (size_t)m*512 + n;
        float v = alpha*acc[mi][ni][rg];
        u16 h = bf16_rne(v);
        Ch[off] = h;
        Cl[off] = bf16_rne(v - bf16f(h));
        if (MODE==0 && trAcc && m==n){ dsum += v; anyd = true; }
      }
    }
  }
  if (MODE==0 && anyd) atomicAdd(&trAcc[z], dsum);
}

// merged NS update (128x128 tile, grid z=48/24 -> already 768 blocks)
__global__ __launch_bounds__(256) void bmmpair(
    const u16* __restrict__ Yh, const u16* __restrict__ Yl,
    const u16* __restrict__ Mh, const u16* __restrict__ Ml,
    const u16* __restrict__ Zh, const u16* __restrict__ Zl,
    u16* __restrict__ Y2h, u16* __restrict__ Y2l,
    u16* __restrict__ Z2h, u16* __restrict__ Z2l,
    const float* __restrict__ trAcc, int last)
{
  const int z = blockIdx.z;
  int zz; bool isY;
  if (last){ zz = z; isY = (z >= 12); }
  else { isY = (z < 24); zz = isY ? z : (z - 24); }
  const size_t zo = (size_t)zz*MSZ;
  const u16 *Abh, *Abl, *Bbh, *Bbl, *Dbh, *Dbl;
  u16 *Cbh, *Cbl;
  if (isY){
    Abh = Yh + zo; Abl = Yl + zo;
    Bbh = Mh + zo; Bbl = Ml + zo;
    Dbh = Yh + zo; Dbl = Yl + zo;
    Cbh = Y2h + zo; Cbl = Y2l + zo;
  } else {
    Abh = Mh + zo; Abl = Ml + zo;
    Bbh = Zh + zo; Bbl = Zl + zo;
    Dbh = Zh + zo; Dbl = Zl + zo;
    Cbh = Z2h + zo; Cbl = Z2l + zo;
  }
  const int m0 = blockIdx.y*128, n0 = blockIdx.x*128;
  const int tid = threadIdx.x;

  __shared__ __align__(16) u16 sAh[128*40], sAl[128*40];
  __shared__ __align__(16) u16 sBh[128*40], sBl[128*40];

  const int ra = tid >> 2, qa = tid & 3;
  const int wid = tid >> 6, lane = tid & 63;
  const int wm = wid >> 1, wn = wid & 1;
  const int quad = lane >> 4, ln = lane & 15;

  f32x4 acc[4][4];
  #pragma unroll
  for (int i=0;i<4;i++)
    #pragma unroll
    for (int j=0;j<4;j++)
      #pragma unroll
      for (int e=0;e<4;e++) acc[i][j][e] = 0.f;

  for (int k0 = 0; k0 < 512; k0 += 32){
    *(bf16x8*)&sAh[ra*40 + qa*8]      = *(const bf16x8*)&Abh[(size_t)(m0+ra)*512    + k0 + qa*8];
    *(bf16x8*)&sAl[ra*40 + qa*8]      = *(const bf16x8*)&Abl[(size_t)(m0+ra)*512    + k0 + qa*8];
    *(bf16x8*)&sAh[(ra+64)*40 + qa*8] = *(const bf16x8*)&Abh[(size_t)(m0+ra+64)*512 + k0 + qa*8];
    *(bf16x8*)&sAl[(ra+64)*40 + qa*8] = *(const bf16x8*)&Abl[(size_t)(m0+ra+64)*512 + k0 + qa*8];
    *(bf16x8*)&sBh[ra*40 + qa*8]      = *(const bf16x8*)&Bbh[(size_t)(n0+ra)*512    + k0 + qa*8];
    *(bf16x8*)&sBl[ra*40 + qa*8]      = *(const bf16x8*)&Bbl[(size_t)(n0+ra)*512    + k0 + qa*8];
    *(bf16x8*)&sBh[(ra+64)*40 + qa*8] = *(const bf16x8*)&Bbh[(size_t)(n0+ra+64)*512 + k0 + qa*8];
    *(bf16x8*)&sBl[(ra+64)*40 + qa*8] = *(const bf16x8*)&Bbl[(size_t)(n0+ra+64)*512 + k0 + qa*8];
    __syncthreads();

    bf16x8 ah[4], al[4], bh[4], bl[4];
    #pragma unroll
    for (int t=0;t<4;t++){
      const int moA = ((wm*4+t)*16 + ln)*40 + quad*8;
      const int moB = ((wn*4+t)*16 + ln)*40 + quad*8;
      ah[t] = *(const bf16x8*)&sAh[moA];
      al[t] = *(const bf16x8*)&sAl[moA];
      bh[t] = *(const bf16x8*)&sBh[moB];
      bl[t] = *(const bf16x8*)&sBl[moB];
    }
    #pragma unroll
    for (int mi=0;mi<4;mi++)
      #pragma unroll
      for (int ni=0;ni<4;ni++){
        acc[mi][ni] = __builtin_amdgcn_mfma_f32_16x16x32_bf16(ah[mi], bh[ni], acc[mi][ni], 0, 0, 0);
        acc[mi][ni] = __builtin_amdgcn_mfma_f32_16x16x32_bf16(ah[mi], bl[ni], acc[mi][ni], 0, 0, 0);
        acc[mi][ni] = __builtin_amdgcn_mfma_f32_16x16x32_bf16(al[mi], bh[ni], acc[mi][ni], 0, 0, 0);
      }
    __syncthreads();
  }

  const float tr = trAcc[zz];
  const float g2 = fminf(512.f/fmaxf(tr, 1e-6f), 2.7f);
  const float oz = 0.5f*sqrtf(g2);
  const float alpha = -g2*oz, beta = 3.f*oz;

  #pragma unroll
  for (int mi=0;mi<4;mi++){
    const int mbase = m0 + (wm*4+mi)*16 + quad*4;
    #pragma unroll
    for (int ni=0;ni<4;ni++){
      const int n = n0 + (wn*4+ni)*16 + ln;
      #pragma unroll
      for (int rg=0;rg<4;rg++){
        const int m = mbase + rg;
        const size_t off = (size_t)m*512 + n;
        float v = alpha*acc[mi][ni][rg] + beta*(bf16f(Dbh[off]) + bf16f(Dbl[off]));
        u16 h = bf16_rne(v);
        Cbh[off] = h;
        Cbl[off] = bf16_rne(v - bf16f(h));
      }
    }
  }
}

// tpts = T[z] @ f[img]: M=512, N=1024, K=512, fp32 out.
// B is pre-transposed fsT [img][n][c] -> both operands row-major-in-K.
// Tile 128M x 64N; grid (16,4,12).
__global__ __launch_bounds__(256,4) void bmmt(
    const u16* __restrict__ Th, const u16* __restrict__ Tl,
    const u16* __restrict__ fh, const u16* __restrict__ fl,
    float* __restrict__ Cf)
{
  const int z = blockIdx.z;
  const u16* Abh = Th + (size_t)z*MSZ;
  const u16* Abl = Tl + (size_t)z*MSZ;
  const u16* Bbh = fh + (size_t)(z/3)*524288;
  const u16* Bbl = fl + (size_t)(z/3)*524288;
  const int m0 = blockIdx.y*128, n0 = blockIdx.x*64;
  const int tid = threadIdx.x;

  __shared__ __align__(16) u16 sAh[128*40], sAl[128*40];
  __shared__ __align__(16) u16 sBh[64*40], sBl[64*40];

  const int ra = tid >> 2, qa = tid & 3;
  const int wid = tid >> 6, lane = tid & 63;
  const int wm = wid >> 1, wn = wid & 1;
  const int quad = lane >> 4, ln = lane & 15;

  f32x4 acc[4][2];
  #pragma unroll
  for (int i=0;i<4;i++)
    #pragma unroll
    for (int j=0;j<2;j++)
      #pragma unroll
      for (int e=0;e<4;e++) acc[i][j][e] = 0.f;

  for (int k0 = 0; k0 < 512; k0 += 32){
    *(bf16x8*)&sAh[ra*40 + qa*8]      = *(const bf16x8*)&Abh[(size_t)(m0+ra)*512    + k0 + qa*8];
    *(bf16x8*)&sAl[ra*40 + qa*8]      = *(const bf16x8*)&Abl[(size_t)(m0+ra)*512    + k0 + qa*8];
    *(bf16x8*)&sAh[(ra+64)*40 + qa*8] = *(const bf16x8*)&Abh[(size_t)(m0+ra+64)*512 + k0 + qa*8];
    *(bf16x8*)&sAl[(ra+64)*40 + qa*8] = *(const bf16x8*)&Abl[(size_t)(m0+ra+64)*512 + k0 + qa*8];
    *(bf16x8*)&sBh[ra*40 + qa*8]      = *(const bf16x8*)&Bbh[(size_t)(n0+ra)*512    + k0 + qa*8];
    *(bf16x8*)&sBl[ra*40 + qa*8]      = *(const bf16x8*)&Bbl[(size_t)(n0+ra)*512    + k0 + qa*8];
    __syncthreads();

    bf16x8 ah[4], al[4], bh[2], bl[2];
    #pragma unroll
    for (int t=0;t<4;t++){
      const int moA = ((wm*4+t)*16 + ln)*40 + quad*8;
      ah[t] = *(const bf16x8*)&sAh[moA];
      al[t] = *(const bf16x8*)&sAl[moA];
    }
    #pragma unroll
    for (int t=0;t<2;t++){
      const int moB = ((wn*2+t)*16 + ln)*40 + quad*8;
      bh[t] = *(const bf16x8*)&sBh[moB];
      bl[t] = *(const bf16x8*)&sBl[moB];
    }
    #pragma unroll
    for (int mi=0;mi<4;mi++)
      #pragma unroll
      for (int ni=0;ni<2;ni++){
        acc[mi][ni] = __builtin_amdgcn_mfma_f32_16x16x32_bf16(ah[mi], bh[ni], acc[mi][ni], 0, 0, 0);
        acc[mi][ni] = __builtin_amdgcn_mfma_f32_16x16x32_bf16(ah[mi], bl[ni], acc[mi][ni], 0, 0, 0);
        acc[mi][ni] = __builtin_amdgcn_mfma_f32_16x16x32_bf16(al[mi], bh[ni], acc[mi][ni], 0, 0, 0);
      }
    __syncthreads();
  }
  #pragma unroll
  for (int mi=0;mi<4;mi++){
    const int mbase = m0 + (wm*4+mi)*16 + quad*4;
    #pragma unroll
    for (int ni=0;ni<2;ni++){
      const int n = n0 + (wn*2+ni)*16 + ln;
      #pragma unroll
      for (int rg=0;rg<4;rg++){
        const int m = mbase + rg;
        Cf[(size_t)z*524288 + (size_t)m*1024 + n] = acc[mi][ni][rg];
      }
    }
  }
}

__global__ void make_scalesk(const float* __restrict__ sval, float* __restrict__ scl){
  int i = threadIdx.x;
  if (i < 12) scl[i] = sqrtf(sval[12+i] / sval[i]);
}

// tvec[b] = mu_s[b] - T[b] @ mu_c[b]
__global__ __launch_bounds__(512) void tveck(const u16* __restrict__ Th, const u16* __restrict__ Tl,
                                             const float* __restrict__ mu, float* __restrict__ tvec){
  int b = blockIdx.x; int c = threadIdx.x;
  __shared__ float mc[512];
  mc[c] = mu[(size_t)b*512 + c];
  __syncthreads();
  const u16* Trh = Th + ((size_t)b*512 + c)*512;
  const u16* Trl = Tl + ((size_t)b*512 + c)*512;
  float s = 0.f;
  for (int d=0; d<512; d++) s = fmaf(bf16f(Trh[d]) + bf16f(Trl[d]), mc[d], s);
  tvec[b*512 + c] = mu[(size_t)(12+b)*512 + c] - s;
}

__global__ __launch_bounds__(256) void selectk(const float* __restrict__ tpts, const float* __restrict__ tvec,
        const int* __restrict__ a, const float* __restrict__ f4c, float* __restrict__ tf){
  size_t idx = (size_t)blockIdx.x*256 + threadIdx.x;
  if (idx >= 2097152ul) return;
  int n = (int)(idx & 1023);
  int c = (int)((idx >> 10) & 511);
  int img = (int)(idx >> 19);
  int k = a[img*1024 + n];
  int b = img*3 + k;
  float v = tpts[((size_t)b*512 + c)*1024 + n] + tvec[b*512 + c];
  tf[idx] = 0.6f*v + 0.4f*f4c[idx];
}

__global__ __launch_bounds__(256) void clossk(const float* __restrict__ x, const float* __restrict__ y,
                                              int n, float* __restrict__ acc){
  int tid = threadIdx.x;
  float s = 0.f;
  for (size_t i = (size_t)blockIdx.x*256 + tid; i < (size_t)n; i += (size_t)gridDim.x*256){
    float d = x[i] - y[i]; s = fmaf(d, d, s);
  }
  __shared__ float sh[256];
  sh[tid] = s; __syncthreads();
  for (int k=128;k>0;k>>=1){ if (tid<k) sh[tid]+=sh[tid+k]; __syncthreads(); }
  if (tid==0) atomicAdd(acc, sh[0]);
}

__global__ __launch_bounds__(256) void finalk(const float* __restrict__ sm, float* __restrict__ out){
  int tid = threadIdx.x;
  const int cnts[4] = {256,512,1024,2048};
  const int offs[4] = {0,256,768,1792};
  const float* mS = sm + SM_STATS_S;
  const float* sS = sm + SM_STATS_S + 3840;
  const float* mD = sm + SM_STATS_D;
  const float* sD = sm + SM_STATS_D + 3840;
  double sl = 0.0;
  for (int L=0; L<4; ++L){
    int cnt = cnts[L], off = offs[L];
    double inv = 1.0/cnt;
    for (int i=tid; i<cnt; i+=256){
      double dm = (double)mD[off+i] - (double)mS[off+i];
      double ds = (double)sD[off+i] - (double)sS[off+i];
      sl += (dm*dm + ds*ds)*inv;
    }
  }
  __shared__ double sh[256];
  sh[tid] = sl; __syncthreads();
  for (int k=128;k>0;k>>=1){ if (tid<k) sh[tid]+=sh[tid+k]; __syncthreads(); }
  if (tid==0){
    double closs = (double)sm[SM_CLOSS] / 2097152.0;
    out[0] = (float)(closs + 0.01*sh[0]);
  }
}

// ---------------- host ----------------

extern "C" void kernel_launch(void* const* d_in, const int* in_sizes, int n_in,
                              void* d_out, int out_size, void* d_ws, size_t ws_size,
                              hipStream_t stream)
{
  const float* content = (const float*)d_in[0];
  const float* style   = (const float*)d_in[1];
  const float* Wm[8]; const float* Bm[8];
  for (int i=0;i<8;i++){ Wm[i] = (const float*)d_in[2+2*i]; Bm[i] = (const float*)d_in[3+2*i]; }
  float* out = (float*)d_out;
  float* ws = (float*)d_ws;

  float* f4c  = ws + OFF_F4C;
  float* f4s  = ws + OFF_F4S;
  float* tf   = ws + OFF_TF;
  float* dec  = ws + OFF_DEC;
  float* sm   = ws + OFF_SMALL;
  float* AR   = ws + OFF_ARENA;
  int*   aPtr = (int*)(sm + SM_ASSIGN);
  float* mu   = sm + SM_MU;
  float* counts = sm + SM_COUNTS;
  float* sval = sm + SM_SVAL;
  float* scl  = sm + SM_SCALE;
  float* tvec = sm + SM_TVEC;
  float* trbuf = sm + SM_TR;

  u16* WB = (u16*)(ws + OFF_WSPL);
  u16 *w2h=WB+0,       *w2l=WB+73728;
  u16 *w3h=WB+147456,  *w3l=WB+442368;
  u16 *w4h=WB+737280,  *w4l=WB+1916928;
  u16 *v1h=WB+3096576, *v1l=WB+4276224;
  u16 *v2h=WB+5455872, *v2l=WB+5750784;
  u16 *v3h=WB+6045696, *v3l=WB+6119424;

  float* Ycov = AR;
  u16* Mh  = (u16*)(AR);
  u16* Ml  = (u16*)(AR + 3145728ul);
  u16* Yh  = (u16*)(AR + 6291456ul);
  u16* Yl  = (u16*)(AR + 9437184ul);
  u16* Zh  = (u16*)(AR + 12582912ul);
  u16* Zl  = (u16*)(AR + 15728640ul);
  u16* Y2h = (u16*)(AR + 18874368ul);
  u16* Y2l = (u16*)(AR + 22020096ul);
  u16* Z2h = (u16*)(AR + 25165824ul);
  u16* Z2l = (u16*)(AR + 28311552ul);
  u16* Ph  = (u16*)(AR + 18874368ul);
  u16* Pl  = (u16*)(AR + 25165824ul);
  float* ptsT = AR + 25165824ul;
  u16* Th  = (u16*)(AR + 18874368ul);
  u16* Tl  = (u16*)(AR + 20971520ul);
  u16* fsh = (u16*)(AR + 23068672ul);
  u16* fsl = (u16*)(AR + 24117248ul);
  float* KACC = AR + 0;

  // NHWC split-bf16 activation planes (u16), placed in lifetime-dead arena slots.
  // encode (B=8):
  u16* xP1h  = (u16*)(AR + 16777216ul);   // 8*128*128*64 u16 -> 4.19M floats
  u16* xP1l  = (u16*)(AR + 20971520ul);
  u16* xF2ph = (u16*)(AR + 16777216ul);   // pooled F2: 8*64*64*128
  u16* xF2pl = (u16*)(AR + 18874368ul);
  u16* xF3ph = (u16*)(AR + 18874368ul);   // pooled F3: 8*32*32*256 (clear of PART8)
  u16* xF3pl = (u16*)(AR + 19922944ul);
  // decode (B=4):
  u16* xTFh  = (u16*)(AR + 8388608ul);    // 4*32*32*512
  u16* xTFl  = (u16*)(AR + 9437184ul);
  u16* xX1h  = (u16*)(AR + 1048576ul);    // 4*32*32*256
  u16* xX1l  = (u16*)(AR + 1572864ul);
  u16* xX2h  = (u16*)(AR + 11534336ul);   // 4*64*64*128
  u16* xX2l  = (u16*)(AR + 12582912ul);
  // decoded encode (B=4):
  u16* xP1dh = (u16*)(AR + 16777216ul);   // 4*128*128*64
  u16* xP1dl = (u16*)(AR + 18874368ul);
  u16* xF2dph= (u16*)(AR + 16777216ul);   // pooled F2d: 4*64*64*128
  u16* xF2dpl= (u16*)(AR + 17825792ul);
  u16* xF3dph= (u16*)(AR + 16777216ul);   // pooled F3d: 4*32*32*256
  u16* xF3dpl= (u16*)(AR + 17301504ul);

  zerok<<<512,256,0,stream>>>(sm, 131072);

  {
    auto wsp = [&](int li, u16* wh, u16* wl, int Co, int Ci){
      int n = 9*Co*Ci;
      wsplitk<<<(n+255)/256,256,0,stream>>>(Wm[li], wh, wl, Co, Ci);
    };
    wsp(1,w2h,w2l,128,64);
    wsp(2,w3h,w3l,256,128);
    wsp(3,w4h,w4l,512,256);
    wsp(4,v1h,v1l,256,512);
    wsp(5,v2h,v2l,128,256);
    wsp(6,v3h,v3l,64,128);
  }

  // MFMA conv on pre-split NHWC u16 input. KS in {1,2,4}, RZ in {0,2}.
  auto convMFMA = [&](const u16* xh, const u16* xl, int li, float* outp,
                      int B,int Ci,int Co,int H,int Wd,int relu,int KS,int RZ,float* part){
    const u16 *wh=nullptr,*wl=nullptr;
    switch(li){
      case 1: wh=w2h; wl=w2l; break;
      case 2: wh=w3h; wl=w3l; break;
      case 3: wh=w4h; wl=w4l; break;
      case 4: wh=v1h; wl=v1l; break;
      case 5: wh=v2h; wl=v2l; break;
      case 6: wh=v3h; wl=v3l; break;
    }
    int tiles = (H>>3)*(Wd>>4);
    if (KS==1){
      dim3 g(tiles,Co>>6,B);
      if (RZ==0) convm<1,0><<<g,256,0,stream>>>(xh,xl,wh,wl,Bm[li],outp,Ci,Co,H,Wd,relu);
      else       convm<1,2><<<g,256,0,stream>>>(xh,xl,wh,wl,Bm[li],outp,Ci,Co,H,Wd,relu);
    } else if (KS==2){
      dim3 g(tiles,Co>>6,B*2);
      if (RZ==0) convm<2,0><<<g,256,0,stream>>>(xh,xl,wh,wl,nullptr,part,Ci,Co,H,Wd,relu);
      else       convm<2,2><<<g,256,0,stream>>>(xh,xl,wh,wl,nullptr,part,Ci,Co,H,Wd,relu);
      int n = B*Co*H*Wd;
      sumk<<<(n+255)/256,256,0,stream>>>(part,Bm[li],outp,Co,H*Wd,2,relu,n);
    } else {
      dim3 g(tiles,Co>>6,B*4);
      convm<4,0><<<g,256,0,stream>>>(xh,xl,wh,wl,nullptr,part,Ci,Co,H,Wd,relu);
      int n = B*Co*H*Wd;
      sumk<<<(n+255)/256,256,0,stream>>>(part,Bm[li],outp,Co,H*Wd,4,relu,n);
    }
  };

  float* mS = sm + SM_STATS_S;
  float* sS = sm + SM_STATS_S + 3840;

  // ---- batched content+style encode (B=8 from e2 down) ----
  float* F1   = AR + 0;
  float* F2_8 = AR + 0;
  float* F3_8 = AR + 0;
  float* PART8 = AR + 10485760ul;

  {
    dim3 ge(64, 8, 4);  // (256/32)^2 tiles, 64/8 co-groups, B=4
    // content e1: fp32 output is dead (style overwrites F1 before any reader) -> OUTW=0
    conv3x3<8,4,1,0,0><<<ge,256,0,stream>>>(content,Wm[0],Bm[0],F1,xP1h,           xP1l,           4,3,64,256,256,1);
    conv3x3<8,4,1,1,0><<<ge,256,0,stream>>>(style,  Wm[0],Bm[0],F1,xP1h+4194304ul, xP1l+4194304ul, 4,3,64,256,256,1);
  }
  statsk<<<256,256,0,stream>>>(F1,65536, mS+0, sS+0);

  convMFMA(xP1h,xP1l, 1, F2_8, 8, 64,128,128,128,1,1,0,nullptr);
  statsk<<<512,256,0,stream>>>(F2_8 + 8388608ul, 16384, mS+256, sS+256);
  repackk<1><<<dim3(128,2,8),256,0,stream>>>(F2_8, xF2ph, xF2pl, 128,64,64);
  convMFMA(xF2ph,xF2pl, 2, F3_8, 8, 128,256,64,64,1,1,0,nullptr);
  statsk<<<1024,256,0,stream>>>(F3_8 + 4194304ul, 4096, mS+768, sS+768);
  repackk<1><<<dim3(32,4,8),256,0,stream>>>(F3_8, xF3ph, xF3pl, 256,32,32);
  convMFMA(xF3ph,xF3pl, 3, f4c, 8, 256,512,32,32,1,2,0,PART8);
  statsk<<<2048,256,0,stream>>>(f4s,1024, mS+1792, sS+1792);

  // ---- fused k-means ----
  transposek<<<dim3(32,16,8),256,0,stream>>>(f4c,f4s,ptsT);
  zerok<<<(12*KSLOT+255)/256,256,0,stream>>>(KACC, 12*KSLOT);
  initcent2k<<<48,256,0,stream>>>(ptsT,KACC);
  for (int it=0; it<=10; ++it){
    kstepk<<<dim3(8,32),256,0,stream>>>(ptsT, KACC + (size_t)it*KSLOT, KACC + (size_t)(it+1)*KSLOT, aPtr, it==0 ? 1 : 0);
  }
  mufink<<<48,256,0,stream>>>(KACC + 11ul*KSLOT, mu, counts);

  // ---- covariances via MFMA ----
  maskcenterk<<<12288,256,0,stream>>>(f4c,f4s,aPtr,mu,Ph,Pl);
  covgemm<<<dim3(8,4,24),256,0,stream>>>(Ph,Pl,counts,Ycov,sval);
  nsinitk<<<24576,256,0,stream>>>(Ycov,sval,Yh,Yl,Zh,Zl);

  // ---- split-bf16 MFMA Newton-Schulz ----
  u16 *Ych=Yh,*Ycl=Yl,*Zch=Zh,*Zcl=Zl,*Yah=Y2h,*Yal=Y2l,*Zah=Z2h,*Zal=Z2l;
  for (int it=0; it<NS_ITERS; ++it){
    bmms<0><<<dim3(8,4,24),256,0,stream>>>(Zch,Zcl,Ych,Ycl,Mh,Ml,nullptr,0,trbuf+it*24);
    if (it < NS_ITERS-1)
      bmmpair<<<dim3(4,4,48),256,0,stream>>>(Ych,Ycl,Mh,Ml,Zch,Zcl,Yah,Yal,Zah,Zal,trbuf+it*24,0);
    else
      bmmpair<<<dim3(4,4,24),256,0,stream>>>(Ych,Ycl,Mh,Ml,Zch,Zcl,Yah,Yal,Zah,Zal,trbuf+it*24,1);
    u16* t;
    t=Ych;Ych=Yah;Yah=t; t=Ycl;Ycl=Yal;Yal=t;
    t=Zch;Zch=Zah;Zah=t; t=Zcl;Zcl=Zal;Zal=t;
  }
  make_scalesk<<<1,64,0,stream>>>(sval,scl);
  bmms<2><<<dim3(8,4,12),256,0,stream>>>(Ych,Ycl,Zch,Zcl,Th,Tl,scl,12,nullptr);
  tveck<<<12,512,0,stream>>>(Th,Tl,mu,tvec);
  // f4c [img][c][n] -> fsT [img][n][c] split-bf16 (transposing repack; N=1024=32x32)
  repackk<0><<<dim3(32,8,4),256,0,stream>>>(f4c, fsh, fsl, 512,32,32);
  float* Mb = AR + 0;
  bmmt<<<dim3(16,4,12),256,0,stream>>>(Th,Tl,fsh,fsl,Mb);
  selectk<<<8192,256,0,stream>>>(Mb,tvec,aPtr,f4c,tf);

  // ---- decode (B=4; up fused into d2/d3 via RZ=2; d4 via dedicated d4upk) ----
  float* X1 = AR + 0;
  float* X2 = AR + 5242880ul;
  float* X3 = AR + 0;
  float* PARTA = AR + 2097152ul;
  float* PARTB = AR + 7340032ul;
  repackk<0><<<dim3(32,8,4),256,0,stream>>>(tf, xTFh, xTFl, 512,32,32);
  convMFMA(xTFh,xTFl, 4, X1, 4, 512,256,32,32,1,4,0,PARTA);
  repackk<0><<<dim3(32,4,4),256,0,stream>>>(X1, xX1h, xX1l, 256,32,32);
  convMFMA(xX1h,xX1l, 5, X2, 4, 256,128,64,64,1,2,2,PARTB);
  repackk<0><<<dim3(128,2,4),256,0,stream>>>(X2, xX2h, xX2l, 128,64,64);
  convMFMA(xX2h,xX2l, 6, X3, 4, 128,64,128,128,1,1,2,nullptr);
  d4upk<<<dim3(256,1,4),256,0,stream>>>(X3, Wm[7], Bm[7], dec);

  // ---- decoded encode + stats + content loss (B=4) ----
  float* mD = sm + SM_STATS_D;
  float* sD = sm + SM_STATS_D + 3840;
  float* F1d = AR + 0;
  float* F2d = AR + 0;
  float* F3d = AR + 10485760ul;
  {
    dim3 ge(64, 8, 4);
    conv3x3<8,4,1,1,0><<<ge,256,0,stream>>>(dec,Wm[0],Bm[0],F1d,xP1dh,xP1dl,4,3,64,256,256,1);
  }
  statsk<<<256,256,0,stream>>>(F1d,65536, mD+0, sD+0);
  convMFMA(xP1dh,xP1dl, 1, F2d, 4, 64,128,128,128,1,1,0,nullptr);
  statsk<<<512,256,0,stream>>>(F2d,16384, mD+256, sD+256);
  repackk<1><<<dim3(128,2,4),256,0,stream>>>(F2d, xF2dph, xF2dpl, 128,64,64);
  convMFMA(xF2dph,xF2dpl, 2, F3d, 4, 128,256,64,64,1,1,0,nullptr);
  statsk<<<1024,256,0,stream>>>(F3d,4096, mD+768, sD+768);
  repackk<1><<<dim3(32,4,4),256,0,stream>>>(F3d, xF3dph, xF3dpl, 256,32,32);
  convMFMA(xF3dph,xF3dpl, 3, tf, 4, 256,512,32,32,1,2,0,PARTA);
  statsk<<<2048,256,0,stream>>>(tf,1024, mD+1792, sD+1792);
  clossk<<<2048,256,0,stream>>>(tf,f4c,2097152, sm+SM_CLOSS);
  finalk<<<1,256,0,stream>>>(sm,out);
}

// Round 7
// 2227.000 us; speedup vs baseline: 1.0679x; 1.0679x over previous
//
#include <hip/hip_runtime.h>
#include <cstddef>

#define NS_ITERS 8
#define MSZ 262144  // 512*512
#define PL  6291456 // 24*MSZ
#define KSLOT 12312 // k-means accumulator slot stride (floats)

typedef unsigned short u16;
typedef __attribute__((ext_vector_type(8))) short bf16x8;
typedef __attribute__((ext_vector_type(4))) float f32x4;
typedef __attribute__((ext_vector_type(4))) short u16x4;

__device__ inline u16 bf16_rne(float x){
  unsigned u = __float_as_uint(x);
  unsigned r = u + 0x7fffu + ((u>>16)&1u);
  return (u16)(r>>16);
}
__device__ inline float bf16f(u16 h){
  return __uint_as_float(((unsigned)h)<<16);
}

// ---------------- workspace offsets (in floats) ----------------
#define OFF_F4C   0ul
#define OFF_F4S   2097152ul
#define OFF_TF    4194304ul
#define OFF_DEC   6291456ul
#define OFF_WSPL  7077888ul
#define OFF_SMALL 10223616ul
#define OFF_ARENA 10354688ul

// SMALL sub-offsets (floats)
#define SM_ASSIGN  12288
#define SM_MU      20480
#define SM_COUNTS  32768
#define SM_SVAL    32800
#define SM_SCALE   32832
#define SM_TVEC    32864
#define SM_STATS_S 39008
#define SM_STATS_D 46688
#define SM_CLOSS   54368
#define SM_TR      54464

// ---------------- kernels ----------------

__global__ __launch_bounds__(256) void zerok(float* p, int n){
  int i = blockIdx.x*256 + threadIdx.x;
  if (i < n) p[i] = 0.f;
}

// direct 3x3 SAME conv (for e1: Cin=3)
template<int COT, int CIT, int POOL, int OUTW, int RZ>
__global__ __launch_bounds__(256,4) void conv3x3(
    const float* __restrict__ in, const float* __restrict__ wgt,
    const float* __restrict__ bias, float* __restrict__ out,
    u16* __restrict__ poh, u16* __restrict__ pol,
    int B, int Cin, int Cout, int H, int W, int relu)
{
  __shared__ float s_in[CIT][34][34];
  __shared__ float s_w[COT][CIT][9];
  const int tid = threadIdx.x;
  const int tx = tid & 15, ty = tid >> 4;
  const int tilesW = W >> 5;
  const int h0 = (blockIdx.x / tilesW) << 5;
  const int w0 = (blockIdx.x % tilesW) << 5;
  const int co0 = blockIdx.y * COT;
  const int b = blockIdx.z;
  float acc[COT][2][2];
  #pragma unroll
  for (int o=0;o<COT;o++){acc[o][0][0]=0.f;acc[o][0][1]=0.f;acc[o][1][0]=0.f;acc[o][1][1]=0.f;}
  const int y0 = ty*2, x0 = tx*2;
  for (int ci0 = 0; ci0 < Cin; ci0 += CIT){
    const int cic = (Cin - ci0 < CIT) ? (Cin - ci0) : CIT;
    const int tot = cic*1156;
    for (int e = tid; e < tot; e += 256){
      int c = e / 1156; int r = e - c*1156;
      int lh = r / 34, lw = r - lh*34;
      int ih = h0 + lh - 1, iw = w0 + lw - 1;
      float v = 0.f;
      if ((unsigned)ih < (unsigned)H && (unsigned)iw < (unsigned)W){
        if constexpr (RZ==2)
          v = in[((size_t)(b*Cin + ci0 + c)*(H>>1) + (ih>>1))*(size_t)(W>>1) + (iw>>1)];
        else
          v = in[((size_t)(b*Cin + ci0 + c)*H + ih)*W + iw];
      }
      s_in[c][lh][lw] = v;
    }
    const int wtot = COT*cic*9;
    for (int e = tid; e < wtot; e += 256){
      int o = e / (cic*9); int r = e - o*(cic*9);
      int c = r / 9, t = r - c*9;
      int co = co0 + o;
      float v = 0.f;
      if (co < Cout) v = wgt[(size_t)(co*Cin + ci0 + c)*9 + t];
      s_w[o][c][t] = v;
    }
    __syncthreads();
    for (int c = 0; c < cic; ++c){
      float p[4][4];
      #pragma unroll
      for (int r=0;r<4;r++)
        #pragma unroll
        for (int s=0;s<4;s++)
          p[r][s] = s_in[c][y0+r][x0+s];
      #pragma unroll
      for (int dh=0; dh<3; dh++)
        #pragma unroll
        for (int dw=0; dw<3; dw++){
          #pragma unroll
          for (int o=0;o<COT;o++){
            float wv = s_w[o][c][dh*3+dw];
            acc[o][0][0] = fmaf(p[dh  ][dw  ], wv, acc[o][0][0]);
            acc[o][0][1] = fmaf(p[dh  ][dw+1], wv, acc[o][0][1]);
            acc[o][1][0] = fmaf(p[dh+1][dw  ], wv, acc[o][1][0]);
            acc[o][1][1] = fmaf(p[dh+1][dw+1], wv, acc[o][1][1]);
          }
        }
    }
    __syncthreads();
  }
  if constexpr (POOL){
    bf16x8 p8h, p8l;
    #pragma unroll
    for (int o=0;o<COT;o++){
      const int co = co0 + o;
      const float bv = bias[co];
      float v00 = fmaxf(acc[o][0][0]+bv, 0.f);
      float v01 = fmaxf(acc[o][0][1]+bv, 0.f);
      float v10 = fmaxf(acc[o][1][0]+bv, 0.f);
      float v11 = fmaxf(acc[o][1][1]+bv, 0.f);
      if constexpr (OUTW){
        *(float2*)&out[((size_t)(b*Cout + co)*H + h0+y0  )*W + w0+x0] = make_float2(v00, v01);
        *(float2*)&out[((size_t)(b*Cout + co)*H + h0+y0+1)*W + w0+x0] = make_float2(v10, v11);
      }
      // same order as pool2k: p[0]+p[1]+p[2W]+p[2W+1]
      float pv = 0.25f*(v00 + v01 + v10 + v11);
      u16 h = bf16_rne(pv);
      p8h[o] = (short)h;
      p8l[o] = (short)bf16_rne(pv - bf16f(h));
    }
    size_t po = ((size_t)(b*(H>>1) + ((h0+y0)>>1))*(W>>1) + ((w0+x0)>>1))*(size_t)Cout + co0;
    *(bf16x8*)&poh[po] = p8h;
    *(bf16x8*)&pol[po] = p8l;
  } else {
    #pragma unroll
    for (int o=0;o<COT;o++){
      int co = co0 + o;
      if (co >= Cout) continue;
      float bv = bias[co];
      float v00 = acc[o][0][0] + bv;
      float v01 = acc[o][0][1] + bv;
      float v10 = acc[o][1][0] + bv;
      float v11 = acc[o][1][1] + bv;
      if (relu){
        v00 = fmaxf(v00, 0.f); v01 = fmaxf(v01, 0.f);
        v10 = fmaxf(v10, 0.f); v11 = fmaxf(v11, 0.f);
      }
      *(float2*)&out[((size_t)(b*Cout + co)*H + h0+y0  )*W + w0+x0] = make_float2(v00, v01);
      *(float2*)&out[((size_t)(b*Cout + co)*H + h0+y0+1)*W + w0+x0] = make_float2(v10, v11);
    }
  }
}

// dedicated d4: Cin=64 -> Cout=3, 256x256 out, nearest-up2 fused (input 128x128 fp32 NCHW).
__global__ __launch_bounds__(256,4) void d4upk(
    const float* __restrict__ in, const float* __restrict__ wgt,
    const float* __restrict__ bias, float* __restrict__ out)
{
  __shared__ float s_in[64][10][10];
  __shared__ float s_w[3][64][9];
  const int tid = threadIdx.x;
  const int b = blockIdx.z;
  const int h0 = (blockIdx.x >> 4) << 4, w0 = (blockIdx.x & 15) << 4;
  const int r0 = (h0 >> 1) - 1, c0 = (w0 >> 1) - 1;
  for (int e = tid; e < 6400; e += 256){
    int c = e / 100, r = e - c*100;
    int lr = r / 10, lc = r - lr*10;
    int gr = r0 + lr, gc = c0 + lc;
    float v = 0.f;
    if ((unsigned)gr < 128u && (unsigned)gc < 128u)
      v = in[((size_t)(b*64 + c)*128 + gr)*128 + gc];
    s_in[c][lr][lc] = v;
  }
  for (int e = tid; e < 1728; e += 256){
    int o = e / 576, r = e - o*576;
    int ci = r / 9, t = r - ci*9;
    s_w[o][ci][t] = wgt[(size_t)(o*64 + ci)*9 + t];
  }
  __syncthreads();
  const int ty = tid >> 4, tx = tid & 15;
  const int oh = h0 + ty, ow = w0 + tx;
  int lr3[3], lc3[3]; bool vr3[3], vc3[3];
  #pragma unroll
  for (int d=0; d<3; d++){
    int ih = oh + d - 1;
    vr3[d] = (unsigned)ih < 256u;
    lr3[d] = (ih >> 1) - r0;
    int iw = ow + d - 1;
    vc3[d] = (unsigned)iw < 256u;
    lc3[d] = (iw >> 1) - c0;
  }
  float a0 = 0.f, a1 = 0.f, a2 = 0.f;
  for (int ci = 0; ci < 64; ++ci){
    #pragma unroll
    for (int dh=0; dh<3; dh++){
      #pragma unroll
      for (int dw=0; dw<3; dw++){
        float v = (vr3[dh] && vc3[dw]) ? s_in[ci][lr3[dh]][lc3[dw]] : 0.f;
        a0 = fmaf(v, s_w[0][ci][dh*3+dw], a0);
        a1 = fmaf(v, s_w[1][ci][dh*3+dw], a1);
        a2 = fmaf(v, s_w[2][ci][dh*3+dw], a2);
      }
    }
  }
  out[((size_t)(b*3 + 0)*256 + oh)*256 + ow] = a0 + bias[0];
  out[((size_t)(b*3 + 1)*256 + oh)*256 + ow] = a1 + bias[1];
  out[((size_t)(b*3 + 2)*256 + oh)*256 + ow] = a2 + bias[2];
}

// pre-split conv weights: dst[(dhw*Cout + co)*Cin + ci]
__global__ __launch_bounds__(256) void wsplitk(const float* __restrict__ wgt,
                                               u16* __restrict__ dh_, u16* __restrict__ dl_,
                                               int Cout, int Cin){
  int idx = blockIdx.x*256 + threadIdx.x;
  int n = 9*Cout*Cin;
  if (idx >= n) return;
  int cc = Cout*Cin;
  int dhw = idx / cc;
  int r = idx - dhw*cc;
  int co = r / Cin, ci = r - co*Cin;
  float v = wgt[((size_t)co*Cin + ci)*9 + dhw];
  u16 h = bf16_rne(v);
  dh_[idx] = h;
  dl_[idx] = bf16_rne(v - bf16f(h));
}

// fp32 NCHW -> split-bf16 NHWC repack (POOL=1: fused avg-pool2, input 2Ho x 2Wo)
// grid: (Ho*Wo/32, C/64, B)
template<int POOL>
__global__ __launch_bounds__(256) void repackk(const float* __restrict__ in,
    u16* __restrict__ oh, u16* __restrict__ ol, int C, int Ho, int Wo)
{
  __shared__ unsigned tr[64][33];
  const int N = Ho*Wo;
  const int n0 = blockIdx.x << 5, c0 = blockIdx.y << 6, b = blockIdx.z;
  const int lnn = threadIdx.x & 31, gc = threadIdx.x >> 5;
  {
    const int n = n0 + lnn;
    const int ho = n / Wo, wo = n - ho*Wo;
    #pragma unroll
    for (int i=0;i<8;i++){
      const int c = (gc<<3) + i;
      float v;
      if constexpr (POOL){
        const float* p = in + ((size_t)(b*C + c0+c)*(Ho*2) + ho*2)*(size_t)(Wo*2) + (size_t)wo*2;
        v = 0.25f*(p[0] + p[1] + p[2*Wo] + p[2*Wo+1]);
      } else {
        v = in[((size_t)(b*C + c0+c))*N + n];
      }
      u16 h = bf16_rne(v);
      tr[c][lnn] = (unsigned)h | ((unsigned)bf16_rne(v - bf16f(h)) << 16);
    }
  }
  __syncthreads();
  const int n2 = threadIdx.x >> 3, oct = threadIdx.x & 7;
  bf16x8 vh, vl;
  #pragma unroll
  for (int j=0;j<8;j++){
    unsigned u = tr[(oct<<3)+j][n2];
    vh[j] = (short)(u & 0xffffu);
    vl[j] = (short)(u >> 16);
  }
  size_t o = ((size_t)b*N + (n0 + n2))*(size_t)C + c0 + (oct<<3);
  *(bf16x8*)&oh[o] = vh;
  *(bf16x8*)&ol[o] = vl;
}

// ---- split-bf16 MFMA direct conv 3x3 SAME; input pre-split NHWC u16 planes ----
// Tile: 64 co x (8x16) px; W staged per (dh,dw) tap. Bit-exact order.
template<int KS, int RESIZE>
__global__ __launch_bounds__(256,4) void convm(
    const u16* __restrict__ xh, const u16* __restrict__ xl,
    const u16* __restrict__ wsh, const u16* __restrict__ wsl,
    const float* __restrict__ bias, float* __restrict__ out,
    int Cin, int Cout, int H, int W, int relu)
{
  const int tilesW = W >> 4;
  const int h0 = (blockIdx.x / tilesW) << 3;
  const int w0 = (blockIdx.x % tilesW) << 4;
  const int co0 = blockIdx.y << 6;
  const int b  = blockIdx.z / KS;
  const int ks = blockIdx.z % KS;
  const int NB = gridDim.z / KS;
  const int tid = threadIdx.x;
  const int wid = tid >> 6, lane = tid & 63;
  const int wm = wid >> 1, wn = wid & 1;
  const int quad = lane >> 4, ln = lane & 15;

  __shared__ __align__(16) u16 sXh[180*40], sXl[180*40];
  __shared__ __align__(16) u16 sWh[64*40],  sWl[64*40];

  f32x4 acc[2][4];
  #pragma unroll
  for (int i=0;i<2;i++)
    #pragma unroll
    for (int j=0;j<4;j++)
      #pragma unroll
      for (int e=0;e<4;e++) acc[i][j][e] = 0.f;

  const int wco = tid >> 2, wcg = (tid & 3) << 3;

  const int ciA = ks*(Cin/KS), ciB = ciA + Cin/KS;
  for (int ci0 = ciA; ci0 < ciB; ci0 += 32){
    // X staging: halo 10x18 px, 4 slots of 8 ci.
    for (int e = tid; e < 720; e += 256){
      const int px = e >> 2, sl = e & 3;
      const int pr = px / 18, pc = px - pr*18;
      const int ih = h0 + pr - 1, iw = w0 + pc - 1;
      bf16x8 vh, vl;
      #pragma unroll
      for (int j=0;j<8;j++){ vh[j] = 0; vl[j] = 0; }
      if ((unsigned)ih < (unsigned)H && (unsigned)iw < (unsigned)W){
        size_t o;
        if constexpr (RESIZE==0)
          o = ((size_t)(b*H + ih)*W + iw)*(size_t)Cin + (size_t)(ci0 + sl*8);
        else
          o = ((size_t)(b*(H>>1) + (ih>>1))*(W>>1) + (iw>>1))*(size_t)Cin + (size_t)(ci0 + sl*8);
        vh = *(const bf16x8*)&xh[o];
        vl = *(const bf16x8*)&xl[o];
      }
      *(bf16x8*)&sXh[px*40 + sl*8] = vh;
      *(bf16x8*)&sXl[px*40 + sl*8] = vl;
    }
    for (int dh = 0; dh < 3; ++dh){
      for (int dw = 0; dw < 3; ++dw){
        {
          const size_t so = ((size_t)((dh*3+dw)*Cout + co0+wco))*Cin + ci0 + wcg;
          *(bf16x8*)&sWh[wco*40 + wcg] = *(const bf16x8*)&wsh[so];
          *(bf16x8*)&sWl[wco*40 + wcg] = *(const bf16x8*)&wsl[so];
        }
        __syncthreads();
        bf16x8 ah[2], al[2], bh[4], bl[4];
        #pragma unroll
        for (int t=0;t<2;t++){
          const int co_l = (wm*2+t)*16 + ln;
          ah[t] = *(const bf16x8*)&sWh[co_l*40 + quad*8];
          al[t] = *(const bf16x8*)&sWl[co_l*40 + quad*8];
        }
        #pragma unroll
        for (int t=0;t<4;t++){
          const int p = (wn*4+t)*16 + ln;
          const int px = ((p>>4) + dh)*18 + (p&15) + dw;
          const int xo = px*40 + quad*8;
          bh[t] = *(const bf16x8*)&sXh[xo];
          bl[t] = *(const bf16x8*)&sXl[xo];
        }
        #pragma unroll
        for (int mi=0;mi<2;mi++)
          #pragma unroll
          for (int ni=0;ni<4;ni++){
            acc[mi][ni] = __builtin_amdgcn_mfma_f32_16x16x32_bf16(ah[mi], bh[ni], acc[mi][ni], 0, 0, 0);
            acc[mi][ni] = __builtin_amdgcn_mfma_f32_16x16x32_bf16(ah[mi], bl[ni], acc[mi][ni], 0, 0, 0);
            acc[mi][ni] = __builtin_amdgcn_mfma_f32_16x16x32_bf16(al[mi], bh[ni], acc[mi][ni], 0, 0, 0);
          }
        __syncthreads();
      }
    }
  }
  #pragma unroll
  for (int mi=0;mi<2;mi++){
    const int co = co0 + (wm*2+mi)*16 + quad*4;
    #pragma unroll
    for (int ni=0;ni<4;ni++){
      const int p = (wn*4+ni)*16 + ln;
      const int oh = h0 + (p>>4), ow = w0 + (p&15);
      #pragma unroll
      for (int rg=0; rg<4; rg++){
        const int cog = co + rg;
        if constexpr (KS==1){
          float v = acc[mi][ni][rg] + bias[cog];
          if (relu) v = fmaxf(v, 0.f);
          out[((size_t)(b*Cout + cog)*H + oh)*W + ow] = v;
        } else {
          out[((size_t)((ks*NB + b)*Cout + cog)*H + oh)*W + ow] = acc[mi][ni][rg];
        }
      }
    }
  }
}

// reduce split-K partials + bias + relu
__global__ __launch_bounds__(256) void sumk(const float* __restrict__ part, const float* __restrict__ bias,
                                            float* __restrict__ out, int Cout, int HW, int KS, int relu, int n){
  int idx = blockIdx.x*256 + threadIdx.x;
  if (idx >= n) return;
  int co = (idx / HW) % Cout;
  float v = bias[co];
  for (int k=0;k<KS;k++) v += part[(size_t)k*n + idx];
  if (relu) v = fmaxf(v, 0.f);
  out[idx] = v;
}

// per-(b,c) spatial mean & std (ddof=0)
__global__ __launch_bounds__(256) void statsk(const float* __restrict__ x, int HW,
                                              float* __restrict__ mo, float* __restrict__ so){
  int bc = blockIdx.x, tid = threadIdx.x;
  const float* p = x + (size_t)bc*HW;
  double s = 0.0, s2 = 0.0;
  for (int i = tid; i < HW; i += 256){ double v = p[i]; s += v; s2 += v*v; }
  __shared__ double sh[256], sh2[256];
  sh[tid] = s; sh2[tid] = s2; __syncthreads();
  for (int k=128;k>0;k>>=1){ if (tid<k){ sh[tid]+=sh[tid+k]; sh2[tid]+=sh2[tid+k]; } __syncthreads(); }
  if (tid == 0){
    double m = sh[0]/HW;
    double var = sh2[0]/HW - m*m;
    if (var < 0.0) var = 0.0;
    mo[bc] = (float)m;
    so[bc] = (float)sqrt(var);
  }
}

// f4 (C-major, per image 512x1024) -> ptsT [8][1024][512]
__global__ __launch_bounds__(256) void transposek(const float* __restrict__ f4c,
                                                  const float* __restrict__ f4s,
                                                  float* __restrict__ ptsT){
  __shared__ float t[32][33];
  int r = blockIdx.z;
  const float* src = (r < 4) ? (f4c + (size_t)r*524288) : (f4s + (size_t)(r-4)*524288);
  int n0 = blockIdx.x*32, c0 = blockIdx.y*32;
  int lx = threadIdx.x & 31, ly = threadIdx.x >> 5;
  for (int j=0;j<32;j+=8)
    t[ly+j][lx] = src[(size_t)(c0+ly+j)*1024 + n0+lx];
  __syncthreads();
  for (int j=0;j<32;j+=8)
    ptsT[((size_t)r*1024 + n0+ly+j)*512 + c0+lx] = t[lx][ly+j];
}

// slot0 init: sums = first 3 points (centroids), counts = 1
__global__ __launch_bounds__(256) void initcent2k(const float* __restrict__ ptsT, float* __restrict__ KACC){
  int i = blockIdx.x*256 + threadIdx.x;
  if (i < 12288){
    int c = i & 511; int k = (i >> 9) % 3; int r = i / 1536;
    KACC[r*1536 + k*512 + c] = ptsT[((size_t)r*1024 + k)*512 + c];
  }
  if (i < 24) KACC[12288 + i] = 1.f;
}

// fused k-means step
__global__ __launch_bounds__(256) void kstepk(const float* __restrict__ ptsT,
    const float* __restrict__ prev, float* __restrict__ next,
    int* __restrict__ a, int nodiv)
{
  const int r = blockIdx.x, sl = blockIdx.y;
  const int tid = threadIdx.x;
  __shared__ float sc[1536];
  __shared__ int sa[32];
  __shared__ float red[3][8][32];
  __shared__ int scnt[3];
  if (tid < 3) scnt[tid] = 0;
  for (int i = tid; i < 1536; i += 256){
    float s = prev[r*1536 + i];
    float cnt = nodiv ? 1.f : (prev[12288 + r*3 + (i>>9)] + 1e-6f);
    sc[i] = s / cnt;
  }
  __syncthreads();
  const float* base = ptsT + (size_t)r*524288;
  const int wid = tid >> 6, lane = tid & 63;
  for (int rep = 0; rep < 8; ++rep){
    int p = wid*8 + rep;
    int n = sl*32 + p;
    const float* pp = base + (size_t)n*512;
    float d0=0.f,d1=0.f,d2=0.f;
    #pragma unroll
    for (int i=0;i<8;i++){
      int c = lane + i*64;
      float v = pp[c];
      float e0 = v - sc[c], e1 = v - sc[512+c], e2 = v - sc[1024+c];
      d0 = fmaf(e0,e0,d0); d1 = fmaf(e1,e1,d1); d2 = fmaf(e2,e2,d2);
    }
    #pragma unroll
    for (int off=32; off>0; off>>=1){
      d0 += __shfl_down(d0, off, 64);
      d1 += __shfl_down(d1, off, 64);
      d2 += __shfl_down(d2, off, 64);
    }
    if (lane == 0){
      int bi = 0; float bd = d0;
      if (d1 < bd){ bd = d1; bi = 1; }
      if (d2 < bd){ bd = d2; bi = 2; }
      sa[p] = bi;
      a[r*1024 + n] = bi;
    }
  }
  __syncthreads();
  if (tid < 32) atomicAdd(&scnt[sa[tid]], 1);
  __syncthreads();
  if (tid < 3) atomicAdd(&next[12288 + r*3 + tid], (float)scnt[tid]);
  const int g = tid >> 5, lc = tid & 31;
  for (int cj = 0; cj < 16; ++cj){
    int c = cj*32 + lc;
    float s0=0.f,s1=0.f,s2=0.f;
    #pragma unroll
    for (int q=0;q<4;q++){
      int nl = g*4 + q;
      float v = base[(size_t)(sl*32+nl)*512 + c];
      int an = sa[nl];
      s0 += (an==0)?v:0.f;
      s1 += (an==1)?v:0.f;
      s2 += (an==2)?v:0.f;
    }
    red[0][g][lc]=s0; red[1][g][lc]=s1; red[2][g][lc]=s2;
    __syncthreads();
    if (g == 0){
      float t0=0.f,t1=0.f,t2=0.f;
      #pragma unroll
      for (int q2=0;q2<8;q2++){ t0+=red[0][q2][lc]; t1+=red[1][q2][lc]; t2+=red[2][q2][lc]; }
      atomicAdd(&next[r*1536 +          c], t0);
      atomicAdd(&next[r*1536 +  512 +   c], t1);
      atomicAdd(&next[r*1536 + 1024 +   c], t2);
    }
    __syncthreads();
  }
}

// final mu/counts from slot 11
__global__ __launch_bounds__(256) void mufink(const float* __restrict__ slot,
                                              float* __restrict__ mu, float* __restrict__ counts){
  int i = blockIdx.x*256 + threadIdx.x;
  if (i >= 12288) return;
  int c = i & 511; int k = (i >> 9) % 3; int r = i / 1536;
  int cs = r >> 2, img = r & 3;
  int i0 = cs*12 + img*3;
  float cnt = slot[12288 + r*3 + k];
  mu[(size_t)(i0+k)*512 + c] = slot[r*1536 + k*512 + c] / (cnt + 1e-6f);
  if (c == 0) counts[i0+k] = cnt;
}

// masked centered split planes
__global__ __launch_bounds__(256) void maskcenterk(const float* __restrict__ f4c, const float* __restrict__ f4s,
        const int* __restrict__ a, const float* __restrict__ mu,
        u16* __restrict__ Ph, u16* __restrict__ Pl){
  size_t i4 = ((size_t)blockIdx.x*256 + threadIdx.x)*4;
  if (i4 >= (size_t)PL*2) return;
  int z = (int)(i4 >> 19);
  int rc = (int)(i4 & 524287);
  int c = rc >> 10, n = rc & 1023;
  int cs = z / 12; int rem = z - cs*12; int img = rem / 3; int k = rem - img*3;
  const float* pts = (cs ? f4s : f4c) + (size_t)img*524288;
  float m = mu[(size_t)z*512 + c];
  const int* an = a + (cs*4 + img)*1024 + n;
  float4 v4 = *(const float4*)&pts[(size_t)c*1024 + n];
  float vv[4] = {v4.x, v4.y, v4.z, v4.w};
  u16x4 oh, ol;
  #pragma unroll
  for (int j=0;j<4;j++){
    float v = (an[j] == k) ? (vv[j] - m) : 0.f;
    u16 h = bf16_rne(v);
    oh[j] = (short)h;
    ol[j] = (short)bf16_rne(v - bf16f(h));
  }
  *(u16x4*)&Ph[i4] = oh;
  *(u16x4*)&Pl[i4] = ol;
}

// covariance via MFMA, trace accumulated. Tile 128x128; grid (4,4,24).
__global__ __launch_bounds__(256) void covgemm(const u16* __restrict__ Ph, const u16* __restrict__ Pl,
        const float* __restrict__ counts, float* __restrict__ Ycov, float* __restrict__ trsum){
  const int z = blockIdx.z;
  const u16* Pbh = Ph + (size_t)z*524288;
  const u16* Pbl = Pl + (size_t)z*524288;
  const int m0 = blockIdx.y*128, n0 = blockIdx.x*128;
  const int tid = threadIdx.x;

  __shared__ __align__(16) u16 sAh[128*40], sAl[128*40];
  __shared__ __align__(16) u16 sBh[128*40], sBl[128*40];

  const int ra = tid >> 2, qa = tid & 3;
  const int wid = tid >> 6, lane = tid & 63;
  const int wm = wid >> 1, wn = wid & 1;
  const int quad = lane >> 4, ln = lane & 15;

  f32x4 acc[4][4];
  #pragma unroll
  for (int i=0;i<4;i++)
    #pragma unroll
    for (int j=0;j<4;j++)
      #pragma unroll
      for (int e=0;e<4;e++) acc[i][j][e] = 0.f;

  for (int k0 = 0; k0 < 1024; k0 += 32){
    *(bf16x8*)&sAh[ra*40 + qa*8]      = *(const bf16x8*)&Pbh[(size_t)(m0+ra)*1024    + k0 + qa*8];
    *(bf16x8*)&sAl[ra*40 + qa*8]      = *(const bf16x8*)&Pbl[(size_t)(m0+ra)*1024    + k0 + qa*8];
    *(bf16x8*)&sAh[(ra+64)*40 + qa*8] = *(const bf16x8*)&Pbh[(size_t)(m0+ra+64)*1024 + k0 + qa*8];
    *(bf16x8*)&sAl[(ra+64)*40 + qa*8] = *(const bf16x8*)&Pbl[(size_t)(m0+ra+64)*1024 + k0 + qa*8];
    *(bf16x8*)&sBh[ra*40 + qa*8]      = *(const bf16x8*)&Pbh[(size_t)(n0+ra)*1024    + k0 + qa*8];
    *(bf16x8*)&sBl[ra*40 + qa*8]      = *(const bf16x8*)&Pbl[(size_t)(n0+ra)*1024    + k0 + qa*8];
    *(bf16x8*)&sBh[(ra+64)*40 + qa*8] = *(const bf16x8*)&Pbh[(size_t)(n0+ra+64)*1024 + k0 + qa*8];
    *(bf16x8*)&sBl[(ra+64)*40 + qa*8] = *(const bf16x8*)&Pbl[(size_t)(n0+ra+64)*1024 + k0 + qa*8];
    __syncthreads();

    bf16x8 ah[4], al[4], bh[4], bl[4];
    #pragma unroll
    for (int t=0;t<4;t++){
      const int moA = ((wm*4+t)*16 + ln)*40 + quad*8;
      const int moB = ((wn*4+t)*16 + ln)*40 + quad*8;
      ah[t] = *(const bf16x8*)&sAh[moA];
      al[t] = *(const bf16x8*)&sAl[moA];
      bh[t] = *(const bf16x8*)&sBh[moB];
      bl[t] = *(const bf16x8*)&sBl[moB];
    }
    #pragma unroll
    for (int mi=0;mi<4;mi++)
      #pragma unroll
      for (int ni=0;ni<4;ni++){
        acc[mi][ni] = __builtin_amdgcn_mfma_f32_16x16x32_bf16(ah[mi], bh[ni], acc[mi][ni], 0, 0, 0);
        acc[mi][ni] = __builtin_amdgcn_mfma_f32_16x16x32_bf16(ah[mi], bl[ni], acc[mi][ni], 0, 0, 0);
        acc[mi][ni] = __builtin_amdgcn_mfma_f32_16x16x32_bf16(al[mi], bh[ni], acc[mi][ni], 0, 0, 0);
      }
    __syncthreads();
  }
  const float inv = 1.f/(counts[z] + 1e-6f);
  float dsum = 0.f; bool anyd = false;
  #pragma unroll
  for (int mi=0;mi<4;mi++){
    const int mbase = m0 + (wm*4+mi)*16 + quad*4;
    #pragma unroll
    for (int ni=0;ni<4;ni++){
      const int n = n0 + (wn*4+ni)*16 + ln;
      #pragma unroll
      for (int rg=0;rg<4;rg++){
        const int m = mbase + rg;
        float v = acc[mi][ni][rg]*inv + ((m==n)?0.1f:0.f);
        Ycov[(size_t)z*MSZ + (size_t)m*512 + n] = v;
        if (m0==n0 && m==n){ dsum += v; anyd = true; }
      }
    }
  }
  if (anyd) atomicAdd(&trsum[z], dsum);
}

// init split planes: Y = Ycov/trace (hi+lo bf16), Z = I
__global__ __launch_bounds__(256) void nsinitk(const float* __restrict__ Ycov, const float* __restrict__ sval,
                                               u16* __restrict__ Yh, u16* __restrict__ Yl,
                                               u16* __restrict__ Zh, u16* __restrict__ Zl){
  size_t idx = (size_t)blockIdx.x*256 + threadIdx.x;
  if (idx >= (size_t)PL) return;
  int z = (int)(idx >> 18);
  int rc = (int)(idx & (MSZ-1));
  int rr = rc >> 9, cc = rc & 511;
  float y = Ycov[idx] / sval[z];
  u16 h = bf16_rne(y);
  Yh[idx] = h;
  Yl[idx] = bf16_rne(y - bf16f(h));
  Zh[idx] = (rr==cc) ? (u16)0x3F80 : (u16)0;
  Zl[idx] = 0;
}

// it=0 specializations (Z == I exactly):
// M = Z*Y via MFMA degenerates to elementwise resplit of (Yh+Yl) — bit-identical.
__global__ __launch_bounds__(256) void nsm0k(const u16* __restrict__ Yh, const u16* __restrict__ Yl,
                                             u16* __restrict__ Mh, u16* __restrict__ Ml){
  size_t i4 = ((size_t)blockIdx.x*256 + threadIdx.x)*4;
  if (i4 >= (size_t)PL) return;
  u16x4 hv = *(const u16x4*)&Yh[i4];
  u16x4 lv = *(const u16x4*)&Yl[i4];
  u16x4 oh, ol;
  #pragma unroll
  for (int j=0;j<4;j++){
    float v = bf16f((u16)hv[j]) + bf16f((u16)lv[j]);
    u16 h = bf16_rne(v);
    oh[j] = (short)h;
    ol[j] = (short)bf16_rne(v - bf16f(h));
  }
  *(u16x4*)&Mh[i4] = oh;
  *(u16x4*)&Ml[i4] = ol;
}

// trace of M (= sum of diag (Yh+Yl)) per z; grid 24 blocks.
__global__ __launch_bounds__(256) void nstr0k(const u16* __restrict__ Yh, const u16* __restrict__ Yl,
                                              float* __restrict__ tr){
  int z = blockIdx.x, tid = threadIdx.x;
  float s = 0.f;
  for (int i = tid; i < 512; i += 256){
    size_t o = (size_t)z*MSZ + (size_t)i*513;
    s += bf16f(Yh[o]) + bf16f(Yl[o]);
  }
  __shared__ float sh[256];
  sh[tid] = s; __syncthreads();
  for (int k=128;k>0;k>>=1){ if (tid<k) sh[tid]+=sh[tid+k]; __syncthreads(); }
  if (tid == 0) tr[z] = sh[0];
}

// it=0 Z-update: Z2 = alpha*(Mh+Ml) + beta*I (since M*Z with Z=I is elementwise-exact).
__global__ __launch_bounds__(256) void nsz0k(const u16* __restrict__ Mh, const u16* __restrict__ Ml,
                                             u16* __restrict__ Z2h, u16* __restrict__ Z2l,
                                             const float* __restrict__ trAcc){
  size_t i4 = ((size_t)blockIdx.x*256 + threadIdx.x)*4;
  if (i4 >= (size_t)PL) return;
  int z = (int)(i4 >> 18);
  int rc = (int)(i4 & (MSZ-1));
  int row = rc >> 9, col = rc & 511;
  const float tr = trAcc[z];
  const float g2 = fminf(512.f/fmaxf(tr, 1e-6f), 2.7f);
  const float oz = 0.5f*sqrtf(g2);
  const float alpha = -g2*oz, beta = 3.f*oz;
  u16x4 hv = *(const u16x4*)&Mh[i4];
  u16x4 lv = *(const u16x4*)&Ml[i4];
  u16x4 oh, ol;
  #pragma unroll
  for (int j=0;j<4;j++){
    float m = bf16f((u16)hv[j]) + bf16f((u16)lv[j]);
    float zv = (row == col + j) ? 1.f : 0.f;
    float v = alpha*m + beta*zv;
    u16 h = bf16_rne(v);
    oh[j] = (short)h;
    ol[j] = (short)bf16_rne(v - bf16f(h));
  }
  *(u16x4*)&Z2h[i4] = oh;
  *(u16x4*)&Z2l[i4] = ol;
}

// ---- split-bf16 MFMA batched GEMM 512x512x512; tile 128x128; grid (4,4,z) ----
template<int MODE>
__global__ __launch_bounds__(256) void bmms(
    const u16* __restrict__ Ah, const u16* __restrict__ Al,
    const u16* __restrict__ Bh, const u16* __restrict__ Bl,
    u16* __restrict__ Ch, u16* __restrict__ Cl,
    const float* __restrict__ osc,
    int aoff, float* __restrict__ trAcc)
{
  const int z = blockIdx.z;
  const u16* Abh = Ah + (size_t)(z+aoff)*MSZ;
  const u16* Abl = Al + (size_t)(z+aoff)*MSZ;
  const u16* Bbh = Bh + (size_t)z*MSZ;
  const u16* Bbl = Bl + (size_t)z*MSZ;
  const int m0 = blockIdx.y*128, n0 = blockIdx.x*128;
  const int tid = threadIdx.x;

  __shared__ __align__(16) u16 sAh[128*40], sAl[128*40];
  __shared__ __align__(16) u16 sBh[128*40], sBl[128*40];

  const int ra = tid >> 2, qa = tid & 3;
  const int wid = tid >> 6, lane = tid & 63;
  const int wm = wid >> 1, wn = wid & 1;
  const int quad = lane >> 4, ln = lane & 15;

  f32x4 acc[4][4];
  #pragma unroll
  for (int i=0;i<4;i++)
    #pragma unroll
    for (int j=0;j<4;j++)
      #pragma unroll
      for (int e=0;e<4;e++) acc[i][j][e] = 0.f;

  for (int k0 = 0; k0 < 512; k0 += 32){
    *(bf16x8*)&sAh[ra*40 + qa*8]      = *(const bf16x8*)&Abh[(size_t)(m0+ra)*512    + k0 + qa*8];
    *(bf16x8*)&sAl[ra*40 + qa*8]      = *(const bf16x8*)&Abl[(size_t)(m0+ra)*512    + k0 + qa*8];
    *(bf16x8*)&sAh[(ra+64)*40 + qa*8] = *(const bf16x8*)&Abh[(size_t)(m0+ra+64)*512 + k0 + qa*8];
    *(bf16x8*)&sAl[(ra+64)*40 + qa*8] = *(const bf16x8*)&Abl[(size_t)(m0+ra+64)*512 + k0 + qa*8];
    *(bf16x8*)&sBh[ra*40 + qa*8]      = *(const bf16x8*)&Bbh[(size_t)(n0+ra)*512    + k0 + qa*8];
    *(bf16x8*)&sBl[ra*40 + qa*8]      = *(const bf16x8*)&Bbl[(size_t)(n0+ra)*512    + k0 + qa*8];
    *(bf16x8*)&sBh[(ra+64)*40 + qa*8] = *(const bf16x8*)&Bbh[(size_t)(n0+ra+64)*512 + k0 + qa*8];
    *(bf16x8*)&sBl[(ra+64)*40 + qa*8] = *(const bf16x8*)&Bbl[(size_t)(n0+ra+64)*512 + k0 + qa*8];
    __syncthreads();

    bf16x8 ah[4], al[4], bh[4], bl[4];
    #pragma unroll
    for (int t=0;t<4;t++){
      const int moA = ((wm*4+t)*16 + ln)*40 + quad*8;
      const int moB = ((wn*4+t)*16 + ln)*40 + quad*8;
      ah[t] = *(const bf16x8*)&sAh[moA];
      al[t] = *(const bf16x8*)&sAl[moA];
      bh[t] = *(const bf16x8*)&sBh[moB];
      bl[t] = *(const bf16x8*)&sBl[moB];
    }
    #pragma unroll
    for (int mi=0;mi<4;mi++)
      #pragma unroll
      for (int ni=0;ni<4;ni++){
        acc[mi][ni] = __builtin_amdgcn_mfma_f32_16x16x32_bf16(ah[mi], bh[ni], acc[mi][ni], 0, 0, 0);
        acc[mi][ni] = __builtin_amdgcn_mfma_f32_16x16x32_bf16(ah[mi], bl[ni], acc[mi][ni], 0, 0, 0);
        acc[mi][ni] = __builtin_amdgcn_mfma_f32_16x16x32_bf16(al[mi], bh[ni], acc[mi][ni], 0, 0, 0);
      }
    __syncthreads();
  }

  float alpha = 1.f;
  if constexpr (MODE==2){ alpha = osc[z]; }

  float dsum = 0.f; bool anyd = false;
  #pragma unroll
  for (int mi=0;mi<4;mi++){
    const int mbase = m0 + (wm*4+mi)*16 + quad*4;
    #pragma unroll
    for (int ni=0;ni<4;ni++){
      const int n = n0 + (wn*4+ni)*16 + ln;
      #pragma unroll
      for (int rg=0;rg<4;rg++){
        const int m = mbase + rg;
        const size_t off = (size_t)z*MSZ + (size_t)m*512 + n;
        float v = alpha*acc[mi][ni][rg];
        u16 h = bf16_rne(v);
        Ch[off] = h;
        Cl[off] = bf16_rne(v - bf16f(h));
        if (MODE==0 && trAcc && m0==n0 && m==n){ dsum += v; anyd = true; }
      }
    }
  }
  if (MODE==0 && anyd) atomicAdd(&trAcc[z], dsum);
}

// merged NS update (128x128 tile)
__global__ __launch_bounds__(256) void bmmpair(
    const u16* __restrict__ Yh, const u16* __restrict__ Yl,
    const u16* __restrict__ Mh, const u16* __restrict__ Ml,
    const u16* __restrict__ Zh, const u16* __restrict__ Zl,
    u16* __restrict__ Y2h, u16* __restrict__ Y2l,
    u16* __restrict__ Z2h, u16* __restrict__ Z2l,
    const float* __restrict__ trAcc, int last)
{
  const int z = blockIdx.z;
  int zz; bool isY;
  if (last){ zz = z; isY = (z >= 12); }
  else { isY = (z < 24); zz = isY ? z : (z - 24); }
  const size_t zo = (size_t)zz*MSZ;
  const u16 *Abh, *Abl, *Bbh, *Bbl, *Dbh, *Dbl;
  u16 *Cbh, *Cbl;
  if (isY){
    Abh = Yh + zo; Abl = Yl + zo;
    Bbh = Mh + zo; Bbl = Ml + zo;
    Dbh = Yh + zo; Dbl = Yl + zo;
    Cbh = Y2h + zo; Cbl = Y2l + zo;
  } else {
    Abh = Mh + zo; Abl = Ml + zo;
    Bbh = Zh + zo; Bbl = Zl + zo;
    Dbh = Zh + zo; Dbl = Zl + zo;
    Cbh = Z2h + zo; Cbl = Z2l + zo;
  }
  const int m0 = blockIdx.y*128, n0 = blockIdx.x*128;
  const int tid = threadIdx.x;

  __shared__ __align__(16) u16 sAh[128*40], sAl[128*40];
  __shared__ __align__(16) u16 sBh[128*40], sBl[128*40];

  const int ra = tid >> 2, qa = tid & 3;
  const int wid = tid >> 6, lane = tid & 63;
  const int wm = wid >> 1, wn = wid & 1;
  const int quad = lane >> 4, ln = lane & 15;

  f32x4 acc[4][4];
  #pragma unroll
  for (int i=0;i<4;i++)
    #pragma unroll
    for (int j=0;j<4;j++)
      #pragma unroll
      for (int e=0;e<4;e++) acc[i][j][e] = 0.f;

  for (int k0 = 0; k0 < 512; k0 += 32){
    *(bf16x8*)&sAh[ra*40 + qa*8]      = *(const bf16x8*)&Abh[(size_t)(m0+ra)*512    + k0 + qa*8];
    *(bf16x8*)&sAl[ra*40 + qa*8]      = *(const bf16x8*)&Abl[(size_t)(m0+ra)*512    + k0 + qa*8];
    *(bf16x8*)&sAh[(ra+64)*40 + qa*8] = *(const bf16x8*)&Abh[(size_t)(m0+ra+64)*512 + k0 + qa*8];
    *(bf16x8*)&sAl[(ra+64)*40 + qa*8] = *(const bf16x8*)&Abl[(size_t)(m0+ra+64)*512 + k0 + qa*8];
    *(bf16x8*)&sBh[ra*40 + qa*8]      = *(const bf16x8*)&Bbh[(size_t)(n0+ra)*512    + k0 + qa*8];
    *(bf16x8*)&sBl[ra*40 + qa*8]      = *(const bf16x8*)&Bbl[(size_t)(n0+ra)*512    + k0 + qa*8];
    *(bf16x8*)&sBh[(ra+64)*40 + qa*8] = *(const bf16x8*)&Bbh[(size_t)(n0+ra+64)*512 + k0 + qa*8];
    *(bf16x8*)&sBl[(ra+64)*40 + qa*8] = *(const bf16x8*)&Bbl[(size_t)(n0+ra+64)*512 + k0 + qa*8];
    __syncthreads();

    bf16x8 ah[4], al[4], bh[4], bl[4];
    #pragma unroll
    for (int t=0;t<4;t++){
      const int moA = ((wm*4+t)*16 + ln)*40 + quad*8;
      const int moB = ((wn*4+t)*16 + ln)*40 + quad*8;
      ah[t] = *(const bf16x8*)&sAh[moA];
      al[t] = *(const bf16x8*)&sAl[moA];
      bh[t] = *(const bf16x8*)&sBh[moB];
      bl[t] = *(const bf16x8*)&sBl[moB];
    }
    #pragma unroll
    for (int mi=0;mi<4;mi++)
      #pragma unroll
      for (int ni=0;ni<4;ni++){
        acc[mi][ni] = __builtin_amdgcn_mfma_f32_16x16x32_bf16(ah[mi], bh[ni], acc[mi][ni], 0, 0, 0);
        acc[mi][ni] = __builtin_amdgcn_mfma_f32_16x16x32_bf16(ah[mi], bl[ni], acc[mi][ni], 0, 0, 0);
        acc[mi][ni] = __builtin_amdgcn_mfma_f32_16x16x32_bf16(al[mi], bh[ni], acc[mi][ni], 0, 0, 0);
      }
    __syncthreads();
  }

  const float tr = trAcc[zz];
  const float g2 = fminf(512.f/fmaxf(tr, 1e-6f), 2.7f);
  const float oz = 0.5f*sqrtf(g2);
  const float alpha = -g2*oz, beta = 3.f*oz;

  #pragma unroll
  for (int mi=0;mi<4;mi++){
    const int mbase = m0 + (wm*4+mi)*16 + quad*4;
    #pragma unroll
    for (int ni=0;ni<4;ni++){
      const int n = n0 + (wn*4+ni)*16 + ln;
      #pragma unroll
      for (int rg=0;rg<4;rg++){
        const int m = mbase + rg;
        const size_t off = (size_t)m*512 + n;
        float v = alpha*acc[mi][ni][rg] + beta*(bf16f(Dbh[off]) + bf16f(Dbl[off]));
        u16 h = bf16_rne(v);
        Cbh[off] = h;
        Cbl[off] = bf16_rne(v - bf16f(h));
      }
    }
  }
}

// tpts = T[z] @ f[img]: M=512, N=1024, K=512, fp32 out.
// B is pre-transposed fsT [img][n][c]; tile 128M x 64N; grid (16,4,12).
__global__ __launch_bounds__(256,4) void bmmt(
    const u16* __restrict__ Th, const u16* __restrict__ Tl,
    const u16* __restrict__ fh, const u16* __restrict__ fl,
    float* __restrict__ Cf)
{
  const int z = blockIdx.z;
  const u16* Abh = Th + (size_t)z*MSZ;
  const u16* Abl = Tl + (size_t)z*MSZ;
  const u16* Bbh = fh + (size_t)(z/3)*524288;
  const u16* Bbl = fl + (size_t)(z/3)*524288;
  const int m0 = blockIdx.y*128, n0 = blockIdx.x*64;
  const int tid = threadIdx.x;

  __shared__ __align__(16) u16 sAh[128*40], sAl[128*40];
  __shared__ __align__(16) u16 sBh[64*40], sBl[64*40];

  const int ra = tid >> 2, qa = tid & 3;
  const int wid = tid >> 6, lane = tid & 63;
  const int wm = wid >> 1, wn = wid & 1;
  const int quad = lane >> 4, ln = lane & 15;

  f32x4 acc[4][2];
  #pragma unroll
  for (int i=0;i<4;i++)
    #pragma unroll
    for (int j=0;j<2;j++)
      #pragma unroll
      for (int e=0;e<4;e++) acc[i][j][e] = 0.f;

  for (int k0 = 0; k0 < 512; k0 += 32){
    *(bf16x8*)&sAh[ra*40 + qa*8]      = *(const bf16x8*)&Abh[(size_t)(m0+ra)*512    + k0 + qa*8];
    *(bf16x8*)&sAl[ra*40 + qa*8]      = *(const bf16x8*)&Abl[(size_t)(m0+ra)*512    + k0 + qa*8];
    *(bf16x8*)&sAh[(ra+64)*40 + qa*8] = *(const bf16x8*)&Abh[(size_t)(m0+ra+64)*512 + k0 + qa*8];
    *(bf16x8*)&sAl[(ra+64)*40 + qa*8] = *(const bf16x8*)&Abl[(size_t)(m0+ra+64)*512 + k0 + qa*8];
    *(bf16x8*)&sBh[ra*40 + qa*8]      = *(const bf16x8*)&Bbh[(size_t)(n0+ra)*512    + k0 + qa*8];
    *(bf16x8*)&sBl[ra*40 + qa*8]      = *(const bf16x8*)&Bbl[(size_t)(n0+ra)*512    + k0 + qa*8];
    __syncthreads();

    bf16x8 ah[4], al[4], bh[2], bl[2];
    #pragma unroll
    for (int t=0;t<4;t++){
      const int moA = ((wm*4+t)*16 + ln)*40 + quad*8;
      ah[t] = *(const bf16x8*)&sAh[moA];
      al[t] = *(const bf16x8*)&sAl[moA];
    }
    #pragma unroll
    for (int t=0;t<2;t++){
      const int moB = ((wn*2+t)*16 + ln)*40 + quad*8;
      bh[t] = *(const bf16x8*)&sBh[moB];
      bl[t] = *(const bf16x8*)&sBl[moB];
    }
    #pragma unroll
    for (int mi=0;mi<4;mi++)
      #pragma unroll
      for (int ni=0;ni<2;ni++){
        acc[mi][ni] = __builtin_amdgcn_mfma_f32_16x16x32_bf16(ah[mi], bh[ni], acc[mi][ni], 0, 0, 0);
        acc[mi][ni] = __builtin_amdgcn_mfma_f32_16x16x32_bf16(ah[mi], bl[ni], acc[mi][ni], 0, 0, 0);
        acc[mi][ni] = __builtin_amdgcn_mfma_f32_16x16x32_bf16(al[mi], bh[ni], acc[mi][ni], 0, 0, 0);
      }
    __syncthreads();
  }
  #pragma unroll
  for (int mi=0;mi<4;mi++){
    const int mbase = m0 + (wm*4+mi)*16 + quad*4;
    #pragma unroll
    for (int ni=0;ni<2;ni++){
      const int n = n0 + (wn*2+ni)*16 + ln;
      #pragma unroll
      for (int rg=0;rg<4;rg++){
        const int m = mbase + rg;
        Cf[(size_t)z*524288 + (size_t)m*1024 + n] = acc[mi][ni][rg];
      }
    }
  }
}

__global__ void make_scalesk(const float* __restrict__ sval, float* __restrict__ scl){
  int i = threadIdx.x;
  if (i < 12) scl[i] = sqrtf(sval[12+i] / sval[i]);
}

// tvec[b] = mu_s[b] - T[b] @ mu_c[b]
__global__ __launch_bounds__(512) void tveck(const u16* __restrict__ Th, const u16* __restrict__ Tl,
                                             const float* __restrict__ mu, float* __restrict__ tvec){
  int b = blockIdx.x; int c = threadIdx.x;
  __shared__ float mc[512];
  mc[c] = mu[(size_t)b*512 + c];
  __syncthreads();
  const u16* Trh = Th + ((size_t)b*512 + c)*512;
  const u16* Trl = Tl + ((size_t)b*512 + c)*512;
  float s = 0.f;
  for (int d=0; d<512; d++) s = fmaf(bf16f(Trh[d]) + bf16f(Trl[d]), mc[d], s);
  tvec[b*512 + c] = mu[(size_t)(12+b)*512 + c] - s;
}

__global__ __launch_bounds__(256) void selectk(const float* __restrict__ tpts, const float* __restrict__ tvec,
        const int* __restrict__ a, const float* __restrict__ f4c, float* __restrict__ tf){
  size_t idx = (size_t)blockIdx.x*256 + threadIdx.x;
  if (idx >= 2097152ul) return;
  int n = (int)(idx & 1023);
  int c = (int)((idx >> 10) & 511);
  int img = (int)(idx >> 19);
  int k = a[img*1024 + n];
  int b = img*3 + k;
  float v = tpts[((size_t)b*512 + c)*1024 + n] + tvec[b*512 + c];
  tf[idx] = 0.6f*v + 0.4f*f4c[idx];
}

__global__ __launch_bounds__(256) void clossk(const float* __restrict__ x, const float* __restrict__ y,
                                              int n, float* __restrict__ acc){
  int tid = threadIdx.x;
  float s = 0.f;
  for (size_t i = (size_t)blockIdx.x*256 + tid; i < (size_t)n; i += (size_t)gridDim.x*256){
    float d = x[i] - y[i]; s = fmaf(d, d, s);
  }
  __shared__ float sh[256];
  sh[tid] = s; __syncthreads();
  for (int k=128;k>0;k>>=1){ if (tid<k) sh[tid]+=sh[tid+k]; __syncthreads(); }
  if (tid==0) atomicAdd(acc, sh[0]);
}

__global__ __launch_bounds__(256) void finalk(const float* __restrict__ sm, float* __restrict__ out){
  int tid = threadIdx.x;
  const int cnts[4] = {256,512,1024,2048};
  const int offs[4] = {0,256,768,1792};
  const float* mS = sm + SM_STATS_S;
  const float* sS = sm + SM_STATS_S + 3840;
  const float* mD = sm + SM_STATS_D;
  const float* sD = sm + SM_STATS_D + 3840;
  double sl = 0.0;
  for (int L=0; L<4; ++L){
    int cnt = cnts[L], off = offs[L];
    double inv = 1.0/cnt;
    for (int i=tid; i<cnt; i+=256){
      double dm = (double)mD[off+i] - (double)mS[off+i];
      double ds = (double)sD[off+i] - (double)sS[off+i];
      sl += (dm*dm + ds*ds)*inv;
    }
  }
  __shared__ double sh[256];
  sh[tid] = sl; __syncthreads();
  for (int k=128;k>0;k>>=1){ if (tid<k) sh[tid]+=sh[tid+k]; __syncthreads(); }
  if (tid==0){
    double closs = (double)sm[SM_CLOSS] / 2097152.0;
    out[0] = (float)(closs + 0.01*sh[0]);
  }
}

// ---------------- host ----------------

extern "C" void kernel_launch(void* const* d_in, const int* in_sizes, int n_in,
                              void* d_out, int out_size, void* d_ws, size_t ws_size,
                              hipStream_t stream)
{
  const float* content = (const float*)d_in[0];
  const float* style   = (const float*)d_in[1];
  const float* Wm[8]; const float* Bm[8];
  for (int i=0;i<8;i++){ Wm[i] = (const float*)d_in[2+2*i]; Bm[i] = (const float*)d_in[3+2*i]; }
  float* out = (float*)d_out;
  float* ws = (float*)d_ws;

  float* f4c  = ws + OFF_F4C;
  float* f4s  = ws + OFF_F4S;
  float* tf   = ws + OFF_TF;
  float* dec  = ws + OFF_DEC;
  float* sm   = ws + OFF_SMALL;
  float* AR   = ws + OFF_ARENA;
  int*   aPtr = (int*)(sm + SM_ASSIGN);
  float* mu   = sm + SM_MU;
  float* counts = sm + SM_COUNTS;
  float* sval = sm + SM_SVAL;
  float* scl  = sm + SM_SCALE;
  float* tvec = sm + SM_TVEC;
  float* trbuf = sm + SM_TR;

  u16* WB = (u16*)(ws + OFF_WSPL);
  u16 *w2h=WB+0,       *w2l=WB+73728;
  u16 *w3h=WB+147456,  *w3l=WB+442368;
  u16 *w4h=WB+737280,  *w4l=WB+1916928;
  u16 *v1h=WB+3096576, *v1l=WB+4276224;
  u16 *v2h=WB+5455872, *v2l=WB+5750784;
  u16 *v3h=WB+6045696, *v3l=WB+6119424;

  float* Ycov = AR;
  u16* Mh  = (u16*)(AR);
  u16* Ml  = (u16*)(AR + 3145728ul);
  u16* Yh  = (u16*)(AR + 6291456ul);
  u16* Yl  = (u16*)(AR + 9437184ul);
  u16* Zh  = (u16*)(AR + 12582912ul);
  u16* Zl  = (u16*)(AR + 15728640ul);
  u16* Y2h = (u16*)(AR + 18874368ul);
  u16* Y2l = (u16*)(AR + 22020096ul);
  u16* Z2h = (u16*)(AR + 25165824ul);
  u16* Z2l = (u16*)(AR + 28311552ul);
  u16* Ph  = (u16*)(AR + 18874368ul);
  u16* Pl  = (u16*)(AR + 25165824ul);
  float* ptsT = AR + 25165824ul;
  u16* Th  = (u16*)(AR + 18874368ul);
  u16* Tl  = (u16*)(AR + 20971520ul);
  u16* fsh = (u16*)(AR + 23068672ul);
  u16* fsl = (u16*)(AR + 24117248ul);
  float* KACC = AR + 0;

  // NHWC split-bf16 activation planes (u16), placed in lifetime-dead arena slots.
  // encode (B=8):
  u16* xP1h  = (u16*)(AR + 16777216ul);   // 8*128*128*64 u16 -> 4.19M floats
  u16* xP1l  = (u16*)(AR + 20971520ul);
  u16* xF2ph = (u16*)(AR + 16777216ul);   // pooled F2: 8*64*64*128
  u16* xF2pl = (u16*)(AR + 18874368ul);
  u16* xF3ph = (u16*)(AR + 18874368ul);   // pooled F3: 8*32*32*256 (clear of PART8)
  u16* xF3pl = (u16*)(AR + 19922944ul);
  // decode (B=4):
  u16* xTFh  = (u16*)(AR + 8388608ul);    // 4*32*32*512
  u16* xTFl  = (u16*)(AR + 9437184ul);
  u16* xX1h  = (u16*)(AR + 1048576ul);    // 4*32*32*256
  u16* xX1l  = (u16*)(AR + 1572864ul);
  u16* xX2h  = (u16*)(AR + 11534336ul);   // 4*64*64*128
  u16* xX2l  = (u16*)(AR + 12582912ul);
  // decoded encode (B=4):
  u16* xP1dh = (u16*)(AR + 16777216ul);   // 4*128*128*64
  u16* xP1dl = (u16*)(AR + 18874368ul);
  u16* xF2dph= (u16*)(AR + 16777216ul);   // pooled F2d: 4*64*64*128
  u16* xF2dpl= (u16*)(AR + 17825792ul);
  u16* xF3dph= (u16*)(AR + 16777216ul);   // pooled F3d: 4*32*32*256
  u16* xF3dpl= (u16*)(AR + 17301504ul);

  zerok<<<512,256,0,stream>>>(sm, 131072);

  {
    auto wsp = [&](int li, u16* wh, u16* wl, int Co, int Ci){
      int n = 9*Co*Ci;
      wsplitk<<<(n+255)/256,256,0,stream>>>(Wm[li], wh, wl, Co, Ci);
    };
    wsp(1,w2h,w2l,128,64);
    wsp(2,w3h,w3l,256,128);
    wsp(3,w4h,w4l,512,256);
    wsp(4,v1h,v1l,256,512);
    wsp(5,v2h,v2l,128,256);
    wsp(6,v3h,v3l,64,128);
  }

  // MFMA conv on pre-split NHWC u16 input. KS in {1,2,4}, RZ in {0,2}.
  auto convMFMA = [&](const u16* xh, const u16* xl, int li, float* outp,
                      int B,int Ci,int Co,int H,int Wd,int relu,int KS,int RZ,float* part){
    const u16 *wh=nullptr,*wl=nullptr;
    switch(li){
      case 1: wh=w2h; wl=w2l; break;
      case 2: wh=w3h; wl=w3l; break;
      case 3: wh=w4h; wl=w4l; break;
      case 4: wh=v1h; wl=v1l; break;
      case 5: wh=v2h; wl=v2l; break;
      case 6: wh=v3h; wl=v3l; break;
    }
    int tiles = (H>>3)*(Wd>>4);
    if (KS==1){
      dim3 g(tiles,Co>>6,B);
      if (RZ==0) convm<1,0><<<g,256,0,stream>>>(xh,xl,wh,wl,Bm[li],outp,Ci,Co,H,Wd,relu);
      else       convm<1,2><<<g,256,0,stream>>>(xh,xl,wh,wl,Bm[li],outp,Ci,Co,H,Wd,relu);
    } else if (KS==2){
      dim3 g(tiles,Co>>6,B*2);
      if (RZ==0) convm<2,0><<<g,256,0,stream>>>(xh,xl,wh,wl,nullptr,part,Ci,Co,H,Wd,relu);
      else       convm<2,2><<<g,256,0,stream>>>(xh,xl,wh,wl,nullptr,part,Ci,Co,H,Wd,relu);
      int n = B*Co*H*Wd;
      sumk<<<(n+255)/256,256,0,stream>>>(part,Bm[li],outp,Co,H*Wd,2,relu,n);
    } else {
      dim3 g(tiles,Co>>6,B*4);
      convm<4,0><<<g,256,0,stream>>>(xh,xl,wh,wl,nullptr,part,Ci,Co,H,Wd,relu);
      int n = B*Co*H*Wd;
      sumk<<<(n+255)/256,256,0,stream>>>(part,Bm[li],outp,Co,H*Wd,4,relu,n);
    }
  };

  float* mS = sm + SM_STATS_S;
  float* sS = sm + SM_STATS_S + 3840;

  // ---- batched content+style encode (B=8 from e2 down) ----
  float* F1   = AR + 0;
  float* F2_8 = AR + 0;
  float* F3_8 = AR + 0;
  float* PART8 = AR + 10485760ul;

  {
    dim3 ge(64, 8, 4);  // (256/32)^2 tiles, 64/8 co-groups, B=4
    // content e1: fp32 output is dead (style overwrites F1 before any reader) -> OUTW=0
    conv3x3<8,4,1,0,0><<<ge,256,0,stream>>>(content,Wm[0],Bm[0],F1,xP1h,           xP1l,           4,3,64,256,256,1);
    conv3x3<8,4,1,1,0><<<ge,256,0,stream>>>(style,  Wm[0],Bm[0],F1,xP1h+4194304ul, xP1l+4194304ul, 4,3,64,256,256,1);
  }
  statsk<<<256,256,0,stream>>>(F1,65536, mS+0, sS+0);

  convMFMA(xP1h,xP1l, 1, F2_8, 8, 64,128,128,128,1,1,0,nullptr);
  statsk<<<512,256,0,stream>>>(F2_8 + 8388608ul, 16384, mS+256, sS+256);
  repackk<1><<<dim3(128,2,8),256,0,stream>>>(F2_8, xF2ph, xF2pl, 128,64,64);
  convMFMA(xF2ph,xF2pl, 2, F3_8, 8, 128,256,64,64,1,1,0,nullptr);
  statsk<<<1024,256,0,stream>>>(F3_8 + 4194304ul, 4096, mS+768, sS+768);
  repackk<1><<<dim3(32,4,8),256,0,stream>>>(F3_8, xF3ph, xF3pl, 256,32,32);
  convMFMA(xF3ph,xF3pl, 3, f4c, 8, 256,512,32,32,1,2,0,PART8);
  statsk<<<2048,256,0,stream>>>(f4s,1024, mS+1792, sS+1792);

  // ---- fused k-means ----
  transposek<<<dim3(32,16,8),256,0,stream>>>(f4c,f4s,ptsT);
  zerok<<<(12*KSLOT+255)/256,256,0,stream>>>(KACC, 12*KSLOT);
  initcent2k<<<48,256,0,stream>>>(ptsT,KACC);
  for (int it=0; it<=10; ++it){
    kstepk<<<dim3(8,32),256,0,stream>>>(ptsT, KACC + (size_t)it*KSLOT, KACC + (size_t)(it+1)*KSLOT, aPtr, it==0 ? 1 : 0);
  }
  mufink<<<48,256,0,stream>>>(KACC + 11ul*KSLOT, mu, counts);

  // ---- covariances via MFMA ----
  maskcenterk<<<12288,256,0,stream>>>(f4c,f4s,aPtr,mu,Ph,Pl);
  covgemm<<<dim3(4,4,24),256,0,stream>>>(Ph,Pl,counts,Ycov,sval);
  nsinitk<<<24576,256,0,stream>>>(Ycov,sval,Yh,Yl,Zh,Zl);

  // ---- split-bf16 MFMA Newton-Schulz ----
  u16 *Ych=Yh,*Ycl=Yl,*Zch=Zh,*Zcl=Zl,*Yah=Y2h,*Yal=Y2l,*Zah=Z2h,*Zal=Z2l;
  for (int it=0; it<NS_ITERS; ++it){
    if (it == 0){
      // Z == I: M = resplit(Y) elementwise (bit-identical to MFMA with identity operand)
      nsm0k<<<6144,256,0,stream>>>(Ych,Ycl,Mh,Ml);
      nstr0k<<<24,256,0,stream>>>(Ych,Ycl,trbuf);
      // Y-update via GEMM (z<24 of last=0 path); Z-update elementwise
      bmmpair<<<dim3(4,4,24),256,0,stream>>>(Ych,Ycl,Mh,Ml,Zch,Zcl,Yah,Yal,Zah,Zal,trbuf,0);
      nsz0k<<<6144,256,0,stream>>>(Mh,Ml,Zah,Zal,trbuf);
    } else {
      bmms<0><<<dim3(4,4,24),256,0,stream>>>(Zch,Zcl,Ych,Ycl,Mh,Ml,nullptr,0,trbuf+it*24);
      if (it < NS_ITERS-1)
        bmmpair<<<dim3(4,4,48),256,0,stream>>>(Ych,Ycl,Mh,Ml,Zch,Zcl,Yah,Yal,Zah,Zal,trbuf+it*24,0);
      else
        bmmpair<<<dim3(4,4,24),256,0,stream>>>(Ych,Ycl,Mh,Ml,Zch,Zcl,Yah,Yal,Zah,Zal,trbuf+it*24,1);
    }
    u16* t;
    t=Ych;Ych=Yah;Yah=t; t=Ycl;Ycl=Yal;Yal=t;
    t=Zch;Zch=Zah;Zah=t; t=Zcl;Zcl=Zal;Zal=t;
  }
  make_scalesk<<<1,64,0,stream>>>(sval,scl);
  bmms<2><<<dim3(4,4,12),256,0,stream>>>(Ych,Ycl,Zch,Zcl,Th,Tl,scl,12,nullptr);
  tveck<<<12,512,0,stream>>>(Th,Tl,mu,tvec);
  // f4c [img][c][n] -> fsT [img][n][c] split-bf16 (transposing repack; N=1024=32x32)
  repackk<0><<<dim3(32,8,4),256,0,stream>>>(f4c, fsh, fsl, 512,32,32);
  float* Mb = AR + 0;
  bmmt<<<dim3(16,4,12),256,0,stream>>>(Th,Tl,fsh,fsl,Mb);
  selectk<<<8192,256,0,stream>>>(Mb,tvec,aPtr,f4c,tf);

  // ---- decode (B=4; up fused into d2/d3 via RZ=2; d4 via dedicated d4upk) ----
  float* X1 = AR + 0;
  float* X2 = AR + 5242880ul;
  float* X3 = AR + 0;
  float* PARTA = AR + 2097152ul;
  float* PARTB = AR + 7340032ul;
  repackk<0><<<dim3(32,8,4),256,0,stream>>>(tf, xTFh, xTFl, 512,32,32);
  convMFMA(xTFh,xTFl, 4, X1, 4, 512,256,32,32,1,4,0,PARTA);
  repackk<0><<<dim3(32,4,4),256,0,stream>>>(X1, xX1h, xX1l, 256,32,32);
  convMFMA(xX1h,xX1l, 5, X2, 4, 256,128,64,64,1,2,2,PARTB);
  repackk<0><<<dim3(128,2,4),256,0,stream>>>(X2, xX2h, xX2l, 128,64,64);
  convMFMA(xX2h,xX2l, 6, X3, 4, 128,64,128,128,1,1,2,nullptr);
  d4upk<<<dim3(256,1,4),256,0,stream>>>(X3, Wm[7], Bm[7], dec);

  // ---- decoded encode + stats + content loss (B=4) ----
  float* mD = sm + SM_STATS_D;
  float* sD = sm + SM_STATS_D + 3840;
  float* F1d = AR + 0;
  float* F2d = AR + 0;
  float* F3d = AR + 10485760ul;
  {
    dim3 ge(64, 8, 4);
    conv3x3<8,4,1,1,0><<<ge,256,0,stream>>>(dec,Wm[0],Bm[0],F1d,xP1dh,xP1dl,4,3,64,256,256,1);
  }
  statsk<<<256,256,0,stream>>>(F1d,65536, mD+0, sD+0);
  convMFMA(xP1dh,xP1dl, 1, F2d, 4, 64,128,128,128,1,1,0,nullptr);
  statsk<<<512,256,0,stream>>>(F2d,16384, mD+256, sD+256);
  repackk<1><<<dim3(128,2,4),256,0,stream>>>(F2d, xF2dph, xF2dpl, 128,64,64);
  convMFMA(xF2dph,xF2dpl, 2, F3d, 4, 128,256,64,64,1,1,0,nullptr);
  statsk<<<1024,256,0,stream>>>(F3d,4096, mD+768, sD+768);
  repackk<1><<<dim3(32,4,4),256,0,stream>>>(F3d, xF3dph, xF3dpl, 256,32,32);
  convMFMA(xF3dph,xF3dpl, 3, tf, 4, 256,512,32,32,1,2,0,PARTA);
  statsk<<<2048,256,0,stream>>>(tf,1024, mD+1792, sD+1792);
  clossk<<<2048,256,0,stream>>>(tf,f4c,2097152, sm+SM_CLOSS);
  finalk<<<1,256,0,stream>>>(sm,out);
}

// Round 9
// 2102.277 us; speedup vs baseline: 1.1313x; 1.0593x over previous
//
#include <hip/hip_runtime.h>
#include <cstddef>

#define NS_ITERS 8
#define MSZ 262144  // 512*512
#define PL  6291456 // 24*MSZ
#define KSLOT 12312 // k-means accumulator slot stride (floats)

typedef unsigned short u16;
typedef __attribute__((ext_vector_type(8))) short bf16x8;
typedef __attribute__((ext_vector_type(4))) float f32x4;
typedef __attribute__((ext_vector_type(4))) short u16x4;

__device__ inline u16 bf16_rne(float x){
  unsigned u = __float_as_uint(x);
  unsigned r = u + 0x7fffu + ((u>>16)&1u);
  return (u16)(r>>16);
}
__device__ inline float bf16f(u16 h){
  return __uint_as_float(((unsigned)h)<<16);
}

// ---------------- workspace offsets (in floats) ----------------
#define OFF_F4C   0ul
#define OFF_F4S   2097152ul
#define OFF_TF    4194304ul
#define OFF_DEC   6291456ul
#define OFF_WSPL  7077888ul
#define OFF_SMALL 10223616ul
#define OFF_ARENA 10354688ul

// SMALL sub-offsets (floats)
#define SM_ASSIGN  12288
#define SM_MU      20480
#define SM_COUNTS  32768
#define SM_SVAL    32800
#define SM_SCALE   32832
#define SM_TVEC    32864
#define SM_STATS_S 39008
#define SM_STATS_D 46688
#define SM_CLOSS   54368
#define SM_TR      54464
#define SM_SPART   60000  // chunked-stats partial sums (doubles; 8B-aligned: 60000*4 % 8 == 0)

// ---------------- kernels ----------------

__global__ __launch_bounds__(256) void zerok(float* p, int n){
  int i = blockIdx.x*256 + threadIdx.x;
  if (i < n) p[i] = 0.f;
}

// direct 3x3 SAME conv (for e1: Cin=3)
template<int COT, int CIT, int POOL, int OUTW, int RZ>
__global__ __launch_bounds__(256,4) void conv3x3(
    const float* __restrict__ in, const float* __restrict__ wgt,
    const float* __restrict__ bias, float* __restrict__ out,
    u16* __restrict__ poh, u16* __restrict__ pol,
    int B, int Cin, int Cout, int H, int W, int relu)
{
  __shared__ float s_in[CIT][34][34];
  __shared__ float s_w[COT][CIT][9];
  const int tid = threadIdx.x;
  const int tx = tid & 15, ty = tid >> 4;
  const int tilesW = W >> 5;
  const int h0 = (blockIdx.x / tilesW) << 5;
  const int w0 = (blockIdx.x % tilesW) << 5;
  const int co0 = blockIdx.y * COT;
  const int b = blockIdx.z;
  float acc[COT][2][2];
  #pragma unroll
  for (int o=0;o<COT;o++){acc[o][0][0]=0.f;acc[o][0][1]=0.f;acc[o][1][0]=0.f;acc[o][1][1]=0.f;}
  const int y0 = ty*2, x0 = tx*2;
  for (int ci0 = 0; ci0 < Cin; ci0 += CIT){
    const int cic = (Cin - ci0 < CIT) ? (Cin - ci0) : CIT;
    const int tot = cic*1156;
    for (int e = tid; e < tot; e += 256){
      int c = e / 1156; int r = e - c*1156;
      int lh = r / 34, lw = r - lh*34;
      int ih = h0 + lh - 1, iw = w0 + lw - 1;
      float v = 0.f;
      if ((unsigned)ih < (unsigned)H && (unsigned)iw < (unsigned)W){
        if constexpr (RZ==2)
          v = in[((size_t)(b*Cin + ci0 + c)*(H>>1) + (ih>>1))*(size_t)(W>>1) + (iw>>1)];
        else
          v = in[((size_t)(b*Cin + ci0 + c)*H + ih)*W + iw];
      }
      s_in[c][lh][lw] = v;
    }
    const int wtot = COT*cic*9;
    for (int e = tid; e < wtot; e += 256){
      int o = e / (cic*9); int r = e - o*(cic*9);
      int c = r / 9, t = r - c*9;
      int co = co0 + o;
      float v = 0.f;
      if (co < Cout) v = wgt[(size_t)(co*Cin + ci0 + c)*9 + t];
      s_w[o][c][t] = v;
    }
    __syncthreads();
    for (int c = 0; c < cic; ++c){
      float p[4][4];
      #pragma unroll
      for (int r=0;r<4;r++)
        #pragma unroll
        for (int s=0;s<4;s++)
          p[r][s] = s_in[c][y0+r][x0+s];
      #pragma unroll
      for (int dh=0; dh<3; dh++)
        #pragma unroll
        for (int dw=0; dw<3; dw++){
          #pragma unroll
          for (int o=0;o<COT;o++){
            float wv = s_w[o][c][dh*3+dw];
            acc[o][0][0] = fmaf(p[dh  ][dw  ], wv, acc[o][0][0]);
            acc[o][0][1] = fmaf(p[dh  ][dw+1], wv, acc[o][0][1]);
            acc[o][1][0] = fmaf(p[dh+1][dw  ], wv, acc[o][1][0]);
            acc[o][1][1] = fmaf(p[dh+1][dw+1], wv, acc[o][1][1]);
          }
        }
    }
    __syncthreads();
  }
  if constexpr (POOL){
    bf16x8 p8h, p8l;
    #pragma unroll
    for (int o=0;o<COT;o++){
      const int co = co0 + o;
      const float bv = bias[co];
      float v00 = fmaxf(acc[o][0][0]+bv, 0.f);
      float v01 = fmaxf(acc[o][0][1]+bv, 0.f);
      float v10 = fmaxf(acc[o][1][0]+bv, 0.f);
      float v11 = fmaxf(acc[o][1][1]+bv, 0.f);
      if constexpr (OUTW){
        *(float2*)&out[((size_t)(b*Cout + co)*H + h0+y0  )*W + w0+x0] = make_float2(v00, v01);
        *(float2*)&out[((size_t)(b*Cout + co)*H + h0+y0+1)*W + w0+x0] = make_float2(v10, v11);
      }
      // same order as pool2k: p[0]+p[1]+p[2W]+p[2W+1]
      float pv = 0.25f*(v00 + v01 + v10 + v11);
      u16 h = bf16_rne(pv);
      p8h[o] = (short)h;
      p8l[o] = (short)bf16_rne(pv - bf16f(h));
    }
    size_t po = ((size_t)(b*(H>>1) + ((h0+y0)>>1))*(W>>1) + ((w0+x0)>>1))*(size_t)Cout + co0;
    *(bf16x8*)&poh[po] = p8h;
    *(bf16x8*)&pol[po] = p8l;
  } else {
    #pragma unroll
    for (int o=0;o<COT;o++){
      int co = co0 + o;
      if (co >= Cout) continue;
      float bv = bias[co];
      float v00 = acc[o][0][0] + bv;
      float v01 = acc[o][0][1] + bv;
      float v10 = acc[o][1][0] + bv;
      float v11 = acc[o][1][1] + bv;
      if (relu){
        v00 = fmaxf(v00, 0.f); v01 = fmaxf(v01, 0.f);
        v10 = fmaxf(v10, 0.f); v11 = fmaxf(v11, 0.f);
      }
      *(float2*)&out[((size_t)(b*Cout + co)*H + h0+y0  )*W + w0+x0] = make_float2(v00, v01);
      *(float2*)&out[((size_t)(b*Cout + co)*H + h0+y0+1)*W + w0+x0] = make_float2(v10, v11);
    }
  }
}

// dedicated d4: Cin=64 -> Cout=3, 256x256 out, nearest-up2 fused (input 128x128 fp32 NCHW).
__global__ __launch_bounds__(256,4) void d4upk(
    const float* __restrict__ in, const float* __restrict__ wgt,
    const float* __restrict__ bias, float* __restrict__ out)
{
  __shared__ float s_in[64][10][10];
  __shared__ float s_w[3][64][9];
  const int tid = threadIdx.x;
  const int b = blockIdx.z;
  const int h0 = (blockIdx.x >> 4) << 4, w0 = (blockIdx.x & 15) << 4;
  const int r0 = (h0 >> 1) - 1, c0 = (w0 >> 1) - 1;
  for (int e = tid; e < 6400; e += 256){
    int c = e / 100, r = e - c*100;
    int lr = r / 10, lc = r - lr*10;
    int gr = r0 + lr, gc = c0 + lc;
    float v = 0.f;
    if ((unsigned)gr < 128u && (unsigned)gc < 128u)
      v = in[((size_t)(b*64 + c)*128 + gr)*128 + gc];
    s_in[c][lr][lc] = v;
  }
  for (int e = tid; e < 1728; e += 256){
    int o = e / 576, r = e - o*576;
    int ci = r / 9, t = r - ci*9;
    s_w[o][ci][t] = wgt[(size_t)(o*64 + ci)*9 + t];
  }
  __syncthreads();
  const int ty = tid >> 4, tx = tid & 15;
  const int oh = h0 + ty, ow = w0 + tx;
  int lr3[3], lc3[3]; bool vr3[3], vc3[3];
  #pragma unroll
  for (int d=0; d<3; d++){
    int ih = oh + d - 1;
    vr3[d] = (unsigned)ih < 256u;
    lr3[d] = (ih >> 1) - r0;
    int iw = ow + d - 1;
    vc3[d] = (unsigned)iw < 256u;
    lc3[d] = (iw >> 1) - c0;
  }
  float a0 = 0.f, a1 = 0.f, a2 = 0.f;
  for (int ci = 0; ci < 64; ++ci){
    #pragma unroll
    for (int dh=0; dh<3; dh++){
      #pragma unroll
      for (int dw=0; dw<3; dw++){
        float v = (vr3[dh] && vc3[dw]) ? s_in[ci][lr3[dh]][lc3[dw]] : 0.f;
        a0 = fmaf(v, s_w[0][ci][dh*3+dw], a0);
        a1 = fmaf(v, s_w[1][ci][dh*3+dw], a1);
        a2 = fmaf(v, s_w[2][ci][dh*3+dw], a2);
      }
    }
  }
  out[((size_t)(b*3 + 0)*256 + oh)*256 + ow] = a0 + bias[0];
  out[((size_t)(b*3 + 1)*256 + oh)*256 + ow] = a1 + bias[1];
  out[((size_t)(b*3 + 2)*256 + oh)*256 + ow] = a2 + bias[2];
}

// pre-split conv weights: dst[(dhw*Cout + co)*Cin + ci]
__global__ __launch_bounds__(256) void wsplitk(const float* __restrict__ wgt,
                                               u16* __restrict__ dh_, u16* __restrict__ dl_,
                                               int Cout, int Cin){
  int idx = blockIdx.x*256 + threadIdx.x;
  int n = 9*Cout*Cin;
  if (idx >= n) return;
  int cc = Cout*Cin;
  int dhw = idx / cc;
  int r = idx - dhw*cc;
  int co = r / Cin, ci = r - co*Cin;
  float v = wgt[((size_t)co*Cin + ci)*9 + dhw];
  u16 h = bf16_rne(v);
  dh_[idx] = h;
  dl_[idx] = bf16_rne(v - bf16f(h));
}

// fp32 NCHW -> split-bf16 NHWC repack (POOL=1: fused avg-pool2, input 2Ho x 2Wo)
// grid: (Ho*Wo/32, C/64, B)
template<int POOL>
__global__ __launch_bounds__(256) void repackk(const float* __restrict__ in,
    u16* __restrict__ oh, u16* __restrict__ ol, int C, int Ho, int Wo)
{
  __shared__ unsigned tr[64][33];
  const int N = Ho*Wo;
  const int n0 = blockIdx.x << 5, c0 = blockIdx.y << 6, b = blockIdx.z;
  const int lnn = threadIdx.x & 31, gc = threadIdx.x >> 5;
  {
    const int n = n0 + lnn;
    const int ho = n / Wo, wo = n - ho*Wo;
    #pragma unroll
    for (int i=0;i<8;i++){
      const int c = (gc<<3) + i;
      float v;
      if constexpr (POOL){
        const float* p = in + ((size_t)(b*C + c0+c)*(Ho*2) + ho*2)*(size_t)(Wo*2) + (size_t)wo*2;
        v = 0.25f*(p[0] + p[1] + p[2*Wo] + p[2*Wo+1]);
      } else {
        v = in[((size_t)(b*C + c0+c))*N + n];
      }
      u16 h = bf16_rne(v);
      tr[c][lnn] = (unsigned)h | ((unsigned)bf16_rne(v - bf16f(h)) << 16);
    }
  }
  __syncthreads();
  const int n2 = threadIdx.x >> 3, oct = threadIdx.x & 7;
  bf16x8 vh, vl;
  #pragma unroll
  for (int j=0;j<8;j++){
    unsigned u = tr[(oct<<3)+j][n2];
    vh[j] = (short)(u & 0xffffu);
    vl[j] = (short)(u >> 16);
  }
  size_t o = ((size_t)b*N + (n0 + n2))*(size_t)C + c0 + (oct<<3);
  *(bf16x8*)&oh[o] = vh;
  *(bf16x8*)&ol[o] = vl;
}

// ---- split-bf16 MFMA direct conv 3x3 SAME; input pre-split NHWC u16 planes ----
// Tile: 64 co x (8x16) px; W staged per (dh,dw) tap. Bit-exact order.
template<int KS, int RESIZE>
__global__ __launch_bounds__(256,4) void convm(
    const u16* __restrict__ xh, const u16* __restrict__ xl,
    const u16* __restrict__ wsh, const u16* __restrict__ wsl,
    const float* __restrict__ bias, float* __restrict__ out,
    int Cin, int Cout, int H, int W, int relu)
{
  const int tilesW = W >> 4;
  const int h0 = (blockIdx.x / tilesW) << 3;
  const int w0 = (blockIdx.x % tilesW) << 4;
  const int co0 = blockIdx.y << 6;
  const int b  = blockIdx.z / KS;
  const int ks = blockIdx.z % KS;
  const int NB = gridDim.z / KS;
  const int tid = threadIdx.x;
  const int wid = tid >> 6, lane = tid & 63;
  const int wm = wid >> 1, wn = wid & 1;
  const int quad = lane >> 4, ln = lane & 15;

  __shared__ __align__(16) u16 sXh[180*40], sXl[180*40];
  __shared__ __align__(16) u16 sWh[64*40],  sWl[64*40];

  f32x4 acc[2][4];
  #pragma unroll
  for (int i=0;i<2;i++)
    #pragma unroll
    for (int j=0;j<4;j++)
      #pragma unroll
      for (int e=0;e<4;e++) acc[i][j][e] = 0.f;

  const int wco = tid >> 2, wcg = (tid & 3) << 3;

  const int ciA = ks*(Cin/KS), ciB = ciA + Cin/KS;
  for (int ci0 = ciA; ci0 < ciB; ci0 += 32){
    // X staging: halo 10x18 px, 4 slots of 8 ci.
    for (int e = tid; e < 720; e += 256){
      const int px = e >> 2, sl = e & 3;
      const int pr = px / 18, pc = px - pr*18;
      const int ih = h0 + pr - 1, iw = w0 + pc - 1;
      bf16x8 vh, vl;
      #pragma unroll
      for (int j=0;j<8;j++){ vh[j] = 0; vl[j] = 0; }
      if ((unsigned)ih < (unsigned)H && (unsigned)iw < (unsigned)W){
        size_t o;
        if constexpr (RESIZE==0)
          o = ((size_t)(b*H + ih)*W + iw)*(size_t)Cin + (size_t)(ci0 + sl*8);
        else
          o = ((size_t)(b*(H>>1) + (ih>>1))*(W>>1) + (iw>>1))*(size_t)Cin + (size_t)(ci0 + sl*8);
        vh = *(const bf16x8*)&xh[o];
        vl = *(const bf16x8*)&xl[o];
      }
      *(bf16x8*)&sXh[px*40 + sl*8] = vh;
      *(bf16x8*)&sXl[px*40 + sl*8] = vl;
    }
    for (int dh = 0; dh < 3; ++dh){
      for (int dw = 0; dw < 3; ++dw){
        {
          const size_t so = ((size_t)((dh*3+dw)*Cout + co0+wco))*Cin + ci0 + wcg;
          *(bf16x8*)&sWh[wco*40 + wcg] = *(const bf16x8*)&wsh[so];
          *(bf16x8*)&sWl[wco*40 + wcg] = *(const bf16x8*)&wsl[so];
        }
        __syncthreads();
        bf16x8 ah[2], al[2], bh[4], bl[4];
        #pragma unroll
        for (int t=0;t<2;t++){
          const int co_l = (wm*2+t)*16 + ln;
          ah[t] = *(const bf16x8*)&sWh[co_l*40 + quad*8];
          al[t] = *(const bf16x8*)&sWl[co_l*40 + quad*8];
        }
        #pragma unroll
        for (int t=0;t<4;t++){
          const int p = (wn*4+t)*16 + ln;
          const int px = ((p>>4) + dh)*18 + (p&15) + dw;
          const int xo = px*40 + quad*8;
          bh[t] = *(const bf16x8*)&sXh[xo];
          bl[t] = *(const bf16x8*)&sXl[xo];
        }
        #pragma unroll
        for (int mi=0;mi<2;mi++)
          #pragma unroll
          for (int ni=0;ni<4;ni++){
            acc[mi][ni] = __builtin_amdgcn_mfma_f32_16x16x32_bf16(ah[mi], bh[ni], acc[mi][ni], 0, 0, 0);
            acc[mi][ni] = __builtin_amdgcn_mfma_f32_16x16x32_bf16(ah[mi], bl[ni], acc[mi][ni], 0, 0, 0);
            acc[mi][ni] = __builtin_amdgcn_mfma_f32_16x16x32_bf16(al[mi], bh[ni], acc[mi][ni], 0, 0, 0);
          }
        __syncthreads();
      }
    }
  }
  #pragma unroll
  for (int mi=0;mi<2;mi++){
    const int co = co0 + (wm*2+mi)*16 + quad*4;
    #pragma unroll
    for (int ni=0;ni<4;ni++){
      const int p = (wn*4+ni)*16 + ln;
      const int oh = h0 + (p>>4), ow = w0 + (p&15);
      #pragma unroll
      for (int rg=0; rg<4; rg++){
        const int cog = co + rg;
        if constexpr (KS==1){
          float v = acc[mi][ni][rg] + bias[cog];
          if (relu) v = fmaxf(v, 0.f);
          out[((size_t)(b*Cout + cog)*H + oh)*W + ow] = v;
        } else {
          out[((size_t)((ks*NB + b)*Cout + cog)*H + oh)*W + ow] = acc[mi][ni][rg];
        }
      }
    }
  }
}

// reduce split-K partials + bias + relu
__global__ __launch_bounds__(256) void sumk(const float* __restrict__ part, const float* __restrict__ bias,
                                            float* __restrict__ out, int Cout, int HW, int KS, int relu, int n){
  int idx = blockIdx.x*256 + threadIdx.x;
  if (idx >= n) return;
  int co = (idx / HW) % Cout;
  float v = bias[co];
  for (int k=0;k<KS;k++) v += part[(size_t)k*n + idx];
  if (relu) v = fmaxf(v, 0.f);
  out[idx] = v;
}

// per-(b,c) spatial mean & std (ddof=0) — single-pass (small HW)
__global__ __launch_bounds__(256) void statsk(const float* __restrict__ x, int HW,
                                              float* __restrict__ mo, float* __restrict__ so){
  int bc = blockIdx.x, tid = threadIdx.x;
  const float* p = x + (size_t)bc*HW;
  double s = 0.0, s2 = 0.0;
  for (int i = tid; i < HW; i += 256){ double v = p[i]; s += v; s2 += v*v; }
  __shared__ double sh[256], sh2[256];
  sh[tid] = s; sh2[tid] = s2; __syncthreads();
  for (int k=128;k>0;k>>=1){ if (tid<k){ sh[tid]+=sh[tid+k]; sh2[tid]+=sh2[tid+k]; } __syncthreads(); }
  if (tid == 0){
    double m = sh[0]/HW;
    double var = sh2[0]/HW - m*m;
    if (var < 0.0) var = 0.0;
    mo[bc] = (float)m;
    so[bc] = (float)sqrt(var);
  }
}

// chunked stats phase 1: grid (bc, CH); partial double sums to part[(bc*CH+ch)*2 +{0,1}]
__global__ __launch_bounds__(256) void statspk(const float* __restrict__ x, int HW,
                                               double* __restrict__ part){
  const int bc = blockIdx.x, ch = blockIdx.y, CH = gridDim.y, tid = threadIdx.x;
  const int clen = HW / CH;
  const float* p = x + (size_t)bc*HW + (size_t)ch*clen;
  double s = 0.0, s2 = 0.0;
  for (int i = tid; i < clen; i += 256){ double v = p[i]; s += v; s2 += v*v; }
  __shared__ double sh[256], sh2[256];
  sh[tid] = s; sh2[tid] = s2; __syncthreads();
  for (int k=128;k>0;k>>=1){ if (tid<k){ sh[tid]+=sh[tid+k]; sh2[tid]+=sh2[tid+k]; } __syncthreads(); }
  if (tid == 0){
    part[(size_t)(bc*CH + ch)*2    ] = sh[0];
    part[(size_t)(bc*CH + ch)*2 + 1] = sh2[0];
  }
}

// chunked stats phase 2: one thread per bc
__global__ __launch_bounds__(256) void statsfk(const double* __restrict__ part, int CH, int HW, int nbc,
                                               float* __restrict__ mo, float* __restrict__ so){
  int bc = blockIdx.x*256 + threadIdx.x;
  if (bc >= nbc) return;
  double s = 0.0, s2 = 0.0;
  for (int ch = 0; ch < CH; ++ch){
    s  += part[(size_t)(bc*CH + ch)*2];
    s2 += part[(size_t)(bc*CH + ch)*2 + 1];
  }
  double m = s/HW;
  double var = s2/HW - m*m;
  if (var < 0.0) var = 0.0;
  mo[bc] = (float)m;
  so[bc] = (float)sqrt(var);
}

// f4 (C-major, per image 512x1024) -> ptsT [8][1024][512]
__global__ __launch_bounds__(256) void transposek(const float* __restrict__ f4c,
                                                  const float* __restrict__ f4s,
                                                  float* __restrict__ ptsT){
  __shared__ float t[32][33];
  int r = blockIdx.z;
  const float* src = (r < 4) ? (f4c + (size_t)r*524288) : (f4s + (size_t)(r-4)*524288);
  int n0 = blockIdx.x*32, c0 = blockIdx.y*32;
  int lx = threadIdx.x & 31, ly = threadIdx.x >> 5;
  for (int j=0;j<32;j+=8)
    t[ly+j][lx] = src[(size_t)(c0+ly+j)*1024 + n0+lx];
  __syncthreads();
  for (int j=0;j<32;j+=8)
    ptsT[((size_t)r*1024 + n0+ly+j)*512 + c0+lx] = t[lx][ly+j];
}

// slot0 init: sums = first 3 points (centroids), counts = 1
__global__ __launch_bounds__(256) void initcent2k(const float* __restrict__ ptsT, float* __restrict__ KACC){
  int i = blockIdx.x*256 + threadIdx.x;
  if (i < 12288){
    int c = i & 511; int k = (i >> 9) % 3; int r = i / 1536;
    KACC[r*1536 + k*512 + c] = ptsT[((size_t)r*1024 + k)*512 + c];
  }
  if (i < 24) KACC[12288 + i] = 1.f;
}

// fused k-means step
__global__ __launch_bounds__(256) void kstepk(const float* __restrict__ ptsT,
    const float* __restrict__ prev, float* __restrict__ next,
    int* __restrict__ a, int nodiv)
{
  const int r = blockIdx.x, sl = blockIdx.y;
  const int tid = threadIdx.x;
  __shared__ float sc[1536];
  __shared__ int sa[32];
  __shared__ float red[3][8][32];
  __shared__ int scnt[3];
  if (tid < 3) scnt[tid] = 0;
  for (int i = tid; i < 1536; i += 256){
    float s = prev[r*1536 + i];
    float cnt = nodiv ? 1.f : (prev[12288 + r*3 + (i>>9)] + 1e-6f);
    sc[i] = s / cnt;
  }
  __syncthreads();
  const float* base = ptsT + (size_t)r*524288;
  const int wid = tid >> 6, lane = tid & 63;
  for (int rep = 0; rep < 8; ++rep){
    int p = wid*8 + rep;
    int n = sl*32 + p;
    const float* pp = base + (size_t)n*512;
    float d0=0.f,d1=0.f,d2=0.f;
    #pragma unroll
    for (int i=0;i<8;i++){
      int c = lane + i*64;
      float v = pp[c];
      float e0 = v - sc[c], e1 = v - sc[512+c], e2 = v - sc[1024+c];
      d0 = fmaf(e0,e0,d0); d1 = fmaf(e1,e1,d1); d2 = fmaf(e2,e2,d2);
    }
    #pragma unroll
    for (int off=32; off>0; off>>=1){
      d0 += __shfl_down(d0, off, 64);
      d1 += __shfl_down(d1, off, 64);
      d2 += __shfl_down(d2, off, 64);
    }
    if (lane == 0){
      int bi = 0; float bd = d0;
      if (d1 < bd){ bd = d1; bi = 1; }
      if (d2 < bd){ bd = d2; bi = 2; }
      sa[p] = bi;
      a[r*1024 + n] = bi;
    }
  }
  __syncthreads();
  if (tid < 32) atomicAdd(&scnt[sa[tid]], 1);
  __syncthreads();
  if (tid < 3) atomicAdd(&next[12288 + r*3 + tid], (float)scnt[tid]);
  const int g = tid >> 5, lc = tid & 31;
  for (int cj = 0; cj < 16; ++cj){
    int c = cj*32 + lc;
    float s0=0.f,s1=0.f,s2=0.f;
    #pragma unroll
    for (int q=0;q<4;q++){
      int nl = g*4 + q;
      float v = base[(size_t)(sl*32+nl)*512 + c];
      int an = sa[nl];
      s0 += (an==0)?v:0.f;
      s1 += (an==1)?v:0.f;
      s2 += (an==2)?v:0.f;
    }
    red[0][g][lc]=s0; red[1][g][lc]=s1; red[2][g][lc]=s2;
    __syncthreads();
    if (g == 0){
      float t0=0.f,t1=0.f,t2=0.f;
      #pragma unroll
      for (int q2=0;q2<8;q2++){ t0+=red[0][q2][lc]; t1+=red[1][q2][lc]; t2+=red[2][q2][lc]; }
      atomicAdd(&next[r*1536 +          c], t0);
      atomicAdd(&next[r*1536 +  512 +   c], t1);
      atomicAdd(&next[r*1536 + 1024 +   c], t2);
    }
    __syncthreads();
  }
}

// final mu/counts from slot 11
__global__ __launch_bounds__(256) void mufink(const float* __restrict__ slot,
                                              float* __restrict__ mu, float* __restrict__ counts){
  int i = blockIdx.x*256 + threadIdx.x;
  if (i >= 12288) return;
  int c = i & 511; int k = (i >> 9) % 3; int r = i / 1536;
  int cs = r >> 2, img = r & 3;
  int i0 = cs*12 + img*3;
  float cnt = slot[12288 + r*3 + k];
  mu[(size_t)(i0+k)*512 + c] = slot[r*1536 + k*512 + c] / (cnt + 1e-6f);
  if (c == 0) counts[i0+k] = cnt;
}

// masked centered split planes
__global__ __launch_bounds__(256) void maskcenterk(const float* __restrict__ f4c, const float* __restrict__ f4s,
        const int* __restrict__ a, const float* __restrict__ mu,
        u16* __restrict__ Ph, u16* __restrict__ Pl){
  size_t i4 = ((size_t)blockIdx.x*256 + threadIdx.x)*4;
  if (i4 >= (size_t)PL*2) return;
  int z = (int)(i4 >> 19);
  int rc = (int)(i4 & 524287);
  int c = rc >> 10, n = rc & 1023;
  int cs = z / 12; int rem = z - cs*12; int img = rem / 3; int k = rem - img*3;
  const float* pts = (cs ? f4s : f4c) + (size_t)img*524288;
  float m = mu[(size_t)z*512 + c];
  const int* an = a + (cs*4 + img)*1024 + n;
  float4 v4 = *(const float4*)&pts[(size_t)c*1024 + n];
  float vv[4] = {v4.x, v4.y, v4.z, v4.w};
  u16x4 oh, ol;
  #pragma unroll
  for (int j=0;j<4;j++){
    float v = (an[j] == k) ? (vv[j] - m) : 0.f;
    u16 h = bf16_rne(v);
    oh[j] = (short)h;
    ol[j] = (short)bf16_rne(v - bf16f(h));
  }
  *(u16x4*)&Ph[i4] = oh;
  *(u16x4*)&Pl[i4] = ol;
}

// covariance via MFMA, trace accumulated. Tile 128x128; grid (4,4,24).
__global__ __launch_bounds__(256) void covgemm(const u16* __restrict__ Ph, const u16* __restrict__ Pl,
        const float* __restrict__ counts, float* __restrict__ Ycov, float* __restrict__ trsum){
  const int z = blockIdx.z;
  const u16* Pbh = Ph + (size_t)z*524288;
  const u16* Pbl = Pl + (size_t)z*524288;
  const int m0 = blockIdx.y*128, n0 = blockIdx.x*128;
  const int tid = threadIdx.x;

  __shared__ __align__(16) u16 sAh[128*40], sAl[128*40];
  __shared__ __align__(16) u16 sBh[128*40], sBl[128*40];

  const int ra = tid >> 2, qa = tid & 3;
  const int wid = tid >> 6, lane = tid & 63;
  const int wm = wid >> 1, wn = wid & 1;
  const int quad = lane >> 4, ln = lane & 15;

  f32x4 acc[4][4];
  #pragma unroll
  for (int i=0;i<4;i++)
    #pragma unroll
    for (int j=0;j<4;j++)
      #pragma unroll
      for (int e=0;e<4;e++) acc[i][j][e] = 0.f;

  for (int k0 = 0; k0 < 1024; k0 += 32){
    *(bf16x8*)&sAh[ra*40 + qa*8]      = *(const bf16x8*)&Pbh[(size_t)(m0+ra)*1024    + k0 + qa*8];
    *(bf16x8*)&sAl[ra*40 + qa*8]      = *(const bf16x8*)&Pbl[(size_t)(m0+ra)*1024    + k0 + qa*8];
    *(bf16x8*)&sAh[(ra+64)*40 + qa*8] = *(const bf16x8*)&Pbh[(size_t)(m0+ra+64)*1024 + k0 + qa*8];
    *(bf16x8*)&sAl[(ra+64)*40 + qa*8] = *(const bf16x8*)&Pbl[(size_t)(m0+ra+64)*1024 + k0 + qa*8];
    *(bf16x8*)&sBh[ra*40 + qa*8]      = *(const bf16x8*)&Pbh[(size_t)(n0+ra)*1024    + k0 + qa*8];
    *(bf16x8*)&sBl[ra*40 + qa*8]      = *(const bf16x8*)&Pbl[(size_t)(n0+ra)*1024    + k0 + qa*8];
    *(bf16x8*)&sBh[(ra+64)*40 + qa*8] = *(const bf16x8*)&Pbh[(size_t)(n0+ra+64)*1024 + k0 + qa*8];
    *(bf16x8*)&sBl[(ra+64)*40 + qa*8] = *(const bf16x8*)&Pbl[(size_t)(n0+ra+64)*1024 + k0 + qa*8];
    __syncthreads();

    bf16x8 ah[4], al[4], bh[4], bl[4];
    #pragma unroll
    for (int t=0;t<4;t++){
      const int moA = ((wm*4+t)*16 + ln)*40 + quad*8;
      const int moB = ((wn*4+t)*16 + ln)*40 + quad*8;
      ah[t] = *(const bf16x8*)&sAh[moA];
      al[t] = *(const bf16x8*)&sAl[moA];
      bh[t] = *(const bf16x8*)&sBh[moB];
      bl[t] = *(const bf16x8*)&sBl[moB];
    }
    #pragma unroll
    for (int mi=0;mi<4;mi++)
      #pragma unroll
      for (int ni=0;ni<4;ni++){
        acc[mi][ni] = __builtin_amdgcn_mfma_f32_16x16x32_bf16(ah[mi], bh[ni], acc[mi][ni], 0, 0, 0);
        acc[mi][ni] = __builtin_amdgcn_mfma_f32_16x16x32_bf16(ah[mi], bl[ni], acc[mi][ni], 0, 0, 0);
        acc[mi][ni] = __builtin_amdgcn_mfma_f32_16x16x32_bf16(al[mi], bh[ni], acc[mi][ni], 0, 0, 0);
      }
    __syncthreads();
  }
  const float inv = 1.f/(counts[z] + 1e-6f);
  float dsum = 0.f; bool anyd = false;
  #pragma unroll
  for (int mi=0;mi<4;mi++){
    const int mbase = m0 + (wm*4+mi)*16 + quad*4;
    #pragma unroll
    for (int ni=0;ni<4;ni++){
      const int n = n0 + (wn*4+ni)*16 + ln;
      #pragma unroll
      for (int rg=0;rg<4;rg++){
        const int m = mbase + rg;
        float v = acc[mi][ni][rg]*inv + ((m==n)?0.1f:0.f);
        Ycov[(size_t)z*MSZ + (size_t)m*512 + n] = v;
        if (m0==n0 && m==n){ dsum += v; anyd = true; }
      }
    }
  }
  if (anyd) atomicAdd(&trsum[z], dsum);
}

// init split planes: Y = Ycov/trace (hi+lo bf16), Z = I
__global__ __launch_bounds__(256) void nsinitk(const float* __restrict__ Ycov, const float* __restrict__ sval,
                                               u16* __restrict__ Yh, u16* __restrict__ Yl,
                                               u16* __restrict__ Zh, u16* __restrict__ Zl){
  size_t idx = (size_t)blockIdx.x*256 + threadIdx.x;
  if (idx >= (size_t)PL) return;
  int z = (int)(idx >> 18);
  int rc = (int)(idx & (MSZ-1));
  int rr = rc >> 9, cc = rc & 511;
  float y = Ycov[idx] / sval[z];
  u16 h = bf16_rne(y);
  Yh[idx] = h;
  Yl[idx] = bf16_rne(y - bf16f(h));
  Zh[idx] = (rr==cc) ? (u16)0x3F80 : (u16)0;
  Zl[idx] = 0;
}

// it=0 specializations (Z == I exactly):
// M = Z*Y via MFMA degenerates to elementwise resplit of (Yh+Yl) — bit-identical.
__global__ __launch_bounds__(256) void nsm0k(const u16* __restrict__ Yh, const u16* __restrict__ Yl,
                                             u16* __restrict__ Mh, u16* __restrict__ Ml){
  size_t i4 = ((size_t)blockIdx.x*256 + threadIdx.x)*4;
  if (i4 >= (size_t)PL) return;
  u16x4 hv = *(const u16x4*)&Yh[i4];
  u16x4 lv = *(const u16x4*)&Yl[i4];
  u16x4 oh, ol;
  #pragma unroll
  for (int j=0;j<4;j++){
    float v = bf16f((u16)hv[j]) + bf16f((u16)lv[j]);
    u16 h = bf16_rne(v);
    oh[j] = (short)h;
    ol[j] = (short)bf16_rne(v - bf16f(h));
  }
  *(u16x4*)&Mh[i4] = oh;
  *(u16x4*)&Ml[i4] = ol;
}

// trace of M (= sum of diag (Yh+Yl)) per z; grid 24 blocks.
__global__ __launch_bounds__(256) void nstr0k(const u16* __restrict__ Yh, const u16* __restrict__ Yl,
                                              float* __restrict__ tr){
  int z = blockIdx.x, tid = threadIdx.x;
  float s = 0.f;
  for (int i = tid; i < 512; i += 256){
    size_t o = (size_t)z*MSZ + (size_t)i*513;
    s += bf16f(Yh[o]) + bf16f(Yl[o]);
  }
  __shared__ float sh[256];
  sh[tid] = s; __syncthreads();
  for (int k=128;k>0;k>>=1){ if (tid<k) sh[tid]+=sh[tid+k]; __syncthreads(); }
  if (tid == 0) tr[z] = sh[0];
}

// it=0 Z-update: Z2 = alpha*(Mh+Ml) + beta*I (since M*Z with Z=I is elementwise-exact).
__global__ __launch_bounds__(256) void nsz0k(const u16* __restrict__ Mh, const u16* __restrict__ Ml,
                                             u16* __restrict__ Z2h, u16* __restrict__ Z2l,
                                             const float* __restrict__ trAcc){
  size_t i4 = ((size_t)blockIdx.x*256 + threadIdx.x)*4;
  if (i4 >= (size_t)PL) return;
  int z = (int)(i4 >> 18);
  int rc = (int)(i4 & (MSZ-1));
  int row = rc >> 9, col = rc & 511;
  const float tr = trAcc[z];
  const float g2 = fminf(512.f/fmaxf(tr, 1e-6f), 2.7f);
  const float oz = 0.5f*sqrtf(g2);
  const float alpha = -g2*oz, beta = 3.f*oz;
  u16x4 hv = *(const u16x4*)&Mh[i4];
  u16x4 lv = *(const u16x4*)&Ml[i4];
  u16x4 oh, ol;
  #pragma unroll
  for (int j=0;j<4;j++){
    float m = bf16f((u16)hv[j]) + bf16f((u16)lv[j]);
    float zv = (row == col + j) ? 1.f : 0.f;
    float v = alpha*m + beta*zv;
    u16 h = bf16_rne(v);
    oh[j] = (short)h;
    ol[j] = (short)bf16_rne(v - bf16f(h));
  }
  *(u16x4*)&Z2h[i4] = oh;
  *(u16x4*)&Z2l[i4] = ol;
}

// ---- split-bf16 MFMA batched GEMM 512x512x512; tile 128x128; grid (4,4,z) ----
template<int MODE>
__global__ __launch_bounds__(256) void bmms(
    const u16* __restrict__ Ah, const u16* __restrict__ Al,
    const u16* __restrict__ Bh, const u16* __restrict__ Bl,
    u16* __restrict__ Ch, u16* __restrict__ Cl,
    const float* __restrict__ osc,
    int aoff, float* __restrict__ trAcc)
{
  const int z = blockIdx.z;
  const u16* Abh = Ah + (size_t)(z+aoff)*MSZ;
  const u16* Abl = Al + (size_t)(z+aoff)*MSZ;
  const u16* Bbh = Bh + (size_t)z*MSZ;
  const u16* Bbl = Bl + (size_t)z*MSZ;
  const int m0 = blockIdx.y*128, n0 = blockIdx.x*128;
  const int tid = threadIdx.x;

  __shared__ __align__(16) u16 sAh[128*40], sAl[128*40];
  __shared__ __align__(16) u16 sBh[128*40], sBl[128*40];

  const int ra = tid >> 2, qa = tid & 3;
  const int wid = tid >> 6, lane = tid & 63;
  const int wm = wid >> 1, wn = wid & 1;
  const int quad = lane >> 4, ln = lane & 15;

  f32x4 acc[4][4];
  #pragma unroll
  for (int i=0;i<4;i++)
    #pragma unroll
    for (int j=0;j<4;j++)
      #pragma unroll
      for (int e=0;e<4;e++) acc[i][j][e] = 0.f;

  for (int k0 = 0; k0 < 512; k0 += 32){
    *(bf16x8*)&sAh[ra*40 + qa*8]      = *(const bf16x8*)&Abh[(size_t)(m0+ra)*512    + k0 + qa*8];
    *(bf16x8*)&sAl[ra*40 + qa*8]      = *(const bf16x8*)&Abl[(size_t)(m0+ra)*512    + k0 + qa*8];
    *(bf16x8*)&sAh[(ra+64)*40 + qa*8] = *(const bf16x8*)&Abh[(size_t)(m0+ra+64)*512 + k0 + qa*8];
    *(bf16x8*)&sAl[(ra+64)*40 + qa*8] = *(const bf16x8*)&Abl[(size_t)(m0+ra+64)*512 + k0 + qa*8];
    *(bf16x8*)&sBh[ra*40 + qa*8]      = *(const bf16x8*)&Bbh[(size_t)(n0+ra)*512    + k0 + qa*8];
    *(bf16x8*)&sBl[ra*40 + qa*8]      = *(const bf16x8*)&Bbl[(size_t)(n0+ra)*512    + k0 + qa*8];
    *(bf16x8*)&sBh[(ra+64)*40 + qa*8] = *(const bf16x8*)&Bbh[(size_t)(n0+ra+64)*512 + k0 + qa*8];
    *(bf16x8*)&sBl[(ra+64)*40 + qa*8] = *(const bf16x8*)&Bbl[(size_t)(n0+ra+64)*512 + k0 + qa*8];
    __syncthreads();

    bf16x8 ah[4], al[4], bh[4], bl[4];
    #pragma unroll
    for (int t=0;t<4;t++){
      const int moA = ((wm*4+t)*16 + ln)*40 + quad*8;
      const int moB = ((wn*4+t)*16 + ln)*40 + quad*8;
      ah[t] = *(const bf16x8*)&sAh[moA];
      al[t] = *(const bf16x8*)&sAl[moA];
      bh[t] = *(const bf16x8*)&sBh[moB];
      bl[t] = *(const bf16x8*)&sBl[moB];
    }
    #pragma unroll
    for (int mi=0;mi<4;mi++)
      #pragma unroll
      for (int ni=0;ni<4;ni++){
        acc[mi][ni] = __builtin_amdgcn_mfma_f32_16x16x32_bf16(ah[mi], bh[ni], acc[mi][ni], 0, 0, 0);
        acc[mi][ni] = __builtin_amdgcn_mfma_f32_16x16x32_bf16(ah[mi], bl[ni], acc[mi][ni], 0, 0, 0);
        acc[mi][ni] = __builtin_amdgcn_mfma_f32_16x16x32_bf16(al[mi], bh[ni], acc[mi][ni], 0, 0, 0);
      }
    __syncthreads();
  }

  float alpha = 1.f;
  if constexpr (MODE==2){ alpha = osc[z]; }

  float dsum = 0.f; bool anyd = false;
  #pragma unroll
  for (int mi=0;mi<4;mi++){
    const int mbase = m0 + (wm*4+mi)*16 + quad*4;
    #pragma unroll
    for (int ni=0;ni<4;ni++){
      const int n = n0 + (wn*4+ni)*16 + ln;
      #pragma unroll
      for (int rg=0;rg<4;rg++){
        const int m = mbase + rg;
        const size_t off = (size_t)z*MSZ + (size_t)m*512 + n;
        float v = alpha*acc[mi][ni][rg];
        u16 h = bf16_rne(v);
        Ch[off] = h;
        Cl[off] = bf16_rne(v - bf16f(h));
        if (MODE==0 && trAcc && m0==n0 && m==n){ dsum += v; anyd = true; }
      }
    }
  }
  if (MODE==0 && anyd) atomicAdd(&trAcc[z], dsum);
}

// merged NS update (128x128 tile)
__global__ __launch_bounds__(256) void bmmpair(
    const u16* __restrict__ Yh, const u16* __restrict__ Yl,
    const u16* __restrict__ Mh, const u16* __restrict__ Ml,
    const u16* __restrict__ Zh, const u16* __restrict__ Zl,
    u16* __restrict__ Y2h, u16* __restrict__ Y2l,
    u16* __restrict__ Z2h, u16* __restrict__ Z2l,
    const float* __restrict__ trAcc, int last)
{
  const int z = blockIdx.z;
  int zz; bool isY;
  if (last){ zz = z; isY = (z >= 12); }
  else { isY = (z < 24); zz = isY ? z : (z - 24); }
  const size_t zo = (size_t)zz*MSZ;
  const u16 *Abh, *Abl, *Bbh, *Bbl, *Dbh, *Dbl;
  u16 *Cbh, *Cbl;
  if (isY){
    Abh = Yh + zo; Abl = Yl + zo;
    Bbh = Mh + zo; Bbl = Ml + zo;
    Dbh = Yh + zo; Dbl = Yl + zo;
    Cbh = Y2h + zo; Cbl = Y2l + zo;
  } else {
    Abh = Mh + zo; Abl = Ml + zo;
    Bbh = Zh + zo; Bbl = Zl + zo;
    Dbh = Zh + zo; Dbl = Zl + zo;
    Cbh = Z2h + zo; Cbl = Z2l + zo;
  }
  const int m0 = blockIdx.y*128, n0 = blockIdx.x*128;
  const int tid = threadIdx.x;

  __shared__ __align__(16) u16 sAh[128*40], sAl[128*40];
  __shared__ __align__(16) u16 sBh[128*40], sBl[128*40];

  const int ra = tid >> 2, qa = tid & 3;
  const int wid = tid >> 6, lane = tid & 63;
  const int wm = wid >> 1, wn = wid & 1;
  const int quad = lane >> 4, ln = lane & 15;

  f32x4 acc[4][4];
  #pragma unroll
  for (int i=0;i<4;i++)
    #pragma unroll
    for (int j=0;j<4;j++)
      #pragma unroll
      for (int e=0;e<4;e++) acc[i][j][e] = 0.f;

  for (int k0 = 0; k0 < 512; k0 += 32){
    *(bf16x8*)&sAh[ra*40 + qa*8]      = *(const bf16x8*)&Abh[(size_t)(m0+ra)*512    + k0 + qa*8];
    *(bf16x8*)&sAl[ra*40 + qa*8]      = *(const bf16x8*)&Abl[(size_t)(m0+ra)*512    + k0 + qa*8];
    *(bf16x8*)&sAh[(ra+64)*40 + qa*8] = *(const bf16x8*)&Abh[(size_t)(m0+ra+64)*512 + k0 + qa*8];
    *(bf16x8*)&sAl[(ra+64)*40 + qa*8] = *(const bf16x8*)&Abl[(size_t)(m0+ra+64)*512 + k0 + qa*8];
    *(bf16x8*)&sBh[ra*40 + qa*8]      = *(const bf16x8*)&Bbh[(size_t)(n0+ra)*512    + k0 + qa*8];
    *(bf16x8*)&sBl[ra*40 + qa*8]      = *(const bf16x8*)&Bbl[(size_t)(n0+ra)*512    + k0 + qa*8];
    *(bf16x8*)&sBh[(ra+64)*40 + qa*8] = *(const bf16x8*)&Bbh[(size_t)(n0+ra+64)*512 + k0 + qa*8];
    *(bf16x8*)&sBl[(ra+64)*40 + qa*8] = *(const bf16x8*)&Bbl[(size_t)(n0+ra+64)*512 + k0 + qa*8];
    __syncthreads();

    bf16x8 ah[4], al[4], bh[4], bl[4];
    #pragma unroll
    for (int t=0;t<4;t++){
      const int moA = ((wm*4+t)*16 + ln)*40 + quad*8;
      const int moB = ((wn*4+t)*16 + ln)*40 + quad*8;
      ah[t] = *(const bf16x8*)&sAh[moA];
      al[t] = *(const bf16x8*)&sAl[moA];
      bh[t] = *(const bf16x8*)&sBh[moB];
      bl[t] = *(const bf16x8*)&sBl[moB];
    }
    #pragma unroll
    for (int mi=0;mi<4;mi++)
      #pragma unroll
      for (int ni=0;ni<4;ni++){
        acc[mi][ni] = __builtin_amdgcn_mfma_f32_16x16x32_bf16(ah[mi], bh[ni], acc[mi][ni], 0, 0, 0);
        acc[mi][ni] = __builtin_amdgcn_mfma_f32_16x16x32_bf16(ah[mi], bl[ni], acc[mi][ni], 0, 0, 0);
        acc[mi][ni] = __builtin_amdgcn_mfma_f32_16x16x32_bf16(al[mi], bh[ni], acc[mi][ni], 0, 0, 0);
      }
    __syncthreads();
  }

  const float tr = trAcc[zz];
  const float g2 = fminf(512.f/fmaxf(tr, 1e-6f), 2.7f);
  const float oz = 0.5f*sqrtf(g2);
  const float alpha = -g2*oz, beta = 3.f*oz;

  #pragma unroll
  for (int mi=0;mi<4;mi++){
    const int mbase = m0 + (wm*4+mi)*16 + quad*4;
    #pragma unroll
    for (int ni=0;ni<4;ni++){
      const int n = n0 + (wn*4+ni)*16 + ln;
      #pragma unroll
      for (int rg=0;rg<4;rg++){
        const int m = mbase + rg;
        const size_t off = (size_t)m*512 + n;
        float v = alpha*acc[mi][ni][rg] + beta*(bf16f(Dbh[off]) + bf16f(Dbl[off]));
        u16 h = bf16_rne(v);
        Cbh[off] = h;
        Cbl[off] = bf16_rne(v - bf16f(h));
      }
    }
  }
}

// tpts = T[z] @ f[img]: M=512, N=1024, K=512, fp32 out.
// B is pre-transposed fsT [img][n][c]; tile 128M x 64N; grid (16,4,12).
__global__ __launch_bounds__(256,4) void bmmt(
    const u16* __restrict__ Th, const u16* __restrict__ Tl,
    const u16* __restrict__ fh, const u16* __restrict__ fl,
    float* __restrict__ Cf)
{
  const int z = blockIdx.z;
  const u16* Abh = Th + (size_t)z*MSZ;
  const u16* Abl = Tl + (size_t)z*MSZ;
  const u16* Bbh = fh + (size_t)(z/3)*524288;
  const u16* Bbl = fl + (size_t)(z/3)*524288;
  const int m0 = blockIdx.y*128, n0 = blockIdx.x*64;
  const int tid = threadIdx.x;

  __shared__ __align__(16) u16 sAh[128*40], sAl[128*40];
  __shared__ __align__(16) u16 sBh[64*40], sBl[64*40];

  const int ra = tid >> 2, qa = tid & 3;
  const int wid = tid >> 6, lane = tid & 63;
  const int wm = wid >> 1, wn = wid & 1;
  const int quad = lane >> 4, ln = lane & 15;

  f32x4 acc[4][2];
  #pragma unroll
  for (int i=0;i<4;i++)
    #pragma unroll
    for (int j=0;j<2;j++)
      #pragma unroll
      for (int e=0;e<4;e++) acc[i][j][e] = 0.f;

  for (int k0 = 0; k0 < 512; k0 += 32){
    *(bf16x8*)&sAh[ra*40 + qa*8]      = *(const bf16x8*)&Abh[(size_t)(m0+ra)*512    + k0 + qa*8];
    *(bf16x8*)&sAl[ra*40 + qa*8]      = *(const bf16x8*)&Abl[(size_t)(m0+ra)*512    + k0 + qa*8];
    *(bf16x8*)&sAh[(ra+64)*40 + qa*8] = *(const bf16x8*)&Abh[(size_t)(m0+ra+64)*512 + k0 + qa*8];
    *(bf16x8*)&sAl[(ra+64)*40 + qa*8] = *(const bf16x8*)&Abl[(size_t)(m0+ra+64)*512 + k0 + qa*8];
    *(bf16x8*)&sBh[ra*40 + qa*8]      = *(const bf16x8*)&Bbh[(size_t)(n0+ra)*512    + k0 + qa*8];
    *(bf16x8*)&sBl[ra*40 + qa*8]      = *(const bf16x8*)&Bbl[(size_t)(n0+ra)*512    + k0 + qa*8];
    __syncthreads();

    bf16x8 ah[4], al[4], bh[2], bl[2];
    #pragma unroll
    for (int t=0;t<4;t++){
      const int moA = ((wm*4+t)*16 + ln)*40 + quad*8;
      ah[t] = *(const bf16x8*)&sAh[moA];
      al[t] = *(const bf16x8*)&sAl[moA];
    }
    #pragma unroll
    for (int t=0;t<2;t++){
      const int moB = ((wn*2+t)*16 + ln)*40 + quad*8;
      bh[t] = *(const bf16x8*)&sBh[moB];
      bl[t] = *(const bf16x8*)&sBl[moB];
    }
    #pragma unroll
    for (int mi=0;mi<4;mi++)
      #pragma unroll
      for (int ni=0;ni<2;ni++){
        acc[mi][ni] = __builtin_amdgcn_mfma_f32_16x16x32_bf16(ah[mi], bh[ni], acc[mi][ni], 0, 0, 0);
        acc[mi][ni] = __builtin_amdgcn_mfma_f32_16x16x32_bf16(ah[mi], bl[ni], acc[mi][ni], 0, 0, 0);
        acc[mi][ni] = __builtin_amdgcn_mfma_f32_16x16x32_bf16(al[mi], bh[ni], acc[mi][ni], 0, 0, 0);
      }
    __syncthreads();
  }
  #pragma unroll
  for (int mi=0;mi<4;mi++){
    const int mbase = m0 + (wm*4+mi)*16 + quad*4;
    #pragma unroll
    for (int ni=0;ni<2;ni++){
      const int n = n0 + (wn*2+ni)*16 + ln;
      #pragma unroll
      for (int rg=0;rg<4;rg++){
        const int m = mbase + rg;
        Cf[(size_t)z*524288 + (size_t)m*1024 + n] = acc[mi][ni][rg];
      }
    }
  }
}

__global__ void make_scalesk(const float* __restrict__ sval, float* __restrict__ scl){
  int i = threadIdx.x;
  if (i < 12) scl[i] = sqrtf(sval[12+i] / sval[i]);
}

// tvec[b] = mu_s[b] - T[b] @ mu_c[b]
__global__ __launch_bounds__(512) void tveck(const u16* __restrict__ Th, const u16* __restrict__ Tl,
                                             const float* __restrict__ mu, float* __restrict__ tvec){
  int b = blockIdx.x; int c = threadIdx.x;
  __shared__ float mc[512];
  mc[c] = mu[(size_t)b*512 + c];
  __syncthreads();
  const u16* Trh = Th + ((size_t)b*512 + c)*512;
  const u16* Trl = Tl + ((size_t)b*512 + c)*512;
  float s = 0.f;
  for (int d=0; d<512; d++) s = fmaf(bf16f(Trh[d]) + bf16f(Trl[d]), mc[d], s);
  tvec[b*512 + c] = mu[(size_t)(12+b)*512 + c] - s;
}

__global__ __launch_bounds__(256) void selectk(const float* __restrict__ tpts, const float* __restrict__ tvec,
        const int* __restrict__ a, const float* __restrict__ f4c, float* __restrict__ tf){
  size_t idx = (size_t)blockIdx.x*256 + threadIdx.x;
  if (idx >= 2097152ul) return;
  int n = (int)(idx & 1023);
  int c = (int)((idx >> 10) & 511);
  int img = (int)(idx >> 19);
  int k = a[img*1024 + n];
  int b = img*3 + k;
  float v = tpts[((size_t)b*512 + c)*1024 + n] + tvec[b*512 + c];
  tf[idx] = 0.6f*v + 0.4f*f4c[idx];
}

__global__ __launch_bounds__(256) void clossk(const float* __restrict__ x, const float* __restrict__ y,
                                              int n, float* __restrict__ acc){
  int tid = threadIdx.x;
  float s = 0.f;
  for (size_t i = (size_t)blockIdx.x*256 + tid; i < (size_t)n; i += (size_t)gridDim.x*256){
    float d = x[i] - y[i]; s = fmaf(d, d, s);
  }
  __shared__ float sh[256];
  sh[tid] = s; __syncthreads();
  for (int k=128;k>0;k>>=1){ if (tid<k) sh[tid]+=sh[tid+k]; __syncthreads(); }
  if (tid==0) atomicAdd(acc, sh[0]);
}

__global__ __launch_bounds__(256) void finalk(const float* __restrict__ sm, float* __restrict__ out){
  int tid = threadIdx.x;
  const int cnts[4] = {256,512,1024,2048};
  const int offs[4] = {0,256,768,1792};
  const float* mS = sm + SM_STATS_S;
  const float* sS = sm + SM_STATS_S + 3840;
  const float* mD = sm + SM_STATS_D;
  const float* sD = sm + SM_STATS_D + 3840;
  double sl = 0.0;
  for (int L=0; L<4; ++L){
    int cnt = cnts[L], off = offs[L];
    double inv = 1.0/cnt;
    for (int i=tid; i<cnt; i+=256){
      double dm = (double)mD[off+i] - (double)mS[off+i];
      double ds = (double)sD[off+i] - (double)sS[off+i];
      sl += (dm*dm + ds*ds)*inv;
    }
  }
  __shared__ double sh[256];
  sh[tid] = sl; __syncthreads();
  for (int k=128;k>0;k>>=1){ if (tid<k) sh[tid]+=sh[tid+k]; __syncthreads(); }
  if (tid==0){
    double closs = (double)sm[SM_CLOSS] / 2097152.0;
    out[0] = (float)(closs + 0.01*sh[0]);
  }
}

// ---------------- host ----------------

extern "C" void kernel_launch(void* const* d_in, const int* in_sizes, int n_in,
                              void* d_out, int out_size, void* d_ws, size_t ws_size,
                              hipStream_t stream)
{
  const float* content = (const float*)d_in[0];
  const float* style   = (const float*)d_in[1];
  const float* Wm[8]; const float* Bm[8];
  for (int i=0;i<8;i++){ Wm[i] = (const float*)d_in[2+2*i]; Bm[i] = (const float*)d_in[3+2*i]; }
  float* out = (float*)d_out;
  float* ws = (float*)d_ws;

  float* f4c  = ws + OFF_F4C;
  float* f4s  = ws + OFF_F4S;
  float* tf   = ws + OFF_TF;
  float* dec  = ws + OFF_DEC;
  float* sm   = ws + OFF_SMALL;
  float* AR   = ws + OFF_ARENA;
  int*   aPtr = (int*)(sm + SM_ASSIGN);
  float* mu   = sm + SM_MU;
  float* counts = sm + SM_COUNTS;
  float* sval = sm + SM_SVAL;
  float* scl  = sm + SM_SCALE;
  float* tvec = sm + SM_TVEC;
  float* trbuf = sm + SM_TR;
  double* spart = (double*)(sm + SM_SPART);

  u16* WB = (u16*)(ws + OFF_WSPL);
  u16 *w2h=WB+0,       *w2l=WB+73728;
  u16 *w3h=WB+147456,  *w3l=WB+442368;
  u16 *w4h=WB+737280,  *w4l=WB+1916928;
  u16 *v1h=WB+3096576, *v1l=WB+4276224;
  u16 *v2h=WB+5455872, *v2l=WB+5750784;
  u16 *v3h=WB+6045696, *v3l=WB+6119424;

  float* Ycov = AR;
  u16* Mh  = (u16*)(AR);
  u16* Ml  = (u16*)(AR + 3145728ul);
  u16* Yh  = (u16*)(AR + 6291456ul);
  u16* Yl  = (u16*)(AR + 9437184ul);
  u16* Zh  = (u16*)(AR + 12582912ul);
  u16* Zl  = (u16*)(AR + 15728640ul);
  u16* Y2h = (u16*)(AR + 18874368ul);
  u16* Y2l = (u16*)(AR + 22020096ul);
  u16* Z2h = (u16*)(AR + 25165824ul);
  u16* Z2l = (u16*)(AR + 28311552ul);
  u16* Ph  = (u16*)(AR + 18874368ul);
  u16* Pl  = (u16*)(AR + 25165824ul);
  float* ptsT = AR + 25165824ul;
  u16* Th  = (u16*)(AR + 18874368ul);
  u16* Tl  = (u16*)(AR + 20971520ul);
  u16* fsh = (u16*)(AR + 23068672ul);
  u16* fsl = (u16*)(AR + 24117248ul);
  float* KACC = AR + 0;

  // NHWC split-bf16 activation planes (u16), placed in lifetime-dead arena slots.
  // encode (B=8):
  u16* xP1h  = (u16*)(AR + 16777216ul);   // 8*128*128*64 u16 -> 4.19M floats
  u16* xP1l  = (u16*)(AR + 20971520ul);
  u16* xF2ph = (u16*)(AR + 16777216ul);   // pooled F2: 8*64*64*128
  u16* xF2pl = (u16*)(AR + 18874368ul);
  u16* xF3ph = (u16*)(AR + 18874368ul);   // pooled F3: 8*32*32*256 (clear of PART8)
  u16* xF3pl = (u16*)(AR + 19922944ul);
  // decode (B=4):
  u16* xTFh  = (u16*)(AR + 8388608ul);    // 4*32*32*512
  u16* xTFl  = (u16*)(AR + 9437184ul);
  u16* xX1h  = (u16*)(AR + 1048576ul);    // 4*32*32*256
  u16* xX1l  = (u16*)(AR + 1572864ul);
  u16* xX2h  = (u16*)(AR + 11534336ul);   // 4*64*64*128
  u16* xX2l  = (u16*)(AR + 12582912ul);
  // decoded encode (B=4):
  u16* xP1dh = (u16*)(AR + 16777216ul);   // 4*128*128*64
  u16* xP1dl = (u16*)(AR + 18874368ul);
  u16* xF2dph= (u16*)(AR + 16777216ul);   // pooled F2d: 4*64*64*128
  u16* xF2dpl= (u16*)(AR + 17825792ul);
  u16* xF3dph= (u16*)(AR + 16777216ul);   // pooled F3d: 4*32*32*256
  u16* xF3dpl= (u16*)(AR + 17301504ul);

  zerok<<<512,256,0,stream>>>(sm, 131072);

  {
    auto wsp = [&](int li, u16* wh, u16* wl, int Co, int Ci){
      int n = 9*Co*Ci;
      wsplitk<<<(n+255)/256,256,0,stream>>>(Wm[li], wh, wl, Co, Ci);
    };
    wsp(1,w2h,w2l,128,64);
    wsp(2,w3h,w3l,256,128);
    wsp(3,w4h,w4l,512,256);
    wsp(4,v1h,v1l,256,512);
    wsp(5,v2h,v2l,128,256);
    wsp(6,v3h,v3l,64,128);
  }

  // MFMA conv on pre-split NHWC u16 input. KS in {1,2,4}, RZ in {0,2}.
  auto convMFMA = [&](const u16* xh, const u16* xl, int li, float* outp,
                      int B,int Ci,int Co,int H,int Wd,int relu,int KS,int RZ,float* part){
    const u16 *wh=nullptr,*wl=nullptr;
    switch(li){
      case 1: wh=w2h; wl=w2l; break;
      case 2: wh=w3h; wl=w3l; break;
      case 3: wh=w4h; wl=w4l; break;
      case 4: wh=v1h; wl=v1l; break;
      case 5: wh=v2h; wl=v2l; break;
      case 6: wh=v3h; wl=v3l; break;
    }
    int tiles = (H>>3)*(Wd>>4);
    if (KS==1){
      dim3 g(tiles,Co>>6,B);
      if (RZ==0) convm<1,0><<<g,256,0,stream>>>(xh,xl,wh,wl,Bm[li],outp,Ci,Co,H,Wd,relu);
      else       convm<1,2><<<g,256,0,stream>>>(xh,xl,wh,wl,Bm[li],outp,Ci,Co,H,Wd,relu);
    } else if (KS==2){
      dim3 g(tiles,Co>>6,B*2);
      if (RZ==0) convm<2,0><<<g,256,0,stream>>>(xh,xl,wh,wl,nullptr,part,Ci,Co,H,Wd,relu);
      else       convm<2,2><<<g,256,0,stream>>>(xh,xl,wh,wl,nullptr,part,Ci,Co,H,Wd,relu);
      int n = B*Co*H*Wd;
      sumk<<<(n+255)/256,256,0,stream>>>(part,Bm[li],outp,Co,H*Wd,2,relu,n);
    } else {
      dim3 g(tiles,Co>>6,B*4);
      convm<4,0><<<g,256,0,stream>>>(xh,xl,wh,wl,nullptr,part,Ci,Co,H,Wd,relu);
      int n = B*Co*H*Wd;
      sumk<<<(n+255)/256,256,0,stream>>>(part,Bm[li],outp,Co,H*Wd,4,relu,n);
    }
  };

  // chunked stats: big HW -> 2-phase
  auto stats = [&](const float* x, int nbc, int HW, float* mo, float* so){
    if (HW >= 16384){
      int CH = (HW >= 65536) ? 8 : 4;
      statspk<<<dim3(nbc,CH),256,0,stream>>>(x, HW, spart);
      statsfk<<<(nbc+255)/256,256,0,stream>>>(spart, CH, HW, nbc, mo, so);
    } else {
      statsk<<<nbc,256,0,stream>>>(x, HW, mo, so);
    }
  };

  float* mS = sm + SM_STATS_S;
  float* sS = sm + SM_STATS_S + 3840;

  // ---- batched content+style encode (B=8 from e2 down) ----
  float* F1   = AR + 0;
  float* F2_8 = AR + 0;
  float* F3_8 = AR + 0;
  float* PART8 = AR + 10485760ul;

  {
    dim3 ge(64, 8, 4);  // (256/32)^2 tiles, 64/8 co-groups, B=4
    // content e1: fp32 output is dead (style overwrites F1 before any reader) -> OUTW=0
    conv3x3<8,4,1,0,0><<<ge,256,0,stream>>>(content,Wm[0],Bm[0],F1,xP1h,           xP1l,           4,3,64,256,256,1);
    conv3x3<8,4,1,1,0><<<ge,256,0,stream>>>(style,  Wm[0],Bm[0],F1,xP1h+4194304ul, xP1l+4194304ul, 4,3,64,256,256,1);
  }
  stats(F1, 256, 65536, mS+0, sS+0);

  convMFMA(xP1h,xP1l, 1, F2_8, 8, 64,128,128,128,1,1,0,nullptr);
  stats(F2_8 + 8388608ul, 512, 16384, mS+256, sS+256);
  repackk<1><<<dim3(128,2,8),256,0,stream>>>(F2_8, xF2ph, xF2pl, 128,64,64);
  convMFMA(xF2ph,xF2pl, 2, F3_8, 8, 128,256,64,64,1,1,0,nullptr);
  statsk<<<1024,256,0,stream>>>(F3_8 + 4194304ul, 4096, mS+768, sS+768);
  repackk<1><<<dim3(32,4,8),256,0,stream>>>(F3_8, xF3ph, xF3pl, 256,32,32);
  convMFMA(xF3ph,xF3pl, 3, f4c, 8, 256,512,32,32,1,2,0,PART8);
  statsk<<<2048,256,0,stream>>>(f4s,1024, mS+1792, sS+1792);

  // ---- fused k-means ----
  transposek<<<dim3(32,16,8),256,0,stream>>>(f4c,f4s,ptsT);
  zerok<<<(12*KSLOT+255)/256,256,0,stream>>>(KACC, 12*KSLOT);
  initcent2k<<<48,256,0,stream>>>(ptsT,KACC);
  for (int it=0; it<=10; ++it){
    kstepk<<<dim3(8,32),256,0,stream>>>(ptsT, KACC + (size_t)it*KSLOT, KACC + (size_t)(it+1)*KSLOT, aPtr, it==0 ? 1 : 0);
  }
  mufink<<<48,256,0,stream>>>(KACC + 11ul*KSLOT, mu, counts);

  // ---- covariances via MFMA ----
  maskcenterk<<<12288,256,0,stream>>>(f4c,f4s,aPtr,mu,Ph,Pl);
  covgemm<<<dim3(4,4,24),256,0,stream>>>(Ph,Pl,counts,Ycov,sval);
  nsinitk<<<24576,256,0,stream>>>(Ycov,sval,Yh,Yl,Zh,Zl);

  // ---- split-bf16 MFMA Newton-Schulz ----
  u16 *Ych=Yh,*Ycl=Yl,*Zch=Zh,*Zcl=Zl,*Yah=Y2h,*Yal=Y2l,*Zah=Z2h,*Zal=Z2l;
  for (int it=0; it<NS_ITERS; ++it){
    if (it == 0){
      // Z == I: M = resplit(Y) elementwise (bit-identical to MFMA with identity operand)
      nsm0k<<<6144,256,0,stream>>>(Ych,Ycl,Mh,Ml);
      nstr0k<<<24,256,0,stream>>>(Ych,Ycl,trbuf);
      // Y-update via GEMM (z<24 of last=0 path); Z-update elementwise
      bmmpair<<<dim3(4,4,24),256,0,stream>>>(Ych,Ycl,Mh,Ml,Zch,Zcl,Yah,Yal,Zah,Zal,trbuf,0);
      nsz0k<<<6144,256,0,stream>>>(Mh,Ml,Zah,Zal,trbuf);
    } else {
      bmms<0><<<dim3(4,4,24),256,0,stream>>>(Zch,Zcl,Ych,Ycl,Mh,Ml,nullptr,0,trbuf+it*24);
      if (it < NS_ITERS-1)
        bmmpair<<<dim3(4,4,48),256,0,stream>>>(Ych,Ycl,Mh,Ml,Zch,Zcl,Yah,Yal,Zah,Zal,trbuf+it*24,0);
      else
        bmmpair<<<dim3(4,4,24),256,0,stream>>>(Ych,Ycl,Mh,Ml,Zch,Zcl,Yah,Yal,Zah,Zal,trbuf+it*24,1);
    }
    u16* t;
    t=Ych;Ych=Yah;Yah=t; t=Ycl;Ycl=Yal;Yal=t;
    t=Zch;Zch=Zah;Zah=t; t=Zcl;Zcl=Zal;Zal=t;
  }
  make_scalesk<<<1,64,0,stream>>>(sval,scl);
  bmms<2><<<dim3(4,4,12),256,0,stream>>>(Ych,Ycl,Zch,Zcl,Th,Tl,scl,12,nullptr);
  tveck<<<12,512,0,stream>>>(Th,Tl,mu,tvec);
  // f4c [img][c][n] -> fsT [img][n][c] split-bf16 (transposing repack; N=1024=32x32)
  repackk<0><<<dim3(32,8,4),256,0,stream>>>(f4c, fsh, fsl, 512,32,32);
  float* Mb = AR + 0;
  bmmt<<<dim3(16,4,12),256,0,stream>>>(Th,Tl,fsh,fsl,Mb);
  selectk<<<8192,256,0,stream>>>(Mb,tvec,aPtr,f4c,tf);

  // ---- decode (B=4; up fused into d2/d3 via RZ=2; d4 via dedicated d4upk) ----
  float* X1 = AR + 0;
  float* X2 = AR + 5242880ul;
  float* X3 = AR + 0;
  float* PARTA = AR + 2097152ul;
  float* PARTB = AR + 7340032ul;
  repackk<0><<<dim3(32,8,4),256,0,stream>>>(tf, xTFh, xTFl, 512,32,32);
  convMFMA(xTFh,xTFl, 4, X1, 4, 512,256,32,32,1,4,0,PARTA);
  repackk<0><<<dim3(32,4,4),256,0,stream>>>(X1, xX1h, xX1l, 256,32,32);
  convMFMA(xX1h,xX1l, 5, X2, 4, 256,128,64,64,1,2,2,PARTB);
  repackk<0><<<dim3(128,2,4),256,0,stream>>>(X2, xX2h, xX2l, 128,64,64);
  convMFMA(xX2h,xX2l, 6, X3, 4, 128,64,128,128,1,1,2,nullptr);
  d4upk<<<dim3(256,1,4),256,0,stream>>>(X3, Wm[7], Bm[7], dec);

  // ---- decoded encode + stats + content loss (B=4) ----
  float* mD = sm + SM_STATS_D;
  float* sD = sm + SM_STATS_D + 3840;
  float* F1d = AR + 0;
  float* F2d = AR + 0;
  float* F3d = AR + 10485760ul;
  {
    dim3 ge(64, 8, 4);
    conv3x3<8,4,1,1,0><<<ge,256,0,stream>>>(dec,Wm[0],Bm[0],F1d,xP1dh,xP1dl,4,3,64,256,256,1);
  }
  stats(F1d, 256, 65536, mD+0, sD+0);
  convMFMA(xP1dh,xP1dl, 1, F2d, 4, 64,128,128,128,1,1,0,nullptr);
  stats(F2d, 512, 16384, mD+256, sD+256);
  repackk<1><<<dim3(128,2,4),256,0,stream>>>(F2d, xF2dph, xF2dpl, 128,64,64);
  convMFMA(xF2dph,xF2dpl, 2, F3d, 4, 128,256,64,64,1,1,0,nullptr);
  statsk<<<1024,256,0,stream>>>(F3d,4096, mD+768, sD+768);
  repackk<1><<<dim3(32,4,4),256,0,stream>>>(F3d, xF3dph, xF3dpl, 256,32,32);
  convMFMA(xF3dph,xF3dpl, 3, tf, 4, 256,512,32,32,1,2,0,PARTA);
  statsk<<<2048,256,0,stream>>>(tf,1024, mD+1792, sD+1792);
  clossk<<<2048,256,0,stream>>>(tf,f4c,2097152, sm+SM_CLOSS);
  finalk<<<1,256,0,stream>>>(sm,out);
}

// Round 10
// 1967.555 us; speedup vs baseline: 1.2088x; 1.0685x over previous
//
#include <hip/hip_runtime.h>
#include <cstddef>

#define NS_ITERS 8
#define MSZ 262144  // 512*512
#define PL  6291456 // 24*MSZ
#define KSLOT 12312 // k-means accumulator slot stride (floats)

typedef unsigned short u16;
typedef __attribute__((ext_vector_type(8))) short bf16x8;
typedef __attribute__((ext_vector_type(4))) float f32x4;
typedef __attribute__((ext_vector_type(4))) short u16x4;

__device__ inline u16 bf16_rne(float x){
  unsigned u = __float_as_uint(x);
  unsigned r = u + 0x7fffu + ((u>>16)&1u);
  return (u16)(r>>16);
}
__device__ inline float bf16f(u16 h){
  return __uint_as_float(((unsigned)h)<<16);
}

// ---------------- workspace offsets (in floats) ----------------
#define OFF_F4C   0ul
#define OFF_F4S   2097152ul
#define OFF_TF    4194304ul
#define OFF_DEC   6291456ul
#define OFF_WSPL  7077888ul
#define OFF_SMALL 10223616ul
#define OFF_ARENA 10354688ul

// SMALL sub-offsets (floats)
#define SM_ASSIGN  12288
#define SM_MU      20480
#define SM_COUNTS  32768
#define SM_SVAL    32800
#define SM_SCALE   32832
#define SM_TVEC    32864
#define SM_STATS_S 39008
#define SM_STATS_D 46688
#define SM_CLOSS   54368
#define SM_TR      54464
#define SM_SPART   60000  // chunked-stats partial sums (doubles; 8B-aligned)

// ---------------- kernels ----------------

__global__ __launch_bounds__(256) void zerok(float* p, int n){
  int i = blockIdx.x*256 + threadIdx.x;
  if (i < n) p[i] = 0.f;
}

// direct 3x3 SAME conv (for e1: Cin=3)
template<int COT, int CIT, int POOL, int OUTW, int RZ>
__global__ __launch_bounds__(256,4) void conv3x3(
    const float* __restrict__ in, const float* __restrict__ wgt,
    const float* __restrict__ bias, float* __restrict__ out,
    u16* __restrict__ poh, u16* __restrict__ pol,
    int B, int Cin, int Cout, int H, int W, int relu)
{
  __shared__ float s_in[CIT][34][34];
  __shared__ float s_w[COT][CIT][9];
  const int tid = threadIdx.x;
  const int tx = tid & 15, ty = tid >> 4;
  const int tilesW = W >> 5;
  const int h0 = (blockIdx.x / tilesW) << 5;
  const int w0 = (blockIdx.x % tilesW) << 5;
  const int co0 = blockIdx.y * COT;
  const int b = blockIdx.z;
  float acc[COT][2][2];
  #pragma unroll
  for (int o=0;o<COT;o++){acc[o][0][0]=0.f;acc[o][0][1]=0.f;acc[o][1][0]=0.f;acc[o][1][1]=0.f;}
  const int y0 = ty*2, x0 = tx*2;
  for (int ci0 = 0; ci0 < Cin; ci0 += CIT){
    const int cic = (Cin - ci0 < CIT) ? (Cin - ci0) : CIT;
    const int tot = cic*1156;
    for (int e = tid; e < tot; e += 256){
      int c = e / 1156; int r = e - c*1156;
      int lh = r / 34, lw = r - lh*34;
      int ih = h0 + lh - 1, iw = w0 + lw - 1;
      float v = 0.f;
      if ((unsigned)ih < (unsigned)H && (unsigned)iw < (unsigned)W){
        if constexpr (RZ==2)
          v = in[((size_t)(b*Cin + ci0 + c)*(H>>1) + (ih>>1))*(size_t)(W>>1) + (iw>>1)];
        else
          v = in[((size_t)(b*Cin + ci0 + c)*H + ih)*W + iw];
      }
      s_in[c][lh][lw] = v;
    }
    const int wtot = COT*cic*9;
    for (int e = tid; e < wtot; e += 256){
      int o = e / (cic*9); int r = e - o*(cic*9);
      int c = r / 9, t = r - c*9;
      int co = co0 + o;
      float v = 0.f;
      if (co < Cout) v = wgt[(size_t)(co*Cin + ci0 + c)*9 + t];
      s_w[o][c][t] = v;
    }
    __syncthreads();
    for (int c = 0; c < cic; ++c){
      float p[4][4];
      #pragma unroll
      for (int r=0;r<4;r++)
        #pragma unroll
        for (int s=0;s<4;s++)
          p[r][s] = s_in[c][y0+r][x0+s];
      #pragma unroll
      for (int dh=0; dh<3; dh++)
        #pragma unroll
        for (int dw=0; dw<3; dw++){
          #pragma unroll
          for (int o=0;o<COT;o++){
            float wv = s_w[o][c][dh*3+dw];
            acc[o][0][0] = fmaf(p[dh  ][dw  ], wv, acc[o][0][0]);
            acc[o][0][1] = fmaf(p[dh  ][dw+1], wv, acc[o][0][1]);
            acc[o][1][0] = fmaf(p[dh+1][dw  ], wv, acc[o][1][0]);
            acc[o][1][1] = fmaf(p[dh+1][dw+1], wv, acc[o][1][1]);
          }
        }
    }
    __syncthreads();
  }
  if constexpr (POOL){
    bf16x8 p8h, p8l;
    #pragma unroll
    for (int o=0;o<COT;o++){
      const int co = co0 + o;
      const float bv = bias[co];
      float v00 = fmaxf(acc[o][0][0]+bv, 0.f);
      float v01 = fmaxf(acc[o][0][1]+bv, 0.f);
      float v10 = fmaxf(acc[o][1][0]+bv, 0.f);
      float v11 = fmaxf(acc[o][1][1]+bv, 0.f);
      if constexpr (OUTW){
        *(float2*)&out[((size_t)(b*Cout + co)*H + h0+y0  )*W + w0+x0] = make_float2(v00, v01);
        *(float2*)&out[((size_t)(b*Cout + co)*H + h0+y0+1)*W + w0+x0] = make_float2(v10, v11);
      }
      // same order as pool2k: p[0]+p[1]+p[2W]+p[2W+1]
      float pv = 0.25f*(v00 + v01 + v10 + v11);
      u16 h = bf16_rne(pv);
      p8h[o] = (short)h;
      p8l[o] = (short)bf16_rne(pv - bf16f(h));
    }
    size_t po = ((size_t)(b*(H>>1) + ((h0+y0)>>1))*(W>>1) + ((w0+x0)>>1))*(size_t)Cout + co0;
    *(bf16x8*)&poh[po] = p8h;
    *(bf16x8*)&pol[po] = p8l;
  } else {
    #pragma unroll
    for (int o=0;o<COT;o++){
      int co = co0 + o;
      if (co >= Cout) continue;
      float bv = bias[co];
      float v00 = acc[o][0][0] + bv;
      float v01 = acc[o][0][1] + bv;
      float v10 = acc[o][1][0] + bv;
      float v11 = acc[o][1][1] + bv;
      if (relu){
        v00 = fmaxf(v00, 0.f); v01 = fmaxf(v01, 0.f);
        v10 = fmaxf(v10, 0.f); v11 = fmaxf(v11, 0.f);
      }
      *(float2*)&out[((size_t)(b*Cout + co)*H + h0+y0  )*W + w0+x0] = make_float2(v00, v01);
      *(float2*)&out[((size_t)(b*Cout + co)*H + h0+y0+1)*W + w0+x0] = make_float2(v10, v11);
    }
  }
}

// dedicated d4: Cin=64 -> Cout=3, 256x256 out, nearest-up2 fused (input 128x128 fp32 NCHW).
__global__ __launch_bounds__(256,4) void d4upk(
    const float* __restrict__ in, const float* __restrict__ wgt,
    const float* __restrict__ bias, float* __restrict__ out)
{
  __shared__ float s_in[64][10][10];
  __shared__ float s_w[3][64][9];
  const int tid = threadIdx.x;
  const int b = blockIdx.z;
  const int h0 = (blockIdx.x >> 4) << 4, w0 = (blockIdx.x & 15) << 4;
  const int r0 = (h0 >> 1) - 1, c0 = (w0 >> 1) - 1;
  for (int e = tid; e < 6400; e += 256){
    int c = e / 100, r = e - c*100;
    int lr = r / 10, lc = r - lr*10;
    int gr = r0 + lr, gc = c0 + lc;
    float v = 0.f;
    if ((unsigned)gr < 128u && (unsigned)gc < 128u)
      v = in[((size_t)(b*64 + c)*128 + gr)*128 + gc];
    s_in[c][lr][lc] = v;
  }
  for (int e = tid; e < 1728; e += 256){
    int o = e / 576, r = e - o*576;
    int ci = r / 9, t = r - ci*9;
    s_w[o][ci][t] = wgt[(size_t)(o*64 + ci)*9 + t];
  }
  __syncthreads();
  const int ty = tid >> 4, tx = tid & 15;
  const int oh = h0 + ty, ow = w0 + tx;
  int lr3[3], lc3[3]; bool vr3[3], vc3[3];
  #pragma unroll
  for (int d=0; d<3; d++){
    int ih = oh + d - 1;
    vr3[d] = (unsigned)ih < 256u;
    lr3[d] = (ih >> 1) - r0;
    int iw = ow + d - 1;
    vc3[d] = (unsigned)iw < 256u;
    lc3[d] = (iw >> 1) - c0;
  }
  float a0 = 0.f, a1 = 0.f, a2 = 0.f;
  for (int ci = 0; ci < 64; ++ci){
    #pragma unroll
    for (int dh=0; dh<3; dh++){
      #pragma unroll
      for (int dw=0; dw<3; dw++){
        float v = (vr3[dh] && vc3[dw]) ? s_in[ci][lr3[dh]][lc3[dw]] : 0.f;
        a0 = fmaf(v, s_w[0][ci][dh*3+dw], a0);
        a1 = fmaf(v, s_w[1][ci][dh*3+dw], a1);
        a2 = fmaf(v, s_w[2][ci][dh*3+dw], a2);
      }
    }
  }
  out[((size_t)(b*3 + 0)*256 + oh)*256 + ow] = a0 + bias[0];
  out[((size_t)(b*3 + 1)*256 + oh)*256 + ow] = a1 + bias[1];
  out[((size_t)(b*3 + 2)*256 + oh)*256 + ow] = a2 + bias[2];
}

// pre-split conv weights: dst[(dhw*Cout + co)*Cin + ci]
__global__ __launch_bounds__(256) void wsplitk(const float* __restrict__ wgt,
                                               u16* __restrict__ dh_, u16* __restrict__ dl_,
                                               int Cout, int Cin){
  int idx = blockIdx.x*256 + threadIdx.x;
  int n = 9*Cout*Cin;
  if (idx >= n) return;
  int cc = Cout*Cin;
  int dhw = idx / cc;
  int r = idx - dhw*cc;
  int co = r / Cin, ci = r - co*Cin;
  float v = wgt[((size_t)co*Cin + ci)*9 + dhw];
  u16 h = bf16_rne(v);
  dh_[idx] = h;
  dl_[idx] = bf16_rne(v - bf16f(h));
}

// fp32 NCHW -> split-bf16 NHWC repack (POOL=1: fused avg-pool2, input 2Ho x 2Wo)
// grid: (Ho*Wo/32, C/64, B)
template<int POOL>
__global__ __launch_bounds__(256) void repackk(const float* __restrict__ in,
    u16* __restrict__ oh, u16* __restrict__ ol, int C, int Ho, int Wo)
{
  __shared__ unsigned tr[64][33];
  const int N = Ho*Wo;
  const int n0 = blockIdx.x << 5, c0 = blockIdx.y << 6, b = blockIdx.z;
  const int lnn = threadIdx.x & 31, gc = threadIdx.x >> 5;
  {
    const int n = n0 + lnn;
    const int ho = n / Wo, wo = n - ho*Wo;
    #pragma unroll
    for (int i=0;i<8;i++){
      const int c = (gc<<3) + i;
      float v;
      if constexpr (POOL){
        const float* p = in + ((size_t)(b*C + c0+c)*(Ho*2) + ho*2)*(size_t)(Wo*2) + (size_t)wo*2;
        v = 0.25f*(p[0] + p[1] + p[2*Wo] + p[2*Wo+1]);
      } else {
        v = in[((size_t)(b*C + c0+c))*N + n];
      }
      u16 h = bf16_rne(v);
      tr[c][lnn] = (unsigned)h | ((unsigned)bf16_rne(v - bf16f(h)) << 16);
    }
  }
  __syncthreads();
  const int n2 = threadIdx.x >> 3, oct = threadIdx.x & 7;
  bf16x8 vh, vl;
  #pragma unroll
  for (int j=0;j<8;j++){
    unsigned u = tr[(oct<<3)+j][n2];
    vh[j] = (short)(u & 0xffffu);
    vl[j] = (short)(u >> 16);
  }
  size_t o = ((size_t)b*N + (n0 + n2))*(size_t)C + c0 + (oct<<3);
  *(bf16x8*)&oh[o] = vh;
  *(bf16x8*)&ol[o] = vl;
}

// ---- split-bf16 MFMA direct conv 3x3 SAME; input pre-split NHWC u16 planes ----
// Tile: 64 co x (8x16) px; W staged per (dh,dw) tap. Bit-exact order.
template<int KS, int RESIZE>
__global__ __launch_bounds__(256,4) void convm(
    const u16* __restrict__ xh, const u16* __restrict__ xl,
    const u16* __restrict__ wsh, const u16* __restrict__ wsl,
    const float* __restrict__ bias, float* __restrict__ out,
    int Cin, int Cout, int H, int W, int relu)
{
  const int tilesW = W >> 4;
  const int h0 = (blockIdx.x / tilesW) << 3;
  const int w0 = (blockIdx.x % tilesW) << 4;
  const int co0 = blockIdx.y << 6;
  const int b  = blockIdx.z / KS;
  const int ks = blockIdx.z % KS;
  const int NB = gridDim.z / KS;
  const int tid = threadIdx.x;
  const int wid = tid >> 6, lane = tid & 63;
  const int wm = wid >> 1, wn = wid & 1;
  const int quad = lane >> 4, ln = lane & 15;

  __shared__ __align__(16) u16 sXh[180*40], sXl[180*40];
  __shared__ __align__(16) u16 sWh[64*40],  sWl[64*40];

  f32x4 acc[2][4];
  #pragma unroll
  for (int i=0;i<2;i++)
    #pragma unroll
    for (int j=0;j<4;j++)
      #pragma unroll
      for (int e=0;e<4;e++) acc[i][j][e] = 0.f;

  const int wco = tid >> 2, wcg = (tid & 3) << 3;

  const int ciA = ks*(Cin/KS), ciB = ciA + Cin/KS;
  for (int ci0 = ciA; ci0 < ciB; ci0 += 32){
    // X staging: halo 10x18 px, 4 slots of 8 ci.
    for (int e = tid; e < 720; e += 256){
      const int px = e >> 2, sl = e & 3;
      const int pr = px / 18, pc = px - pr*18;
      const int ih = h0 + pr - 1, iw = w0 + pc - 1;
      bf16x8 vh, vl;
      #pragma unroll
      for (int j=0;j<8;j++){ vh[j] = 0; vl[j] = 0; }
      if ((unsigned)ih < (unsigned)H && (unsigned)iw < (unsigned)W){
        size_t o;
        if constexpr (RESIZE==0)
          o = ((size_t)(b*H + ih)*W + iw)*(size_t)Cin + (size_t)(ci0 + sl*8);
        else
          o = ((size_t)(b*(H>>1) + (ih>>1))*(W>>1) + (iw>>1))*(size_t)Cin + (size_t)(ci0 + sl*8);
        vh = *(const bf16x8*)&xh[o];
        vl = *(const bf16x8*)&xl[o];
      }
      *(bf16x8*)&sXh[px*40 + sl*8] = vh;
      *(bf16x8*)&sXl[px*40 + sl*8] = vl;
    }
    for (int dh = 0; dh < 3; ++dh){
      for (int dw = 0; dw < 3; ++dw){
        {
          const size_t so = ((size_t)((dh*3+dw)*Cout + co0+wco))*Cin + ci0 + wcg;
          *(bf16x8*)&sWh[wco*40 + wcg] = *(const bf16x8*)&wsh[so];
          *(bf16x8*)&sWl[wco*40 + wcg] = *(const bf16x8*)&wsl[so];
        }
        __syncthreads();
        bf16x8 ah[2], al[2], bh[4], bl[4];
        #pragma unroll
        for (int t=0;t<2;t++){
          const int co_l = (wm*2+t)*16 + ln;
          ah[t] = *(const bf16x8*)&sWh[co_l*40 + quad*8];
          al[t] = *(const bf16x8*)&sWl[co_l*40 + quad*8];
        }
        #pragma unroll
        for (int t=0;t<4;t++){
          const int p = (wn*4+t)*16 + ln;
          const int px = ((p>>4) + dh)*18 + (p&15) + dw;
          const int xo = px*40 + quad*8;
          bh[t] = *(const bf16x8*)&sXh[xo];
          bl[t] = *(const bf16x8*)&sXl[xo];
        }
        #pragma unroll
        for (int mi=0;mi<2;mi++)
          #pragma unroll
          for (int ni=0;ni<4;ni++){
            acc[mi][ni] = __builtin_amdgcn_mfma_f32_16x16x32_bf16(ah[mi], bh[ni], acc[mi][ni], 0, 0, 0);
            acc[mi][ni] = __builtin_amdgcn_mfma_f32_16x16x32_bf16(ah[mi], bl[ni], acc[mi][ni], 0, 0, 0);
            acc[mi][ni] = __builtin_amdgcn_mfma_f32_16x16x32_bf16(al[mi], bh[ni], acc[mi][ni], 0, 0, 0);
          }
        __syncthreads();
      }
    }
  }
  #pragma unroll
  for (int mi=0;mi<2;mi++){
    const int co = co0 + (wm*2+mi)*16 + quad*4;
    #pragma unroll
    for (int ni=0;ni<4;ni++){
      const int p = (wn*4+ni)*16 + ln;
      const int oh = h0 + (p>>4), ow = w0 + (p&15);
      #pragma unroll
      for (int rg=0; rg<4; rg++){
        const int cog = co + rg;
        if constexpr (KS==1){
          float v = acc[mi][ni][rg] + bias[cog];
          if (relu) v = fmaxf(v, 0.f);
          out[((size_t)(b*Cout + cog)*H + oh)*W + ow] = v;
        } else {
          out[((size_t)((ks*NB + b)*Cout + cog)*H + oh)*W + ow] = acc[mi][ni][rg];
        }
      }
    }
  }
}

// reduce split-K partials + bias + relu
__global__ __launch_bounds__(256) void sumk(const float* __restrict__ part, const float* __restrict__ bias,
                                            float* __restrict__ out, int Cout, int HW, int KS, int relu, int n){
  int idx = blockIdx.x*256 + threadIdx.x;
  if (idx >= n) return;
  int co = (idx / HW) % Cout;
  float v = bias[co];
  for (int k=0;k<KS;k++) v += part[(size_t)k*n + idx];
  if (relu) v = fmaxf(v, 0.f);
  out[idx] = v;
}

// per-(b,c) spatial mean & std (ddof=0) — single-pass (small HW)
__global__ __launch_bounds__(256) void statsk(const float* __restrict__ x, int HW,
                                              float* __restrict__ mo, float* __restrict__ so){
  int bc = blockIdx.x, tid = threadIdx.x;
  const float* p = x + (size_t)bc*HW;
  double s = 0.0, s2 = 0.0;
  for (int i = tid; i < HW; i += 256){ double v = p[i]; s += v; s2 += v*v; }
  __shared__ double sh[256], sh2[256];
  sh[tid] = s; sh2[tid] = s2; __syncthreads();
  for (int k=128;k>0;k>>=1){ if (tid<k){ sh[tid]+=sh[tid+k]; sh2[tid]+=sh2[tid+k]; } __syncthreads(); }
  if (tid == 0){
    double m = sh[0]/HW;
    double var = sh2[0]/HW - m*m;
    if (var < 0.0) var = 0.0;
    mo[bc] = (float)m;
    so[bc] = (float)sqrt(var);
  }
}

// chunked stats phase 1: grid (bc, CH); partial double sums to part[(bc*CH+ch)*2 +{0,1}]
__global__ __launch_bounds__(256) void statspk(const float* __restrict__ x, int HW,
                                               double* __restrict__ part){
  const int bc = blockIdx.x, ch = blockIdx.y, CH = gridDim.y, tid = threadIdx.x;
  const int clen = HW / CH;
  const float* p = x + (size_t)bc*HW + (size_t)ch*clen;
  double s = 0.0, s2 = 0.0;
  for (int i = tid; i < clen; i += 256){ double v = p[i]; s += v; s2 += v*v; }
  __shared__ double sh[256], sh2[256];
  sh[tid] = s; sh2[tid] = s2; __syncthreads();
  for (int k=128;k>0;k>>=1){ if (tid<k){ sh[tid]+=sh[tid+k]; sh2[tid]+=sh2[tid+k]; } __syncthreads(); }
  if (tid == 0){
    part[(size_t)(bc*CH + ch)*2    ] = sh[0];
    part[(size_t)(bc*CH + ch)*2 + 1] = sh2[0];
  }
}

// chunked stats phase 2: one thread per bc
__global__ __launch_bounds__(256) void statsfk(const double* __restrict__ part, int CH, int HW, int nbc,
                                               float* __restrict__ mo, float* __restrict__ so){
  int bc = blockIdx.x*256 + threadIdx.x;
  if (bc >= nbc) return;
  double s = 0.0, s2 = 0.0;
  for (int ch = 0; ch < CH; ++ch){
    s  += part[(size_t)(bc*CH + ch)*2];
    s2 += part[(size_t)(bc*CH + ch)*2 + 1];
  }
  double m = s/HW;
  double var = s2/HW - m*m;
  if (var < 0.0) var = 0.0;
  mo[bc] = (float)m;
  so[bc] = (float)sqrt(var);
}

// f4 (C-major, per image 512x1024) -> ptsT [8][1024][512]
__global__ __launch_bounds__(256) void transposek(const float* __restrict__ f4c,
                                                  const float* __restrict__ f4s,
                                                  float* __restrict__ ptsT){
  __shared__ float t[32][33];
  int r = blockIdx.z;
  const float* src = (r < 4) ? (f4c + (size_t)r*524288) : (f4s + (size_t)(r-4)*524288);
  int n0 = blockIdx.x*32, c0 = blockIdx.y*32;
  int lx = threadIdx.x & 31, ly = threadIdx.x >> 5;
  for (int j=0;j<32;j+=8)
    t[ly+j][lx] = src[(size_t)(c0+ly+j)*1024 + n0+lx];
  __syncthreads();
  for (int j=0;j<32;j+=8)
    ptsT[((size_t)r*1024 + n0+ly+j)*512 + c0+lx] = t[lx][ly+j];
}

// slot0 init: sums = first 3 points (centroids), counts = 1
__global__ __launch_bounds__(256) void initcent2k(const float* __restrict__ ptsT, float* __restrict__ KACC){
  int i = blockIdx.x*256 + threadIdx.x;
  if (i < 12288){
    int c = i & 511; int k = (i >> 9) % 3; int r = i / 1536;
    KACC[r*1536 + k*512 + c] = ptsT[((size_t)r*1024 + k)*512 + c];
  }
  if (i < 24) KACC[12288 + i] = 1.f;
}

// fused k-means step
__global__ __launch_bounds__(256) void kstepk(const float* __restrict__ ptsT,
    const float* __restrict__ prev, float* __restrict__ next,
    int* __restrict__ a, int nodiv)
{
  const int r = blockIdx.x, sl = blockIdx.y;
  const int tid = threadIdx.x;
  __shared__ float sc[1536];
  __shared__ int sa[32];
  __shared__ float red[3][8][32];
  __shared__ int scnt[3];
  if (tid < 3) scnt[tid] = 0;
  for (int i = tid; i < 1536; i += 256){
    float s = prev[r*1536 + i];
    float cnt = nodiv ? 1.f : (prev[12288 + r*3 + (i>>9)] + 1e-6f);
    sc[i] = s / cnt;
  }
  __syncthreads();
  const float* base = ptsT + (size_t)r*524288;
  const int wid = tid >> 6, lane = tid & 63;
  for (int rep = 0; rep < 8; ++rep){
    int p = wid*8 + rep;
    int n = sl*32 + p;
    const float* pp = base + (size_t)n*512;
    float d0=0.f,d1=0.f,d2=0.f;
    #pragma unroll
    for (int i=0;i<8;i++){
      int c = lane + i*64;
      float v = pp[c];
      float e0 = v - sc[c], e1 = v - sc[512+c], e2 = v - sc[1024+c];
      d0 = fmaf(e0,e0,d0); d1 = fmaf(e1,e1,d1); d2 = fmaf(e2,e2,d2);
    }
    #pragma unroll
    for (int off=32; off>0; off>>=1){
      d0 += __shfl_down(d0, off, 64);
      d1 += __shfl_down(d1, off, 64);
      d2 += __shfl_down(d2, off, 64);
    }
    if (lane == 0){
      int bi = 0; float bd = d0;
      if (d1 < bd){ bd = d1; bi = 1; }
      if (d2 < bd){ bd = d2; bi = 2; }
      sa[p] = bi;
      a[r*1024 + n] = bi;
    }
  }
  __syncthreads();
  if (tid < 32) atomicAdd(&scnt[sa[tid]], 1);
  __syncthreads();
  if (tid < 3) atomicAdd(&next[12288 + r*3 + tid], (float)scnt[tid]);
  const int g = tid >> 5, lc = tid & 31;
  for (int cj = 0; cj < 16; ++cj){
    int c = cj*32 + lc;
    float s0=0.f,s1=0.f,s2=0.f;
    #pragma unroll
    for (int q=0;q<4;q++){
      int nl = g*4 + q;
      float v = base[(size_t)(sl*32+nl)*512 + c];
      int an = sa[nl];
      s0 += (an==0)?v:0.f;
      s1 += (an==1)?v:0.f;
      s2 += (an==2)?v:0.f;
    }
    red[0][g][lc]=s0; red[1][g][lc]=s1; red[2][g][lc]=s2;
    __syncthreads();
    if (g == 0){
      float t0=0.f,t1=0.f,t2=0.f;
      #pragma unroll
      for (int q2=0;q2<8;q2++){ t0+=red[0][q2][lc]; t1+=red[1][q2][lc]; t2+=red[2][q2][lc]; }
      atomicAdd(&next[r*1536 +          c], t0);
      atomicAdd(&next[r*1536 +  512 +   c], t1);
      atomicAdd(&next[r*1536 + 1024 +   c], t2);
    }
    __syncthreads();
  }
}

// final mu/counts from slot 11
__global__ __launch_bounds__(256) void mufink(const float* __restrict__ slot,
                                              float* __restrict__ mu, float* __restrict__ counts){
  int i = blockIdx.x*256 + threadIdx.x;
  if (i >= 12288) return;
  int c = i & 511; int k = (i >> 9) % 3; int r = i / 1536;
  int cs = r >> 2, img = r & 3;
  int i0 = cs*12 + img*3;
  float cnt = slot[12288 + r*3 + k];
  mu[(size_t)(i0+k)*512 + c] = slot[r*1536 + k*512 + c] / (cnt + 1e-6f);
  if (c == 0) counts[i0+k] = cnt;
}

// masked centered split planes
__global__ __launch_bounds__(256) void maskcenterk(const float* __restrict__ f4c, const float* __restrict__ f4s,
        const int* __restrict__ a, const float* __restrict__ mu,
        u16* __restrict__ Ph, u16* __restrict__ Pl){
  size_t i4 = ((size_t)blockIdx.x*256 + threadIdx.x)*4;
  if (i4 >= (size_t)PL*2) return;
  int z = (int)(i4 >> 19);
  int rc = (int)(i4 & 524287);
  int c = rc >> 10, n = rc & 1023;
  int cs = z / 12; int rem = z - cs*12; int img = rem / 3; int k = rem - img*3;
  const float* pts = (cs ? f4s : f4c) + (size_t)img*524288;
  float m = mu[(size_t)z*512 + c];
  const int* an = a + (cs*4 + img)*1024 + n;
  float4 v4 = *(const float4*)&pts[(size_t)c*1024 + n];
  float vv[4] = {v4.x, v4.y, v4.z, v4.w};
  u16x4 oh, ol;
  #pragma unroll
  for (int j=0;j<4;j++){
    float v = (an[j] == k) ? (vv[j] - m) : 0.f;
    u16 h = bf16_rne(v);
    oh[j] = (short)h;
    ol[j] = (short)bf16_rne(v - bf16f(h));
  }
  *(u16x4*)&Ph[i4] = oh;
  *(u16x4*)&Pl[i4] = ol;
}

// covariance via MFMA, trace accumulated. Tile 128x128; 1-D grid 384 blocks,
// XCD-swizzled: all 16 tiles of a z share one XCD (z = (bid&7) + 8*(w>>4)).
__global__ __launch_bounds__(256) void covgemm(const u16* __restrict__ Ph, const u16* __restrict__ Pl,
        const float* __restrict__ counts, float* __restrict__ Ycov, float* __restrict__ trsum){
  const int bid = blockIdx.x;
  const int xcd = bid & 7, w = bid >> 3;
  const int z = xcd + ((w >> 4) << 3);
  const int t4 = w & 15;
  const int m0 = (t4 >> 2) << 7, n0 = (t4 & 3) << 7;
  const u16* Pbh = Ph + (size_t)z*524288;
  const u16* Pbl = Pl + (size_t)z*524288;
  const int tid = threadIdx.x;

  __shared__ __align__(16) u16 sAh[128*40], sAl[128*40];
  __shared__ __align__(16) u16 sBh[128*40], sBl[128*40];

  const int ra = tid >> 2, qa = tid & 3;
  const int wid = tid >> 6, lane = tid & 63;
  const int wm = wid >> 1, wn = wid & 1;
  const int quad = lane >> 4, ln = lane & 15;

  f32x4 acc[4][4];
  #pragma unroll
  for (int i=0;i<4;i++)
    #pragma unroll
    for (int j=0;j<4;j++)
      #pragma unroll
      for (int e=0;e<4;e++) acc[i][j][e] = 0.f;

  for (int k0 = 0; k0 < 1024; k0 += 32){
    *(bf16x8*)&sAh[ra*40 + qa*8]      = *(const bf16x8*)&Pbh[(size_t)(m0+ra)*1024    + k0 + qa*8];
    *(bf16x8*)&sAl[ra*40 + qa*8]      = *(const bf16x8*)&Pbl[(size_t)(m0+ra)*1024    + k0 + qa*8];
    *(bf16x8*)&sAh[(ra+64)*40 + qa*8] = *(const bf16x8*)&Pbh[(size_t)(m0+ra+64)*1024 + k0 + qa*8];
    *(bf16x8*)&sAl[(ra+64)*40 + qa*8] = *(const bf16x8*)&Pbl[(size_t)(m0+ra+64)*1024 + k0 + qa*8];
    *(bf16x8*)&sBh[ra*40 + qa*8]      = *(const bf16x8*)&Pbh[(size_t)(n0+ra)*1024    + k0 + qa*8];
    *(bf16x8*)&sBl[ra*40 + qa*8]      = *(const bf16x8*)&Pbl[(size_t)(n0+ra)*1024    + k0 + qa*8];
    *(bf16x8*)&sBh[(ra+64)*40 + qa*8] = *(const bf16x8*)&Pbh[(size_t)(n0+ra+64)*1024 + k0 + qa*8];
    *(bf16x8*)&sBl[(ra+64)*40 + qa*8] = *(const bf16x8*)&Pbl[(size_t)(n0+ra+64)*1024 + k0 + qa*8];
    __syncthreads();

    bf16x8 ah[4], al[4], bh[4], bl[4];
    #pragma unroll
    for (int t=0;t<4;t++){
      const int moA = ((wm*4+t)*16 + ln)*40 + quad*8;
      const int moB = ((wn*4+t)*16 + ln)*40 + quad*8;
      ah[t] = *(const bf16x8*)&sAh[moA];
      al[t] = *(const bf16x8*)&sAl[moA];
      bh[t] = *(const bf16x8*)&sBh[moB];
      bl[t] = *(const bf16x8*)&sBl[moB];
    }
    #pragma unroll
    for (int mi=0;mi<4;mi++)
      #pragma unroll
      for (int ni=0;ni<4;ni++){
        acc[mi][ni] = __builtin_amdgcn_mfma_f32_16x16x32_bf16(ah[mi], bh[ni], acc[mi][ni], 0, 0, 0);
        acc[mi][ni] = __builtin_amdgcn_mfma_f32_16x16x32_bf16(ah[mi], bl[ni], acc[mi][ni], 0, 0, 0);
        acc[mi][ni] = __builtin_amdgcn_mfma_f32_16x16x32_bf16(al[mi], bh[ni], acc[mi][ni], 0, 0, 0);
      }
    __syncthreads();
  }
  const float inv = 1.f/(counts[z] + 1e-6f);
  float dsum = 0.f; bool anyd = false;
  #pragma unroll
  for (int mi=0;mi<4;mi++){
    const int mbase = m0 + (wm*4+mi)*16 + quad*4;
    #pragma unroll
    for (int ni=0;ni<4;ni++){
      const int n = n0 + (wn*4+ni)*16 + ln;
      #pragma unroll
      for (int rg=0;rg<4;rg++){
        const int m = mbase + rg;
        float v = acc[mi][ni][rg]*inv + ((m==n)?0.1f:0.f);
        Ycov[(size_t)z*MSZ + (size_t)m*512 + n] = v;
        if (m0==n0 && m==n){ dsum += v; anyd = true; }
      }
    }
  }
  if (anyd) atomicAdd(&trsum[z], dsum);
}

// init split planes: Y = Ycov/trace (hi+lo bf16), Z = I
__global__ __launch_bounds__(256) void nsinitk(const float* __restrict__ Ycov, const float* __restrict__ sval,
                                               u16* __restrict__ Yh, u16* __restrict__ Yl,
                                               u16* __restrict__ Zh, u16* __restrict__ Zl){
  size_t idx = (size_t)blockIdx.x*256 + threadIdx.x;
  if (idx >= (size_t)PL) return;
  int z = (int)(idx >> 18);
  int rc = (int)(idx & (MSZ-1));
  int rr = rc >> 9, cc = rc & 511;
  float y = Ycov[idx] / sval[z];
  u16 h = bf16_rne(y);
  Yh[idx] = h;
  Yl[idx] = bf16_rne(y - bf16f(h));
  Zh[idx] = (rr==cc) ? (u16)0x3F80 : (u16)0;
  Zl[idx] = 0;
}

// it=0 specializations (Z == I exactly):
// M = Z*Y via MFMA degenerates to elementwise resplit of (Yh+Yl) — bit-identical.
__global__ __launch_bounds__(256) void nsm0k(const u16* __restrict__ Yh, const u16* __restrict__ Yl,
                                             u16* __restrict__ Mh, u16* __restrict__ Ml){
  size_t i4 = ((size_t)blockIdx.x*256 + threadIdx.x)*4;
  if (i4 >= (size_t)PL) return;
  u16x4 hv = *(const u16x4*)&Yh[i4];
  u16x4 lv = *(const u16x4*)&Yl[i4];
  u16x4 oh, ol;
  #pragma unroll
  for (int j=0;j<4;j++){
    float v = bf16f((u16)hv[j]) + bf16f((u16)lv[j]);
    u16 h = bf16_rne(v);
    oh[j] = (short)h;
    ol[j] = (short)bf16_rne(v - bf16f(h));
  }
  *(u16x4*)&Mh[i4] = oh;
  *(u16x4*)&Ml[i4] = ol;
}

// trace of M (= sum of diag (Yh+Yl)) per z; grid 24 blocks.
__global__ __launch_bounds__(256) void nstr0k(const u16* __restrict__ Yh, const u16* __restrict__ Yl,
                                              float* __restrict__ tr){
  int z = blockIdx.x, tid = threadIdx.x;
  float s = 0.f;
  for (int i = tid; i < 512; i += 256){
    size_t o = (size_t)z*MSZ + (size_t)i*513;
    s += bf16f(Yh[o]) + bf16f(Yl[o]);
  }
  __shared__ float sh[256];
  sh[tid] = s; __syncthreads();
  for (int k=128;k>0;k>>=1){ if (tid<k) sh[tid]+=sh[tid+k]; __syncthreads(); }
  if (tid == 0) tr[z] = sh[0];
}

// it=0 Z-update: Z2 = alpha*(Mh+Ml) + beta*I (since M*Z with Z=I is elementwise-exact).
__global__ __launch_bounds__(256) void nsz0k(const u16* __restrict__ Mh, const u16* __restrict__ Ml,
                                             u16* __restrict__ Z2h, u16* __restrict__ Z2l,
                                             const float* __restrict__ trAcc){
  size_t i4 = ((size_t)blockIdx.x*256 + threadIdx.x)*4;
  if (i4 >= (size_t)PL) return;
  int z = (int)(i4 >> 18);
  int rc = (int)(i4 & (MSZ-1));
  int row = rc >> 9, col = rc & 511;
  const float tr = trAcc[z];
  const float g2 = fminf(512.f/fmaxf(tr, 1e-6f), 2.7f);
  const float oz = 0.5f*sqrtf(g2);
  const float alpha = -g2*oz, beta = 3.f*oz;
  u16x4 hv = *(const u16x4*)&Mh[i4];
  u16x4 lv = *(const u16x4*)&Ml[i4];
  u16x4 oh, ol;
  #pragma unroll
  for (int j=0;j<4;j++){
    float m = bf16f((u16)hv[j]) + bf16f((u16)lv[j]);
    float zv = (row == col + j) ? 1.f : 0.f;
    float v = alpha*m + beta*zv;
    u16 h = bf16_rne(v);
    oh[j] = (short)h;
    ol[j] = (short)bf16_rne(v - bf16f(h));
  }
  *(u16x4*)&Z2h[i4] = oh;
  *(u16x4*)&Z2l[i4] = ol;
}

// ---- split-bf16 MFMA batched GEMM 512x512x512; tile 128x128 ----
// SWZ=1: 1-D grid NZ*16 blocks, XCD-swizzled (NZ%8==0). SWZ=0: 3-D grid (4,4,NZ).
template<int MODE, int SWZ>
__global__ __launch_bounds__(256) void bmms(
    const u16* __restrict__ Ah, const u16* __restrict__ Al,
    const u16* __restrict__ Bh, const u16* __restrict__ Bl,
    u16* __restrict__ Ch, u16* __restrict__ Cl,
    const float* __restrict__ osc,
    int aoff, float* __restrict__ trAcc)
{
  int z, m0, n0;
  if constexpr (SWZ){
    const int bid = blockIdx.x;
    const int xcd = bid & 7, w = bid >> 3;
    z = xcd + ((w >> 4) << 3);
    const int t4 = w & 15;
    m0 = (t4 >> 2) << 7; n0 = (t4 & 3) << 7;
  } else {
    z = blockIdx.z; m0 = blockIdx.y*128; n0 = blockIdx.x*128;
  }
  const u16* Abh = Ah + (size_t)(z+aoff)*MSZ;
  const u16* Abl = Al + (size_t)(z+aoff)*MSZ;
  const u16* Bbh = Bh + (size_t)z*MSZ;
  const u16* Bbl = Bl + (size_t)z*MSZ;
  const int tid = threadIdx.x;

  __shared__ __align__(16) u16 sAh[128*40], sAl[128*40];
  __shared__ __align__(16) u16 sBh[128*40], sBl[128*40];

  const int ra = tid >> 2, qa = tid & 3;
  const int wid = tid >> 6, lane = tid & 63;
  const int wm = wid >> 1, wn = wid & 1;
  const int quad = lane >> 4, ln = lane & 15;

  f32x4 acc[4][4];
  #pragma unroll
  for (int i=0;i<4;i++)
    #pragma unroll
    for (int j=0;j<4;j++)
      #pragma unroll
      for (int e=0;e<4;e++) acc[i][j][e] = 0.f;

  for (int k0 = 0; k0 < 512; k0 += 32){
    *(bf16x8*)&sAh[ra*40 + qa*8]      = *(const bf16x8*)&Abh[(size_t)(m0+ra)*512    + k0 + qa*8];
    *(bf16x8*)&sAl[ra*40 + qa*8]      = *(const bf16x8*)&Abl[(size_t)(m0+ra)*512    + k0 + qa*8];
    *(bf16x8*)&sAh[(ra+64)*40 + qa*8] = *(const bf16x8*)&Abh[(size_t)(m0+ra+64)*512 + k0 + qa*8];
    *(bf16x8*)&sAl[(ra+64)*40 + qa*8] = *(const bf16x8*)&Abl[(size_t)(m0+ra+64)*512 + k0 + qa*8];
    *(bf16x8*)&sBh[ra*40 + qa*8]      = *(const bf16x8*)&Bbh[(size_t)(n0+ra)*512    + k0 + qa*8];
    *(bf16x8*)&sBl[ra*40 + qa*8]      = *(const bf16x8*)&Bbl[(size_t)(n0+ra)*512    + k0 + qa*8];
    *(bf16x8*)&sBh[(ra+64)*40 + qa*8] = *(const bf16x8*)&Bbh[(size_t)(n0+ra+64)*512 + k0 + qa*8];
    *(bf16x8*)&sBl[(ra+64)*40 + qa*8] = *(const bf16x8*)&Bbl[(size_t)(n0+ra+64)*512 + k0 + qa*8];
    __syncthreads();

    bf16x8 ah[4], al[4], bh[4], bl[4];
    #pragma unroll
    for (int t=0;t<4;t++){
      const int moA = ((wm*4+t)*16 + ln)*40 + quad*8;
      const int moB = ((wn*4+t)*16 + ln)*40 + quad*8;
      ah[t] = *(const bf16x8*)&sAh[moA];
      al[t] = *(const bf16x8*)&sAl[moA];
      bh[t] = *(const bf16x8*)&sBh[moB];
      bl[t] = *(const bf16x8*)&sBl[moB];
    }
    #pragma unroll
    for (int mi=0;mi<4;mi++)
      #pragma unroll
      for (int ni=0;ni<4;ni++){
        acc[mi][ni] = __builtin_amdgcn_mfma_f32_16x16x32_bf16(ah[mi], bh[ni], acc[mi][ni], 0, 0, 0);
        acc[mi][ni] = __builtin_amdgcn_mfma_f32_16x16x32_bf16(ah[mi], bl[ni], acc[mi][ni], 0, 0, 0);
        acc[mi][ni] = __builtin_amdgcn_mfma_f32_16x16x32_bf16(al[mi], bh[ni], acc[mi][ni], 0, 0, 0);
      }
    __syncthreads();
  }

  float alpha = 1.f;
  if constexpr (MODE==2){ alpha = osc[z]; }

  float dsum = 0.f; bool anyd = false;
  #pragma unroll
  for (int mi=0;mi<4;mi++){
    const int mbase = m0 + (wm*4+mi)*16 + quad*4;
    #pragma unroll
    for (int ni=0;ni<4;ni++){
      const int n = n0 + (wn*4+ni)*16 + ln;
      #pragma unroll
      for (int rg=0;rg<4;rg++){
        const int m = mbase + rg;
        const size_t off = (size_t)z*MSZ + (size_t)m*512 + n;
        float v = alpha*acc[mi][ni][rg];
        u16 h = bf16_rne(v);
        Ch[off] = h;
        Cl[off] = bf16_rne(v - bf16f(h));
        if (MODE==0 && trAcc && m0==n0 && m==n){ dsum += v; anyd = true; }
      }
    }
  }
  if (MODE==0 && anyd) atomicAdd(&trAcc[z], dsum);
}

// merged NS update (128x128 tile); 1-D grid NZ*16 blocks, XCD-swizzled.
__global__ __launch_bounds__(256) void bmmpair(
    const u16* __restrict__ Yh, const u16* __restrict__ Yl,
    const u16* __restrict__ Mh, const u16* __restrict__ Ml,
    const u16* __restrict__ Zh, const u16* __restrict__ Zl,
    u16* __restrict__ Y2h, u16* __restrict__ Y2l,
    u16* __restrict__ Z2h, u16* __restrict__ Z2l,
    const float* __restrict__ trAcc, int last)
{
  const int bid = blockIdx.x;
  const int xcd = bid & 7, w = bid >> 3;
  const int z = xcd + ((w >> 4) << 3);
  const int t4 = w & 15;
  const int m0 = (t4 >> 2) << 7, n0 = (t4 & 3) << 7;
  int zz; bool isY;
  if (last){ zz = z; isY = (z >= 12); }
  else { isY = (z < 24); zz = isY ? z : (z - 24); }
  const size_t zo = (size_t)zz*MSZ;
  const u16 *Abh, *Abl, *Bbh, *Bbl, *Dbh, *Dbl;
  u16 *Cbh, *Cbl;
  if (isY){
    Abh = Yh + zo; Abl = Yl + zo;
    Bbh = Mh + zo; Bbl = Ml + zo;
    Dbh = Yh + zo; Dbl = Yl + zo;
    Cbh = Y2h + zo; Cbl = Y2l + zo;
  } else {
    Abh = Mh + zo; Abl = Ml + zo;
    Bbh = Zh + zo; Bbl = Zl + zo;
    Dbh = Zh + zo; Dbl = Zl + zo;
    Cbh = Z2h + zo; Cbl = Z2l + zo;
  }
  const int tid = threadIdx.x;

  __shared__ __align__(16) u16 sAh[128*40], sAl[128*40];
  __shared__ __align__(16) u16 sBh[128*40], sBl[128*40];

  const int ra = tid >> 2, qa = tid & 3;
  const int wid = tid >> 6, lane = tid & 63;
  const int wm = wid >> 1, wn = wid & 1;
  const int quad = lane >> 4, ln = lane & 15;

  f32x4 acc[4][4];
  #pragma unroll
  for (int i=0;i<4;i++)
    #pragma unroll
    for (int j=0;j<4;j++)
      #pragma unroll
      for (int e=0;e<4;e++) acc[i][j][e] = 0.f;

  for (int k0 = 0; k0 < 512; k0 += 32){
    *(bf16x8*)&sAh[ra*40 + qa*8]      = *(const bf16x8*)&Abh[(size_t)(m0+ra)*512    + k0 + qa*8];
    *(bf16x8*)&sAl[ra*40 + qa*8]      = *(const bf16x8*)&Abl[(size_t)(m0+ra)*512    + k0 + qa*8];
    *(bf16x8*)&sAh[(ra+64)*40 + qa*8] = *(const bf16x8*)&Abh[(size_t)(m0+ra+64)*512 + k0 + qa*8];
    *(bf16x8*)&sAl[(ra+64)*40 + qa*8] = *(const bf16x8*)&Abl[(size_t)(m0+ra+64)*512 + k0 + qa*8];
    *(bf16x8*)&sBh[ra*40 + qa*8]      = *(const bf16x8*)&Bbh[(size_t)(n0+ra)*512    + k0 + qa*8];
    *(bf16x8*)&sBl[ra*40 + qa*8]      = *(const bf16x8*)&Bbl[(size_t)(n0+ra)*512    + k0 + qa*8];
    *(bf16x8*)&sBh[(ra+64)*40 + qa*8] = *(const bf16x8*)&Bbh[(size_t)(n0+ra+64)*512 + k0 + qa*8];
    *(bf16x8*)&sBl[(ra+64)*40 + qa*8] = *(const bf16x8*)&Bbl[(size_t)(n0+ra+64)*512 + k0 + qa*8];
    __syncthreads();

    bf16x8 ah[4], al[4], bh[4], bl[4];
    #pragma unroll
    for (int t=0;t<4;t++){
      const int moA = ((wm*4+t)*16 + ln)*40 + quad*8;
      const int moB = ((wn*4+t)*16 + ln)*40 + quad*8;
      ah[t] = *(const bf16x8*)&sAh[moA];
      al[t] = *(const bf16x8*)&sAl[moA];
      bh[t] = *(const bf16x8*)&sBh[moB];
      bl[t] = *(const bf16x8*)&sBl[moB];
    }
    #pragma unroll
    for (int mi=0;mi<4;mi++)
      #pragma unroll
      for (int ni=0;ni<4;ni++){
        acc[mi][ni] = __builtin_amdgcn_mfma_f32_16x16x32_bf16(ah[mi], bh[ni], acc[mi][ni], 0, 0, 0);
        acc[mi][ni] = __builtin_amdgcn_mfma_f32_16x16x32_bf16(ah[mi], bl[ni], acc[mi][ni], 0, 0, 0);
        acc[mi][ni] = __builtin_amdgcn_mfma_f32_16x16x32_bf16(al[mi], bh[ni], acc[mi][ni], 0, 0, 0);
      }
    __syncthreads();
  }

  const float tr = trAcc[zz];
  const float g2 = fminf(512.f/fmaxf(tr, 1e-6f), 2.7f);
  const float oz = 0.5f*sqrtf(g2);
  const float alpha = -g2*oz, beta = 3.f*oz;

  #pragma unroll
  for (int mi=0;mi<4;mi++){
    const int mbase = m0 + (wm*4+mi)*16 + quad*4;
    #pragma unroll
    for (int ni=0;ni<4;ni++){
      const int n = n0 + (wn*4+ni)*16 + ln;
      #pragma unroll
      for (int rg=0;rg<4;rg++){
        const int m = mbase + rg;
        const size_t off = (size_t)m*512 + n;
        float v = alpha*acc[mi][ni][rg] + beta*(bf16f(Dbh[off]) + bf16f(Dbl[off]));
        u16 h = bf16_rne(v);
        Cbh[off] = h;
        Cbl[off] = bf16_rne(v - bf16f(h));
      }
    }
  }
}

// tpts = T[z] @ f[img]: M=512, N=1024, K=512, fp32 out.
// B is pre-transposed fsT [img][n][c]; tile 128M x 64N; grid (16,4,12).
__global__ __launch_bounds__(256,4) void bmmt(
    const u16* __restrict__ Th, const u16* __restrict__ Tl,
    const u16* __restrict__ fh, const u16* __restrict__ fl,
    float* __restrict__ Cf)
{
  const int z = blockIdx.z;
  const u16* Abh = Th + (size_t)z*MSZ;
  const u16* Abl = Tl + (size_t)z*MSZ;
  const u16* Bbh = fh + (size_t)(z/3)*524288;
  const u16* Bbl = fl + (size_t)(z/3)*524288;
  const int m0 = blockIdx.y*128, n0 = blockIdx.x*64;
  const int tid = threadIdx.x;

  __shared__ __align__(16) u16 sAh[128*40], sAl[128*40];
  __shared__ __align__(16) u16 sBh[64*40], sBl[64*40];

  const int ra = tid >> 2, qa = tid & 3;
  const int wid = tid >> 6, lane = tid & 63;
  const int wm = wid >> 1, wn = wid & 1;
  const int quad = lane >> 4, ln = lane & 15;

  f32x4 acc[4][2];
  #pragma unroll
  for (int i=0;i<4;i++)
    #pragma unroll
    for (int j=0;j<2;j++)
      #pragma unroll
      for (int e=0;e<4;e++) acc[i][j][e] = 0.f;

  for (int k0 = 0; k0 < 512; k0 += 32){
    *(bf16x8*)&sAh[ra*40 + qa*8]      = *(const bf16x8*)&Abh[(size_t)(m0+ra)*512    + k0 + qa*8];
    *(bf16x8*)&sAl[ra*40 + qa*8]      = *(const bf16x8*)&Abl[(size_t)(m0+ra)*512    + k0 + qa*8];
    *(bf16x8*)&sAh[(ra+64)*40 + qa*8] = *(const bf16x8*)&Abh[(size_t)(m0+ra+64)*512 + k0 + qa*8];
    *(bf16x8*)&sAl[(ra+64)*40 + qa*8] = *(const bf16x8*)&Abl[(size_t)(m0+ra+64)*512 + k0 + qa*8];
    *(bf16x8*)&sBh[ra*40 + qa*8]      = *(const bf16x8*)&Bbh[(size_t)(n0+ra)*512    + k0 + qa*8];
    *(bf16x8*)&sBl[ra*40 + qa*8]      = *(const bf16x8*)&Bbl[(size_t)(n0+ra)*512    + k0 + qa*8];
    __syncthreads();

    bf16x8 ah[4], al[4], bh[2], bl[2];
    #pragma unroll
    for (int t=0;t<4;t++){
      const int moA = ((wm*4+t)*16 + ln)*40 + quad*8;
      ah[t] = *(const bf16x8*)&sAh[moA];
      al[t] = *(const bf16x8*)&sAl[moA];
    }
    #pragma unroll
    for (int t=0;t<2;t++){
      const int moB = ((wn*2+t)*16 + ln)*40 + quad*8;
      bh[t] = *(const bf16x8*)&sBh[moB];
      bl[t] = *(const bf16x8*)&sBl[moB];
    }
    #pragma unroll
    for (int mi=0;mi<4;mi++)
      #pragma unroll
      for (int ni=0;ni<2;ni++){
        acc[mi][ni] = __builtin_amdgcn_mfma_f32_16x16x32_bf16(ah[mi], bh[ni], acc[mi][ni], 0, 0, 0);
        acc[mi][ni] = __builtin_amdgcn_mfma_f32_16x16x32_bf16(ah[mi], bl[ni], acc[mi][ni], 0, 0, 0);
        acc[mi][ni] = __builtin_amdgcn_mfma_f32_16x16x32_bf16(al[mi], bh[ni], acc[mi][ni], 0, 0, 0);
      }
    __syncthreads();
  }
  #pragma unroll
  for (int mi=0;mi<4;mi++){
    const int mbase = m0 + (wm*4+mi)*16 + quad*4;
    #pragma unroll
    for (int ni=0;ni<2;ni++){
      const int n = n0 + (wn*2+ni)*16 + ln;
      #pragma unroll
      for (int rg=0;rg<4;rg++){
        const int m = mbase + rg;
        Cf[(size_t)z*524288 + (size_t)m*1024 + n] = acc[mi][ni][rg];
      }
    }
  }
}

__global__ void make_scalesk(const float* __restrict__ sval, float* __restrict__ scl){
  int i = threadIdx.x;
  if (i < 12) scl[i] = sqrtf(sval[12+i] / sval[i]);
}

// tvec[b] = mu_s[b] - T[b] @ mu_c[b]
__global__ __launch_bounds__(512) void tveck(const u16* __restrict__ Th, const u16* __restrict__ Tl,
                                             const float* __restrict__ mu, float* __restrict__ tvec){
  int b = blockIdx.x; int c = threadIdx.x;
  __shared__ float mc[512];
  mc[c] = mu[(size_t)b*512 + c];
  __syncthreads();
  const u16* Trh = Th + ((size_t)b*512 + c)*512;
  const u16* Trl = Tl + ((size_t)b*512 + c)*512;
  float s = 0.f;
  for (int d=0; d<512; d++) s = fmaf(bf16f(Trh[d]) + bf16f(Trl[d]), mc[d], s);
  tvec[b*512 + c] = mu[(size_t)(12+b)*512 + c] - s;
}

__global__ __launch_bounds__(256) void selectk(const float* __restrict__ tpts, const float* __restrict__ tvec,
        const int* __restrict__ a, const float* __restrict__ f4c, float* __restrict__ tf){
  size_t idx = (size_t)blockIdx.x*256 + threadIdx.x;
  if (idx >= 2097152ul) return;
  int n = (int)(idx & 1023);
  int c = (int)((idx >> 10) & 511);
  int img = (int)(idx >> 19);
  int k = a[img*1024 + n];
  int b = img*3 + k;
  float v = tpts[((size_t)b*512 + c)*1024 + n] + tvec[b*512 + c];
  tf[idx] = 0.6f*v + 0.4f*f4c[idx];
}

__global__ __launch_bounds__(256) void clossk(const float* __restrict__ x, const float* __restrict__ y,
                                              int n, float* __restrict__ acc){
  int tid = threadIdx.x;
  float s = 0.f;
  for (size_t i = (size_t)blockIdx.x*256 + tid; i < (size_t)n; i += (size_t)gridDim.x*256){
    float d = x[i] - y[i]; s = fmaf(d, d, s);
  }
  __shared__ float sh[256];
  sh[tid] = s; __syncthreads();
  for (int k=128;k>0;k>>=1){ if (tid<k) sh[tid]+=sh[tid+k]; __syncthreads(); }
  if (tid==0) atomicAdd(acc, sh[0]);
}

__global__ __launch_bounds__(256) void finalk(const float* __restrict__ sm, float* __restrict__ out){
  int tid = threadIdx.x;
  const int cnts[4] = {256,512,1024,2048};
  const int offs[4] = {0,256,768,1792};
  const float* mS = sm + SM_STATS_S;
  const float* sS = sm + SM_STATS_S + 3840;
  const float* mD = sm + SM_STATS_D;
  const float* sD = sm + SM_STATS_D + 3840;
  double sl = 0.0;
  for (int L=0; L<4; ++L){
    int cnt = cnts[L], off = offs[L];
    double inv = 1.0/cnt;
    for (int i=tid; i<cnt; i+=256){
      double dm = (double)mD[off+i] - (double)mS[off+i];
      double ds = (double)sD[off+i] - (double)sS[off+i];
      sl += (dm*dm + ds*ds)*inv;
    }
  }
  __shared__ double sh[256];
  sh[tid] = sl; __syncthreads();
  for (int k=128;k>0;k>>=1){ if (tid<k) sh[tid]+=sh[tid+k]; __syncthreads(); }
  if (tid==0){
    double closs = (double)sm[SM_CLOSS] / 2097152.0;
    out[0] = (float)(closs + 0.01*sh[0]);
  }
}

// ---------------- host ----------------

extern "C" void kernel_launch(void* const* d_in, const int* in_sizes, int n_in,
                              void* d_out, int out_size, void* d_ws, size_t ws_size,
                              hipStream_t stream)
{
  const float* content = (const float*)d_in[0];
  const float* style   = (const float*)d_in[1];
  const float* Wm[8]; const float* Bm[8];
  for (int i=0;i<8;i++){ Wm[i] = (const float*)d_in[2+2*i]; Bm[i] = (const float*)d_in[3+2*i]; }
  float* out = (float*)d_out;
  float* ws = (float*)d_ws;

  float* f4c  = ws + OFF_F4C;
  float* f4s  = ws + OFF_F4S;
  float* tf   = ws + OFF_TF;
  float* dec  = ws + OFF_DEC;
  float* sm   = ws + OFF_SMALL;
  float* AR   = ws + OFF_ARENA;
  int*   aPtr = (int*)(sm + SM_ASSIGN);
  float* mu   = sm + SM_MU;
  float* counts = sm + SM_COUNTS;
  float* sval = sm + SM_SVAL;
  float* scl  = sm + SM_SCALE;
  float* tvec = sm + SM_TVEC;
  float* trbuf = sm + SM_TR;
  double* spart = (double*)(sm + SM_SPART);

  u16* WB = (u16*)(ws + OFF_WSPL);
  u16 *w2h=WB+0,       *w2l=WB+73728;
  u16 *w3h=WB+147456,  *w3l=WB+442368;
  u16 *w4h=WB+737280,  *w4l=WB+1916928;
  u16 *v1h=WB+3096576, *v1l=WB+4276224;
  u16 *v2h=WB+5455872, *v2l=WB+5750784;
  u16 *v3h=WB+6045696, *v3l=WB+6119424;

  float* Ycov = AR;
  u16* Mh  = (u16*)(AR);
  u16* Ml  = (u16*)(AR + 3145728ul);
  u16* Yh  = (u16*)(AR + 6291456ul);
  u16* Yl  = (u16*)(AR + 9437184ul);
  u16* Zh  = (u16*)(AR + 12582912ul);
  u16* Zl  = (u16*)(AR + 15728640ul);
  u16* Y2h = (u16*)(AR + 18874368ul);
  u16* Y2l = (u16*)(AR + 22020096ul);
  u16* Z2h = (u16*)(AR + 25165824ul);
  u16* Z2l = (u16*)(AR + 28311552ul);
  u16* Ph  = (u16*)(AR + 18874368ul);
  u16* Pl  = (u16*)(AR + 25165824ul);
  float* ptsT = AR + 25165824ul;
  u16* Th  = (u16*)(AR + 18874368ul);
  u16* Tl  = (u16*)(AR + 20971520ul);
  u16* fsh = (u16*)(AR + 23068672ul);
  u16* fsl = (u16*)(AR + 24117248ul);
  float* KACC = AR + 0;

  // NHWC split-bf16 activation planes (u16), placed in lifetime-dead arena slots.
  // encode (B=8):
  u16* xP1h  = (u16*)(AR + 16777216ul);   // 8*128*128*64 u16 -> 4.19M floats
  u16* xP1l  = (u16*)(AR + 20971520ul);
  u16* xF2ph = (u16*)(AR + 16777216ul);   // pooled F2: 8*64*64*128
  u16* xF2pl = (u16*)(AR + 18874368ul);
  u16* xF3ph = (u16*)(AR + 18874368ul);   // pooled F3: 8*32*32*256 (clear of PART8)
  u16* xF3pl = (u16*)(AR + 19922944ul);
  // decode (B=4):
  u16* xTFh  = (u16*)(AR + 8388608ul);    // 4*32*32*512
  u16* xTFl  = (u16*)(AR + 9437184ul);
  u16* xX1h  = (u16*)(AR + 1048576ul);    // 4*32*32*256
  u16* xX1l  = (u16*)(AR + 1572864ul);
  u16* xX2h  = (u16*)(AR + 11534336ul);   // 4*64*64*128
  u16* xX2l  = (u16*)(AR + 12582912ul);
  // decoded encode (B=4):
  u16* xP1dh = (u16*)(AR + 16777216ul);   // 4*128*128*64
  u16* xP1dl = (u16*)(AR + 18874368ul);
  u16* xF2dph= (u16*)(AR + 16777216ul);   // pooled F2d: 4*64*64*128
  u16* xF2dpl= (u16*)(AR + 17825792ul);
  u16* xF3dph= (u16*)(AR + 16777216ul);   // pooled F3d: 4*32*32*256
  u16* xF3dpl= (u16*)(AR + 17301504ul);

  zerok<<<512,256,0,stream>>>(sm, 131072);

  {
    auto wsp = [&](int li, u16* wh, u16* wl, int Co, int Ci){
      int n = 9*Co*Ci;
      wsplitk<<<(n+255)/256,256,0,stream>>>(Wm[li], wh, wl, Co, Ci);
    };
    wsp(1,w2h,w2l,128,64);
    wsp(2,w3h,w3l,256,128);
    wsp(3,w4h,w4l,512,256);
    wsp(4,v1h,v1l,256,512);
    wsp(5,v2h,v2l,128,256);
    wsp(6,v3h,v3l,64,128);
  }

  // MFMA conv on pre-split NHWC u16 input. KS in {1,2,4}, RZ in {0,2}.
  auto convMFMA = [&](const u16* xh, const u16* xl, int li, float* outp,
                      int B,int Ci,int Co,int H,int Wd,int relu,int KS,int RZ,float* part){
    const u16 *wh=nullptr,*wl=nullptr;
    switch(li){
      case 1: wh=w2h; wl=w2l; break;
      case 2: wh=w3h; wl=w3l; break;
      case 3: wh=w4h; wl=w4l; break;
      case 4: wh=v1h; wl=v1l; break;
      case 5: wh=v2h; wl=v2l; break;
      case 6: wh=v3h; wl=v3l; break;
    }
    int tiles = (H>>3)*(Wd>>4);
    if (KS==1){
      dim3 g(tiles,Co>>6,B);
      if (RZ==0) convm<1,0><<<g,256,0,stream>>>(xh,xl,wh,wl,Bm[li],outp,Ci,Co,H,Wd,relu);
      else       convm<1,2><<<g,256,0,stream>>>(xh,xl,wh,wl,Bm[li],outp,Ci,Co,H,Wd,relu);
    } else if (KS==2){
      dim3 g(tiles,Co>>6,B*2);
      if (RZ==0) convm<2,0><<<g,256,0,stream>>>(xh,xl,wh,wl,nullptr,part,Ci,Co,H,Wd,relu);
      else       convm<2,2><<<g,256,0,stream>>>(xh,xl,wh,wl,nullptr,part,Ci,Co,H,Wd,relu);
      int n = B*Co*H*Wd;
      sumk<<<(n+255)/256,256,0,stream>>>(part,Bm[li],outp,Co,H*Wd,2,relu,n);
    } else {
      dim3 g(tiles,Co>>6,B*4);
      convm<4,0><<<g,256,0,stream>>>(xh,xl,wh,wl,nullptr,part,Ci,Co,H,Wd,relu);
      int n = B*Co*H*Wd;
      sumk<<<(n+255)/256,256,0,stream>>>(part,Bm[li],outp,Co,H*Wd,4,relu,n);
    }
  };

  // chunked stats: big HW -> 2-phase
  auto stats = [&](const float* x, int nbc, int HW, float* mo, float* so){
    if (HW >= 16384){
      int CH = (HW >= 65536) ? 8 : 4;
      statspk<<<dim3(nbc,CH),256,0,stream>>>(x, HW, spart);
      statsfk<<<(nbc+255)/256,256,0,stream>>>(spart, CH, HW, nbc, mo, so);
    } else {
      statsk<<<nbc,256,0,stream>>>(x, HW, mo, so);
    }
  };

  float* mS = sm + SM_STATS_S;
  float* sS = sm + SM_STATS_S + 3840;

  // ---- batched content+style encode (B=8 from e2 down) ----
  float* F1   = AR + 0;
  float* F2_8 = AR + 0;
  float* F3_8 = AR + 0;
  float* PART8 = AR + 10485760ul;

  {
    dim3 ge(64, 8, 4);  // (256/32)^2 tiles, 64/8 co-groups, B=4
    // content e1: fp32 output is dead (style overwrites F1 before any reader) -> OUTW=0
    conv3x3<8,4,1,0,0><<<ge,256,0,stream>>>(content,Wm[0],Bm[0],F1,xP1h,           xP1l,           4,3,64,256,256,1);
    conv3x3<8,4,1,1,0><<<ge,256,0,stream>>>(style,  Wm[0],Bm[0],F1,xP1h+4194304ul, xP1l+4194304ul, 4,3,64,256,256,1);
  }
  stats(F1, 256, 65536, mS+0, sS+0);

  convMFMA(xP1h,xP1l, 1, F2_8, 8, 64,128,128,128,1,1,0,nullptr);
  stats(F2_8 + 8388608ul, 512, 16384, mS+256, sS+256);
  repackk<1><<<dim3(128,2,8),256,0,stream>>>(F2_8, xF2ph, xF2pl, 128,64,64);
  convMFMA(xF2ph,xF2pl, 2, F3_8, 8, 128,256,64,64,1,1,0,nullptr);
  statsk<<<1024,256,0,stream>>>(F3_8 + 4194304ul, 4096, mS+768, sS+768);
  repackk<1><<<dim3(32,4,8),256,0,stream>>>(F3_8, xF3ph, xF3pl, 256,32,32);
  convMFMA(xF3ph,xF3pl, 3, f4c, 8, 256,512,32,32,1,2,0,PART8);
  statsk<<<2048,256,0,stream>>>(f4s,1024, mS+1792, sS+1792);

  // ---- fused k-means ----
  transposek<<<dim3(32,16,8),256,0,stream>>>(f4c,f4s,ptsT);
  zerok<<<(12*KSLOT+255)/256,256,0,stream>>>(KACC, 12*KSLOT);
  initcent2k<<<48,256,0,stream>>>(ptsT,KACC);
  for (int it=0; it<=10; ++it){
    kstepk<<<dim3(8,32),256,0,stream>>>(ptsT, KACC + (size_t)it*KSLOT, KACC + (size_t)(it+1)*KSLOT, aPtr, it==0 ? 1 : 0);
  }
  mufink<<<48,256,0,stream>>>(KACC + 11ul*KSLOT, mu, counts);

  // ---- covariances via MFMA (XCD-swizzled 1-D grid) ----
  maskcenterk<<<12288,256,0,stream>>>(f4c,f4s,aPtr,mu,Ph,Pl);
  covgemm<<<384,256,0,stream>>>(Ph,Pl,counts,Ycov,sval);
  nsinitk<<<24576,256,0,stream>>>(Ycov,sval,Yh,Yl,Zh,Zl);

  // ---- split-bf16 MFMA Newton-Schulz ----
  u16 *Ych=Yh,*Ycl=Yl,*Zch=Zh,*Zcl=Zl,*Yah=Y2h,*Yal=Y2l,*Zah=Z2h,*Zal=Z2l;
  for (int it=0; it<NS_ITERS; ++it){
    if (it == 0){
      // Z == I: M = resplit(Y) elementwise (bit-identical to MFMA with identity operand)
      nsm0k<<<6144,256,0,stream>>>(Ych,Ycl,Mh,Ml);
      nstr0k<<<24,256,0,stream>>>(Ych,Ycl,trbuf);
      // Y-update via GEMM (z<24 of last=0 path); Z-update elementwise
      bmmpair<<<384,256,0,stream>>>(Ych,Ycl,Mh,Ml,Zch,Zcl,Yah,Yal,Zah,Zal,trbuf,0);
      nsz0k<<<6144,256,0,stream>>>(Mh,Ml,Zah,Zal,trbuf);
    } else {
      bmms<0,1><<<384,256,0,stream>>>(Zch,Zcl,Ych,Ycl,Mh,Ml,nullptr,0,trbuf+it*24);
      if (it < NS_ITERS-1)
        bmmpair<<<768,256,0,stream>>>(Ych,Ycl,Mh,Ml,Zch,Zcl,Yah,Yal,Zah,Zal,trbuf+it*24,0);
      else
        bmmpair<<<384,256,0,stream>>>(Ych,Ycl,Mh,Ml,Zch,Zcl,Yah,Yal,Zah,Zal,trbuf+it*24,1);
    }
    u16* t;
    t=Ych;Ych=Yah;Yah=t; t=Ycl;Ycl=Yal;Yal=t;
    t=Zch;Zch=Zah;Zah=t; t=Zcl;Zcl=Zal;Zal=t;
  }
  make_scalesk<<<1,64,0,stream>>>(sval,scl);
  bmms<2,0><<<dim3(4,4,12),256,0,stream>>>(Ych,Ycl,Zch,Zcl,Th,Tl,scl,12,nullptr);
  tveck<<<12,512,0,stream>>>(Th,Tl,mu,tvec);
  // f4c [img][c][n] -> fsT [img][n][c] split-bf16 (transposing repack; N=1024=32x32)
  repackk<0><<<dim3(32,8,4),256,0,stream>>>(f4c, fsh, fsl, 512,32,32);
  float* Mb = AR + 0;
  bmmt<<<dim3(16,4,12),256,0,stream>>>(Th,Tl,fsh,fsl,Mb);
  selectk<<<8192,256,0,stream>>>(Mb,tvec,aPtr,f4c,tf);

  // ---- decode (B=4; up fused into d2/d3 via RZ=2; d4 via dedicated d4upk) ----
  float* X1 = AR + 0;
  float* X2 = AR + 5242880ul;
  float* X3 = AR + 0;
  float* PARTA = AR + 2097152ul;
  float* PARTB = AR + 7340032ul;
  repackk<0><<<dim3(32,8,4),256,0,stream>>>(tf, xTFh, xTFl, 512,32,32);
  convMFMA(xTFh,xTFl, 4, X1, 4, 512,256,32,32,1,4,0,PARTA);
  repackk<0><<<dim3(32,4,4),256,0,stream>>>(X1, xX1h, xX1l, 256,32,32);
  convMFMA(xX1h,xX1l, 5, X2, 4, 256,128,64,64,1,2,2,PARTB);
  repackk<0><<<dim3(128,2,4),256,0,stream>>>(X2, xX2h, xX2l, 128,64,64);
  convMFMA(xX2h,xX2l, 6, X3, 4, 128,64,128,128,1,1,2,nullptr);
  d4upk<<<dim3(256,1,4),256,0,stream>>>(X3, Wm[7], Bm[7], dec);

  // ---- decoded encode + stats + content loss (B=4) ----
  float* mD = sm + SM_STATS_D;
  float* sD = sm + SM_STATS_D + 3840;
  float* F1d = AR + 0;
  float* F2d = AR + 0;
  float* F3d = AR + 10485760ul;
  {
    dim3 ge(64, 8, 4);
    conv3x3<8,4,1,1,0><<<ge,256,0,stream>>>(dec,Wm[0],Bm[0],F1d,xP1dh,xP1dl,4,3,64,256,256,1);
  }
  stats(F1d, 256, 65536, mD+0, sD+0);
  convMFMA(xP1dh,xP1dl, 1, F2d, 4, 64,128,128,128,1,1,0,nullptr);
  stats(F2d, 512, 16384, mD+256, sD+256);
  repackk<1><<<dim3(128,2,4),256,0,stream>>>(F2d, xF2dph, xF2dpl, 128,64,64);
  convMFMA(xF2dph,xF2dpl, 2, F3d, 4, 128,256,64,64,1,1,0,nullptr);
  statsk<<<1024,256,0,stream>>>(F3d,4096, mD+768, sD+768);
  repackk<1><<<dim3(32,4,4),256,0,stream>>>(F3d, xF3dph, xF3dpl, 256,32,32);
  convMFMA(xF3dph,xF3dpl, 3, tf, 4, 256,512,32,32,1,2,0,PARTA);
  statsk<<<2048,256,0,stream>>>(tf,1024, mD+1792, sD+1792);
  clossk<<<2048,256,0,stream>>>(tf,f4c,2097152, sm+SM_CLOSS);
  finalk<<<1,256,0,stream>>>(sm,out);
}

// Round 11
// 1940.912 us; speedup vs baseline: 1.2254x; 1.0137x over previous
//
#include <hip/hip_runtime.h>
#include <cstddef>

#define NS_ITERS 8
#define MSZ 262144  // 512*512
#define PL  6291456 // 24*MSZ
#define KSLOT 12312 // k-means accumulator slot stride (floats)

typedef unsigned short u16;
typedef __attribute__((ext_vector_type(8))) short bf16x8;
typedef __attribute__((ext_vector_type(4))) float f32x4;
typedef __attribute__((ext_vector_type(4))) short u16x4;

__device__ inline u16 bf16_rne(float x){
  unsigned u = __float_as_uint(x);
  unsigned r = u + 0x7fffu + ((u>>16)&1u);
  return (u16)(r>>16);
}
__device__ inline float bf16f(u16 h){
  return __uint_as_float(((unsigned)h)<<16);
}

// ---------------- workspace offsets (in floats) ----------------
#define OFF_F4C   0ul
#define OFF_F4S   2097152ul
#define OFF_TF    4194304ul
#define OFF_DEC   6291456ul
#define OFF_WSPL  7077888ul
#define OFF_SMALL 10223616ul
#define OFF_ARENA 10354688ul

// SMALL sub-offsets (floats)
#define SM_ASSIGN  12288
#define SM_MU      20480
#define SM_COUNTS  32768
#define SM_SVAL    32800
#define SM_SCALE   32832
#define SM_TVEC    32864
#define SM_STATS_S 39008
#define SM_STATS_D 46688
#define SM_CLOSS   54368
#define SM_TR      54464
#define SM_SPART   60000  // chunked-stats partial sums (doubles; 8B-aligned)

// ---------------- kernels ----------------

__global__ __launch_bounds__(256) void zerok(float* p, int n){
  int i = blockIdx.x*256 + threadIdx.x;
  if (i < n) p[i] = 0.f;
}

// direct 3x3 SAME conv (for e1: Cin=3)
template<int COT, int CIT, int POOL, int OUTW, int RZ>
__global__ __launch_bounds__(256,4) void conv3x3(
    const float* __restrict__ in, const float* __restrict__ wgt,
    const float* __restrict__ bias, float* __restrict__ out,
    u16* __restrict__ poh, u16* __restrict__ pol,
    int B, int Cin, int Cout, int H, int W, int relu)
{
  __shared__ float s_in[CIT][34][34];
  __shared__ float s_w[COT][CIT][9];
  const int tid = threadIdx.x;
  const int tx = tid & 15, ty = tid >> 4;
  const int tilesW = W >> 5;
  const int h0 = (blockIdx.x / tilesW) << 5;
  const int w0 = (blockIdx.x % tilesW) << 5;
  const int co0 = blockIdx.y * COT;
  const int b = blockIdx.z;
  float acc[COT][2][2];
  #pragma unroll
  for (int o=0;o<COT;o++){acc[o][0][0]=0.f;acc[o][0][1]=0.f;acc[o][1][0]=0.f;acc[o][1][1]=0.f;}
  const int y0 = ty*2, x0 = tx*2;
  for (int ci0 = 0; ci0 < Cin; ci0 += CIT){
    const int cic = (Cin - ci0 < CIT) ? (Cin - ci0) : CIT;
    const int tot = cic*1156;
    for (int e = tid; e < tot; e += 256){
      int c = e / 1156; int r = e - c*1156;
      int lh = r / 34, lw = r - lh*34;
      int ih = h0 + lh - 1, iw = w0 + lw - 1;
      float v = 0.f;
      if ((unsigned)ih < (unsigned)H && (unsigned)iw < (unsigned)W){
        if constexpr (RZ==2)
          v = in[((size_t)(b*Cin + ci0 + c)*(H>>1) + (ih>>1))*(size_t)(W>>1) + (iw>>1)];
        else
          v = in[((size_t)(b*Cin + ci0 + c)*H + ih)*W + iw];
      }
      s_in[c][lh][lw] = v;
    }
    const int wtot = COT*cic*9;
    for (int e = tid; e < wtot; e += 256){
      int o = e / (cic*9); int r = e - o*(cic*9);
      int c = r / 9, t = r - c*9;
      int co = co0 + o;
      float v = 0.f;
      if (co < Cout) v = wgt[(size_t)(co*Cin + ci0 + c)*9 + t];
      s_w[o][c][t] = v;
    }
    __syncthreads();
    for (int c = 0; c < cic; ++c){
      float p[4][4];
      #pragma unroll
      for (int r=0;r<4;r++)
        #pragma unroll
        for (int s=0;s<4;s++)
          p[r][s] = s_in[c][y0+r][x0+s];
      #pragma unroll
      for (int dh=0; dh<3; dh++)
        #pragma unroll
        for (int dw=0; dw<3; dw++){
          #pragma unroll
          for (int o=0;o<COT;o++){
            float wv = s_w[o][c][dh*3+dw];
            acc[o][0][0] = fmaf(p[dh  ][dw  ], wv, acc[o][0][0]);
            acc[o][0][1] = fmaf(p[dh  ][dw+1], wv, acc[o][0][1]);
            acc[o][1][0] = fmaf(p[dh+1][dw  ], wv, acc[o][1][0]);
            acc[o][1][1] = fmaf(p[dh+1][dw+1], wv, acc[o][1][1]);
          }
        }
    }
    __syncthreads();
  }
  if constexpr (POOL){
    bf16x8 p8h, p8l;
    #pragma unroll
    for (int o=0;o<COT;o++){
      const int co = co0 + o;
      const float bv = bias[co];
      float v00 = fmaxf(acc[o][0][0]+bv, 0.f);
      float v01 = fmaxf(acc[o][0][1]+bv, 0.f);
      float v10 = fmaxf(acc[o][1][0]+bv, 0.f);
      float v11 = fmaxf(acc[o][1][1]+bv, 0.f);
      if constexpr (OUTW){
        *(float2*)&out[((size_t)(b*Cout + co)*H + h0+y0  )*W + w0+x0] = make_float2(v00, v01);
        *(float2*)&out[((size_t)(b*Cout + co)*H + h0+y0+1)*W + w0+x0] = make_float2(v10, v11);
      }
      // same order as pool2k: p[0]+p[1]+p[2W]+p[2W+1]
      float pv = 0.25f*(v00 + v01 + v10 + v11);
      u16 h = bf16_rne(pv);
      p8h[o] = (short)h;
      p8l[o] = (short)bf16_rne(pv - bf16f(h));
    }
    size_t po = ((size_t)(b*(H>>1) + ((h0+y0)>>1))*(W>>1) + ((w0+x0)>>1))*(size_t)Cout + co0;
    *(bf16x8*)&poh[po] = p8h;
    *(bf16x8*)&pol[po] = p8l;
  } else {
    #pragma unroll
    for (int o=0;o<COT;o++){
      int co = co0 + o;
      if (co >= Cout) continue;
      float bv = bias[co];
      float v00 = acc[o][0][0] + bv;
      float v01 = acc[o][0][1] + bv;
      float v10 = acc[o][1][0] + bv;
      float v11 = acc[o][1][1] + bv;
      if (relu){
        v00 = fmaxf(v00, 0.f); v01 = fmaxf(v01, 0.f);
        v10 = fmaxf(v10, 0.f); v11 = fmaxf(v11, 0.f);
      }
      *(float2*)&out[((size_t)(b*Cout + co)*H + h0+y0  )*W + w0+x0] = make_float2(v00, v01);
      *(float2*)&out[((size_t)(b*Cout + co)*H + h0+y0+1)*W + w0+x0] = make_float2(v10, v11);
    }
  }
}

// dedicated d4: Cin=64 -> Cout=3, 256x256 out, nearest-up2 fused (input 128x128 fp32 NCHW).
__global__ __launch_bounds__(256,4) void d4upk(
    const float* __restrict__ in, const float* __restrict__ wgt,
    const float* __restrict__ bias, float* __restrict__ out)
{
  __shared__ float s_in[64][10][10];
  __shared__ float s_w[3][64][9];
  const int tid = threadIdx.x;
  const int b = blockIdx.z;
  const int h0 = (blockIdx.x >> 4) << 4, w0 = (blockIdx.x & 15) << 4;
  const int r0 = (h0 >> 1) - 1, c0 = (w0 >> 1) - 1;
  for (int e = tid; e < 6400; e += 256){
    int c = e / 100, r = e - c*100;
    int lr = r / 10, lc = r - lr*10;
    int gr = r0 + lr, gc = c0 + lc;
    float v = 0.f;
    if ((unsigned)gr < 128u && (unsigned)gc < 128u)
      v = in[((size_t)(b*64 + c)*128 + gr)*128 + gc];
    s_in[c][lr][lc] = v;
  }
  for (int e = tid; e < 1728; e += 256){
    int o = e / 576, r = e - o*576;
    int ci = r / 9, t = r - ci*9;
    s_w[o][ci][t] = wgt[(size_t)(o*64 + ci)*9 + t];
  }
  __syncthreads();
  const int ty = tid >> 4, tx = tid & 15;
  const int oh = h0 + ty, ow = w0 + tx;
  int lr3[3], lc3[3]; bool vr3[3], vc3[3];
  #pragma unroll
  for (int d=0; d<3; d++){
    int ih = oh + d - 1;
    vr3[d] = (unsigned)ih < 256u;
    lr3[d] = (ih >> 1) - r0;
    int iw = ow + d - 1;
    vc3[d] = (unsigned)iw < 256u;
    lc3[d] = (iw >> 1) - c0;
  }
  float a0 = 0.f, a1 = 0.f, a2 = 0.f;
  for (int ci = 0; ci < 64; ++ci){
    #pragma unroll
    for (int dh=0; dh<3; dh++){
      #pragma unroll
      for (int dw=0; dw<3; dw++){
        float v = (vr3[dh] && vc3[dw]) ? s_in[ci][lr3[dh]][lc3[dw]] : 0.f;
        a0 = fmaf(v, s_w[0][ci][dh*3+dw], a0);
        a1 = fmaf(v, s_w[1][ci][dh*3+dw], a1);
        a2 = fmaf(v, s_w[2][ci][dh*3+dw], a2);
      }
    }
  }
  out[((size_t)(b*3 + 0)*256 + oh)*256 + ow] = a0 + bias[0];
  out[((size_t)(b*3 + 1)*256 + oh)*256 + ow] = a1 + bias[1];
  out[((size_t)(b*3 + 2)*256 + oh)*256 + ow] = a2 + bias[2];
}

// pre-split conv weights: dst[(dhw*Cout + co)*Cin + ci]
__global__ __launch_bounds__(256) void wsplitk(const float* __restrict__ wgt,
                                               u16* __restrict__ dh_, u16* __restrict__ dl_,
                                               int Cout, int Cin){
  int idx = blockIdx.x*256 + threadIdx.x;
  int n = 9*Cout*Cin;
  if (idx >= n) return;
  int cc = Cout*Cin;
  int dhw = idx / cc;
  int r = idx - dhw*cc;
  int co = r / Cin, ci = r - co*Cin;
  float v = wgt[((size_t)co*Cin + ci)*9 + dhw];
  u16 h = bf16_rne(v);
  dh_[idx] = h;
  dl_[idx] = bf16_rne(v - bf16f(h));
}

// fp32 NCHW -> split-bf16 NHWC repack (POOL=1: fused avg-pool2, input 2Ho x 2Wo)
// grid: (Ho*Wo/32, C/64, B)
template<int POOL>
__global__ __launch_bounds__(256) void repackk(const float* __restrict__ in,
    u16* __restrict__ oh, u16* __restrict__ ol, int C, int Ho, int Wo)
{
  __shared__ unsigned tr[64][33];
  const int N = Ho*Wo;
  const int n0 = blockIdx.x << 5, c0 = blockIdx.y << 6, b = blockIdx.z;
  const int lnn = threadIdx.x & 31, gc = threadIdx.x >> 5;
  {
    const int n = n0 + lnn;
    const int ho = n / Wo, wo = n - ho*Wo;
    #pragma unroll
    for (int i=0;i<8;i++){
      const int c = (gc<<3) + i;
      float v;
      if constexpr (POOL){
        const float* p = in + ((size_t)(b*C + c0+c)*(Ho*2) + ho*2)*(size_t)(Wo*2) + (size_t)wo*2;
        v = 0.25f*(p[0] + p[1] + p[2*Wo] + p[2*Wo+1]);
      } else {
        v = in[((size_t)(b*C + c0+c))*N + n];
      }
      u16 h = bf16_rne(v);
      tr[c][lnn] = (unsigned)h | ((unsigned)bf16_rne(v - bf16f(h)) << 16);
    }
  }
  __syncthreads();
  const int n2 = threadIdx.x >> 3, oct = threadIdx.x & 7;
  bf16x8 vh, vl;
  #pragma unroll
  for (int j=0;j<8;j++){
    unsigned u = tr[(oct<<3)+j][n2];
    vh[j] = (short)(u & 0xffffu);
    vl[j] = (short)(u >> 16);
  }
  size_t o = ((size_t)b*N + (n0 + n2))*(size_t)C + c0 + (oct<<3);
  *(bf16x8*)&oh[o] = vh;
  *(bf16x8*)&ol[o] = vl;
}

// ---- split-bf16 MFMA direct conv 3x3 SAME; input pre-split NHWC u16 planes ----
// Tile: 64 co x (8x16) px; W staged per (dh,dw) tap via register prefetch
// (issue tap t+1's global load while tap t computes -> vmcnt off critical path).
// Bit-exact accumulation order: ci0 asc -> tap asc -> (hh,hl,lh).
template<int KS, int RESIZE>
__global__ __launch_bounds__(256,4) void convm(
    const u16* __restrict__ xh, const u16* __restrict__ xl,
    const u16* __restrict__ wsh, const u16* __restrict__ wsl,
    const float* __restrict__ bias, float* __restrict__ out,
    int Cin, int Cout, int H, int W, int relu)
{
  const int tilesW = W >> 4;
  const int h0 = (blockIdx.x / tilesW) << 3;
  const int w0 = (blockIdx.x % tilesW) << 4;
  const int co0 = blockIdx.y << 6;
  const int b  = blockIdx.z / KS;
  const int ks = blockIdx.z % KS;
  const int NB = gridDim.z / KS;
  const int tid = threadIdx.x;
  const int wid = tid >> 6, lane = tid & 63;
  const int wm = wid >> 1, wn = wid & 1;
  const int quad = lane >> 4, ln = lane & 15;

  __shared__ __align__(16) u16 sXh[180*40], sXl[180*40];
  __shared__ __align__(16) u16 sWh[64*40],  sWl[64*40];

  f32x4 acc[2][4];
  #pragma unroll
  for (int i=0;i<2;i++)
    #pragma unroll
    for (int j=0;j<4;j++)
      #pragma unroll
      for (int e=0;e<4;e++) acc[i][j][e] = 0.f;

  const int wco = tid >> 2, wcg = (tid & 3) << 3;

  const int ciA = ks*(Cin/KS), ciB = ciA + Cin/KS;

  // prefetch W tap0 of first chunk into registers
  bf16x8 wvh, wvl;
  {
    const size_t so = ((size_t)(co0 + wco))*Cin + ciA + wcg;  // dhw = 0
    wvh = *(const bf16x8*)&wsh[so];
    wvl = *(const bf16x8*)&wsl[so];
  }

  for (int ci0 = ciA; ci0 < ciB; ci0 += 32){
    // X staging: halo 10x18 px, 4 slots of 8 ci.
    for (int e = tid; e < 720; e += 256){
      const int px = e >> 2, sl = e & 3;
      const int pr = px / 18, pc = px - pr*18;
      const int ih = h0 + pr - 1, iw = w0 + pc - 1;
      bf16x8 vh, vl;
      #pragma unroll
      for (int j=0;j<8;j++){ vh[j] = 0; vl[j] = 0; }
      if ((unsigned)ih < (unsigned)H && (unsigned)iw < (unsigned)W){
        size_t o;
        if constexpr (RESIZE==0)
          o = ((size_t)(b*H + ih)*W + iw)*(size_t)Cin + (size_t)(ci0 + sl*8);
        else
          o = ((size_t)(b*(H>>1) + (ih>>1))*(W>>1) + (iw>>1))*(size_t)Cin + (size_t)(ci0 + sl*8);
        vh = *(const bf16x8*)&xh[o];
        vl = *(const bf16x8*)&xl[o];
      }
      *(bf16x8*)&sXh[px*40 + sl*8] = vh;
      *(bf16x8*)&sXl[px*40 + sl*8] = vl;
    }
    #pragma unroll
    for (int tap = 0; tap < 9; ++tap){
      const int dh = tap/3, dw = tap - dh*3;
      // write prefetched W fragment to LDS (prev tap's trailing barrier protects sW)
      *(bf16x8*)&sWh[wco*40 + wcg] = wvh;
      *(bf16x8*)&sWl[wco*40 + wcg] = wvl;
      // issue next tap's W load (or tap0 of next chunk) — hidden under MFMA phase
      {
        int ntap = tap + 1, nci = ci0;
        if (ntap == 9){ ntap = 0; nci = ci0 + 32; }
        if (nci < ciB){
          const size_t so = ((size_t)(ntap*Cout + co0 + wco))*Cin + nci + wcg;
          wvh = *(const bf16x8*)&wsh[so];
          wvl = *(const bf16x8*)&wsl[so];
        }
      }
      __syncthreads();
      bf16x8 ah[2], al[2], bh[4], bl[4];
      #pragma unroll
      for (int t=0;t<2;t++){
        const int co_l = (wm*2+t)*16 + ln;
        ah[t] = *(const bf16x8*)&sWh[co_l*40 + quad*8];
        al[t] = *(const bf16x8*)&sWl[co_l*40 + quad*8];
      }
      #pragma unroll
      for (int t=0;t<4;t++){
        const int p = (wn*4+t)*16 + ln;
        const int px = ((p>>4) + dh)*18 + (p&15) + dw;
        const int xo = px*40 + quad*8;
        bh[t] = *(const bf16x8*)&sXh[xo];
        bl[t] = *(const bf16x8*)&sXl[xo];
      }
      #pragma unroll
      for (int mi=0;mi<2;mi++)
        #pragma unroll
        for (int ni=0;ni<4;ni++){
          acc[mi][ni] = __builtin_amdgcn_mfma_f32_16x16x32_bf16(ah[mi], bh[ni], acc[mi][ni], 0, 0, 0);
          acc[mi][ni] = __builtin_amdgcn_mfma_f32_16x16x32_bf16(ah[mi], bl[ni], acc[mi][ni], 0, 0, 0);
          acc[mi][ni] = __builtin_amdgcn_mfma_f32_16x16x32_bf16(al[mi], bh[ni], acc[mi][ni], 0, 0, 0);
        }
      __syncthreads();
    }
  }
  #pragma unroll
  for (int mi=0;mi<2;mi++){
    const int co = co0 + (wm*2+mi)*16 + quad*4;
    #pragma unroll
    for (int ni=0;ni<4;ni++){
      const int p = (wn*4+ni)*16 + ln;
      const int oh = h0 + (p>>4), ow = w0 + (p&15);
      #pragma unroll
      for (int rg=0; rg<4; rg++){
        const int cog = co + rg;
        if constexpr (KS==1){
          float v = acc[mi][ni][rg] + bias[cog];
          if (relu) v = fmaxf(v, 0.f);
          out[((size_t)(b*Cout + cog)*H + oh)*W + ow] = v;
        } else {
          out[((size_t)((ks*NB + b)*Cout + cog)*H + oh)*W + ow] = acc[mi][ni][rg];
        }
      }
    }
  }
}

// reduce split-K partials + bias + relu
__global__ __launch_bounds__(256) void sumk(const float* __restrict__ part, const float* __restrict__ bias,
                                            float* __restrict__ out, int Cout, int HW, int KS, int relu, int n){
  int idx = blockIdx.x*256 + threadIdx.x;
  if (idx >= n) return;
  int co = (idx / HW) % Cout;
  float v = bias[co];
  for (int k=0;k<KS;k++) v += part[(size_t)k*n + idx];
  if (relu) v = fmaxf(v, 0.f);
  out[idx] = v;
}

// per-(b,c) spatial mean & std (ddof=0) — single-pass (small HW)
__global__ __launch_bounds__(256) void statsk(const float* __restrict__ x, int HW,
                                              float* __restrict__ mo, float* __restrict__ so){
  int bc = blockIdx.x, tid = threadIdx.x;
  const float* p = x + (size_t)bc*HW;
  double s = 0.0, s2 = 0.0;
  for (int i = tid; i < HW; i += 256){ double v = p[i]; s += v; s2 += v*v; }
  __shared__ double sh[256], sh2[256];
  sh[tid] = s; sh2[tid] = s2; __syncthreads();
  for (int k=128;k>0;k>>=1){ if (tid<k){ sh[tid]+=sh[tid+k]; sh2[tid]+=sh2[tid+k]; } __syncthreads(); }
  if (tid == 0){
    double m = sh[0]/HW;
    double var = sh2[0]/HW - m*m;
    if (var < 0.0) var = 0.0;
    mo[bc] = (float)m;
    so[bc] = (float)sqrt(var);
  }
}

// chunked stats phase 1: grid (bc, CH); partial double sums to part[(bc*CH+ch)*2 +{0,1}]
__global__ __launch_bounds__(256) void statspk(const float* __restrict__ x, int HW,
                                               double* __restrict__ part){
  const int bc = blockIdx.x, ch = blockIdx.y, CH = gridDim.y, tid = threadIdx.x;
  const int clen = HW / CH;
  const float* p = x + (size_t)bc*HW + (size_t)ch*clen;
  double s = 0.0, s2 = 0.0;
  for (int i = tid; i < clen; i += 256){ double v = p[i]; s += v; s2 += v*v; }
  __shared__ double sh[256], sh2[256];
  sh[tid] = s; sh2[tid] = s2; __syncthreads();
  for (int k=128;k>0;k>>=1){ if (tid<k){ sh[tid]+=sh[tid+k]; sh2[tid]+=sh2[tid+k]; } __syncthreads(); }
  if (tid == 0){
    part[(size_t)(bc*CH + ch)*2    ] = sh[0];
    part[(size_t)(bc*CH + ch)*2 + 1] = sh2[0];
  }
}

// chunked stats phase 2: one thread per bc
__global__ __launch_bounds__(256) void statsfk(const double* __restrict__ part, int CH, int HW, int nbc,
                                               float* __restrict__ mo, float* __restrict__ so){
  int bc = blockIdx.x*256 + threadIdx.x;
  if (bc >= nbc) return;
  double s = 0.0, s2 = 0.0;
  for (int ch = 0; ch < CH; ++ch){
    s  += part[(size_t)(bc*CH + ch)*2];
    s2 += part[(size_t)(bc*CH + ch)*2 + 1];
  }
  double m = s/HW;
  double var = s2/HW - m*m;
  if (var < 0.0) var = 0.0;
  mo[bc] = (float)m;
  so[bc] = (float)sqrt(var);
}

// f4 (C-major, per image 512x1024) -> ptsT [8][1024][512]
__global__ __launch_bounds__(256) void transposek(const float* __restrict__ f4c,
                                                  const float* __restrict__ f4s,
                                                  float* __restrict__ ptsT){
  __shared__ float t[32][33];
  int r = blockIdx.z;
  const float* src = (r < 4) ? (f4c + (size_t)r*524288) : (f4s + (size_t)(r-4)*524288);
  int n0 = blockIdx.x*32, c0 = blockIdx.y*32;
  int lx = threadIdx.x & 31, ly = threadIdx.x >> 5;
  for (int j=0;j<32;j+=8)
    t[ly+j][lx] = src[(size_t)(c0+ly+j)*1024 + n0+lx];
  __syncthreads();
  for (int j=0;j<32;j+=8)
    ptsT[((size_t)r*1024 + n0+ly+j)*512 + c0+lx] = t[lx][ly+j];
}

// slot0 init: sums = first 3 points (centroids), counts = 1
__global__ __launch_bounds__(256) void initcent2k(const float* __restrict__ ptsT, float* __restrict__ KACC){
  int i = blockIdx.x*256 + threadIdx.x;
  if (i < 12288){
    int c = i & 511; int k = (i >> 9) % 3; int r = i / 1536;
    KACC[r*1536 + k*512 + c] = ptsT[((size_t)r*1024 + k)*512 + c];
  }
  if (i < 24) KACC[12288 + i] = 1.f;
}

// fused k-means step
__global__ __launch_bounds__(256) void kstepk(const float* __restrict__ ptsT,
    const float* __restrict__ prev, float* __restrict__ next,
    int* __restrict__ a, int nodiv)
{
  const int r = blockIdx.x, sl = blockIdx.y;
  const int tid = threadIdx.x;
  __shared__ float sc[1536];
  __shared__ int sa[32];
  __shared__ float red[3][8][32];
  __shared__ int scnt[3];
  if (tid < 3) scnt[tid] = 0;
  for (int i = tid; i < 1536; i += 256){
    float s = prev[r*1536 + i];
    float cnt = nodiv ? 1.f : (prev[12288 + r*3 + (i>>9)] + 1e-6f);
    sc[i] = s / cnt;
  }
  __syncthreads();
  const float* base = ptsT + (size_t)r*524288;
  const int wid = tid >> 6, lane = tid & 63;
  for (int rep = 0; rep < 8; ++rep){
    int p = wid*8 + rep;
    int n = sl*32 + p;
    const float* pp = base + (size_t)n*512;
    float d0=0.f,d1=0.f,d2=0.f;
    #pragma unroll
    for (int i=0;i<8;i++){
      int c = lane + i*64;
      float v = pp[c];
      float e0 = v - sc[c], e1 = v - sc[512+c], e2 = v - sc[1024+c];
      d0 = fmaf(e0,e0,d0); d1 = fmaf(e1,e1,d1); d2 = fmaf(e2,e2,d2);
    }
    #pragma unroll
    for (int off=32; off>0; off>>=1){
      d0 += __shfl_down(d0, off, 64);
      d1 += __shfl_down(d1, off, 64);
      d2 += __shfl_down(d2, off, 64);
    }
    if (lane == 0){
      int bi = 0; float bd = d0;
      if (d1 < bd){ bd = d1; bi = 1; }
      if (d2 < bd){ bd = d2; bi = 2; }
      sa[p] = bi;
      a[r*1024 + n] = bi;
    }
  }
  __syncthreads();
  if (tid < 32) atomicAdd(&scnt[sa[tid]], 1);
  __syncthreads();
  if (tid < 3) atomicAdd(&next[12288 + r*3 + tid], (float)scnt[tid]);
  const int g = tid >> 5, lc = tid & 31;
  for (int cj = 0; cj < 16; ++cj){
    int c = cj*32 + lc;
    float s0=0.f,s1=0.f,s2=0.f;
    #pragma unroll
    for (int q=0;q<4;q++){
      int nl = g*4 + q;
      float v = base[(size_t)(sl*32+nl)*512 + c];
      int an = sa[nl];
      s0 += (an==0)?v:0.f;
      s1 += (an==1)?v:0.f;
      s2 += (an==2)?v:0.f;
    }
    red[0][g][lc]=s0; red[1][g][lc]=s1; red[2][g][lc]=s2;
    __syncthreads();
    if (g == 0){
      float t0=0.f,t1=0.f,t2=0.f;
      #pragma unroll
      for (int q2=0;q2<8;q2++){ t0+=red[0][q2][lc]; t1+=red[1][q2][lc]; t2+=red[2][q2][lc]; }
      atomicAdd(&next[r*1536 +          c], t0);
      atomicAdd(&next[r*1536 +  512 +   c], t1);
      atomicAdd(&next[r*1536 + 1024 +   c], t2);
    }
    __syncthreads();
  }
}

// final mu/counts from slot 11
__global__ __launch_bounds__(256) void mufink(const float* __restrict__ slot,
                                              float* __restrict__ mu, float* __restrict__ counts){
  int i = blockIdx.x*256 + threadIdx.x;
  if (i >= 12288) return;
  int c = i & 511; int k = (i >> 9) % 3; int r = i / 1536;
  int cs = r >> 2, img = r & 3;
  int i0 = cs*12 + img*3;
  float cnt = slot[12288 + r*3 + k];
  mu[(size_t)(i0+k)*512 + c] = slot[r*1536 + k*512 + c] / (cnt + 1e-6f);
  if (c == 0) counts[i0+k] = cnt;
}

// masked centered split planes
__global__ __launch_bounds__(256) void maskcenterk(const float* __restrict__ f4c, const float* __restrict__ f4s,
        const int* __restrict__ a, const float* __restrict__ mu,
        u16* __restrict__ Ph, u16* __restrict__ Pl){
  size_t i4 = ((size_t)blockIdx.x*256 + threadIdx.x)*4;
  if (i4 >= (size_t)PL*2) return;
  int z = (int)(i4 >> 19);
  int rc = (int)(i4 & 524287);
  int c = rc >> 10, n = rc & 1023;
  int cs = z / 12; int rem = z - cs*12; int img = rem / 3; int k = rem - img*3;
  const float* pts = (cs ? f4s : f4c) + (size_t)img*524288;
  float m = mu[(size_t)z*512 + c];
  const int* an = a + (cs*4 + img)*1024 + n;
  float4 v4 = *(const float4*)&pts[(size_t)c*1024 + n];
  float vv[4] = {v4.x, v4.y, v4.z, v4.w};
  u16x4 oh, ol;
  #pragma unroll
  for (int j=0;j<4;j++){
    float v = (an[j] == k) ? (vv[j] - m) : 0.f;
    u16 h = bf16_rne(v);
    oh[j] = (short)h;
    ol[j] = (short)bf16_rne(v - bf16f(h));
  }
  *(u16x4*)&Ph[i4] = oh;
  *(u16x4*)&Pl[i4] = ol;
}

// covariance via MFMA, trace accumulated. Tile 128x128; 1-D grid 384 blocks,
// XCD-swizzled: all 16 tiles of a z share one XCD (z = (bid&7) + 8*(w>>4)).
__global__ __launch_bounds__(256) void covgemm(const u16* __restrict__ Ph, const u16* __restrict__ Pl,
        const float* __restrict__ counts, float* __restrict__ Ycov, float* __restrict__ trsum){
  const int bid = blockIdx.x;
  const int xcd = bid & 7, w = bid >> 3;
  const int z = xcd + ((w >> 4) << 3);
  const int t4 = w & 15;
  const int m0 = (t4 >> 2) << 7, n0 = (t4 & 3) << 7;
  const u16* Pbh = Ph + (size_t)z*524288;
  const u16* Pbl = Pl + (size_t)z*524288;
  const int tid = threadIdx.x;

  __shared__ __align__(16) u16 sAh[128*40], sAl[128*40];
  __shared__ __align__(16) u16 sBh[128*40], sBl[128*40];

  const int ra = tid >> 2, qa = tid & 3;
  const int wid = tid >> 6, lane = tid & 63;
  const int wm = wid >> 1, wn = wid & 1;
  const int quad = lane >> 4, ln = lane & 15;

  f32x4 acc[4][4];
  #pragma unroll
  for (int i=0;i<4;i++)
    #pragma unroll
    for (int j=0;j<4;j++)
      #pragma unroll
      for (int e=0;e<4;e++) acc[i][j][e] = 0.f;

  for (int k0 = 0; k0 < 1024; k0 += 32){
    *(bf16x8*)&sAh[ra*40 + qa*8]      = *(const bf16x8*)&Pbh[(size_t)(m0+ra)*1024    + k0 + qa*8];
    *(bf16x8*)&sAl[ra*40 + qa*8]      = *(const bf16x8*)&Pbl[(size_t)(m0+ra)*1024    + k0 + qa*8];
    *(bf16x8*)&sAh[(ra+64)*40 + qa*8] = *(const bf16x8*)&Pbh[(size_t)(m0+ra+64)*1024 + k0 + qa*8];
    *(bf16x8*)&sAl[(ra+64)*40 + qa*8] = *(const bf16x8*)&Pbl[(size_t)(m0+ra+64)*1024 + k0 + qa*8];
    *(bf16x8*)&sBh[ra*40 + qa*8]      = *(const bf16x8*)&Pbh[(size_t)(n0+ra)*1024    + k0 + qa*8];
    *(bf16x8*)&sBl[ra*40 + qa*8]      = *(const bf16x8*)&Pbl[(size_t)(n0+ra)*1024    + k0 + qa*8];
    *(bf16x8*)&sBh[(ra+64)*40 + qa*8] = *(const bf16x8*)&Pbh[(size_t)(n0+ra+64)*1024 + k0 + qa*8];
    *(bf16x8*)&sBl[(ra+64)*40 + qa*8] = *(const bf16x8*)&Pbl[(size_t)(n0+ra+64)*1024 + k0 + qa*8];
    __syncthreads();

    bf16x8 ah[4], al[4], bh[4], bl[4];
    #pragma unroll
    for (int t=0;t<4;t++){
      const int moA = ((wm*4+t)*16 + ln)*40 + quad*8;
      const int moB = ((wn*4+t)*16 + ln)*40 + quad*8;
      ah[t] = *(const bf16x8*)&sAh[moA];
      al[t] = *(const bf16x8*)&sAl[moA];
      bh[t] = *(const bf16x8*)&sBh[moB];
      bl[t] = *(const bf16x8*)&sBl[moB];
    }
    #pragma unroll
    for (int mi=0;mi<4;mi++)
      #pragma unroll
      for (int ni=0;ni<4;ni++){
        acc[mi][ni] = __builtin_amdgcn_mfma_f32_16x16x32_bf16(ah[mi], bh[ni], acc[mi][ni], 0, 0, 0);
        acc[mi][ni] = __builtin_amdgcn_mfma_f32_16x16x32_bf16(ah[mi], bl[ni], acc[mi][ni], 0, 0, 0);
        acc[mi][ni] = __builtin_amdgcn_mfma_f32_16x16x32_bf16(al[mi], bh[ni], acc[mi][ni], 0, 0, 0);
      }
    __syncthreads();
  }
  const float inv = 1.f/(counts[z] + 1e-6f);
  float dsum = 0.f; bool anyd = false;
  #pragma unroll
  for (int mi=0;mi<4;mi++){
    const int mbase = m0 + (wm*4+mi)*16 + quad*4;
    #pragma unroll
    for (int ni=0;ni<4;ni++){
      const int n = n0 + (wn*4+ni)*16 + ln;
      #pragma unroll
      for (int rg=0;rg<4;rg++){
        const int m = mbase + rg;
        float v = acc[mi][ni][rg]*inv + ((m==n)?0.1f:0.f);
        Ycov[(size_t)z*MSZ + (size_t)m*512 + n] = v;
        if (m0==n0 && m==n){ dsum += v; anyd = true; }
      }
    }
  }
  if (anyd) atomicAdd(&trsum[z], dsum);
}

// init split planes: Y = Ycov/trace (hi+lo bf16), Z = I
__global__ __launch_bounds__(256) void nsinitk(const float* __restrict__ Ycov, const float* __restrict__ sval,
                                               u16* __restrict__ Yh, u16* __restrict__ Yl,
                                               u16* __restrict__ Zh, u16* __restrict__ Zl){
  size_t idx = (size_t)blockIdx.x*256 + threadIdx.x;
  if (idx >= (size_t)PL) return;
  int z = (int)(idx >> 18);
  int rc = (int)(idx & (MSZ-1));
  int rr = rc >> 9, cc = rc & 511;
  float y = Ycov[idx] / sval[z];
  u16 h = bf16_rne(y);
  Yh[idx] = h;
  Yl[idx] = bf16_rne(y - bf16f(h));
  Zh[idx] = (rr==cc) ? (u16)0x3F80 : (u16)0;
  Zl[idx] = 0;
}

// it=0 specializations (Z == I exactly):
// M = Z*Y via MFMA degenerates to elementwise resplit of (Yh+Yl) — bit-identical.
__global__ __launch_bounds__(256) void nsm0k(const u16* __restrict__ Yh, const u16* __restrict__ Yl,
                                             u16* __restrict__ Mh, u16* __restrict__ Ml){
  size_t i4 = ((size_t)blockIdx.x*256 + threadIdx.x)*4;
  if (i4 >= (size_t)PL) return;
  u16x4 hv = *(const u16x4*)&Yh[i4];
  u16x4 lv = *(const u16x4*)&Yl[i4];
  u16x4 oh, ol;
  #pragma unroll
  for (int j=0;j<4;j++){
    float v = bf16f((u16)hv[j]) + bf16f((u16)lv[j]);
    u16 h = bf16_rne(v);
    oh[j] = (short)h;
    ol[j] = (short)bf16_rne(v - bf16f(h));
  }
  *(u16x4*)&Mh[i4] = oh;
  *(u16x4*)&Ml[i4] = ol;
}

// trace of M (= sum of diag (Yh+Yl)) per z; grid 24 blocks.
__global__ __launch_bounds__(256) void nstr0k(const u16* __restrict__ Yh, const u16* __restrict__ Yl,
                                              float* __restrict__ tr){
  int z = blockIdx.x, tid = threadIdx.x;
  float s = 0.f;
  for (int i = tid; i < 512; i += 256){
    size_t o = (size_t)z*MSZ + (size_t)i*513;
    s += bf16f(Yh[o]) + bf16f(Yl[o]);
  }
  __shared__ float sh[256];
  sh[tid] = s; __syncthreads();
  for (int k=128;k>0;k>>=1){ if (tid<k) sh[tid]+=sh[tid+k]; __syncthreads(); }
  if (tid == 0) tr[z] = sh[0];
}

// it=0 Z-update: Z2 = alpha*(Mh+Ml) + beta*I (since M*Z with Z=I is elementwise-exact).
__global__ __launch_bounds__(256) void nsz0k(const u16* __restrict__ Mh, const u16* __restrict__ Ml,
                                             u16* __restrict__ Z2h, u16* __restrict__ Z2l,
                                             const float* __restrict__ trAcc){
  size_t i4 = ((size_t)blockIdx.x*256 + threadIdx.x)*4;
  if (i4 >= (size_t)PL) return;
  int z = (int)(i4 >> 18);
  int rc = (int)(i4 & (MSZ-1));
  int row = rc >> 9, col = rc & 511;
  const float tr = trAcc[z];
  const float g2 = fminf(512.f/fmaxf(tr, 1e-6f), 2.7f);
  const float oz = 0.5f*sqrtf(g2);
  const float alpha = -g2*oz, beta = 3.f*oz;
  u16x4 hv = *(const u16x4*)&Mh[i4];
  u16x4 lv = *(const u16x4*)&Ml[i4];
  u16x4 oh, ol;
  #pragma unroll
  for (int j=0;j<4;j++){
    float m = bf16f((u16)hv[j]) + bf16f((u16)lv[j]);
    float zv = (row == col + j) ? 1.f : 0.f;
    float v = alpha*m + beta*zv;
    u16 h = bf16_rne(v);
    oh[j] = (short)h;
    ol[j] = (short)bf16_rne(v - bf16f(h));
  }
  *(u16x4*)&Z2h[i4] = oh;
  *(u16x4*)&Z2l[i4] = ol;
}

// ---- split-bf16 MFMA batched GEMM 512x512x512; tile 128x128 ----
// SWZ=1: 1-D grid NZ*16 blocks, XCD-swizzled (NZ%8==0). SWZ=0: 3-D grid (4,4,NZ).
template<int MODE, int SWZ>
__global__ __launch_bounds__(256) void bmms(
    const u16* __restrict__ Ah, const u16* __restrict__ Al,
    const u16* __restrict__ Bh, const u16* __restrict__ Bl,
    u16* __restrict__ Ch, u16* __restrict__ Cl,
    const float* __restrict__ osc,
    int aoff, float* __restrict__ trAcc)
{
  int z, m0, n0;
  if constexpr (SWZ){
    const int bid = blockIdx.x;
    const int xcd = bid & 7, w = bid >> 3;
    z = xcd + ((w >> 4) << 3);
    const int t4 = w & 15;
    m0 = (t4 >> 2) << 7; n0 = (t4 & 3) << 7;
  } else {
    z = blockIdx.z; m0 = blockIdx.y*128; n0 = blockIdx.x*128;
  }
  const u16* Abh = Ah + (size_t)(z+aoff)*MSZ;
  const u16* Abl = Al + (size_t)(z+aoff)*MSZ;
  const u16* Bbh = Bh + (size_t)z*MSZ;
  const u16* Bbl = Bl + (size_t)z*MSZ;
  const int tid = threadIdx.x;

  __shared__ __align__(16) u16 sAh[128*40], sAl[128*40];
  __shared__ __align__(16) u16 sBh[128*40], sBl[128*40];

  const int ra = tid >> 2, qa = tid & 3;
  const int wid = tid >> 6, lane = tid & 63;
  const int wm = wid >> 1, wn = wid & 1;
  const int quad = lane >> 4, ln = lane & 15;

  f32x4 acc[4][4];
  #pragma unroll
  for (int i=0;i<4;i++)
    #pragma unroll
    for (int j=0;j<4;j++)
      #pragma unroll
      for (int e=0;e<4;e++) acc[i][j][e] = 0.f;

  for (int k0 = 0; k0 < 512; k0 += 32){
    *(bf16x8*)&sAh[ra*40 + qa*8]      = *(const bf16x8*)&Abh[(size_t)(m0+ra)*512    + k0 + qa*8];
    *(bf16x8*)&sAl[ra*40 + qa*8]      = *(const bf16x8*)&Abl[(size_t)(m0+ra)*512    + k0 + qa*8];
    *(bf16x8*)&sAh[(ra+64)*40 + qa*8] = *(const bf16x8*)&Abh[(size_t)(m0+ra+64)*512 + k0 + qa*8];
    *(bf16x8*)&sAl[(ra+64)*40 + qa*8] = *(const bf16x8*)&Abl[(size_t)(m0+ra+64)*512 + k0 + qa*8];
    *(bf16x8*)&sBh[ra*40 + qa*8]      = *(const bf16x8*)&Bbh[(size_t)(n0+ra)*512    + k0 + qa*8];
    *(bf16x8*)&sBl[ra*40 + qa*8]      = *(const bf16x8*)&Bbl[(size_t)(n0+ra)*512    + k0 + qa*8];
    *(bf16x8*)&sBh[(ra+64)*40 + qa*8] = *(const bf16x8*)&Bbh[(size_t)(n0+ra+64)*512 + k0 + qa*8];
    *(bf16x8*)&sBl[(ra+64)*40 + qa*8] = *(const bf16x8*)&Bbl[(size_t)(n0+ra+64)*512 + k0 + qa*8];
    __syncthreads();

    bf16x8 ah[4], al[4], bh[4], bl[4];
    #pragma unroll
    for (int t=0;t<4;t++){
      const int moA = ((wm*4+t)*16 + ln)*40 + quad*8;
      const int moB = ((wn*4+t)*16 + ln)*40 + quad*8;
      ah[t] = *(const bf16x8*)&sAh[moA];
      al[t] = *(const bf16x8*)&sAl[moA];
      bh[t] = *(const bf16x8*)&sBh[moB];
      bl[t] = *(const bf16x8*)&sBl[moB];
    }
    #pragma unroll
    for (int mi=0;mi<4;mi++)
      #pragma unroll
      for (int ni=0;ni<4;ni++){
        acc[mi][ni] = __builtin_amdgcn_mfma_f32_16x16x32_bf16(ah[mi], bh[ni], acc[mi][ni], 0, 0, 0);
        acc[mi][ni] = __builtin_amdgcn_mfma_f32_16x16x32_bf16(ah[mi], bl[ni], acc[mi][ni], 0, 0, 0);
        acc[mi][ni] = __builtin_amdgcn_mfma_f32_16x16x32_bf16(al[mi], bh[ni], acc[mi][ni], 0, 0, 0);
      }
    __syncthreads();
  }

  float alpha = 1.f;
  if constexpr (MODE==2){ alpha = osc[z]; }

  float dsum = 0.f; bool anyd = false;
  #pragma unroll
  for (int mi=0;mi<4;mi++){
    const int mbase = m0 + (wm*4+mi)*16 + quad*4;
    #pragma unroll
    for (int ni=0;ni<4;ni++){
      const int n = n0 + (wn*4+ni)*16 + ln;
      #pragma unroll
      for (int rg=0;rg<4;rg++){
        const int m = mbase + rg;
        const size_t off = (size_t)z*MSZ + (size_t)m*512 + n;
        float v = alpha*acc[mi][ni][rg];
        u16 h = bf16_rne(v);
        Ch[off] = h;
        Cl[off] = bf16_rne(v - bf16f(h));
        if (MODE==0 && trAcc && m0==n0 && m==n){ dsum += v; anyd = true; }
      }
    }
  }
  if (MODE==0 && anyd) atomicAdd(&trAcc[z], dsum);
}

// merged NS update (128x128 tile); 1-D grid NZ*16 blocks, XCD-swizzled.
__global__ __launch_bounds__(256) void bmmpair(
    const u16* __restrict__ Yh, const u16* __restrict__ Yl,
    const u16* __restrict__ Mh, const u16* __restrict__ Ml,
    const u16* __restrict__ Zh, const u16* __restrict__ Zl,
    u16* __restrict__ Y2h, u16* __restrict__ Y2l,
    u16* __restrict__ Z2h, u16* __restrict__ Z2l,
    const float* __restrict__ trAcc, int last)
{
  const int bid = blockIdx.x;
  const int xcd = bid & 7, w = bid >> 3;
  const int z = xcd + ((w >> 4) << 3);
  const int t4 = w & 15;
  const int m0 = (t4 >> 2) << 7, n0 = (t4 & 3) << 7;
  int zz; bool isY;
  if (last){ zz = z; isY = (z >= 12); }
  else { isY = (z < 24); zz = isY ? z : (z - 24); }
  const size_t zo = (size_t)zz*MSZ;
  const u16 *Abh, *Abl, *Bbh, *Bbl, *Dbh, *Dbl;
  u16 *Cbh, *Cbl;
  if (isY){
    Abh = Yh + zo; Abl = Yl + zo;
    Bbh = Mh + zo; Bbl = Ml + zo;
    Dbh = Yh + zo; Dbl = Yl + zo;
    Cbh = Y2h + zo; Cbl = Y2l + zo;
  } else {
    Abh = Mh + zo; Abl = Ml + zo;
    Bbh = Zh + zo; Bbl = Zl + zo;
    Dbh = Zh + zo; Dbl = Zl + zo;
    Cbh = Z2h + zo; Cbl = Z2l + zo;
  }
  const int tid = threadIdx.x;

  __shared__ __align__(16) u16 sAh[128*40], sAl[128*40];
  __shared__ __align__(16) u16 sBh[128*40], sBl[128*40];

  const int ra = tid >> 2, qa = tid & 3;
  const int wid = tid >> 6, lane = tid & 63;
  const int wm = wid >> 1, wn = wid & 1;
  const int quad = lane >> 4, ln = lane & 15;

  f32x4 acc[4][4];
  #pragma unroll
  for (int i=0;i<4;i++)
    #pragma unroll
    for (int j=0;j<4;j++)
      #pragma unroll
      for (int e=0;e<4;e++) acc[i][j][e] = 0.f;

  for (int k0 = 0; k0 < 512; k0 += 32){
    *(bf16x8*)&sAh[ra*40 + qa*8]      = *(const bf16x8*)&Abh[(size_t)(m0+ra)*512    + k0 + qa*8];
    *(bf16x8*)&sAl[ra*40 + qa*8]      = *(const bf16x8*)&Abl[(size_t)(m0+ra)*512    + k0 + qa*8];
    *(bf16x8*)&sAh[(ra+64)*40 + qa*8] = *(const bf16x8*)&Abh[(size_t)(m0+ra+64)*512 + k0 + qa*8];
    *(bf16x8*)&sAl[(ra+64)*40 + qa*8] = *(const bf16x8*)&Abl[(size_t)(m0+ra+64)*512 + k0 + qa*8];
    *(bf16x8*)&sBh[ra*40 + qa*8]      = *(const bf16x8*)&Bbh[(size_t)(n0+ra)*512    + k0 + qa*8];
    *(bf16x8*)&sBl[ra*40 + qa*8]      = *(const bf16x8*)&Bbl[(size_t)(n0+ra)*512    + k0 + qa*8];
    *(bf16x8*)&sBh[(ra+64)*40 + qa*8] = *(const bf16x8*)&Bbh[(size_t)(n0+ra+64)*512 + k0 + qa*8];
    *(bf16x8*)&sBl[(ra+64)*40 + qa*8] = *(const bf16x8*)&Bbl[(size_t)(n0+ra+64)*512 + k0 + qa*8];
    __syncthreads();

    bf16x8 ah[4], al[4], bh[4], bl[4];
    #pragma unroll
    for (int t=0;t<4;t++){
      const int moA = ((wm*4+t)*16 + ln)*40 + quad*8;
      const int moB = ((wn*4+t)*16 + ln)*40 + quad*8;
      ah[t] = *(const bf16x8*)&sAh[moA];
      al[t] = *(const bf16x8*)&sAl[moA];
      bh[t] = *(const bf16x8*)&sBh[moB];
      bl[t] = *(const bf16x8*)&sBl[moB];
    }
    #pragma unroll
    for (int mi=0;mi<4;mi++)
      #pragma unroll
      for (int ni=0;ni<4;ni++){
        acc[mi][ni] = __builtin_amdgcn_mfma_f32_16x16x32_bf16(ah[mi], bh[ni], acc[mi][ni], 0, 0, 0);
        acc[mi][ni] = __builtin_amdgcn_mfma_f32_16x16x32_bf16(ah[mi], bl[ni], acc[mi][ni], 0, 0, 0);
        acc[mi][ni] = __builtin_amdgcn_mfma_f32_16x16x32_bf16(al[mi], bh[ni], acc[mi][ni], 0, 0, 0);
      }
    __syncthreads();
  }

  const float tr = trAcc[zz];
  const float g2 = fminf(512.f/fmaxf(tr, 1e-6f), 2.7f);
  const float oz = 0.5f*sqrtf(g2);
  const float alpha = -g2*oz, beta = 3.f*oz;

  #pragma unroll
  for (int mi=0;mi<4;mi++){
    const int mbase = m0 + (wm*4+mi)*16 + quad*4;
    #pragma unroll
    for (int ni=0;ni<4;ni++){
      const int n = n0 + (wn*4+ni)*16 + ln;
      #pragma unroll
      for (int rg=0;rg<4;rg++){
        const int m = mbase + rg;
        const size_t off = (size_t)m*512 + n;
        float v = alpha*acc[mi][ni][rg] + beta*(bf16f(Dbh[off]) + bf16f(Dbl[off]));
        u16 h = bf16_rne(v);
        Cbh[off] = h;
        Cbl[off] = bf16_rne(v - bf16f(h));
      }
    }
  }
}

// tpts = T[z] @ f[img]: M=512, N=1024, K=512, fp32 out.
// B is pre-transposed fsT [img][n][c]; tile 128M x 64N; grid (16,4,12).
__global__ __launch_bounds__(256,4) void bmmt(
    const u16* __restrict__ Th, const u16* __restrict__ Tl,
    const u16* __restrict__ fh, const u16* __restrict__ fl,
    float* __restrict__ Cf)
{
  const int z = blockIdx.z;
  const u16* Abh = Th + (size_t)z*MSZ;
  const u16* Abl = Tl + (size_t)z*MSZ;
  const u16* Bbh = fh + (size_t)(z/3)*524288;
  const u16* Bbl = fl + (size_t)(z/3)*524288;
  const int m0 = blockIdx.y*128, n0 = blockIdx.x*64;
  const int tid = threadIdx.x;

  __shared__ __align__(16) u16 sAh[128*40], sAl[128*40];
  __shared__ __align__(16) u16 sBh[64*40], sBl[64*40];

  const int ra = tid >> 2, qa = tid & 3;
  const int wid = tid >> 6, lane = tid & 63;
  const int wm = wid >> 1, wn = wid & 1;
  const int quad = lane >> 4, ln = lane & 15;

  f32x4 acc[4][2];
  #pragma unroll
  for (int i=0;i<4;i++)
    #pragma unroll
    for (int j=0;j<2;j++)
      #pragma unroll
      for (int e=0;e<4;e++) acc[i][j][e] = 0.f;

  for (int k0 = 0; k0 < 512; k0 += 32){
    *(bf16x8*)&sAh[ra*40 + qa*8]      = *(const bf16x8*)&Abh[(size_t)(m0+ra)*512    + k0 + qa*8];
    *(bf16x8*)&sAl[ra*40 + qa*8]      = *(const bf16x8*)&Abl[(size_t)(m0+ra)*512    + k0 + qa*8];
    *(bf16x8*)&sAh[(ra+64)*40 + qa*8] = *(const bf16x8*)&Abh[(size_t)(m0+ra+64)*512 + k0 + qa*8];
    *(bf16x8*)&sAl[(ra+64)*40 + qa*8] = *(const bf16x8*)&Abl[(size_t)(m0+ra+64)*512 + k0 + qa*8];
    *(bf16x8*)&sBh[ra*40 + qa*8]      = *(const bf16x8*)&Bbh[(size_t)(n0+ra)*512    + k0 + qa*8];
    *(bf16x8*)&sBl[ra*40 + qa*8]      = *(const bf16x8*)&Bbl[(size_t)(n0+ra)*512    + k0 + qa*8];
    __syncthreads();

    bf16x8 ah[4], al[4], bh[2], bl[2];
    #pragma unroll
    for (int t=0;t<4;t++){
      const int moA = ((wm*4+t)*16 + ln)*40 + quad*8;
      ah[t] = *(const bf16x8*)&sAh[moA];
      al[t] = *(const bf16x8*)&sAl[moA];
    }
    #pragma unroll
    for (int t=0;t<2;t++){
      const int moB = ((wn*2+t)*16 + ln)*40 + quad*8;
      bh[t] = *(const bf16x8*)&sBh[moB];
      bl[t] = *(const bf16x8*)&sBl[moB];
    }
    #pragma unroll
    for (int mi=0;mi<4;mi++)
      #pragma unroll
      for (int ni=0;ni<2;ni++){
        acc[mi][ni] = __builtin_amdgcn_mfma_f32_16x16x32_bf16(ah[mi], bh[ni], acc[mi][ni], 0, 0, 0);
        acc[mi][ni] = __builtin_amdgcn_mfma_f32_16x16x32_bf16(ah[mi], bl[ni], acc[mi][ni], 0, 0, 0);
        acc[mi][ni] = __builtin_amdgcn_mfma_f32_16x16x32_bf16(al[mi], bh[ni], acc[mi][ni], 0, 0, 0);
      }
    __syncthreads();
  }
  #pragma unroll
  for (int mi=0;mi<4;mi++){
    const int mbase = m0 + (wm*4+mi)*16 + quad*4;
    #pragma unroll
    for (int ni=0;ni<2;ni++){
      const int n = n0 + (wn*2+ni)*16 + ln;
      #pragma unroll
      for (int rg=0;rg<4;rg++){
        const int m = mbase + rg;
        Cf[(size_t)z*524288 + (size_t)m*1024 + n] = acc[mi][ni][rg];
      }
    }
  }
}

__global__ void make_scalesk(const float* __restrict__ sval, float* __restrict__ scl){
  int i = threadIdx.x;
  if (i < 12) scl[i] = sqrtf(sval[12+i] / sval[i]);
}

// tvec[b] = mu_s[b] - T[b] @ mu_c[b]
__global__ __launch_bounds__(512) void tveck(const u16* __restrict__ Th, const u16* __restrict__ Tl,
                                             const float* __restrict__ mu, float* __restrict__ tvec){
  int b = blockIdx.x; int c = threadIdx.x;
  __shared__ float mc[512];
  mc[c] = mu[(size_t)b*512 + c];
  __syncthreads();
  const u16* Trh = Th + ((size_t)b*512 + c)*512;
  const u16* Trl = Tl + ((size_t)b*512 + c)*512;
  float s = 0.f;
  for (int d=0; d<512; d++) s = fmaf(bf16f(Trh[d]) + bf16f(Trl[d]), mc[d], s);
  tvec[b*512 + c] = mu[(size_t)(12+b)*512 + c] - s;
}

__global__ __launch_bounds__(256) void selectk(const float* __restrict__ tpts, const float* __restrict__ tvec,
        const int* __restrict__ a, const float* __restrict__ f4c, float* __restrict__ tf){
  size_t idx = (size_t)blockIdx.x*256 + threadIdx.x;
  if (idx >= 2097152ul) return;
  int n = (int)(idx & 1023);
  int c = (int)((idx >> 10) & 511);
  int img = (int)(idx >> 19);
  int k = a[img*1024 + n];
  int b = img*3 + k;
  float v = tpts[((size_t)b*512 + c)*1024 + n] + tvec[b*512 + c];
  tf[idx] = 0.6f*v + 0.4f*f4c[idx];
}

__global__ __launch_bounds__(256) void clossk(const float* __restrict__ x, const float* __restrict__ y,
                                              int n, float* __restrict__ acc){
  int tid = threadIdx.x;
  float s = 0.f;
  for (size_t i = (size_t)blockIdx.x*256 + tid; i < (size_t)n; i += (size_t)gridDim.x*256){
    float d = x[i] - y[i]; s = fmaf(d, d, s);
  }
  __shared__ float sh[256];
  sh[tid] = s; __syncthreads();
  for (int k=128;k>0;k>>=1){ if (tid<k) sh[tid]+=sh[tid+k]; __syncthreads(); }
  if (tid==0) atomicAdd(acc, sh[0]);
}

__global__ __launch_bounds__(256) void finalk(const float* __restrict__ sm, float* __restrict__ out){
  int tid = threadIdx.x;
  const int cnts[4] = {256,512,1024,2048};
  const int offs[4] = {0,256,768,1792};
  const float* mS = sm + SM_STATS_S;
  const float* sS = sm + SM_STATS_S + 3840;
  const float* mD = sm + SM_STATS_D;
  const float* sD = sm + SM_STATS_D + 3840;
  double sl = 0.0;
  for (int L=0; L<4; ++L){
    int cnt = cnts[L], off = offs[L];
    double inv = 1.0/cnt;
    for (int i=tid; i<cnt; i+=256){
      double dm = (double)mD[off+i] - (double)mS[off+i];
      double ds = (double)sD[off+i] - (double)sS[off+i];
      sl += (dm*dm + ds*ds)*inv;
    }
  }
  __shared__ double sh[256];
  sh[tid] = sl; __syncthreads();
  for (int k=128;k>0;k>>=1){ if (tid<k) sh[tid]+=sh[tid+k]; __syncthreads(); }
  if (tid==0){
    double closs = (double)sm[SM_CLOSS] / 2097152.0;
    out[0] = (float)(closs + 0.01*sh[0]);
  }
}

// ---------------- host ----------------

extern "C" void kernel_launch(void* const* d_in, const int* in_sizes, int n_in,
                              void* d_out, int out_size, void* d_ws, size_t ws_size,
                              hipStream_t stream)
{
  const float* content = (const float*)d_in[0];
  const float* style   = (const float*)d_in[1];
  const float* Wm[8]; const float* Bm[8];
  for (int i=0;i<8;i++){ Wm[i] = (const float*)d_in[2+2*i]; Bm[i] = (const float*)d_in[3+2*i]; }
  float* out = (float*)d_out;
  float* ws = (float*)d_ws;

  float* f4c  = ws + OFF_F4C;
  float* f4s  = ws + OFF_F4S;
  float* tf   = ws + OFF_TF;
  float* dec  = ws + OFF_DEC;
  float* sm   = ws + OFF_SMALL;
  float* AR   = ws + OFF_ARENA;
  int*   aPtr = (int*)(sm + SM_ASSIGN);
  float* mu   = sm + SM_MU;
  float* counts = sm + SM_COUNTS;
  float* sval = sm + SM_SVAL;
  float* scl  = sm + SM_SCALE;
  float* tvec = sm + SM_TVEC;
  float* trbuf = sm + SM_TR;
  double* spart = (double*)(sm + SM_SPART);

  u16* WB = (u16*)(ws + OFF_WSPL);
  u16 *w2h=WB+0,       *w2l=WB+73728;
  u16 *w3h=WB+147456,  *w3l=WB+442368;
  u16 *w4h=WB+737280,  *w4l=WB+1916928;
  u16 *v1h=WB+3096576, *v1l=WB+4276224;
  u16 *v2h=WB+5455872, *v2l=WB+5750784;
  u16 *v3h=WB+6045696, *v3l=WB+6119424;

  float* Ycov = AR;
  u16* Mh  = (u16*)(AR);
  u16* Ml  = (u16*)(AR + 3145728ul);
  u16* Yh  = (u16*)(AR + 6291456ul);
  u16* Yl  = (u16*)(AR + 9437184ul);
  u16* Zh  = (u16*)(AR + 12582912ul);
  u16* Zl  = (u16*)(AR + 15728640ul);
  u16* Y2h = (u16*)(AR + 18874368ul);
  u16* Y2l = (u16*)(AR + 22020096ul);
  u16* Z2h = (u16*)(AR + 25165824ul);
  u16* Z2l = (u16*)(AR + 28311552ul);
  u16* Ph  = (u16*)(AR + 18874368ul);
  u16* Pl  = (u16*)(AR + 25165824ul);
  float* ptsT = AR + 25165824ul;
  u16* Th  = (u16*)(AR + 18874368ul);
  u16* Tl  = (u16*)(AR + 20971520ul);
  u16* fsh = (u16*)(AR + 23068672ul);
  u16* fsl = (u16*)(AR + 24117248ul);
  float* KACC = AR + 0;

  // NHWC split-bf16 activation planes (u16), placed in lifetime-dead arena slots.
  // encode (B=8):
  u16* xP1h  = (u16*)(AR + 16777216ul);   // 8*128*128*64 u16 -> 4.19M floats
  u16* xP1l  = (u16*)(AR + 20971520ul);
  u16* xF2ph = (u16*)(AR + 16777216ul);   // pooled F2: 8*64*64*128
  u16* xF2pl = (u16*)(AR + 18874368ul);
  u16* xF3ph = (u16*)(AR + 18874368ul);   // pooled F3: 8*32*32*256 (clear of PART8)
  u16* xF3pl = (u16*)(AR + 19922944ul);
  // decode (B=4):
  u16* xTFh  = (u16*)(AR + 8388608ul);    // 4*32*32*512
  u16* xTFl  = (u16*)(AR + 9437184ul);
  u16* xX1h  = (u16*)(AR + 1048576ul);    // 4*32*32*256
  u16* xX1l  = (u16*)(AR + 1572864ul);
  u16* xX2h  = (u16*)(AR + 11534336ul);   // 4*64*64*128
  u16* xX2l  = (u16*)(AR + 12582912ul);
  // decoded encode (B=4):
  u16* xP1dh = (u16*)(AR + 16777216ul);   // 4*128*128*64
  u16* xP1dl = (u16*)(AR + 18874368ul);
  u16* xF2dph= (u16*)(AR + 16777216ul);   // pooled F2d: 4*64*64*128
  u16* xF2dpl= (u16*)(AR + 17825792ul);
  u16* xF3dph= (u16*)(AR + 16777216ul);   // pooled F3d: 4*32*32*256
  u16* xF3dpl= (u16*)(AR + 17301504ul);

  zerok<<<512,256,0,stream>>>(sm, 131072);

  {
    auto wsp = [&](int li, u16* wh, u16* wl, int Co, int Ci){
      int n = 9*Co*Ci;
      wsplitk<<<(n+255)/256,256,0,stream>>>(Wm[li], wh, wl, Co, Ci);
    };
    wsp(1,w2h,w2l,128,64);
    wsp(2,w3h,w3l,256,128);
    wsp(3,w4h,w4l,512,256);
    wsp(4,v1h,v1l,256,512);
    wsp(5,v2h,v2l,128,256);
    wsp(6,v3h,v3l,64,128);
  }

  // MFMA conv on pre-split NHWC u16 input. KS in {1,2,4}, RZ in {0,2}.
  auto convMFMA = [&](const u16* xh, const u16* xl, int li, float* outp,
                      int B,int Ci,int Co,int H,int Wd,int relu,int KS,int RZ,float* part){
    const u16 *wh=nullptr,*wl=nullptr;
    switch(li){
      case 1: wh=w2h; wl=w2l; break;
      case 2: wh=w3h; wl=w3l; break;
      case 3: wh=w4h; wl=w4l; break;
      case 4: wh=v1h; wl=v1l; break;
      case 5: wh=v2h; wl=v2l; break;
      case 6: wh=v3h; wl=v3l; break;
    }
    int tiles = (H>>3)*(Wd>>4);
    if (KS==1){
      dim3 g(tiles,Co>>6,B);
      if (RZ==0) convm<1,0><<<g,256,0,stream>>>(xh,xl,wh,wl,Bm[li],outp,Ci,Co,H,Wd,relu);
      else       convm<1,2><<<g,256,0,stream>>>(xh,xl,wh,wl,Bm[li],outp,Ci,Co,H,Wd,relu);
    } else if (KS==2){
      dim3 g(tiles,Co>>6,B*2);
      if (RZ==0) convm<2,0><<<g,256,0,stream>>>(xh,xl,wh,wl,nullptr,part,Ci,Co,H,Wd,relu);
      else       convm<2,2><<<g,256,0,stream>>>(xh,xl,wh,wl,nullptr,part,Ci,Co,H,Wd,relu);
      int n = B*Co*H*Wd;
      sumk<<<(n+255)/256,256,0,stream>>>(part,Bm[li],outp,Co,H*Wd,2,relu,n);
    } else {
      dim3 g(tiles,Co>>6,B*4);
      convm<4,0><<<g,256,0,stream>>>(xh,xl,wh,wl,nullptr,part,Ci,Co,H,Wd,relu);
      int n = B*Co*H*Wd;
      sumk<<<(n+255)/256,256,0,stream>>>(part,Bm[li],outp,Co,H*Wd,4,relu,n);
    }
  };

  // chunked stats: big HW -> 2-phase
  auto stats = [&](const float* x, int nbc, int HW, float* mo, float* so){
    if (HW >= 16384){
      int CH = (HW >= 65536) ? 8 : 4;
      statspk<<<dim3(nbc,CH),256,0,stream>>>(x, HW, spart);
      statsfk<<<(nbc+255)/256,256,0,stream>>>(spart, CH, HW, nbc, mo, so);
    } else {
      statsk<<<nbc,256,0,stream>>>(x, HW, mo, so);
    }
  };

  float* mS = sm + SM_STATS_S;
  float* sS = sm + SM_STATS_S + 3840;

  // ---- batched content+style encode (B=8 from e2 down) ----
  float* F1   = AR + 0;
  float* F2_8 = AR + 0;
  float* F3_8 = AR + 0;
  float* PART8 = AR + 10485760ul;

  {
    dim3 ge(64, 8, 4);  // (256/32)^2 tiles, 64/8 co-groups, B=4
    // content e1: fp32 output is dead (style overwrites F1 before any reader) -> OUTW=0
    conv3x3<8,4,1,0,0><<<ge,256,0,stream>>>(content,Wm[0],Bm[0],F1,xP1h,           xP1l,           4,3,64,256,256,1);
    conv3x3<8,4,1,1,0><<<ge,256,0,stream>>>(style,  Wm[0],Bm[0],F1,xP1h+4194304ul, xP1l+4194304ul, 4,3,64,256,256,1);
  }
  stats(F1, 256, 65536, mS+0, sS+0);

  convMFMA(xP1h,xP1l, 1, F2_8, 8, 64,128,128,128,1,1,0,nullptr);
  stats(F2_8 + 8388608ul, 512, 16384, mS+256, sS+256);
  repackk<1><<<dim3(128,2,8),256,0,stream>>>(F2_8, xF2ph, xF2pl, 128,64,64);
  convMFMA(xF2ph,xF2pl, 2, F3_8, 8, 128,256,64,64,1,1,0,nullptr);
  statsk<<<1024,256,0,stream>>>(F3_8 + 4194304ul, 4096, mS+768, sS+768);
  repackk<1><<<dim3(32,4,8),256,0,stream>>>(F3_8, xF3ph, xF3pl, 256,32,32);
  convMFMA(xF3ph,xF3pl, 3, f4c, 8, 256,512,32,32,1,2,0,PART8);
  statsk<<<2048,256,0,stream>>>(f4s,1024, mS+1792, sS+1792);

  // ---- fused k-means ----
  transposek<<<dim3(32,16,8),256,0,stream>>>(f4c,f4s,ptsT);
  zerok<<<(12*KSLOT+255)/256,256,0,stream>>>(KACC, 12*KSLOT);
  initcent2k<<<48,256,0,stream>>>(ptsT,KACC);
  for (int it=0; it<=10; ++it){
    kstepk<<<dim3(8,32),256,0,stream>>>(ptsT, KACC + (size_t)it*KSLOT, KACC + (size_t)(it+1)*KSLOT, aPtr, it==0 ? 1 : 0);
  }
  mufink<<<48,256,0,stream>>>(KACC + 11ul*KSLOT, mu, counts);

  // ---- covariances via MFMA (XCD-swizzled 1-D grid) ----
  maskcenterk<<<12288,256,0,stream>>>(f4c,f4s,aPtr,mu,Ph,Pl);
  covgemm<<<384,256,0,stream>>>(Ph,Pl,counts,Ycov,sval);
  nsinitk<<<24576,256,0,stream>>>(Ycov,sval,Yh,Yl,Zh,Zl);

  // ---- split-bf16 MFMA Newton-Schulz ----
  u16 *Ych=Yh,*Ycl=Yl,*Zch=Zh,*Zcl=Zl,*Yah=Y2h,*Yal=Y2l,*Zah=Z2h,*Zal=Z2l;
  for (int it=0; it<NS_ITERS; ++it){
    if (it == 0){
      // Z == I: M = resplit(Y) elementwise (bit-identical to MFMA with identity operand)
      nsm0k<<<6144,256,0,stream>>>(Ych,Ycl,Mh,Ml);
      nstr0k<<<24,256,0,stream>>>(Ych,Ycl,trbuf);
      // Y-update via GEMM (z<24 of last=0 path); Z-update elementwise
      bmmpair<<<384,256,0,stream>>>(Ych,Ycl,Mh,Ml,Zch,Zcl,Yah,Yal,Zah,Zal,trbuf,0);
      nsz0k<<<6144,256,0,stream>>>(Mh,Ml,Zah,Zal,trbuf);
    } else {
      bmms<0,1><<<384,256,0,stream>>>(Zch,Zcl,Ych,Ycl,Mh,Ml,nullptr,0,trbuf+it*24);
      if (it < NS_ITERS-1)
        bmmpair<<<768,256,0,stream>>>(Ych,Ycl,Mh,Ml,Zch,Zcl,Yah,Yal,Zah,Zal,trbuf+it*24,0);
      else
        bmmpair<<<384,256,0,stream>>>(Ych,Ycl,Mh,Ml,Zch,Zcl,Yah,Yal,Zah,Zal,trbuf+it*24,1);
    }
    u16* t;
    t=Ych;Ych=Yah;Yah=t; t=Ycl;Ycl=Yal;Yal=t;
    t=Zch;Zch=Zah;Zah=t; t=Zcl;Zcl=Zal;Zal=t;
  }
  make_scalesk<<<1,64,0,stream>>>(sval,scl);
  bmms<2,0><<<dim3(4,4,12),256,0,stream>>>(Ych,Ycl,Zch,Zcl,Th,Tl,scl,12,nullptr);
  tveck<<<12,512,0,stream>>>(Th,Tl,mu,tvec);
  // f4c [img][c][n] -> fsT [img][n][c] split-bf16 (transposing repack; N=1024=32x32)
  repackk<0><<<dim3(32,8,4),256,0,stream>>>(f4c, fsh, fsl, 512,32,32);
  float* Mb = AR + 0;
  bmmt<<<dim3(16,4,12),256,0,stream>>>(Th,Tl,fsh,fsl,Mb);
  selectk<<<8192,256,0,stream>>>(Mb,tvec,aPtr,f4c,tf);

  // ---- decode (B=4; up fused into d2/d3 via RZ=2; d4 via dedicated d4upk) ----
  float* X1 = AR + 0;
  float* X2 = AR + 5242880ul;
  float* X3 = AR + 0;
  float* PARTA = AR + 2097152ul;
  float* PARTB = AR + 7340032ul;
  repackk<0><<<dim3(32,8,4),256,0,stream>>>(tf, xTFh, xTFl, 512,32,32);
  convMFMA(xTFh,xTFl, 4, X1, 4, 512,256,32,32,1,4,0,PARTA);
  repackk<0><<<dim3(32,4,4),256,0,stream>>>(X1, xX1h, xX1l, 256,32,32);
  convMFMA(xX1h,xX1l, 5, X2, 4, 256,128,64,64,1,2,2,PARTB);
  repackk<0><<<dim3(128,2,4),256,0,stream>>>(X2, xX2h, xX2l, 128,64,64);
  convMFMA(xX2h,xX2l, 6, X3, 4, 128,64,128,128,1,1,2,nullptr);
  d4upk<<<dim3(256,1,4),256,0,stream>>>(X3, Wm[7], Bm[7], dec);

  // ---- decoded encode + stats + content loss (B=4) ----
  float* mD = sm + SM_STATS_D;
  float* sD = sm + SM_STATS_D + 3840;
  float* F1d = AR + 0;
  float* F2d = AR + 0;
  float* F3d = AR + 10485760ul;
  {
    dim3 ge(64, 8, 4);
    conv3x3<8,4,1,1,0><<<ge,256,0,stream>>>(dec,Wm[0],Bm[0],F1d,xP1dh,xP1dl,4,3,64,256,256,1);
  }
  stats(F1d, 256, 65536, mD+0, sD+0);
  convMFMA(xP1dh,xP1dl, 1, F2d, 4, 64,128,128,128,1,1,0,nullptr);
  stats(F2d, 512, 16384, mD+256, sD+256);
  repackk<1><<<dim3(128,2,4),256,0,stream>>>(F2d, xF2dph, xF2dpl, 128,64,64);
  convMFMA(xF2dph,xF2dpl, 2, F3d, 4, 128,256,64,64,1,1,0,nullptr);
  statsk<<<1024,256,0,stream>>>(F3d,4096, mD+768, sD+768);
  repackk<1><<<dim3(32,4,4),256,0,stream>>>(F3d, xF3dph, xF3dpl, 256,32,32);
  convMFMA(xF3dph,xF3dpl, 3, tf, 4, 256,512,32,32,1,2,0,PARTA);
  statsk<<<2048,256,0,stream>>>(tf,1024, mD+1792, sD+1792);
  clossk<<<2048,256,0,stream>>>(tf,f4c,2097152, sm+SM_CLOSS);
  finalk<<<1,256,0,stream>>>(sm,out);
}

// Round 12
// 1922.477 us; speedup vs baseline: 1.2371x; 1.0096x over previous
//
#include <hip/hip_runtime.h>
#include <cstddef>

#define NS_ITERS 8
#define MSZ 262144  // 512*512
#define PL  6291456 // 24*MSZ
#define KSLOT 12312 // k-means accumulator slot stride (floats)

typedef unsigned short u16;
typedef __attribute__((ext_vector_type(8))) short bf16x8;
typedef __attribute__((ext_vector_type(4))) float f32x4;
typedef __attribute__((ext_vector_type(4))) short u16x4;

__device__ inline u16 bf16_rne(float x){
  unsigned u = __float_as_uint(x);
  unsigned r = u + 0x7fffu + ((u>>16)&1u);
  return (u16)(r>>16);
}
__device__ inline float bf16f(u16 h){
  return __uint_as_float(((unsigned)h)<<16);
}

// ---------------- workspace offsets (in floats) ----------------
#define OFF_F4C   0ul
#define OFF_F4S   2097152ul
#define OFF_TF    4194304ul
#define OFF_DEC   6291456ul
#define OFF_WSPL  7077888ul
#define OFF_SMALL 10223616ul
#define OFF_ARENA 10354688ul

// SMALL sub-offsets (floats)
#define SM_ASSIGN  12288
#define SM_MU      20480
#define SM_COUNTS  32768
#define SM_SVAL    32800
#define SM_SCALE   32832
#define SM_TVEC    32864
#define SM_STATS_S 39008
#define SM_STATS_D 46688
#define SM_CLOSS   54368
#define SM_TR      54464
#define SM_SPART   60000  // chunked-stats partial sums (doubles; 8B-aligned)

// ---------------- kernels ----------------

__global__ __launch_bounds__(256) void zerok(float* p, int n){
  int i = blockIdx.x*256 + threadIdx.x;
  if (i < n) p[i] = 0.f;
}

// direct 3x3 SAME conv (for e1: Cin=3)
template<int COT, int CIT, int POOL, int OUTW, int RZ>
__global__ __launch_bounds__(256,4) void conv3x3(
    const float* __restrict__ in, const float* __restrict__ wgt,
    const float* __restrict__ bias, float* __restrict__ out,
    u16* __restrict__ poh, u16* __restrict__ pol,
    int B, int Cin, int Cout, int H, int W, int relu)
{
  __shared__ float s_in[CIT][34][34];
  __shared__ float s_w[COT][CIT][9];
  const int tid = threadIdx.x;
  const int tx = tid & 15, ty = tid >> 4;
  const int tilesW = W >> 5;
  const int h0 = (blockIdx.x / tilesW) << 5;
  const int w0 = (blockIdx.x % tilesW) << 5;
  const int co0 = blockIdx.y * COT;
  const int b = blockIdx.z;
  float acc[COT][2][2];
  #pragma unroll
  for (int o=0;o<COT;o++){acc[o][0][0]=0.f;acc[o][0][1]=0.f;acc[o][1][0]=0.f;acc[o][1][1]=0.f;}
  const int y0 = ty*2, x0 = tx*2;
  for (int ci0 = 0; ci0 < Cin; ci0 += CIT){
    const int cic = (Cin - ci0 < CIT) ? (Cin - ci0) : CIT;
    const int tot = cic*1156;
    for (int e = tid; e < tot; e += 256){
      int c = e / 1156; int r = e - c*1156;
      int lh = r / 34, lw = r - lh*34;
      int ih = h0 + lh - 1, iw = w0 + lw - 1;
      float v = 0.f;
      if ((unsigned)ih < (unsigned)H && (unsigned)iw < (unsigned)W){
        if constexpr (RZ==2)
          v = in[((size_t)(b*Cin + ci0 + c)*(H>>1) + (ih>>1))*(size_t)(W>>1) + (iw>>1)];
        else
          v = in[((size_t)(b*Cin + ci0 + c)*H + ih)*W + iw];
      }
      s_in[c][lh][lw] = v;
    }
    const int wtot = COT*cic*9;
    for (int e = tid; e < wtot; e += 256){
      int o = e / (cic*9); int r = e - o*(cic*9);
      int c = r / 9, t = r - c*9;
      int co = co0 + o;
      float v = 0.f;
      if (co < Cout) v = wgt[(size_t)(co*Cin + ci0 + c)*9 + t];
      s_w[o][c][t] = v;
    }
    __syncthreads();
    for (int c = 0; c < cic; ++c){
      float p[4][4];
      #pragma unroll
      for (int r=0;r<4;r++)
        #pragma unroll
        for (int s=0;s<4;s++)
          p[r][s] = s_in[c][y0+r][x0+s];
      #pragma unroll
      for (int dh=0; dh<3; dh++)
        #pragma unroll
        for (int dw=0; dw<3; dw++){
          #pragma unroll
          for (int o=0;o<COT;o++){
            float wv = s_w[o][c][dh*3+dw];
            acc[o][0][0] = fmaf(p[dh  ][dw  ], wv, acc[o][0][0]);
            acc[o][0][1] = fmaf(p[dh  ][dw+1], wv, acc[o][0][1]);
            acc[o][1][0] = fmaf(p[dh+1][dw  ], wv, acc[o][1][0]);
            acc[o][1][1] = fmaf(p[dh+1][dw+1], wv, acc[o][1][1]);
          }
        }
    }
    __syncthreads();
  }
  if constexpr (POOL){
    bf16x8 p8h, p8l;
    #pragma unroll
    for (int o=0;o<COT;o++){
      const int co = co0 + o;
      const float bv = bias[co];
      float v00 = fmaxf(acc[o][0][0]+bv, 0.f);
      float v01 = fmaxf(acc[o][0][1]+bv, 0.f);
      float v10 = fmaxf(acc[o][1][0]+bv, 0.f);
      float v11 = fmaxf(acc[o][1][1]+bv, 0.f);
      if constexpr (OUTW){
        *(float2*)&out[((size_t)(b*Cout + co)*H + h0+y0  )*W + w0+x0] = make_float2(v00, v01);
        *(float2*)&out[((size_t)(b*Cout + co)*H + h0+y0+1)*W + w0+x0] = make_float2(v10, v11);
      }
      // same order as pool2k: p[0]+p[1]+p[2W]+p[2W+1]
      float pv = 0.25f*(v00 + v01 + v10 + v11);
      u16 h = bf16_rne(pv);
      p8h[o] = (short)h;
      p8l[o] = (short)bf16_rne(pv - bf16f(h));
    }
    size_t po = ((size_t)(b*(H>>1) + ((h0+y0)>>1))*(W>>1) + ((w0+x0)>>1))*(size_t)Cout + co0;
    *(bf16x8*)&poh[po] = p8h;
    *(bf16x8*)&pol[po] = p8l;
  } else {
    #pragma unroll
    for (int o=0;o<COT;o++){
      int co = co0 + o;
      if (co >= Cout) continue;
      float bv = bias[co];
      float v00 = acc[o][0][0] + bv;
      float v01 = acc[o][0][1] + bv;
      float v10 = acc[o][1][0] + bv;
      float v11 = acc[o][1][1] + bv;
      if (relu){
        v00 = fmaxf(v00, 0.f); v01 = fmaxf(v01, 0.f);
        v10 = fmaxf(v10, 0.f); v11 = fmaxf(v11, 0.f);
      }
      *(float2*)&out[((size_t)(b*Cout + co)*H + h0+y0  )*W + w0+x0] = make_float2(v00, v01);
      *(float2*)&out[((size_t)(b*Cout + co)*H + h0+y0+1)*W + w0+x0] = make_float2(v10, v11);
    }
  }
}

// dedicated d4: Cin=64 -> Cout=3, 256x256 out, nearest-up2 fused (input 128x128 fp32 NCHW).
__global__ __launch_bounds__(256,4) void d4upk(
    const float* __restrict__ in, const float* __restrict__ wgt,
    const float* __restrict__ bias, float* __restrict__ out)
{
  __shared__ float s_in[64][10][10];
  __shared__ float s_w[3][64][9];
  const int tid = threadIdx.x;
  const int b = blockIdx.z;
  const int h0 = (blockIdx.x >> 4) << 4, w0 = (blockIdx.x & 15) << 4;
  const int r0 = (h0 >> 1) - 1, c0 = (w0 >> 1) - 1;
  for (int e = tid; e < 6400; e += 256){
    int c = e / 100, r = e - c*100;
    int lr = r / 10, lc = r - lr*10;
    int gr = r0 + lr, gc = c0 + lc;
    float v = 0.f;
    if ((unsigned)gr < 128u && (unsigned)gc < 128u)
      v = in[((size_t)(b*64 + c)*128 + gr)*128 + gc];
    s_in[c][lr][lc] = v;
  }
  for (int e = tid; e < 1728; e += 256){
    int o = e / 576, r = e - o*576;
    int ci = r / 9, t = r - ci*9;
    s_w[o][ci][t] = wgt[(size_t)(o*64 + ci)*9 + t];
  }
  __syncthreads();
  const int ty = tid >> 4, tx = tid & 15;
  const int oh = h0 + ty, ow = w0 + tx;
  int lr3[3], lc3[3]; bool vr3[3], vc3[3];
  #pragma unroll
  for (int d=0; d<3; d++){
    int ih = oh + d - 1;
    vr3[d] = (unsigned)ih < 256u;
    lr3[d] = (ih >> 1) - r0;
    int iw = ow + d - 1;
    vc3[d] = (unsigned)iw < 256u;
    lc3[d] = (iw >> 1) - c0;
  }
  float a0 = 0.f, a1 = 0.f, a2 = 0.f;
  for (int ci = 0; ci < 64; ++ci){
    #pragma unroll
    for (int dh=0; dh<3; dh++){
      #pragma unroll
      for (int dw=0; dw<3; dw++){
        float v = (vr3[dh] && vc3[dw]) ? s_in[ci][lr3[dh]][lc3[dw]] : 0.f;
        a0 = fmaf(v, s_w[0][ci][dh*3+dw], a0);
        a1 = fmaf(v, s_w[1][ci][dh*3+dw], a1);
        a2 = fmaf(v, s_w[2][ci][dh*3+dw], a2);
      }
    }
  }
  out[((size_t)(b*3 + 0)*256 + oh)*256 + ow] = a0 + bias[0];
  out[((size_t)(b*3 + 1)*256 + oh)*256 + ow] = a1 + bias[1];
  out[((size_t)(b*3 + 2)*256 + oh)*256 + ow] = a2 + bias[2];
}

// pre-split conv weights: dst[(dhw*Cout + co)*Cin + ci]
__global__ __launch_bounds__(256) void wsplitk(const float* __restrict__ wgt,
                                               u16* __restrict__ dh_, u16* __restrict__ dl_,
                                               int Cout, int Cin){
  int idx = blockIdx.x*256 + threadIdx.x;
  int n = 9*Cout*Cin;
  if (idx >= n) return;
  int cc = Cout*Cin;
  int dhw = idx / cc;
  int r = idx - dhw*cc;
  int co = r / Cin, ci = r - co*Cin;
  float v = wgt[((size_t)co*Cin + ci)*9 + dhw];
  u16 h = bf16_rne(v);
  dh_[idx] = h;
  dl_[idx] = bf16_rne(v - bf16f(h));
}

// fp32 NCHW -> split-bf16 NHWC repack (POOL=1: fused avg-pool2, input 2Ho x 2Wo)
// grid: (Ho*Wo/32, C/64, B)
template<int POOL>
__global__ __launch_bounds__(256) void repackk(const float* __restrict__ in,
    u16* __restrict__ oh, u16* __restrict__ ol, int C, int Ho, int Wo)
{
  __shared__ unsigned tr[64][33];
  const int N = Ho*Wo;
  const int n0 = blockIdx.x << 5, c0 = blockIdx.y << 6, b = blockIdx.z;
  const int lnn = threadIdx.x & 31, gc = threadIdx.x >> 5;
  {
    const int n = n0 + lnn;
    const int ho = n / Wo, wo = n - ho*Wo;
    #pragma unroll
    for (int i=0;i<8;i++){
      const int c = (gc<<3) + i;
      float v;
      if constexpr (POOL){
        const float* p = in + ((size_t)(b*C + c0+c)*(Ho*2) + ho*2)*(size_t)(Wo*2) + (size_t)wo*2;
        v = 0.25f*(p[0] + p[1] + p[2*Wo] + p[2*Wo+1]);
      } else {
        v = in[((size_t)(b*C + c0+c))*N + n];
      }
      u16 h = bf16_rne(v);
      tr[c][lnn] = (unsigned)h | ((unsigned)bf16_rne(v - bf16f(h)) << 16);
    }
  }
  __syncthreads();
  const int n2 = threadIdx.x >> 3, oct = threadIdx.x & 7;
  bf16x8 vh, vl;
  #pragma unroll
  for (int j=0;j<8;j++){
    unsigned u = tr[(oct<<3)+j][n2];
    vh[j] = (short)(u & 0xffffu);
    vl[j] = (short)(u >> 16);
  }
  size_t o = ((size_t)b*N + (n0 + n2))*(size_t)C + c0 + (oct<<3);
  *(bf16x8*)&oh[o] = vh;
  *(bf16x8*)&ol[o] = vl;
}

// ---- split-bf16 MFMA direct conv 3x3 SAME; input pre-split NHWC u16 planes ----
// 1-D XCD-swizzled grid (total = T*G*NB*KS, %8==0): xcd = bid&7,
// ig = xcd*(total/8) + (bid>>3); decode g (co-group) innermost, then tile, then z.
// Consecutive blocks on an XCD share the X halo tile -> L2 reuse.
// W staged per tap via register prefetch. Bit-exact accumulation order.
template<int KS, int RESIZE>
__global__ __launch_bounds__(256,4) void convm(
    const u16* __restrict__ xh, const u16* __restrict__ xl,
    const u16* __restrict__ wsh, const u16* __restrict__ wsl,
    const float* __restrict__ bias, float* __restrict__ out,
    int Cin, int Cout, int H, int W, int relu, int T, int G, int NB)
{
  const int per_xcd = gridDim.x >> 3;
  const int ig = (blockIdx.x & 7)*per_xcd + (blockIdx.x >> 3);
  const int g  = ig % G;
  const int tz = ig / G;
  const int t  = tz % T;
  const int zz = tz / T;

  const int tilesW = W >> 4;
  const int h0 = (t / tilesW) << 3;
  const int w0 = (t % tilesW) << 4;
  const int co0 = g << 6;
  const int b  = zz / KS;
  const int ks = zz % KS;
  const int tid = threadIdx.x;
  const int wid = tid >> 6, lane = tid & 63;
  const int wm = wid >> 1, wn = wid & 1;
  const int quad = lane >> 4, ln = lane & 15;

  __shared__ __align__(16) u16 sXh[180*40], sXl[180*40];
  __shared__ __align__(16) u16 sWh[64*40],  sWl[64*40];

  f32x4 acc[2][4];
  #pragma unroll
  for (int i=0;i<2;i++)
    #pragma unroll
    for (int j=0;j<4;j++)
      #pragma unroll
      for (int e=0;e<4;e++) acc[i][j][e] = 0.f;

  const int wco = tid >> 2, wcg = (tid & 3) << 3;

  const int ciA = ks*(Cin/KS), ciB = ciA + Cin/KS;

  // prefetch W tap0 of first chunk into registers
  bf16x8 wvh, wvl;
  {
    const size_t so = ((size_t)(co0 + wco))*Cin + ciA + wcg;  // dhw = 0
    wvh = *(const bf16x8*)&wsh[so];
    wvl = *(const bf16x8*)&wsl[so];
  }

  for (int ci0 = ciA; ci0 < ciB; ci0 += 32){
    // X staging: halo 10x18 px, 4 slots of 8 ci.
    for (int e = tid; e < 720; e += 256){
      const int px = e >> 2, sl = e & 3;
      const int pr = px / 18, pc = px - pr*18;
      const int ih = h0 + pr - 1, iw = w0 + pc - 1;
      bf16x8 vh, vl;
      #pragma unroll
      for (int j=0;j<8;j++){ vh[j] = 0; vl[j] = 0; }
      if ((unsigned)ih < (unsigned)H && (unsigned)iw < (unsigned)W){
        size_t o;
        if constexpr (RESIZE==0)
          o = ((size_t)(b*H + ih)*W + iw)*(size_t)Cin + (size_t)(ci0 + sl*8);
        else
          o = ((size_t)(b*(H>>1) + (ih>>1))*(W>>1) + (iw>>1))*(size_t)Cin + (size_t)(ci0 + sl*8);
        vh = *(const bf16x8*)&xh[o];
        vl = *(const bf16x8*)&xl[o];
      }
      *(bf16x8*)&sXh[px*40 + sl*8] = vh;
      *(bf16x8*)&sXl[px*40 + sl*8] = vl;
    }
    #pragma unroll
    for (int tap = 0; tap < 9; ++tap){
      const int dh = tap/3, dw = tap - dh*3;
      // write prefetched W fragment to LDS (prev tap's trailing barrier protects sW)
      *(bf16x8*)&sWh[wco*40 + wcg] = wvh;
      *(bf16x8*)&sWl[wco*40 + wcg] = wvl;
      // issue next tap's W load (or tap0 of next chunk) — hidden under MFMA phase
      {
        int ntap = tap + 1, nci = ci0;
        if (ntap == 9){ ntap = 0; nci = ci0 + 32; }
        if (nci < ciB){
          const size_t so = ((size_t)(ntap*Cout + co0 + wco))*Cin + nci + wcg;
          wvh = *(const bf16x8*)&wsh[so];
          wvl = *(const bf16x8*)&wsl[so];
        }
      }
      __syncthreads();
      bf16x8 ah[2], al[2], bh[4], bl[4];
      #pragma unroll
      for (int t2=0;t2<2;t2++){
        const int co_l = (wm*2+t2)*16 + ln;
        ah[t2] = *(const bf16x8*)&sWh[co_l*40 + quad*8];
        al[t2] = *(const bf16x8*)&sWl[co_l*40 + quad*8];
      }
      #pragma unroll
      for (int t2=0;t2<4;t2++){
        const int p = (wn*4+t2)*16 + ln;
        const int px = ((p>>4) + dh)*18 + (p&15) + dw;
        const int xo = px*40 + quad*8;
        bh[t2] = *(const bf16x8*)&sXh[xo];
        bl[t2] = *(const bf16x8*)&sXl[xo];
      }
      #pragma unroll
      for (int mi=0;mi<2;mi++)
        #pragma unroll
        for (int ni=0;ni<4;ni++){
          acc[mi][ni] = __builtin_amdgcn_mfma_f32_16x16x32_bf16(ah[mi], bh[ni], acc[mi][ni], 0, 0, 0);
          acc[mi][ni] = __builtin_amdgcn_mfma_f32_16x16x32_bf16(ah[mi], bl[ni], acc[mi][ni], 0, 0, 0);
          acc[mi][ni] = __builtin_amdgcn_mfma_f32_16x16x32_bf16(al[mi], bh[ni], acc[mi][ni], 0, 0, 0);
        }
      __syncthreads();
    }
  }
  #pragma unroll
  for (int mi=0;mi<2;mi++){
    const int co = co0 + (wm*2+mi)*16 + quad*4;
    #pragma unroll
    for (int ni=0;ni<4;ni++){
      const int p = (wn*4+ni)*16 + ln;
      const int oh = h0 + (p>>4), ow = w0 + (p&15);
      #pragma unroll
      for (int rg=0; rg<4; rg++){
        const int cog = co + rg;
        if constexpr (KS==1){
          float v = acc[mi][ni][rg] + bias[cog];
          if (relu) v = fmaxf(v, 0.f);
          out[((size_t)(b*Cout + cog)*H + oh)*W + ow] = v;
        } else {
          out[((size_t)((ks*NB + b)*Cout + cog)*H + oh)*W + ow] = acc[mi][ni][rg];
        }
      }
    }
  }
}

// reduce split-K partials + bias + relu
__global__ __launch_bounds__(256) void sumk(const float* __restrict__ part, const float* __restrict__ bias,
                                            float* __restrict__ out, int Cout, int HW, int KS, int relu, int n){
  int idx = blockIdx.x*256 + threadIdx.x;
  if (idx >= n) return;
  int co = (idx / HW) % Cout;
  float v = bias[co];
  for (int k=0;k<KS;k++) v += part[(size_t)k*n + idx];
  if (relu) v = fmaxf(v, 0.f);
  out[idx] = v;
}

// per-(b,c) spatial mean & std (ddof=0) — single-pass (small HW)
__global__ __launch_bounds__(256) void statsk(const float* __restrict__ x, int HW,
                                              float* __restrict__ mo, float* __restrict__ so){
  int bc = blockIdx.x, tid = threadIdx.x;
  const float* p = x + (size_t)bc*HW;
  double s = 0.0, s2 = 0.0;
  for (int i = tid; i < HW; i += 256){ double v = p[i]; s += v; s2 += v*v; }
  __shared__ double sh[256], sh2[256];
  sh[tid] = s; sh2[tid] = s2; __syncthreads();
  for (int k=128;k>0;k>>=1){ if (tid<k){ sh[tid]+=sh[tid+k]; sh2[tid]+=sh2[tid+k]; } __syncthreads(); }
  if (tid == 0){
    double m = sh[0]/HW;
    double var = sh2[0]/HW - m*m;
    if (var < 0.0) var = 0.0;
    mo[bc] = (float)m;
    so[bc] = (float)sqrt(var);
  }
}

// chunked stats phase 1: grid (bc, CH); partial double sums to part[(bc*CH+ch)*2 +{0,1}]
__global__ __launch_bounds__(256) void statspk(const float* __restrict__ x, int HW,
                                               double* __restrict__ part){
  const int bc = blockIdx.x, ch = blockIdx.y, CH = gridDim.y, tid = threadIdx.x;
  const int clen = HW / CH;
  const float* p = x + (size_t)bc*HW + (size_t)ch*clen;
  double s = 0.0, s2 = 0.0;
  for (int i = tid; i < clen; i += 256){ double v = p[i]; s += v; s2 += v*v; }
  __shared__ double sh[256], sh2[256];
  sh[tid] = s; sh2[tid] = s2; __syncthreads();
  for (int k=128;k>0;k>>=1){ if (tid<k){ sh[tid]+=sh[tid+k]; sh2[tid]+=sh2[tid+k]; } __syncthreads(); }
  if (tid == 0){
    part[(size_t)(bc*CH + ch)*2    ] = sh[0];
    part[(size_t)(bc*CH + ch)*2 + 1] = sh2[0];
  }
}

// chunked stats phase 2: one thread per bc
__global__ __launch_bounds__(256) void statsfk(const double* __restrict__ part, int CH, int HW, int nbc,
                                               float* __restrict__ mo, float* __restrict__ so){
  int bc = blockIdx.x*256 + threadIdx.x;
  if (bc >= nbc) return;
  double s = 0.0, s2 = 0.0;
  for (int ch = 0; ch < CH; ++ch){
    s  += part[(size_t)(bc*CH + ch)*2];
    s2 += part[(size_t)(bc*CH + ch)*2 + 1];
  }
  double m = s/HW;
  double var = s2/HW - m*m;
  if (var < 0.0) var = 0.0;
  mo[bc] = (float)m;
  so[bc] = (float)sqrt(var);
}

// f4 (C-major, per image 512x1024) -> ptsT [8][1024][512]
__global__ __launch_bounds__(256) void transposek(const float* __restrict__ f4c,
                                                  const float* __restrict__ f4s,
                                                  float* __restrict__ ptsT){
  __shared__ float t[32][33];
  int r = blockIdx.z;
  const float* src = (r < 4) ? (f4c + (size_t)r*524288) : (f4s + (size_t)(r-4)*524288);
  int n0 = blockIdx.x*32, c0 = blockIdx.y*32;
  int lx = threadIdx.x & 31, ly = threadIdx.x >> 5;
  for (int j=0;j<32;j+=8)
    t[ly+j][lx] = src[(size_t)(c0+ly+j)*1024 + n0+lx];
  __syncthreads();
  for (int j=0;j<32;j+=8)
    ptsT[((size_t)r*1024 + n0+ly+j)*512 + c0+lx] = t[lx][ly+j];
}

// slot0 init: sums = first 3 points (centroids), counts = 1
__global__ __launch_bounds__(256) void initcent2k(const float* __restrict__ ptsT, float* __restrict__ KACC){
  int i = blockIdx.x*256 + threadIdx.x;
  if (i < 12288){
    int c = i & 511; int k = (i >> 9) % 3; int r = i / 1536;
    KACC[r*1536 + k*512 + c] = ptsT[((size_t)r*1024 + k)*512 + c];
  }
  if (i < 24) KACC[12288 + i] = 1.f;
}

// fused k-means step
__global__ __launch_bounds__(256) void kstepk(const float* __restrict__ ptsT,
    const float* __restrict__ prev, float* __restrict__ next,
    int* __restrict__ a, int nodiv)
{
  const int r = blockIdx.x, sl = blockIdx.y;
  const int tid = threadIdx.x;
  __shared__ float sc[1536];
  __shared__ int sa[32];
  __shared__ float red[3][8][32];
  __shared__ int scnt[3];
  if (tid < 3) scnt[tid] = 0;
  for (int i = tid; i < 1536; i += 256){
    float s = prev[r*1536 + i];
    float cnt = nodiv ? 1.f : (prev[12288 + r*3 + (i>>9)] + 1e-6f);
    sc[i] = s / cnt;
  }
  __syncthreads();
  const float* base = ptsT + (size_t)r*524288;
  const int wid = tid >> 6, lane = tid & 63;
  for (int rep = 0; rep < 8; ++rep){
    int p = wid*8 + rep;
    int n = sl*32 + p;
    const float* pp = base + (size_t)n*512;
    float d0=0.f,d1=0.f,d2=0.f;
    #pragma unroll
    for (int i=0;i<8;i++){
      int c = lane + i*64;
      float v = pp[c];
      float e0 = v - sc[c], e1 = v - sc[512+c], e2 = v - sc[1024+c];
      d0 = fmaf(e0,e0,d0); d1 = fmaf(e1,e1,d1); d2 = fmaf(e2,e2,d2);
    }
    #pragma unroll
    for (int off=32; off>0; off>>=1){
      d0 += __shfl_down(d0, off, 64);
      d1 += __shfl_down(d1, off, 64);
      d2 += __shfl_down(d2, off, 64);
    }
    if (lane == 0){
      int bi = 0; float bd = d0;
      if (d1 < bd){ bd = d1; bi = 1; }
      if (d2 < bd){ bd = d2; bi = 2; }
      sa[p] = bi;
      a[r*1024 + n] = bi;
    }
  }
  __syncthreads();
  if (tid < 32) atomicAdd(&scnt[sa[tid]], 1);
  __syncthreads();
  if (tid < 3) atomicAdd(&next[12288 + r*3 + tid], (float)scnt[tid]);
  const int g = tid >> 5, lc = tid & 31;
  for (int cj = 0; cj < 16; ++cj){
    int c = cj*32 + lc;
    float s0=0.f,s1=0.f,s2=0.f;
    #pragma unroll
    for (int q=0;q<4;q++){
      int nl = g*4 + q;
      float v = base[(size_t)(sl*32+nl)*512 + c];
      int an = sa[nl];
      s0 += (an==0)?v:0.f;
      s1 += (an==1)?v:0.f;
      s2 += (an==2)?v:0.f;
    }
    red[0][g][lc]=s0; red[1][g][lc]=s1; red[2][g][lc]=s2;
    __syncthreads();
    if (g == 0){
      float t0=0.f,t1=0.f,t2=0.f;
      #pragma unroll
      for (int q2=0;q2<8;q2++){ t0+=red[0][q2][lc]; t1+=red[1][q2][lc]; t2+=red[2][q2][lc]; }
      atomicAdd(&next[r*1536 +          c], t0);
      atomicAdd(&next[r*1536 +  512 +   c], t1);
      atomicAdd(&next[r*1536 + 1024 +   c], t2);
    }
    __syncthreads();
  }
}

// final mu/counts from slot 11
__global__ __launch_bounds__(256) void mufink(const float* __restrict__ slot,
                                              float* __restrict__ mu, float* __restrict__ counts){
  int i = blockIdx.x*256 + threadIdx.x;
  if (i >= 12288) return;
  int c = i & 511; int k = (i >> 9) % 3; int r = i / 1536;
  int cs = r >> 2, img = r & 3;
  int i0 = cs*12 + img*3;
  float cnt = slot[12288 + r*3 + k];
  mu[(size_t)(i0+k)*512 + c] = slot[r*1536 + k*512 + c] / (cnt + 1e-6f);
  if (c == 0) counts[i0+k] = cnt;
}

// masked centered split planes
__global__ __launch_bounds__(256) void maskcenterk(const float* __restrict__ f4c, const float* __restrict__ f4s,
        const int* __restrict__ a, const float* __restrict__ mu,
        u16* __restrict__ Ph, u16* __restrict__ Pl){
  size_t i4 = ((size_t)blockIdx.x*256 + threadIdx.x)*4;
  if (i4 >= (size_t)PL*2) return;
  int z = (int)(i4 >> 19);
  int rc = (int)(i4 & 524287);
  int c = rc >> 10, n = rc & 1023;
  int cs = z / 12; int rem = z - cs*12; int img = rem / 3; int k = rem - img*3;
  const float* pts = (cs ? f4s : f4c) + (size_t)img*524288;
  float m = mu[(size_t)z*512 + c];
  const int* an = a + (cs*4 + img)*1024 + n;
  float4 v4 = *(const float4*)&pts[(size_t)c*1024 + n];
  float vv[4] = {v4.x, v4.y, v4.z, v4.w};
  u16x4 oh, ol;
  #pragma unroll
  for (int j=0;j<4;j++){
    float v = (an[j] == k) ? (vv[j] - m) : 0.f;
    u16 h = bf16_rne(v);
    oh[j] = (short)h;
    ol[j] = (short)bf16_rne(v - bf16f(h));
  }
  *(u16x4*)&Ph[i4] = oh;
  *(u16x4*)&Pl[i4] = ol;
}

// covariance via MFMA, trace accumulated. Tile 128x128; 1-D grid 384 blocks,
// XCD-swizzled: all 16 tiles of a z share one XCD (z = (bid&7) + 8*(w>>4)).
__global__ __launch_bounds__(256) void covgemm(const u16* __restrict__ Ph, const u16* __restrict__ Pl,
        const float* __restrict__ counts, float* __restrict__ Ycov, float* __restrict__ trsum){
  const int bid = blockIdx.x;
  const int xcd = bid & 7, w = bid >> 3;
  const int z = xcd + ((w >> 4) << 3);
  const int t4 = w & 15;
  const int m0 = (t4 >> 2) << 7, n0 = (t4 & 3) << 7;
  const u16* Pbh = Ph + (size_t)z*524288;
  const u16* Pbl = Pl + (size_t)z*524288;
  const int tid = threadIdx.x;

  __shared__ __align__(16) u16 sAh[128*40], sAl[128*40];
  __shared__ __align__(16) u16 sBh[128*40], sBl[128*40];

  const int ra = tid >> 2, qa = tid & 3;
  const int wid = tid >> 6, lane = tid & 63;
  const int wm = wid >> 1, wn = wid & 1;
  const int quad = lane >> 4, ln = lane & 15;

  f32x4 acc[4][4];
  #pragma unroll
  for (int i=0;i<4;i++)
    #pragma unroll
    for (int j=0;j<4;j++)
      #pragma unroll
      for (int e=0;e<4;e++) acc[i][j][e] = 0.f;

  for (int k0 = 0; k0 < 1024; k0 += 32){
    *(bf16x8*)&sAh[ra*40 + qa*8]      = *(const bf16x8*)&Pbh[(size_t)(m0+ra)*1024    + k0 + qa*8];
    *(bf16x8*)&sAl[ra*40 + qa*8]      = *(const bf16x8*)&Pbl[(size_t)(m0+ra)*1024    + k0 + qa*8];
    *(bf16x8*)&sAh[(ra+64)*40 + qa*8] = *(const bf16x8*)&Pbh[(size_t)(m0+ra+64)*1024 + k0 + qa*8];
    *(bf16x8*)&sAl[(ra+64)*40 + qa*8] = *(const bf16x8*)&Pbl[(size_t)(m0+ra+64)*1024 + k0 + qa*8];
    *(bf16x8*)&sBh[ra*40 + qa*8]      = *(const bf16x8*)&Pbh[(size_t)(n0+ra)*1024    + k0 + qa*8];
    *(bf16x8*)&sBl[ra*40 + qa*8]      = *(const bf16x8*)&Pbl[(size_t)(n0+ra)*1024    + k0 + qa*8];
    *(bf16x8*)&sBh[(ra+64)*40 + qa*8] = *(const bf16x8*)&Pbh[(size_t)(n0+ra+64)*1024 + k0 + qa*8];
    *(bf16x8*)&sBl[(ra+64)*40 + qa*8] = *(const bf16x8*)&Pbl[(size_t)(n0+ra+64)*1024 + k0 + qa*8];
    __syncthreads();

    bf16x8 ah[4], al[4], bh[4], bl[4];
    #pragma unroll
    for (int t=0;t<4;t++){
      const int moA = ((wm*4+t)*16 + ln)*40 + quad*8;
      const int moB = ((wn*4+t)*16 + ln)*40 + quad*8;
      ah[t] = *(const bf16x8*)&sAh[moA];
      al[t] = *(const bf16x8*)&sAl[moA];
      bh[t] = *(const bf16x8*)&sBh[moB];
      bl[t] = *(const bf16x8*)&sBl[moB];
    }
    #pragma unroll
    for (int mi=0;mi<4;mi++)
      #pragma unroll
      for (int ni=0;ni<4;ni++){
        acc[mi][ni] = __builtin_amdgcn_mfma_f32_16x16x32_bf16(ah[mi], bh[ni], acc[mi][ni], 0, 0, 0);
        acc[mi][ni] = __builtin_amdgcn_mfma_f32_16x16x32_bf16(ah[mi], bl[ni], acc[mi][ni], 0, 0, 0);
        acc[mi][ni] = __builtin_amdgcn_mfma_f32_16x16x32_bf16(al[mi], bh[ni], acc[mi][ni], 0, 0, 0);
      }
    __syncthreads();
  }
  const float inv = 1.f/(counts[z] + 1e-6f);
  float dsum = 0.f; bool anyd = false;
  #pragma unroll
  for (int mi=0;mi<4;mi++){
    const int mbase = m0 + (wm*4+mi)*16 + quad*4;
    #pragma unroll
    for (int ni=0;ni<4;ni++){
      const int n = n0 + (wn*4+ni)*16 + ln;
      #pragma unroll
      for (int rg=0;rg<4;rg++){
        const int m = mbase + rg;
        float v = acc[mi][ni][rg]*inv + ((m==n)?0.1f:0.f);
        Ycov[(size_t)z*MSZ + (size_t)m*512 + n] = v;
        if (m0==n0 && m==n){ dsum += v; anyd = true; }
      }
    }
  }
  if (anyd) atomicAdd(&trsum[z], dsum);
}

// init split planes: Y = Ycov/trace (hi+lo bf16), Z = I
__global__ __launch_bounds__(256) void nsinitk(const float* __restrict__ Ycov, const float* __restrict__ sval,
                                               u16* __restrict__ Yh, u16* __restrict__ Yl,
                                               u16* __restrict__ Zh, u16* __restrict__ Zl){
  size_t idx = (size_t)blockIdx.x*256 + threadIdx.x;
  if (idx >= (size_t)PL) return;
  int z = (int)(idx >> 18);
  int rc = (int)(idx & (MSZ-1));
  int rr = rc >> 9, cc = rc & 511;
  float y = Ycov[idx] / sval[z];
  u16 h = bf16_rne(y);
  Yh[idx] = h;
  Yl[idx] = bf16_rne(y - bf16f(h));
  Zh[idx] = (rr==cc) ? (u16)0x3F80 : (u16)0;
  Zl[idx] = 0;
}

// it=0 specializations (Z == I exactly):
// M = Z*Y via MFMA degenerates to elementwise resplit of (Yh+Yl) — bit-identical.
__global__ __launch_bounds__(256) void nsm0k(const u16* __restrict__ Yh, const u16* __restrict__ Yl,
                                             u16* __restrict__ Mh, u16* __restrict__ Ml){
  size_t i4 = ((size_t)blockIdx.x*256 + threadIdx.x)*4;
  if (i4 >= (size_t)PL) return;
  u16x4 hv = *(const u16x4*)&Yh[i4];
  u16x4 lv = *(const u16x4*)&Yl[i4];
  u16x4 oh, ol;
  #pragma unroll
  for (int j=0;j<4;j++){
    float v = bf16f((u16)hv[j]) + bf16f((u16)lv[j]);
    u16 h = bf16_rne(v);
    oh[j] = (short)h;
    ol[j] = (short)bf16_rne(v - bf16f(h));
  }
  *(u16x4*)&Mh[i4] = oh;
  *(u16x4*)&Ml[i4] = ol;
}

// trace of M (= sum of diag (Yh+Yl)) per z; grid 24 blocks.
__global__ __launch_bounds__(256) void nstr0k(const u16* __restrict__ Yh, const u16* __restrict__ Yl,
                                              float* __restrict__ tr){
  int z = blockIdx.x, tid = threadIdx.x;
  float s = 0.f;
  for (int i = tid; i < 512; i += 256){
    size_t o = (size_t)z*MSZ + (size_t)i*513;
    s += bf16f(Yh[o]) + bf16f(Yl[o]);
  }
  __shared__ float sh[256];
  sh[tid] = s; __syncthreads();
  for (int k=128;k>0;k>>=1){ if (tid<k) sh[tid]+=sh[tid+k]; __syncthreads(); }
  if (tid == 0) tr[z] = sh[0];
}

// it=0 Z-update: Z2 = alpha*(Mh+Ml) + beta*I (since M*Z with Z=I is elementwise-exact).
__global__ __launch_bounds__(256) void nsz0k(const u16* __restrict__ Mh, const u16* __restrict__ Ml,
                                             u16* __restrict__ Z2h, u16* __restrict__ Z2l,
                                             const float* __restrict__ trAcc){
  size_t i4 = ((size_t)blockIdx.x*256 + threadIdx.x)*4;
  if (i4 >= (size_t)PL) return;
  int z = (int)(i4 >> 18);
  int rc = (int)(i4 & (MSZ-1));
  int row = rc >> 9, col = rc & 511;
  const float tr = trAcc[z];
  const float g2 = fminf(512.f/fmaxf(tr, 1e-6f), 2.7f);
  const float oz = 0.5f*sqrtf(g2);
  const float alpha = -g2*oz, beta = 3.f*oz;
  u16x4 hv = *(const u16x4*)&Mh[i4];
  u16x4 lv = *(const u16x4*)&Ml[i4];
  u16x4 oh, ol;
  #pragma unroll
  for (int j=0;j<4;j++){
    float m = bf16f((u16)hv[j]) + bf16f((u16)lv[j]);
    float zv = (row == col + j) ? 1.f : 0.f;
    float v = alpha*m + beta*zv;
    u16 h = bf16_rne(v);
    oh[j] = (short)h;
    ol[j] = (short)bf16_rne(v - bf16f(h));
  }
  *(u16x4*)&Z2h[i4] = oh;
  *(u16x4*)&Z2l[i4] = ol;
}

// ---- split-bf16 MFMA batched GEMM 512x512x512; tile 128x128 ----
// SWZ=1: 1-D grid NZ*16 blocks, XCD-swizzled (NZ%8==0). SWZ=0: 3-D grid (4,4,NZ).
template<int MODE, int SWZ>
__global__ __launch_bounds__(256) void bmms(
    const u16* __restrict__ Ah, const u16* __restrict__ Al,
    const u16* __restrict__ Bh, const u16* __restrict__ Bl,
    u16* __restrict__ Ch, u16* __restrict__ Cl,
    const float* __restrict__ osc,
    int aoff, float* __restrict__ trAcc)
{
  int z, m0, n0;
  if constexpr (SWZ){
    const int bid = blockIdx.x;
    const int xcd = bid & 7, w = bid >> 3;
    z = xcd + ((w >> 4) << 3);
    const int t4 = w & 15;
    m0 = (t4 >> 2) << 7; n0 = (t4 & 3) << 7;
  } else {
    z = blockIdx.z; m0 = blockIdx.y*128; n0 = blockIdx.x*128;
  }
  const u16* Abh = Ah + (size_t)(z+aoff)*MSZ;
  const u16* Abl = Al + (size_t)(z+aoff)*MSZ;
  const u16* Bbh = Bh + (size_t)z*MSZ;
  const u16* Bbl = Bl + (size_t)z*MSZ;
  const int tid = threadIdx.x;

  __shared__ __align__(16) u16 sAh[128*40], sAl[128*40];
  __shared__ __align__(16) u16 sBh[128*40], sBl[128*40];

  const int ra = tid >> 2, qa = tid & 3;
  const int wid = tid >> 6, lane = tid & 63;
  const int wm = wid >> 1, wn = wid & 1;
  const int quad = lane >> 4, ln = lane & 15;

  f32x4 acc[4][4];
  #pragma unroll
  for (int i=0;i<4;i++)
    #pragma unroll
    for (int j=0;j<4;j++)
      #pragma unroll
      for (int e=0;e<4;e++) acc[i][j][e] = 0.f;

  for (int k0 = 0; k0 < 512; k0 += 32){
    *(bf16x8*)&sAh[ra*40 + qa*8]      = *(const bf16x8*)&Abh[(size_t)(m0+ra)*512    + k0 + qa*8];
    *(bf16x8*)&sAl[ra*40 + qa*8]      = *(const bf16x8*)&Abl[(size_t)(m0+ra)*512    + k0 + qa*8];
    *(bf16x8*)&sAh[(ra+64)*40 + qa*8] = *(const bf16x8*)&Abh[(size_t)(m0+ra+64)*512 + k0 + qa*8];
    *(bf16x8*)&sAl[(ra+64)*40 + qa*8] = *(const bf16x8*)&Abl[(size_t)(m0+ra+64)*512 + k0 + qa*8];
    *(bf16x8*)&sBh[ra*40 + qa*8]      = *(const bf16x8*)&Bbh[(size_t)(n0+ra)*512    + k0 + qa*8];
    *(bf16x8*)&sBl[ra*40 + qa*8]      = *(const bf16x8*)&Bbl[(size_t)(n0+ra)*512    + k0 + qa*8];
    *(bf16x8*)&sBh[(ra+64)*40 + qa*8] = *(const bf16x8*)&Bbh[(size_t)(n0+ra+64)*512 + k0 + qa*8];
    *(bf16x8*)&sBl[(ra+64)*40 + qa*8] = *(const bf16x8*)&Bbl[(size_t)(n0+ra+64)*512 + k0 + qa*8];
    __syncthreads();

    bf16x8 ah[4], al[4], bh[4], bl[4];
    #pragma unroll
    for (int t=0;t<4;t++){
      const int moA = ((wm*4+t)*16 + ln)*40 + quad*8;
      const int moB = ((wn*4+t)*16 + ln)*40 + quad*8;
      ah[t] = *(const bf16x8*)&sAh[moA];
      al[t] = *(const bf16x8*)&sAl[moA];
      bh[t] = *(const bf16x8*)&sBh[moB];
      bl[t] = *(const bf16x8*)&sBl[moB];
    }
    #pragma unroll
    for (int mi=0;mi<4;mi++)
      #pragma unroll
      for (int ni=0;ni<4;ni++){
        acc[mi][ni] = __builtin_amdgcn_mfma_f32_16x16x32_bf16(ah[mi], bh[ni], acc[mi][ni], 0, 0, 0);
        acc[mi][ni] = __builtin_amdgcn_mfma_f32_16x16x32_bf16(ah[mi], bl[ni], acc[mi][ni], 0, 0, 0);
        acc[mi][ni] = __builtin_amdgcn_mfma_f32_16x16x32_bf16(al[mi], bh[ni], acc[mi][ni], 0, 0, 0);
      }
    __syncthreads();
  }

  float alpha = 1.f;
  if constexpr (MODE==2){ alpha = osc[z]; }

  float dsum = 0.f; bool anyd = false;
  #pragma unroll
  for (int mi=0;mi<4;mi++){
    const int mbase = m0 + (wm*4+mi)*16 + quad*4;
    #pragma unroll
    for (int ni=0;ni<4;ni++){
      const int n = n0 + (wn*4+ni)*16 + ln;
      #pragma unroll
      for (int rg=0;rg<4;rg++){
        const int m = mbase + rg;
        const size_t off = (size_t)z*MSZ + (size_t)m*512 + n;
        float v = alpha*acc[mi][ni][rg];
        u16 h = bf16_rne(v);
        Ch[off] = h;
        Cl[off] = bf16_rne(v - bf16f(h));
        if (MODE==0 && trAcc && m0==n0 && m==n){ dsum += v; anyd = true; }
      }
    }
  }
  if (MODE==0 && anyd) atomicAdd(&trAcc[z], dsum);
}

// merged NS update (128x128 tile); 1-D grid NZ*16 blocks, XCD-swizzled.
__global__ __launch_bounds__(256) void bmmpair(
    const u16* __restrict__ Yh, const u16* __restrict__ Yl,
    const u16* __restrict__ Mh, const u16* __restrict__ Ml,
    const u16* __restrict__ Zh, const u16* __restrict__ Zl,
    u16* __restrict__ Y2h, u16* __restrict__ Y2l,
    u16* __restrict__ Z2h, u16* __restrict__ Z2l,
    const float* __restrict__ trAcc, int last)
{
  const int bid = blockIdx.x;
  const int xcd = bid & 7, w = bid >> 3;
  const int z = xcd + ((w >> 4) << 3);
  const int t4 = w & 15;
  const int m0 = (t4 >> 2) << 7, n0 = (t4 & 3) << 7;
  int zz; bool isY;
  if (last){ zz = z; isY = (z >= 12); }
  else { isY = (z < 24); zz = isY ? z : (z - 24); }
  const size_t zo = (size_t)zz*MSZ;
  const u16 *Abh, *Abl, *Bbh, *Bbl, *Dbh, *Dbl;
  u16 *Cbh, *Cbl;
  if (isY){
    Abh = Yh + zo; Abl = Yl + zo;
    Bbh = Mh + zo; Bbl = Ml + zo;
    Dbh = Yh + zo; Dbl = Yl + zo;
    Cbh = Y2h + zo; Cbl = Y2l + zo;
  } else {
    Abh = Mh + zo; Abl = Ml + zo;
    Bbh = Zh + zo; Bbl = Zl + zo;
    Dbh = Zh + zo; Dbl = Zl + zo;
    Cbh = Z2h + zo; Cbl = Z2l + zo;
  }
  const int tid = threadIdx.x;

  __shared__ __align__(16) u16 sAh[128*40], sAl[128*40];
  __shared__ __align__(16) u16 sBh[128*40], sBl[128*40];

  const int ra = tid >> 2, qa = tid & 3;
  const int wid = tid >> 6, lane = tid & 63;
  const int wm = wid >> 1, wn = wid & 1;
  const int quad = lane >> 4, ln = lane & 15;

  f32x4 acc[4][4];
  #pragma unroll
  for (int i=0;i<4;i++)
    #pragma unroll
    for (int j=0;j<4;j++)
      #pragma unroll
      for (int e=0;e<4;e++) acc[i][j][e] = 0.f;

  for (int k0 = 0; k0 < 512; k0 += 32){
    *(bf16x8*)&sAh[ra*40 + qa*8]      = *(const bf16x8*)&Abh[(size_t)(m0+ra)*512    + k0 + qa*8];
    *(bf16x8*)&sAl[ra*40 + qa*8]      = *(const bf16x8*)&Abl[(size_t)(m0+ra)*512    + k0 + qa*8];
    *(bf16x8*)&sAh[(ra+64)*40 + qa*8] = *(const bf16x8*)&Abh[(size_t)(m0+ra+64)*512 + k0 + qa*8];
    *(bf16x8*)&sAl[(ra+64)*40 + qa*8] = *(const bf16x8*)&Abl[(size_t)(m0+ra+64)*512 + k0 + qa*8];
    *(bf16x8*)&sBh[ra*40 + qa*8]      = *(const bf16x8*)&Bbh[(size_t)(n0+ra)*512    + k0 + qa*8];
    *(bf16x8*)&sBl[ra*40 + qa*8]      = *(const bf16x8*)&Bbl[(size_t)(n0+ra)*512    + k0 + qa*8];
    *(bf16x8*)&sBh[(ra+64)*40 + qa*8] = *(const bf16x8*)&Bbh[(size_t)(n0+ra+64)*512 + k0 + qa*8];
    *(bf16x8*)&sBl[(ra+64)*40 + qa*8] = *(const bf16x8*)&Bbl[(size_t)(n0+ra+64)*512 + k0 + qa*8];
    __syncthreads();

    bf16x8 ah[4], al[4], bh[4], bl[4];
    #pragma unroll
    for (int t=0;t<4;t++){
      const int moA = ((wm*4+t)*16 + ln)*40 + quad*8;
      const int moB = ((wn*4+t)*16 + ln)*40 + quad*8;
      ah[t] = *(const bf16x8*)&sAh[moA];
      al[t] = *(const bf16x8*)&sAl[moA];
      bh[t] = *(const bf16x8*)&sBh[moB];
      bl[t] = *(const bf16x8*)&sBl[moB];
    }
    #pragma unroll
    for (int mi=0;mi<4;mi++)
      #pragma unroll
      for (int ni=0;ni<4;ni++){
        acc[mi][ni] = __builtin_amdgcn_mfma_f32_16x16x32_bf16(ah[mi], bh[ni], acc[mi][ni], 0, 0, 0);
        acc[mi][ni] = __builtin_amdgcn_mfma_f32_16x16x32_bf16(ah[mi], bl[ni], acc[mi][ni], 0, 0, 0);
        acc[mi][ni] = __builtin_amdgcn_mfma_f32_16x16x32_bf16(al[mi], bh[ni], acc[mi][ni], 0, 0, 0);
      }
    __syncthreads();
  }

  const float tr = trAcc[zz];
  const float g2 = fminf(512.f/fmaxf(tr, 1e-6f), 2.7f);
  const float oz = 0.5f*sqrtf(g2);
  const float alpha = -g2*oz, beta = 3.f*oz;

  #pragma unroll
  for (int mi=0;mi<4;mi++){
    const int mbase = m0 + (wm*4+mi)*16 + quad*4;
    #pragma unroll
    for (int ni=0;ni<4;ni++){
      const int n = n0 + (wn*4+ni)*16 + ln;
      #pragma unroll
      for (int rg=0;rg<4;rg++){
        const int m = mbase + rg;
        const size_t off = (size_t)m*512 + n;
        float v = alpha*acc[mi][ni][rg] + beta*(bf16f(Dbh[off]) + bf16f(Dbl[off]));
        u16 h = bf16_rne(v);
        Cbh[off] = h;
        Cbl[off] = bf16_rne(v - bf16f(h));
      }
    }
  }
}

// tpts = T[z] @ f[img]: M=512, N=1024, K=512, fp32 out.
// B is pre-transposed fsT [img][n][c]; tile 128M x 64N; grid (16,4,12).
__global__ __launch_bounds__(256,4) void bmmt(
    const u16* __restrict__ Th, const u16* __restrict__ Tl,
    const u16* __restrict__ fh, const u16* __restrict__ fl,
    float* __restrict__ Cf)
{
  const int z = blockIdx.z;
  const u16* Abh = Th + (size_t)z*MSZ;
  const u16* Abl = Tl + (size_t)z*MSZ;
  const u16* Bbh = fh + (size_t)(z/3)*524288;
  const u16* Bbl = fl + (size_t)(z/3)*524288;
  const int m0 = blockIdx.y*128, n0 = blockIdx.x*64;
  const int tid = threadIdx.x;

  __shared__ __align__(16) u16 sAh[128*40], sAl[128*40];
  __shared__ __align__(16) u16 sBh[64*40], sBl[64*40];

  const int ra = tid >> 2, qa = tid & 3;
  const int wid = tid >> 6, lane = tid & 63;
  const int wm = wid >> 1, wn = wid & 1;
  const int quad = lane >> 4, ln = lane & 15;

  f32x4 acc[4][2];
  #pragma unroll
  for (int i=0;i<4;i++)
    #pragma unroll
    for (int j=0;j<2;j++)
      #pragma unroll
      for (int e=0;e<4;e++) acc[i][j][e] = 0.f;

  for (int k0 = 0; k0 < 512; k0 += 32){
    *(bf16x8*)&sAh[ra*40 + qa*8]      = *(const bf16x8*)&Abh[(size_t)(m0+ra)*512    + k0 + qa*8];
    *(bf16x8*)&sAl[ra*40 + qa*8]      = *(const bf16x8*)&Abl[(size_t)(m0+ra)*512    + k0 + qa*8];
    *(bf16x8*)&sAh[(ra+64)*40 + qa*8] = *(const bf16x8*)&Abh[(size_t)(m0+ra+64)*512 + k0 + qa*8];
    *(bf16x8*)&sAl[(ra+64)*40 + qa*8] = *(const bf16x8*)&Abl[(size_t)(m0+ra+64)*512 + k0 + qa*8];
    *(bf16x8*)&sBh[ra*40 + qa*8]      = *(const bf16x8*)&Bbh[(size_t)(n0+ra)*512    + k0 + qa*8];
    *(bf16x8*)&sBl[ra*40 + qa*8]      = *(const bf16x8*)&Bbl[(size_t)(n0+ra)*512    + k0 + qa*8];
    __syncthreads();

    bf16x8 ah[4], al[4], bh[2], bl[2];
    #pragma unroll
    for (int t=0;t<4;t++){
      const int moA = ((wm*4+t)*16 + ln)*40 + quad*8;
      ah[t] = *(const bf16x8*)&sAh[moA];
      al[t] = *(const bf16x8*)&sAl[moA];
    }
    #pragma unroll
    for (int t=0;t<2;t++){
      const int moB = ((wn*2+t)*16 + ln)*40 + quad*8;
      bh[t] = *(const bf16x8*)&sBh[moB];
      bl[t] = *(const bf16x8*)&sBl[moB];
    }
    #pragma unroll
    for (int mi=0;mi<4;mi++)
      #pragma unroll
      for (int ni=0;ni<2;ni++){
        acc[mi][ni] = __builtin_amdgcn_mfma_f32_16x16x32_bf16(ah[mi], bh[ni], acc[mi][ni], 0, 0, 0);
        acc[mi][ni] = __builtin_amdgcn_mfma_f32_16x16x32_bf16(ah[mi], bl[ni], acc[mi][ni], 0, 0, 0);
        acc[mi][ni] = __builtin_amdgcn_mfma_f32_16x16x32_bf16(al[mi], bh[ni], acc[mi][ni], 0, 0, 0);
      }
    __syncthreads();
  }
  #pragma unroll
  for (int mi=0;mi<4;mi++){
    const int mbase = m0 + (wm*4+mi)*16 + quad*4;
    #pragma unroll
    for (int ni=0;ni<2;ni++){
      const int n = n0 + (wn*2+ni)*16 + ln;
      #pragma unroll
      for (int rg=0;rg<4;rg++){
        const int m = mbase + rg;
        Cf[(size_t)z*524288 + (size_t)m*1024 + n] = acc[mi][ni][rg];
      }
    }
  }
}

__global__ void make_scalesk(const float* __restrict__ sval, float* __restrict__ scl){
  int i = threadIdx.x;
  if (i < 12) scl[i] = sqrtf(sval[12+i] / sval[i]);
}

// tvec[b] = mu_s[b] - T[b] @ mu_c[b]
__global__ __launch_bounds__(512) void tveck(const u16* __restrict__ Th, const u16* __restrict__ Tl,
                                             const float* __restrict__ mu, float* __restrict__ tvec){
  int b = blockIdx.x; int c = threadIdx.x;
  __shared__ float mc[512];
  mc[c] = mu[(size_t)b*512 + c];
  __syncthreads();
  const u16* Trh = Th + ((size_t)b*512 + c)*512;
  const u16* Trl = Tl + ((size_t)b*512 + c)*512;
  float s = 0.f;
  for (int d=0; d<512; d++) s = fmaf(bf16f(Trh[d]) + bf16f(Trl[d]), mc[d], s);
  tvec[b*512 + c] = mu[(size_t)(12+b)*512 + c] - s;
}

__global__ __launch_bounds__(256) void selectk(const float* __restrict__ tpts, const float* __restrict__ tvec,
        const int* __restrict__ a, const float* __restrict__ f4c, float* __restrict__ tf){
  size_t idx = (size_t)blockIdx.x*256 + threadIdx.x;
  if (idx >= 2097152ul) return;
  int n = (int)(idx & 1023);
  int c = (int)((idx >> 10) & 511);
  int img = (int)(idx >> 19);
  int k = a[img*1024 + n];
  int b = img*3 + k;
  float v = tpts[((size_t)b*512 + c)*1024 + n] + tvec[b*512 + c];
  tf[idx] = 0.6f*v + 0.4f*f4c[idx];
}

__global__ __launch_bounds__(256) void clossk(const float* __restrict__ x, const float* __restrict__ y,
                                              int n, float* __restrict__ acc){
  int tid = threadIdx.x;
  float s = 0.f;
  for (size_t i = (size_t)blockIdx.x*256 + tid; i < (size_t)n; i += (size_t)gridDim.x*256){
    float d = x[i] - y[i]; s = fmaf(d, d, s);
  }
  __shared__ float sh[256];
  sh[tid] = s; __syncthreads();
  for (int k=128;k>0;k>>=1){ if (tid<k) sh[tid]+=sh[tid+k]; __syncthreads(); }
  if (tid==0) atomicAdd(acc, sh[0]);
}

__global__ __launch_bounds__(256) void finalk(const float* __restrict__ sm, float* __restrict__ out){
  int tid = threadIdx.x;
  const int cnts[4] = {256,512,1024,2048};
  const int offs[4] = {0,256,768,1792};
  const float* mS = sm + SM_STATS_S;
  const float* sS = sm + SM_STATS_S + 3840;
  const float* mD = sm + SM_STATS_D;
  const float* sD = sm + SM_STATS_D + 3840;
  double sl = 0.0;
  for (int L=0; L<4; ++L){
    int cnt = cnts[L], off = offs[L];
    double inv = 1.0/cnt;
    for (int i=tid; i<cnt; i+=256){
      double dm = (double)mD[off+i] - (double)mS[off+i];
      double ds = (double)sD[off+i] - (double)sS[off+i];
      sl += (dm*dm + ds*ds)*inv;
    }
  }
  __shared__ double sh[256];
  sh[tid] = sl; __syncthreads();
  for (int k=128;k>0;k>>=1){ if (tid<k) sh[tid]+=sh[tid+k]; __syncthreads(); }
  if (tid==0){
    double closs = (double)sm[SM_CLOSS] / 2097152.0;
    out[0] = (float)(closs + 0.01*sh[0]);
  }
}

// ---------------- host ----------------

extern "C" void kernel_launch(void* const* d_in, const int* in_sizes, int n_in,
                              void* d_out, int out_size, void* d_ws, size_t ws_size,
                              hipStream_t stream)
{
  const float* content = (const float*)d_in[0];
  const float* style   = (const float*)d_in[1];
  const float* Wm[8]; const float* Bm[8];
  for (int i=0;i<8;i++){ Wm[i] = (const float*)d_in[2+2*i]; Bm[i] = (const float*)d_in[3+2*i]; }
  float* out = (float*)d_out;
  float* ws = (float*)d_ws;

  float* f4c  = ws + OFF_F4C;
  float* f4s  = ws + OFF_F4S;
  float* tf   = ws + OFF_TF;
  float* dec  = ws + OFF_DEC;
  float* sm   = ws + OFF_SMALL;
  float* AR   = ws + OFF_ARENA;
  int*   aPtr = (int*)(sm + SM_ASSIGN);
  float* mu   = sm + SM_MU;
  float* counts = sm + SM_COUNTS;
  float* sval = sm + SM_SVAL;
  float* scl  = sm + SM_SCALE;
  float* tvec = sm + SM_TVEC;
  float* trbuf = sm + SM_TR;
  double* spart = (double*)(sm + SM_SPART);

  u16* WB = (u16*)(ws + OFF_WSPL);
  u16 *w2h=WB+0,       *w2l=WB+73728;
  u16 *w3h=WB+147456,  *w3l=WB+442368;
  u16 *w4h=WB+737280,  *w4l=WB+1916928;
  u16 *v1h=WB+3096576, *v1l=WB+4276224;
  u16 *v2h=WB+5455872, *v2l=WB+5750784;
  u16 *v3h=WB+6045696, *v3l=WB+6119424;

  float* Ycov = AR;
  u16* Mh  = (u16*)(AR);
  u16* Ml  = (u16*)(AR + 3145728ul);
  u16* Yh  = (u16*)(AR + 6291456ul);
  u16* Yl  = (u16*)(AR + 9437184ul);
  u16* Zh  = (u16*)(AR + 12582912ul);
  u16* Zl  = (u16*)(AR + 15728640ul);
  u16* Y2h = (u16*)(AR + 18874368ul);
  u16* Y2l = (u16*)(AR + 22020096ul);
  u16* Z2h = (u16*)(AR + 25165824ul);
  u16* Z2l = (u16*)(AR + 28311552ul);
  u16* Ph  = (u16*)(AR + 18874368ul);
  u16* Pl  = (u16*)(AR + 25165824ul);
  float* ptsT = AR + 25165824ul;
  u16* Th  = (u16*)(AR + 18874368ul);
  u16* Tl  = (u16*)(AR + 20971520ul);
  u16* fsh = (u16*)(AR + 23068672ul);
  u16* fsl = (u16*)(AR + 24117248ul);
  float* KACC = AR + 0;

  // NHWC split-bf16 activation planes (u16), placed in lifetime-dead arena slots.
  // encode (B=8):
  u16* xP1h  = (u16*)(AR + 16777216ul);   // 8*128*128*64 u16 -> 4.19M floats
  u16* xP1l  = (u16*)(AR + 20971520ul);
  u16* xF2ph = (u16*)(AR + 16777216ul);   // pooled F2: 8*64*64*128
  u16* xF2pl = (u16*)(AR + 18874368ul);
  u16* xF3ph = (u16*)(AR + 18874368ul);   // pooled F3: 8*32*32*256 (clear of PART8)
  u16* xF3pl = (u16*)(AR + 19922944ul);
  // decode (B=4):
  u16* xTFh  = (u16*)(AR + 8388608ul);    // 4*32*32*512
  u16* xTFl  = (u16*)(AR + 9437184ul);
  u16* xX1h  = (u16*)(AR + 1048576ul);    // 4*32*32*256
  u16* xX1l  = (u16*)(AR + 1572864ul);
  u16* xX2h  = (u16*)(AR + 11534336ul);   // 4*64*64*128
  u16* xX2l  = (u16*)(AR + 12582912ul);
  // decoded encode (B=4):
  u16* xP1dh = (u16*)(AR + 16777216ul);   // 4*128*128*64
  u16* xP1dl = (u16*)(AR + 18874368ul);
  u16* xF2dph= (u16*)(AR + 16777216ul);   // pooled F2d: 4*64*64*128
  u16* xF2dpl= (u16*)(AR + 17825792ul);
  u16* xF3dph= (u16*)(AR + 16777216ul);   // pooled F3d: 4*32*32*256
  u16* xF3dpl= (u16*)(AR + 17301504ul);

  zerok<<<512,256,0,stream>>>(sm, 131072);

  {
    auto wsp = [&](int li, u16* wh, u16* wl, int Co, int Ci){
      int n = 9*Co*Ci;
      wsplitk<<<(n+255)/256,256,0,stream>>>(Wm[li], wh, wl, Co, Ci);
    };
    wsp(1,w2h,w2l,128,64);
    wsp(2,w3h,w3l,256,128);
    wsp(3,w4h,w4l,512,256);
    wsp(4,v1h,v1l,256,512);
    wsp(5,v2h,v2l,128,256);
    wsp(6,v3h,v3l,64,128);
  }

  // MFMA conv on pre-split NHWC u16 input; 1-D XCD-swizzled grid.
  auto convMFMA = [&](const u16* xh, const u16* xl, int li, float* outp,
                      int B,int Ci,int Co,int H,int Wd,int relu,int KS,int RZ,float* part){
    const u16 *wh=nullptr,*wl=nullptr;
    switch(li){
      case 1: wh=w2h; wl=w2l; break;
      case 2: wh=w3h; wl=w3l; break;
      case 3: wh=w4h; wl=w4l; break;
      case 4: wh=v1h; wl=v1l; break;
      case 5: wh=v2h; wl=v2l; break;
      case 6: wh=v3h; wl=v3l; break;
    }
    int T = (H>>3)*(Wd>>4);
    int G = Co>>6;
    int total = T*G*B*KS;
    if (KS==1){
      if (RZ==0) convm<1,0><<<total,256,0,stream>>>(xh,xl,wh,wl,Bm[li],outp,Ci,Co,H,Wd,relu,T,G,B);
      else       convm<1,2><<<total,256,0,stream>>>(xh,xl,wh,wl,Bm[li],outp,Ci,Co,H,Wd,relu,T,G,B);
    } else if (KS==2){
      if (RZ==0) convm<2,0><<<total,256,0,stream>>>(xh,xl,wh,wl,nullptr,part,Ci,Co,H,Wd,relu,T,G,B);
      else       convm<2,2><<<total,256,0,stream>>>(xh,xl,wh,wl,nullptr,part,Ci,Co,H,Wd,relu,T,G,B);
      int n = B*Co*H*Wd;
      sumk<<<(n+255)/256,256,0,stream>>>(part,Bm[li],outp,Co,H*Wd,2,relu,n);
    } else {
      convm<4,0><<<total,256,0,stream>>>(xh,xl,wh,wl,nullptr,part,Ci,Co,H,Wd,relu,T,G,B);
      int n = B*Co*H*Wd;
      sumk<<<(n+255)/256,256,0,stream>>>(part,Bm[li],outp,Co,H*Wd,4,relu,n);
    }
  };

  // chunked stats: big HW -> 2-phase
  auto stats = [&](const float* x, int nbc, int HW, float* mo, float* so){
    if (HW >= 16384){
      int CH = (HW >= 65536) ? 8 : 4;
      statspk<<<dim3(nbc,CH),256,0,stream>>>(x, HW, spart);
      statsfk<<<(nbc+255)/256,256,0,stream>>>(spart, CH, HW, nbc, mo, so);
    } else {
      statsk<<<nbc,256,0,stream>>>(x, HW, mo, so);
    }
  };

  float* mS = sm + SM_STATS_S;
  float* sS = sm + SM_STATS_S + 3840;

  // ---- batched content+style encode (B=8 from e2 down) ----
  float* F1   = AR + 0;
  float* F2_8 = AR + 0;
  float* F3_8 = AR + 0;
  float* PART8 = AR + 10485760ul;

  {
    dim3 ge(64, 8, 4);  // (256/32)^2 tiles, 64/8 co-groups, B=4
    // content e1: fp32 output is dead (style overwrites F1 before any reader) -> OUTW=0
    conv3x3<8,4,1,0,0><<<ge,256,0,stream>>>(content,Wm[0],Bm[0],F1,xP1h,           xP1l,           4,3,64,256,256,1);
    conv3x3<8,4,1,1,0><<<ge,256,0,stream>>>(style,  Wm[0],Bm[0],F1,xP1h+4194304ul, xP1l+4194304ul, 4,3,64,256,256,1);
  }
  stats(F1, 256, 65536, mS+0, sS+0);

  convMFMA(xP1h,xP1l, 1, F2_8, 8, 64,128,128,128,1,1,0,nullptr);
  stats(F2_8 + 8388608ul, 512, 16384, mS+256, sS+256);
  repackk<1><<<dim3(128,2,8),256,0,stream>>>(F2_8, xF2ph, xF2pl, 128,64,64);
  convMFMA(xF2ph,xF2pl, 2, F3_8, 8, 128,256,64,64,1,1,0,nullptr);
  statsk<<<1024,256,0,stream>>>(F3_8 + 4194304ul, 4096, mS+768, sS+768);
  repackk<1><<<dim3(32,4,8),256,0,stream>>>(F3_8, xF3ph, xF3pl, 256,32,32);
  convMFMA(xF3ph,xF3pl, 3, f4c, 8, 256,512,32,32,1,2,0,PART8);
  statsk<<<2048,256,0,stream>>>(f4s,1024, mS+1792, sS+1792);

  // ---- fused k-means ----
  transposek<<<dim3(32,16,8),256,0,stream>>>(f4c,f4s,ptsT);
  zerok<<<(12*KSLOT+255)/256,256,0,stream>>>(KACC, 12*KSLOT);
  initcent2k<<<48,256,0,stream>>>(ptsT,KACC);
  for (int it=0; it<=10; ++it){
    kstepk<<<dim3(8,32),256,0,stream>>>(ptsT, KACC + (size_t)it*KSLOT, KACC + (size_t)(it+1)*KSLOT, aPtr, it==0 ? 1 : 0);
  }
  mufink<<<48,256,0,stream>>>(KACC + 11ul*KSLOT, mu, counts);

  // ---- covariances via MFMA (XCD-swizzled 1-D grid) ----
  maskcenterk<<<12288,256,0,stream>>>(f4c,f4s,aPtr,mu,Ph,Pl);
  covgemm<<<384,256,0,stream>>>(Ph,Pl,counts,Ycov,sval);
  nsinitk<<<24576,256,0,stream>>>(Ycov,sval,Yh,Yl,Zh,Zl);

  // ---- split-bf16 MFMA Newton-Schulz ----
  u16 *Ych=Yh,*Ycl=Yl,*Zch=Zh,*Zcl=Zl,*Yah=Y2h,*Yal=Y2l,*Zah=Z2h,*Zal=Z2l;
  for (int it=0; it<NS_ITERS; ++it){
    if (it == 0){
      // Z == I: M = resplit(Y) elementwise (bit-identical to MFMA with identity operand)
      nsm0k<<<6144,256,0,stream>>>(Ych,Ycl,Mh,Ml);
      nstr0k<<<24,256,0,stream>>>(Ych,Ycl,trbuf);
      // Y-update via GEMM (z<24 of last=0 path); Z-update elementwise
      bmmpair<<<384,256,0,stream>>>(Ych,Ycl,Mh,Ml,Zch,Zcl,Yah,Yal,Zah,Zal,trbuf,0);
      nsz0k<<<6144,256,0,stream>>>(Mh,Ml,Zah,Zal,trbuf);
    } else {
      bmms<0,1><<<384,256,0,stream>>>(Zch,Zcl,Ych,Ycl,Mh,Ml,nullptr,0,trbuf+it*24);
      if (it < NS_ITERS-1)
        bmmpair<<<768,256,0,stream>>>(Ych,Ycl,Mh,Ml,Zch,Zcl,Yah,Yal,Zah,Zal,trbuf+it*24,0);
      else
        bmmpair<<<384,256,0,stream>>>(Ych,Ycl,Mh,Ml,Zch,Zcl,Yah,Yal,Zah,Zal,trbuf+it*24,1);
    }
    u16* t;
    t=Ych;Ych=Yah;Yah=t; t=Ycl;Ycl=Yal;Yal=t;
    t=Zch;Zch=Zah;Zah=t; t=Zcl;Zcl=Zal;Zal=t;
  }
  make_scalesk<<<1,64,0,stream>>>(sval,scl);
  bmms<2,0><<<dim3(4,4,12),256,0,stream>>>(Ych,Ycl,Zch,Zcl,Th,Tl,scl,12,nullptr);
  tveck<<<12,512,0,stream>>>(Th,Tl,mu,tvec);
  // f4c [img][c][n] -> fsT [img][n][c] split-bf16 (transposing repack; N=1024=32x32)
  repackk<0><<<dim3(32,8,4),256,0,stream>>>(f4c, fsh, fsl, 512,32,32);
  float* Mb = AR + 0;
  bmmt<<<dim3(16,4,12),256,0,stream>>>(Th,Tl,fsh,fsl,Mb);
  selectk<<<8192,256,0,stream>>>(Mb,tvec,aPtr,f4c,tf);

  // ---- decode (B=4; up fused into d2/d3 via RZ=2; d4 via dedicated d4upk) ----
  float* X1 = AR + 0;
  float* X2 = AR + 5242880ul;
  float* X3 = AR + 0;
  float* PARTA = AR + 2097152ul;
  float* PARTB = AR + 7340032ul;
  repackk<0><<<dim3(32,8,4),256,0,stream>>>(tf, xTFh, xTFl, 512,32,32);
  convMFMA(xTFh,xTFl, 4, X1, 4, 512,256,32,32,1,4,0,PARTA);
  repackk<0><<<dim3(32,4,4),256,0,stream>>>(X1, xX1h, xX1l, 256,32,32);
  convMFMA(xX1h,xX1l, 5, X2, 4, 256,128,64,64,1,2,2,PARTB);
  repackk<0><<<dim3(128,2,4),256,0,stream>>>(X2, xX2h, xX2l, 128,64,64);
  convMFMA(xX2h,xX2l, 6, X3, 4, 128,64,128,128,1,1,2,nullptr);
  d4upk<<<dim3(256,1,4),256,0,stream>>>(X3, Wm[7], Bm[7], dec);

  // ---- decoded encode + stats + content loss (B=4) ----
  float* mD = sm + SM_STATS_D;
  float* sD = sm + SM_STATS_D + 3840;
  float* F1d = AR + 0;
  float* F2d = AR + 0;
  float* F3d = AR + 10485760ul;
  {
    dim3 ge(64, 8, 4);
    conv3x3<8,4,1,1,0><<<ge,256,0,stream>>>(dec,Wm[0],Bm[0],F1d,xP1dh,xP1dl,4,3,64,256,256,1);
  }
  stats(F1d, 256, 65536, mD+0, sD+0);
  convMFMA(xP1dh,xP1dl, 1, F2d, 4, 64,128,128,128,1,1,0,nullptr);
  stats(F2d, 512, 16384, mD+256, sD+256);
  repackk<1><<<dim3(128,2,4),256,0,stream>>>(F2d, xF2dph, xF2dpl, 128,64,64);
  convMFMA(xF2dph,xF2dpl, 2, F3d, 4, 128,256,64,64,1,1,0,nullptr);
  statsk<<<1024,256,0,stream>>>(F3d,4096, mD+768, sD+768);
  repackk<1><<<dim3(32,4,4),256,0,stream>>>(F3d, xF3dph, xF3dpl, 256,32,32);
  convMFMA(xF3dph,xF3dpl, 3, tf, 4, 256,512,32,32,1,2,0,PARTA);
  statsk<<<2048,256,0,stream>>>(tf,1024, mD+1792, sD+1792);
  clossk<<<2048,256,0,stream>>>(tf,f4c,2097152, sm+SM_CLOSS);
  finalk<<<1,256,0,stream>>>(sm,out);
}